// Round 2
// baseline (3795.663 us; speedup 1.0000x reference)
//
#include <hip/hip_runtime.h>
#include <math.h>

// ---------------- problem constants ----------------
constexpr int C_  = 16;
constexpr int N_  = 10000;
constexpr int NC_ = 2000;
constexpr int E_  = 50000;
constexpr int D_  = 256;
constexpr int SZ_ = N_ * D_;          // per-config slab (floats)
constexpr float EPS_ = 1e-5f;

__device__ __forceinline__ float gelu_f(float x) {
    return 0.5f * x * (1.0f + erff(x * 0.70710678118654752f));
}

// ---------------- tiny prep kernels ----------------

// T[s][i][d] = sum_k emb_layout[i,k] * lin1_W[134+4s+k, d]   (18*8*256)
__global__ __launch_bounds__(256) void tbl_k(const float* __restrict__ embL,
                                             const float* __restrict__ W,
                                             float* __restrict__ T) {
    int b = blockIdx.x;            // 0..143
    int s = b >> 3, i = b & 7, d = threadIdx.x;
    float acc = 0.f;
#pragma unroll
    for (int k = 0; k < 4; ++k)
        acc = fmaf(embL[i * 4 + k], W[(134 + s * 4 + k) * 256 + d], acc);
    T[(s * 8 + i) * 256 + d] = acc;
}

// feat162 padded to 176 cols: [x_feat(134) | layout_emb(24) | op_emb(4) | 0(14)]
__global__ __launch_bounds__(192) void feat_k(const float* __restrict__ xf,
                                              const int* __restrict__ xlay,
                                              const int* __restrict__ xop,
                                              const float* __restrict__ embL,
                                              const float* __restrict__ embO,
                                              float* __restrict__ f) {
    int n = blockIdx.x, j = threadIdx.x;
    if (j >= 176) return;
    float v;
    if (j < 134) v = xf[n * 134 + j];
    else if (j < 158) { int q = j - 134; int t = q >> 2, k = q & 3; v = embL[(xlay[n * 6 + t] + 2) * 4 + k]; }
    else if (j < 162) { int k = j - 158; v = embO[xop[n] * 4 + k]; }
    else v = 0.f;
    f[n * 176 + j] = v;
}

// pack lin1_W rows {0..133, 206..229, 230..233} into 176x256 (pad zeros)
__global__ __launch_bounds__(256) void wpack_k(const float* __restrict__ W,
                                               float* __restrict__ Wp) {
    int j = blockIdx.x, d = threadIdx.x;
    float v = 0.f;
    if (j < 134) v = W[j * 256 + d];
    else if (j < 158) v = W[(206 + j - 134) * 256 + d];
    else if (j < 162) v = W[(230 + j - 158) * 256 + d];
    Wp[j * 256 + d] = v;
}

__global__ __launch_bounds__(256) void cfgpos_k(const int* __restrict__ ncid,
                                                int* __restrict__ cfgpos) {
    int i = blockIdx.x * 256 + threadIdx.x;
    if (i < NC_) cfgpos[ncid[i]] = i;
}

__global__ __launch_bounds__(256) void hist_k(const int* __restrict__ ei, int* __restrict__ cnt) {
    int e = blockIdx.x * 256 + threadIdx.x;
    if (e < E_) atomicAdd(&cnt[ei[E_ + e]], 1);
}

// single-block scan over 10000 counts -> offsets, cursor copy, inv_cnt
__global__ __launch_bounds__(1024) void scan_k(const int* __restrict__ cnt,
                                               int* __restrict__ off,
                                               int* __restrict__ cursor,
                                               float* __restrict__ invcnt) {
    __shared__ int s[1024];
    int t = threadIdx.x;
    int base = t * 10;
    int local[10];
    int part = 0;
#pragma unroll
    for (int k = 0; k < 10; ++k) {
        int idx = base + k;
        int v = (idx < N_) ? cnt[idx] : 0;
        local[k] = v; part += v;
    }
    s[t] = part;
    __syncthreads();
    for (int o = 1; o < 1024; o <<= 1) {
        int val = (t >= o) ? s[t - o] : 0;
        __syncthreads();
        s[t] += val;
        __syncthreads();
    }
    int pre = s[t] - part;
#pragma unroll
    for (int k = 0; k < 10; ++k) {
        int idx = base + k;
        if (idx < N_) {
            off[idx] = pre;
            cursor[idx] = pre;
            invcnt[idx] = 1.0f / (float)(local[k] > 1 ? local[k] : 1);
            pre += local[k];
        }
    }
    if (t == 1023) off[N_] = s[1023];
}

__global__ __launch_bounds__(256) void fill_k(const int* __restrict__ ei,
                                              int* __restrict__ cursor,
                                              int* __restrict__ csr) {
    int e = blockIdx.x * 256 + threadIdx.x;
    if (e < E_) {
        int t = ei[E_ + e];
        int p = atomicAdd(&cursor[t], 1);
        csr[p] = ei[e];
    }
}

// ---------------- lin1: h = base + table-sum, with stats ----------------
// xcfg is pre-offset to this chunk's first config; ssum/ssq pre-offset too.
__global__ __launch_bounds__(256) void lin1_k(const float* __restrict__ base,
                                              const float* __restrict__ T,
                                              const int* __restrict__ cfgpos,
                                              const int* __restrict__ xcfg,
                                              float* __restrict__ H,
                                              float* __restrict__ ssum,
                                              float* __restrict__ ssq) {
    const int c = blockIdx.z, n0 = blockIdx.x * 16, d = threadIdx.x;
    float psum = 0.f, psq = 0.f;
    for (int g = 0; g < 16; ++g) {
        int n = n0 + g;
        float acc = base[n * 256 + d];
        int j = cfgpos[n];
        if (j >= 0) {
            const int* ip = &xcfg[((size_t)c * NC_ + j) * 18];
#pragma unroll
            for (int s = 0; s < 18; ++s)
                acc += T[(s * 8 + ip[s] + 2) * 256 + d];
        } else {
#pragma unroll
            for (int s = 0; s < 18; ++s)
                acc += T[(s * 8) * 256 + d];
        }
        H[((size_t)c * N_ + n) * 256 + d] = acc;
        psum += acc; psq += acc * acc;
    }
    atomicAdd(&ssum[c * 256 + d], psum);
    atomicAdd(&ssq[c * 256 + d], psq);
}

// ---------------- finalize stats (grid = nc blocks; ptrs pre-offset) ----------------
__global__ __launch_bounds__(256) void finstat_k(const float* __restrict__ ssum,
                                                 const float* __restrict__ ssq,
                                                 float* __restrict__ mu,
                                                 float* __restrict__ rs) {
    int i = blockIdx.x * 256 + threadIdx.x;
    float m = ssum[i] * (1.0f / (float)N_);
    float v = ssq[i] * (1.0f / (float)N_) - m * m;
    mu[i] = m;
    rs[i] = rsqrtf(v + EPS_);
}

// ---------------- CSR gather-mean with on-the-fly norm ----------------
__global__ __launch_bounds__(256) void agg_k(const float* __restrict__ H,
                                             const int* __restrict__ off,
                                             const int* __restrict__ csr,
                                             const float* __restrict__ invcnt,
                                             const float* __restrict__ mu,
                                             const float* __restrict__ rs,
                                             float* __restrict__ Agg) {
    int wave = threadIdx.x >> 6, lane = threadIdx.x & 63;
    int pair = blockIdx.x * 4 + wave;
    int c = pair / N_, t = pair - c * N_;
    int d4 = lane * 4;
    int o0 = off[t], o1 = off[t + 1];
    float ax = 0.f, ay = 0.f, az = 0.f, aw = 0.f;
    for (int i = o0; i < o1; ++i) {
        int s = csr[i];
        const float4 hv = *(const float4*)&H[((size_t)c * N_ + s) * 256 + d4];
        ax += hv.x; ay += hv.y; az += hv.z; aw += hv.w;
    }
    float4 o;
    if (o1 > o0) {
        float inv = invcnt[t];
        const float4 m = *(const float4*)&mu[c * 256 + d4];
        const float4 r = *(const float4*)&rs[c * 256 + d4];
        o.x = (ax * inv - m.x) * r.x;
        o.y = (ay * inv - m.y) * r.y;
        o.z = (az * inv - m.z) * r.z;
        o.w = (aw * inv - m.w) * r.w;
    } else {
        o = make_float4(0.f, 0.f, 0.f, 0.f);
    }
    *(float4*)&Agg[((size_t)c * N_ + t) * 256 + d4] = o;
}

// ---------------- fp32 tiled GEMM: Y = A1@W1 [+ A2n@W2] + bias ----------------
template <int NORM2, int STATS>
__global__ __launch_bounds__(256) void gemm_k(const float* __restrict__ A1, int lda1, int sA1z,
                                              const float* __restrict__ W1, int K1,
                                              const float* __restrict__ A2, int sA2z,
                                              const float* __restrict__ W2, int K2,
                                              const float* __restrict__ bias,
                                              const float* __restrict__ mu2,
                                              const float* __restrict__ rs2,
                                              float* __restrict__ Y, int sYz, int Mrows,
                                              float* __restrict__ ssum,
                                              float* __restrict__ ssq) {
    __shared__ float As[16][132];
    __shared__ float Bs[16][132];
    float acc[8][8];
#pragma unroll
    for (int i = 0; i < 8; ++i)
#pragma unroll
        for (int j = 0; j < 8; ++j) acc[i][j] = 0.f;

    const int tid = threadIdx.x;
    const int tr = tid >> 4, tc = tid & 15;
    const int c = blockIdx.z;
    const int rowbase = blockIdx.y * 128, colbase = blockIdx.x * 128;

    const float* Ap = A1 + (size_t)c * sA1z;
    const float* Wp = W1;
    int K = K1, lda = lda1, useNorm = 0;

    for (int pair = 0; pair < 2; ++pair) {
        if (pair == 1) {
            if (K2 == 0) break;
            Ap = A2 + (size_t)c * sA2z; Wp = W2; K = K2; lda = 256; useNorm = NORM2;
        }
        for (int k0 = 0; k0 < K; k0 += 16) {
#pragma unroll
            for (int ii = 0; ii < 2; ++ii) {
                int i = tid + ii * 256;
                int rr = i >> 2, qq = i & 3;
                int grow = rowbase + rr;
                float4 vv = make_float4(0.f, 0.f, 0.f, 0.f);
                if (grow < Mrows) vv = *(const float4*)&Ap[(size_t)grow * lda + k0 + qq * 4];
                if (NORM2 && useNorm) {
                    const float4 m = *(const float4*)&mu2[c * 256 + k0 + qq * 4];
                    const float4 r = *(const float4*)&rs2[c * 256 + k0 + qq * 4];
                    vv.x = (vv.x - m.x) * r.x; vv.y = (vv.y - m.y) * r.y;
                    vv.z = (vv.z - m.z) * r.z; vv.w = (vv.w - m.w) * r.w;
                }
                As[qq * 4 + 0][rr] = vv.x;
                As[qq * 4 + 1][rr] = vv.y;
                As[qq * 4 + 2][rr] = vv.z;
                As[qq * 4 + 3][rr] = vv.w;
            }
#pragma unroll
            for (int ii = 0; ii < 2; ++ii) {
                int i = tid + ii * 256;
                int rr = i >> 5, qq = i & 31;
                float4 vv = *(const float4*)&Wp[(size_t)(k0 + rr) * 256 + colbase + qq * 4];
                *(float4*)&Bs[rr][qq * 4] = vv;
            }
            __syncthreads();
#pragma unroll
            for (int kk = 0; kk < 16; ++kk) {
                float a[8], b[8];
                *(float4*)&a[0] = *(const float4*)&As[kk][tr * 4];
                *(float4*)&a[4] = *(const float4*)&As[kk][64 + tr * 4];
                *(float4*)&b[0] = *(const float4*)&Bs[kk][tc * 4];
                *(float4*)&b[4] = *(const float4*)&Bs[kk][64 + tc * 4];
#pragma unroll
                for (int i = 0; i < 8; ++i)
#pragma unroll
                    for (int j = 0; j < 8; ++j)
                        acc[i][j] = fmaf(a[i], b[j], acc[i][j]);
            }
            __syncthreads();
        }
    }

    float4 blo = *(const float4*)&bias[colbase + tc * 4];
    float4 bhi = *(const float4*)&bias[colbase + 64 + tc * 4];
    float bb[8] = {blo.x, blo.y, blo.z, blo.w, bhi.x, bhi.y, bhi.z, bhi.w};
#pragma unroll
    for (int i = 0; i < 8; ++i)
#pragma unroll
        for (int j = 0; j < 8; ++j) acc[i][j] += bb[j];

    float* Yp = Y + (size_t)c * sYz;
#pragma unroll
    for (int i = 0; i < 8; ++i) {
        int lrow = (i < 4) ? (tr * 4 + i) : (64 + tr * 4 + (i - 4));
        int grow = rowbase + lrow;
        if (grow < Mrows) {
            *(float4*)&Yp[(size_t)grow * 256 + colbase + tc * 4] =
                make_float4(acc[i][0], acc[i][1], acc[i][2], acc[i][3]);
            *(float4*)&Yp[(size_t)grow * 256 + colbase + 64 + tc * 4] =
                make_float4(acc[i][4], acc[i][5], acc[i][6], acc[i][7]);
        }
    }

    if (STATS) {
        float* red = &As[0][0];
        __syncthreads();
        {
            float p[8] = {0, 0, 0, 0, 0, 0, 0, 0};
#pragma unroll
            for (int i = 0; i < 8; ++i) {
                int lrow = (i < 4) ? (tr * 4 + i) : (64 + tr * 4 + (i - 4));
                if (rowbase + lrow < Mrows) {
#pragma unroll
                    for (int j = 0; j < 8; ++j) p[j] += acc[i][j];
                }
            }
#pragma unroll
            for (int j = 0; j < 8; ++j) {
                int lcol = (j < 4) ? (tc * 4 + j) : (64 + tc * 4 + (j - 4));
                red[tr * 128 + lcol] = p[j];
            }
        }
        __syncthreads();
        if (tid < 128) {
            float s = 0.f;
#pragma unroll
            for (int t2 = 0; t2 < 16; ++t2) s += red[t2 * 128 + tid];
            atomicAdd(&ssum[c * 256 + colbase + tid], s);
        }
        __syncthreads();
        {
            float p[8] = {0, 0, 0, 0, 0, 0, 0, 0};
#pragma unroll
            for (int i = 0; i < 8; ++i) {
                int lrow = (i < 4) ? (tr * 4 + i) : (64 + tr * 4 + (i - 4));
                if (rowbase + lrow < Mrows) {
#pragma unroll
                    for (int j = 0; j < 8; ++j) p[j] += acc[i][j] * acc[i][j];
                }
            }
#pragma unroll
            for (int j = 0; j < 8; ++j) {
                int lcol = (j < 4) ? (tc * 4 + j) : (64 + tc * 4 + (j - 4));
                red[tr * 128 + lcol] = p[j];
            }
        }
        __syncthreads();
        if (tid < 128) {
            float s = 0.f;
#pragma unroll
            for (int t2 = 0; t2 < 16; ++t2) s += red[t2 * 128 + tid];
            atomicAdd(&ssq[c * 256 + colbase + tid], s);
        }
    }
}

// ---------------- per-row: [norm] -> channel-attn -> [residual] -> gelu ----------------
// SMODE: 0 none, 1 sum+sumsq, 2 sum only (pooling)
template <int NORM, int RES, int SMODE>
__global__ __launch_bounds__(256) void apply_k(const float* __restrict__ Yin,
                                               float* __restrict__ Hout,
                                               const float* __restrict__ Hsc,
                                               const float* __restrict__ W1,
                                               const float* __restrict__ b1,
                                               const float* __restrict__ W2,
                                               const float* __restrict__ b2,
                                               const float* __restrict__ mu,
                                               const float* __restrict__ rs,
                                               float* __restrict__ ssum,
                                               float* __restrict__ ssq) {
    __shared__ float v[16][256];
    __shared__ float tt[16][32];
    const int c = blockIdx.z, n0 = blockIdx.x * 16, tid = threadIdx.x;
    const int d = tid;
    const size_t rowbase = ((size_t)c * N_ + n0) * 256;

    float muv = 0.f, rsv = 1.f;
    if (NORM) { muv = mu[c * 256 + d]; rsv = rs[c * 256 + d]; }
#pragma unroll 4
    for (int g = 0; g < 16; ++g) {
        float x = Yin[rowbase + g * 256 + d];
        v[g][d] = NORM ? (x - muv) * rsv : x;
    }
    __syncthreads();
    {
        const int r = tid & 31, g2 = tid >> 5;
#pragma unroll
        for (int hh = 0; hh < 2; ++hh) {
            const int g = g2 * 2 + hh;
            float acc = b1[r];
#pragma unroll 4
            for (int dd = 0; dd < 256; dd += 4) {
                float4 vv = *(const float4*)&v[g][dd];
                acc = fmaf(vv.x, W1[(dd + 0) * 32 + r], acc);
                acc = fmaf(vv.y, W1[(dd + 1) * 32 + r], acc);
                acc = fmaf(vv.z, W1[(dd + 2) * 32 + r], acc);
                acc = fmaf(vv.w, W1[(dd + 3) * 32 + r], acc);
            }
            tt[g][r] = fmaxf(acc, 0.f);
        }
    }
    __syncthreads();
    float psum = 0.f, psq = 0.f;
    const float b2v = b2[d];
#pragma unroll 2
    for (int g = 0; g < 16; ++g) {
        float s = b2v;
#pragma unroll
        for (int rr = 0; rr < 32; ++rr)
            s = fmaf(tt[g][rr], W2[rr * 256 + d], s);
        float sig = 1.0f / (1.0f + expf(-s));
        float val = sig * v[g][d];
        if (RES) val += Hsc[rowbase + g * 256 + d];
        val = gelu_f(val);
        Hout[rowbase + g * 256 + d] = val;
        if (SMODE == 1) { psum += val; psq += val * val; }
        if (SMODE == 2) { psum += val; }
    }
    if (SMODE == 1) {
        atomicAdd(&ssum[c * 256 + d], psum);
        atomicAdd(&ssq[c * 256 + d], psq);
    }
    if (SMODE == 2) {
        atomicAdd(&ssum[c * 256 + d], psum);
    }
}

// ---------------- classifier ----------------
__global__ __launch_bounds__(256) void cls_k(const float* __restrict__ pooled_sum,
                                             const float* __restrict__ clsW,
                                             const float* __restrict__ clsb,
                                             float* __restrict__ out) {
    __shared__ float red[256];
    int c = blockIdx.x, d = threadIdx.x;
    red[d] = pooled_sum[c * 256 + d] * (1.0f / (float)N_) * clsW[d];
    __syncthreads();
    for (int s = 128; s > 0; s >>= 1) {
        if (d < s) red[d] += red[d + s];
        __syncthreads();
    }
    if (d == 0) out[c] = red[0] + clsb[0];
}

// ---------------- host launch ----------------
static inline size_t alup(size_t x) { return (x + 255) & ~(size_t)255; }

extern "C" void kernel_launch(void* const* d_in, const int* in_sizes, int n_in,
                              void* d_out, int out_size, void* d_ws, size_t ws_size,
                              hipStream_t stream) {
    const int*   xcfg   = (const int*)d_in[0];
    const float* xfeat  = (const float*)d_in[1];
    const int*   xlay   = (const int*)d_in[2];
    const int*   xop    = (const int*)d_in[3];
    const int*   ei     = (const int*)d_in[4];
    const int*   ncid   = (const int*)d_in[5];
    const float* embO   = (const float*)d_in[6];
    const float* embL   = (const float*)d_in[7];
    const float* lin1W  = (const float*)d_in[8];
    const float* lin1b  = (const float*)d_in[9];
    const float* ca1W1  = (const float*)d_in[10];
    const float* ca1b1  = (const float*)d_in[11];
    const float* ca1W2  = (const float*)d_in[12];
    const float* ca1b2  = (const float*)d_in[13];
    const float* lin2W  = (const float*)d_in[14];
    const float* lin2b  = (const float*)d_in[15];
    const float* ca2W1  = (const float*)d_in[16];
    const float* ca2b1  = (const float*)d_in[17];
    const float* ca2W2  = (const float*)d_in[18];
    const float* ca2b2  = (const float*)d_in[19];
    const float* sageWl = (const float*)d_in[20];
    const float* sagebl = (const float*)d_in[21];
    const float* sageWr = (const float*)d_in[22];
    const float* scaW1  = (const float*)d_in[23];
    const float* scab1  = (const float*)d_in[24];
    const float* scaW2  = (const float*)d_in[25];
    const float* scab2  = (const float*)d_in[26];
    const float* clsW   = (const float*)d_in[27];
    const float* clsb   = (const float*)d_in[28];
    float* out = (float*)d_out;

    // ---- workspace carve-up: fixed buffers first, then config-chunk slabs ----
    char* w = (char*)d_ws;
    size_t o = 0;
    auto take = [&](size_t bytes) { char* p = w + o; o = alup(o + bytes); return p; };
    float* base    = (float*)take((size_t)N_ * 256 * 4);
    float* feat162 = (float*)take((size_t)N_ * 176 * 4);
    float* W162    = (float*)take((size_t)176 * 256 * 4);
    float* T       = (float*)take((size_t)18 * 8 * 256 * 4);
    float* stats   = (float*)take((size_t)6 * 8192 * 4);    // per set: [sum(4096) | sq(4096)]
    float* MU      = (float*)take((size_t)5 * 4096 * 4);
    float* RS      = (float*)take((size_t)5 * 4096 * 4);
    float* invcnt  = (float*)take((size_t)N_ * 4);
    int*   cnt     = (int*)take((size_t)N_ * 4);
    int*   off     = (int*)take((size_t)(N_ + 1) * 4);
    int*   cursor  = (int*)take((size_t)N_ * 4);
    int*   csr     = (int*)take((size_t)E_ * 4);
    int*   cfgpos  = (int*)take((size_t)N_ * 4);

    const size_t slab = (size_t)SZ_ * 4;                    // 10.24 MB
    size_t avail = (ws_size > o) ? (ws_size - o) : 0;
    int Cc = (int)(avail / (3 * slab + 768));               // chunk size in configs
    if (Cc > 8) Cc = 8;                                     // cap: keeps footprint <300MB
    if (Cc < 1) Cc = 1;                                     // last-ditch (will need ~49MB)
    float* BufH = (float*)take((size_t)Cc * slab);
    float* BufY = (float*)take((size_t)Cc * slab);
    float* BufA = (float*)take((size_t)Cc * slab);
    (void)in_sizes; (void)n_in; (void)out_size;

    auto S = [&](int s) { return stats + (size_t)s * 8192; };
    auto Q = [&](int s) { return stats + (size_t)s * 8192 + 4096; };

    // per-launch init
    hipMemsetAsync(stats, 0, 6 * 8192 * 4, stream);
    hipMemsetAsync(cnt, 0, N_ * 4, stream);
    hipMemsetAsync(cfgpos, 0xFF, N_ * 4, stream);

    // shared prep (config-independent)
    tbl_k<<<144, 256, 0, stream>>>(embL, lin1W, T);
    feat_k<<<N_, 192, 0, stream>>>(xfeat, xlay, xop, embL, embO, feat162);
    wpack_k<<<176, 256, 0, stream>>>(lin1W, W162);
    cfgpos_k<<<(NC_ + 255) / 256, 256, 0, stream>>>(ncid, cfgpos);
    hist_k<<<(E_ + 255) / 256, 256, 0, stream>>>(ei, cnt);
    scan_k<<<1, 1024, 0, stream>>>(cnt, off, cursor, invcnt);
    fill_k<<<(E_ + 255) / 256, 256, 0, stream>>>(ei, cursor, csr);

    // base = feat162 @ W162 + lin1_b   (M=10000, K=176)
    gemm_k<0, 0><<<dim3(2, 79, 1), 256, 0, stream>>>(
        feat162, 176, 0, W162, 176,
        nullptr, 0, nullptr, 0,
        lin1b, nullptr, nullptr,
        base, 0, N_, nullptr, nullptr);

    // ---- per-config-chunk pipeline ----
    for (int c0 = 0; c0 < C_; c0 += Cc) {
        const int nc = (C_ - c0 < Cc) ? (C_ - c0) : Cc;
        const int co = c0 * 256;

        // lin1 + stats set 0
        lin1_k<<<dim3(625, 1, nc), 256, 0, stream>>>(
            base, T, cfgpos, xcfg + (size_t)c0 * NC_ * 18, BufH, S(0) + co, Q(0) + co);
        finstat_k<<<nc, 256, 0, stream>>>(S(0) + co, Q(0) + co, MU + 0 * 4096 + co, RS + 0 * 4096 + co);

        // apply1: norm + ca1 + gelu, in-place
        apply_k<1, 0, 0><<<dim3(625, 1, nc), 256, 0, stream>>>(
            BufH, BufH, nullptr, ca1W1, ca1b1, ca1W2, ca1b2,
            MU + 0 * 4096 + co, RS + 0 * 4096 + co, nullptr, nullptr);

        // lin2 + stats set 1
        gemm_k<0, 1><<<dim3(2, 79, nc), 256, 0, stream>>>(
            BufH, 256, SZ_, lin2W, 256,
            nullptr, 0, nullptr, 0,
            lin2b, nullptr, nullptr,
            BufY, SZ_, N_, S(1) + co, Q(1) + co);
        finstat_k<<<nc, 256, 0, stream>>>(S(1) + co, Q(1) + co, MU + 1 * 4096 + co, RS + 1 * 4096 + co);

        // apply2: norm + ca2 + gelu; stats set 2
        apply_k<1, 0, 1><<<dim3(625, 1, nc), 256, 0, stream>>>(
            BufY, BufY, nullptr, ca2W1, ca2b1, ca2W2, ca2b2,
            MU + 1 * 4096 + co, RS + 1 * 4096 + co, S(2) + co, Q(2) + co);

        // SAGE blocks: h lives in BufY
        for (int i = 0; i < 3; ++i) {
            const int set = 2 + i;
            finstat_k<<<nc, 256, 0, stream>>>(S(set) + co, Q(set) + co,
                                              MU + set * 4096 + co, RS + set * 4096 + co);
            agg_k<<<nc * 2500, 256, 0, stream>>>(BufY, off, csr, invcnt,
                                                 MU + set * 4096 + co, RS + set * 4096 + co, BufA);
            gemm_k<1, 0><<<dim3(2, 79, nc), 256, 0, stream>>>(
                BufA, 256, SZ_, sageWl + (size_t)i * 65536, 256,
                BufY, SZ_, sageWr + (size_t)i * 65536, 256,
                sagebl + i * 256, MU + set * 4096 + co, RS + set * 4096 + co,
                BufH, SZ_, N_, nullptr, nullptr);
            if (i < 2) {
                apply_k<0, 1, 1><<<dim3(625, 1, nc), 256, 0, stream>>>(
                    BufH, BufY, BufY,
                    scaW1 + (size_t)i * 8192, scab1 + i * 32,
                    scaW2 + (size_t)i * 8192, scab2 + i * 256,
                    nullptr, nullptr, S(3 + i) + co, Q(3 + i) + co);
            } else {
                apply_k<0, 1, 2><<<dim3(625, 1, nc), 256, 0, stream>>>(
                    BufH, BufY, BufY,
                    scaW1 + (size_t)i * 8192, scab1 + i * 32,
                    scaW2 + (size_t)i * 8192, scab2 + i * 256,
                    nullptr, nullptr, S(5) + co, nullptr);
            }
        }
    }

    cls_k<<<16, 256, 0, stream>>>(S(5), clsW, clsb, out);
}

// Round 3
// 2199.433 us; speedup vs baseline: 1.7257x; 1.7257x over previous
//
#include <hip/hip_runtime.h>
#include <math.h>

// ---------------- problem constants ----------------
constexpr int C_  = 16;
constexpr int N_  = 10000;
constexpr int NC_ = 2000;
constexpr int E_  = 50000;
constexpr int D_  = 256;
constexpr int SZ_ = N_ * D_;          // per-config slab (elements)
constexpr float EPS_ = 1e-5f;

typedef unsigned short u16;
typedef __attribute__((ext_vector_type(8))) unsigned short us8v;
typedef __attribute__((ext_vector_type(4))) unsigned short us4v;
typedef __attribute__((ext_vector_type(8))) short s16x8;
typedef __attribute__((ext_vector_type(4))) float f32x4;

__device__ __forceinline__ float gelu_f(float x) {
    return 0.5f * x * (1.0f + erff(x * 0.70710678118654752f));
}
__device__ __forceinline__ u16 f2bf(float f) {
    unsigned u = __float_as_uint(f);
    u += 0x7fffu + ((u >> 16) & 1u);
    return (u16)(u >> 16);
}
__device__ __forceinline__ float bf2f(u16 h) {
    return __uint_as_float(((unsigned)h) << 16);
}

// ---------------- tiny prep kernels ----------------

// T[s][i][d] = sum_k emb_layout[i,k] * lin1_W[134+4s+k, d]
__global__ __launch_bounds__(256) void tbl_k(const float* __restrict__ embL,
                                             const float* __restrict__ W,
                                             float* __restrict__ T) {
    int b = blockIdx.x;            // 0..143
    int s = b >> 3, i = b & 7, d = threadIdx.x;
    float acc = 0.f;
#pragma unroll
    for (int k = 0; k < 4; ++k)
        acc = fmaf(embL[i * 4 + k], W[(134 + s * 4 + k) * 256 + d], acc);
    T[(s * 8 + i) * 256 + d] = acc;
}

// feat162 padded to 176 cols
__global__ __launch_bounds__(192) void feat_k(const float* __restrict__ xf,
                                              const int* __restrict__ xlay,
                                              const int* __restrict__ xop,
                                              const float* __restrict__ embL,
                                              const float* __restrict__ embO,
                                              float* __restrict__ f) {
    int n = blockIdx.x, j = threadIdx.x;
    if (j >= 176) return;
    float v;
    if (j < 134) v = xf[n * 134 + j];
    else if (j < 158) { int q = j - 134; int t = q >> 2, k = q & 3; v = embL[(xlay[n * 6 + t] + 2) * 4 + k]; }
    else if (j < 162) { int k = j - 158; v = embO[xop[n] * 4 + k]; }
    else v = 0.f;
    f[n * 176 + j] = v;
}

// pack lin1_W rows {0..133, 206..233} into 176x256
__global__ __launch_bounds__(256) void wpack_k(const float* __restrict__ W,
                                               float* __restrict__ Wp) {
    int j = blockIdx.x, d = threadIdx.x;
    float v = 0.f;
    if (j < 134) v = W[j * 256 + d];
    else if (j < 158) v = W[(206 + j - 134) * 256 + d];
    else if (j < 162) v = W[(230 + j - 158) * 256 + d];
    Wp[j * 256 + d] = v;
}

__global__ __launch_bounds__(256) void cfgpos_k(const int* __restrict__ ncid,
                                                int* __restrict__ cfgpos) {
    int i = blockIdx.x * 256 + threadIdx.x;
    if (i < NC_) cfgpos[ncid[i]] = i;
}

__global__ __launch_bounds__(256) void hist_k(const int* __restrict__ ei, int* __restrict__ cnt) {
    int e = blockIdx.x * 256 + threadIdx.x;
    if (e < E_) atomicAdd(&cnt[ei[E_ + e]], 1);
}

__global__ __launch_bounds__(1024) void scan_k(const int* __restrict__ cnt,
                                               int* __restrict__ off,
                                               int* __restrict__ cursor,
                                               float* __restrict__ invcnt) {
    __shared__ int s[1024];
    int t = threadIdx.x;
    int base = t * 10;
    int local[10];
    int part = 0;
#pragma unroll
    for (int k = 0; k < 10; ++k) {
        int idx = base + k;
        int v = (idx < N_) ? cnt[idx] : 0;
        local[k] = v; part += v;
    }
    s[t] = part;
    __syncthreads();
    for (int o = 1; o < 1024; o <<= 1) {
        int val = (t >= o) ? s[t - o] : 0;
        __syncthreads();
        s[t] += val;
        __syncthreads();
    }
    int pre = s[t] - part;
#pragma unroll
    for (int k = 0; k < 10; ++k) {
        int idx = base + k;
        if (idx < N_) {
            off[idx] = pre;
            cursor[idx] = pre;
            invcnt[idx] = 1.0f / (float)(local[k] > 1 ? local[k] : 1);
            pre += local[k];
        }
    }
    if (t == 1023) off[N_] = s[1023];
}

__global__ __launch_bounds__(256) void fill_k(const int* __restrict__ ei,
                                              int* __restrict__ cursor,
                                              int* __restrict__ csr) {
    int e = blockIdx.x * 256 + threadIdx.x;
    if (e < E_) {
        int t = ei[E_ + e];
        int p = atomicAdd(&cursor[t], 1);
        csr[p] = ei[e];
    }
}

// transpose lin2_W -> Wt2[j][k] bf16
__global__ __launch_bounds__(256) void wt2_k(const float* __restrict__ W,
                                             u16* __restrict__ Wt) {
    int j = blockIdx.x, k = threadIdx.x;
    Wt[j * 256 + k] = f2bf(W[k * 256 + j]);
}

// fold instance-norm into sage weights (per config):
// Wt[c][j][k]       = bf16(rs[c,k] * Wl[k][j])        k<256
// Wt[c][j][256+k]   = bf16(rs[c,k] * Wr[k][j])
// biasF[c][j]       = bl[j] - sum_k mu*rs*(Wl+Wr)[k][j]
__global__ __launch_bounds__(256) void foldw_k(const float* __restrict__ Wl,
                                               const float* __restrict__ Wr,
                                               const float* __restrict__ bl,
                                               const float* __restrict__ mu,
                                               const float* __restrict__ rs,
                                               u16* __restrict__ Wt,
                                               float* __restrict__ biasF) {
    __shared__ float red[256];
    int c = blockIdx.y, j = blockIdx.x, k = threadIdx.x;
    float rsv = rs[c * 256 + k], muv = mu[c * 256 + k];
    float fl = rsv * Wl[k * 256 + j];
    float fr = rsv * Wr[k * 256 + j];
    size_t wb = ((size_t)c * 256 + j) * 512;
    Wt[wb + k] = f2bf(fl);
    Wt[wb + 256 + k] = f2bf(fr);
    red[k] = muv * (fl + fr);
    __syncthreads();
    for (int s = 128; s > 0; s >>= 1) {
        if (k < s) red[k] += red[k + s];
        __syncthreads();
    }
    if (k == 0) biasF[c * 256 + j] = bl[j] - red[0];
}

// ---------------- lin1: h = base + table-sum, bf16 out, fp32 stats ----------------
__global__ __launch_bounds__(256) void lin1_k(const float* __restrict__ base,
                                              const float* __restrict__ T,
                                              const int* __restrict__ cfgpos,
                                              const int* __restrict__ xcfg,
                                              u16* __restrict__ H,
                                              float* __restrict__ ssum,
                                              float* __restrict__ ssq) {
    const int c = blockIdx.z, n0 = blockIdx.x * 16, d = threadIdx.x;
    float psum = 0.f, psq = 0.f;
    for (int g = 0; g < 16; ++g) {
        int n = n0 + g;
        float acc = base[n * 256 + d];
        int j = cfgpos[n];
        if (j >= 0) {
            const int* ip = &xcfg[((size_t)c * NC_ + j) * 18];
#pragma unroll
            for (int s = 0; s < 18; ++s)
                acc += T[(s * 8 + ip[s] + 2) * 256 + d];
        } else {
#pragma unroll
            for (int s = 0; s < 18; ++s)
                acc += T[(s * 8) * 256 + d];
        }
        H[((size_t)c * N_ + n) * 256 + d] = f2bf(acc);
        psum += acc; psq += acc * acc;
    }
    atomicAdd(&ssum[c * 256 + d], psum);
    atomicAdd(&ssq[c * 256 + d], psq);
}

__global__ __launch_bounds__(256) void finstat_k(const float* __restrict__ ssum,
                                                 const float* __restrict__ ssq,
                                                 float* __restrict__ mu,
                                                 float* __restrict__ rs) {
    int i = blockIdx.x * 256 + threadIdx.x;
    float m = ssum[i] * (1.0f / (float)N_);
    float v = ssq[i] * (1.0f / (float)N_) - m * m;
    mu[i] = m;
    rs[i] = rsqrtf(v + EPS_);
}

// ---------------- CSR gather-mean (raw mean; mu for deg-0 rows) ----------------
__global__ __launch_bounds__(256) void agg_k(const u16* __restrict__ H,
                                             const int* __restrict__ off,
                                             const int* __restrict__ csr,
                                             const float* __restrict__ invcnt,
                                             const float* __restrict__ mu,
                                             u16* __restrict__ Agg) {
    int wave = threadIdx.x >> 6, lane = threadIdx.x & 63;
    int pair = blockIdx.x * 4 + wave;
    int c = pair / N_, t = pair - c * N_;
    int d4 = lane * 4;
    int o0 = off[t], o1 = off[t + 1];
    float ax = 0.f, ay = 0.f, az = 0.f, aw = 0.f;
    for (int i = o0; i < o1; ++i) {
        int s = csr[i];
        us4v hv = *(const us4v*)&H[((size_t)c * N_ + s) * 256 + d4];
        ax += bf2f(hv.x); ay += bf2f(hv.y); az += bf2f(hv.z); aw += bf2f(hv.w);
    }
    us4v o;
    if (o1 > o0) {
        float inv = invcnt[t];
        o.x = f2bf(ax * inv); o.y = f2bf(ay * inv);
        o.z = f2bf(az * inv); o.w = f2bf(aw * inv);
    } else {
        // write mu so the norm-folded GEMM yields ~0 for this row
        o.x = f2bf(mu[c * 256 + d4 + 0]);
        o.y = f2bf(mu[c * 256 + d4 + 1]);
        o.z = f2bf(mu[c * 256 + d4 + 2]);
        o.w = f2bf(mu[c * 256 + d4 + 3]);
    }
    *(us4v*)&Agg[((size_t)c * N_ + t) * 256 + d4] = o;
}

// ---------------- bf16 MFMA GEMM: Y = [A1|A2] @ Wt^T + bias ----------------
// A1/A2: [M x 256] bf16 row-major per-config slabs. Wt: [256 cols][Ktot] bf16
// (pre-transposed weights, optionally per-config). 128x128 tile, 4 waves,
// each wave a 64x64 quadrant of 16x16x32 MFMAs. XOR-swizzled LDS.
template <int STATS>
__global__ __launch_bounds__(256) void mgemm_k(
    const u16* __restrict__ A1, size_t sA1,
    const u16* __restrict__ A2, size_t sA2,
    const u16* __restrict__ Wt, size_t sW, int K1, int Ktot,
    const float* __restrict__ bias, size_t sBias,
    u16* __restrict__ Y, size_t sY, int Mrows,
    float* __restrict__ ssum, float* __restrict__ ssq)
{
    __shared__ u16 Asm[128 * 64];
    __shared__ u16 Bsm[128 * 64];
    const int tid = threadIdx.x;
    const int lane = tid & 63, wid = tid >> 6;
    const int wr = wid >> 1, wc = wid & 1;
    const int c = blockIdx.z;
    const int rowbase = blockIdx.y * 128, colbase = blockIdx.x * 128;

    const u16* A1p = A1 + (size_t)c * sA1;
    const u16* A2p = A2 ? (A2 + (size_t)c * sA2) : nullptr;
    const u16* Wp  = Wt + (size_t)c * sW;

    f32x4 acc[4][4];
#pragma unroll
    for (int i = 0; i < 4; ++i)
#pragma unroll
        for (int j = 0; j < 4; ++j) acc[i][j] = (f32x4)0.f;

    const int srow = tid >> 1;          // 0..127
    const int scol = (tid & 1) * 32;    // 0 / 32
    const int sgrow = rowbase + srow;

    for (int k0 = 0; k0 < Ktot; k0 += 64) {
        const u16* asrc; int ak;
        if (k0 < K1) { asrc = A1p; ak = k0; } else { asrc = A2p; ak = k0 - K1; }
        const u16* ag = asrc + (size_t)sgrow * 256 + ak + scol;
        const u16* bg = Wp + (size_t)(colbase + srow) * Ktot + k0 + scol;
#pragma unroll
        for (int i = 0; i < 4; ++i) {
            us8v av = (us8v)0;
            if (sgrow < Mrows) av = *(const us8v*)(ag + i * 8);
            *(us8v*)&Asm[(srow * 64 + scol + i * 8) ^ ((srow & 7) << 3)] = av;
            us8v bv = *(const us8v*)(bg + i * 8);
            *(us8v*)&Bsm[(srow * 64 + scol + i * 8) ^ ((srow & 7) << 3)] = bv;
        }
        __syncthreads();
#pragma unroll
        for (int ks = 0; ks < 2; ++ks) {
            s16x8 aF[4], bF[4];
            const int kk = ks * 32 + ((lane >> 4) << 3);
#pragma unroll
            for (int f = 0; f < 4; ++f) {
                int ar = wr * 64 + f * 16 + (lane & 15);
                aF[f] = *(const s16x8*)&Asm[(ar * 64 + kk) ^ ((ar & 7) << 3)];
                int br = wc * 64 + f * 16 + (lane & 15);
                bF[f] = *(const s16x8*)&Bsm[(br * 64 + kk) ^ ((br & 7) << 3)];
            }
#pragma unroll
            for (int fr = 0; fr < 4; ++fr)
#pragma unroll
                for (int fc = 0; fc < 4; ++fc)
                    acc[fr][fc] = __builtin_amdgcn_mfma_f32_16x16x32_bf16(
                        aF[fr], bF[fc], acc[fr][fc], 0, 0, 0);
        }
        __syncthreads();
    }

    // epilogue: bias, bf16 store, optional fp32 column stats
    float bcol[4];
#pragma unroll
    for (int fc = 0; fc < 4; ++fc)
        bcol[fc] = bias[(size_t)c * sBias + colbase + wc * 64 + fc * 16 + (lane & 15)];
    u16* Yp = Y + (size_t)c * sY;
    float ps[4] = {0, 0, 0, 0}, pq[4] = {0, 0, 0, 0};
#pragma unroll
    for (int fr = 0; fr < 4; ++fr) {
#pragma unroll
        for (int i = 0; i < 4; ++i) {
            int grow = rowbase + wr * 64 + fr * 16 + ((lane >> 4) << 2) + i;
            if (grow < Mrows) {
                size_t rb = (size_t)grow * 256 + colbase + wc * 64 + (lane & 15);
#pragma unroll
                for (int fc = 0; fc < 4; ++fc) {
                    float v = acc[fr][fc][i] + bcol[fc];
                    Yp[rb + fc * 16] = f2bf(v);
                    if (STATS) { ps[fc] += v; pq[fc] += v * v; }
                }
            }
        }
    }
    if (STATS) {
#pragma unroll
        for (int fc = 0; fc < 4; ++fc) {
            float s = ps[fc], q = pq[fc];
            s += __shfl_xor(s, 16); s += __shfl_xor(s, 32);
            q += __shfl_xor(q, 16); q += __shfl_xor(q, 32);
            if (lane < 16) {
                int col = colbase + wc * 64 + fc * 16 + lane;
                atomicAdd(&ssum[c * 256 + col], s);
                atomicAdd(&ssq[c * 256 + col], q);
            }
        }
    }
}

// ---------------- fp32 tiled GEMM (kept for the one-time base GEMM) ----------------
__global__ __launch_bounds__(256) void gemm_k(const float* __restrict__ A1, int lda1,
                                              const float* __restrict__ W1, int K1,
                                              const float* __restrict__ bias,
                                              float* __restrict__ Y, int Mrows) {
    __shared__ float As[16][132];
    __shared__ float Bs[16][132];
    float acc[8][8];
#pragma unroll
    for (int i = 0; i < 8; ++i)
#pragma unroll
        for (int j = 0; j < 8; ++j) acc[i][j] = 0.f;

    const int tid = threadIdx.x;
    const int tr = tid >> 4, tc = tid & 15;
    const int rowbase = blockIdx.y * 128, colbase = blockIdx.x * 128;

    for (int k0 = 0; k0 < K1; k0 += 16) {
#pragma unroll
        for (int ii = 0; ii < 2; ++ii) {
            int i = tid + ii * 256;
            int rr = i >> 2, qq = i & 3;
            int grow = rowbase + rr;
            float4 vv = make_float4(0.f, 0.f, 0.f, 0.f);
            if (grow < Mrows) vv = *(const float4*)&A1[(size_t)grow * lda1 + k0 + qq * 4];
            As[qq * 4 + 0][rr] = vv.x;
            As[qq * 4 + 1][rr] = vv.y;
            As[qq * 4 + 2][rr] = vv.z;
            As[qq * 4 + 3][rr] = vv.w;
        }
#pragma unroll
        for (int ii = 0; ii < 2; ++ii) {
            int i = tid + ii * 256;
            int rr = i >> 5, qq = i & 31;
            float4 vv = *(const float4*)&W1[(size_t)(k0 + rr) * 256 + colbase + qq * 4];
            *(float4*)&Bs[rr][qq * 4] = vv;
        }
        __syncthreads();
#pragma unroll
        for (int kk = 0; kk < 16; ++kk) {
            float a[8], b[8];
            *(float4*)&a[0] = *(const float4*)&As[kk][tr * 4];
            *(float4*)&a[4] = *(const float4*)&As[kk][64 + tr * 4];
            *(float4*)&b[0] = *(const float4*)&Bs[kk][tc * 4];
            *(float4*)&b[4] = *(const float4*)&Bs[kk][64 + tc * 4];
#pragma unroll
            for (int i = 0; i < 8; ++i)
#pragma unroll
                for (int j = 0; j < 8; ++j)
                    acc[i][j] = fmaf(a[i], b[j], acc[i][j]);
        }
        __syncthreads();
    }

    float4 blo = *(const float4*)&bias[colbase + tc * 4];
    float4 bhi = *(const float4*)&bias[colbase + 64 + tc * 4];
    float bb[8] = {blo.x, blo.y, blo.z, blo.w, bhi.x, bhi.y, bhi.z, bhi.w};
#pragma unroll
    for (int i = 0; i < 8; ++i)
#pragma unroll
        for (int j = 0; j < 8; ++j) acc[i][j] += bb[j];

#pragma unroll
    for (int i = 0; i < 8; ++i) {
        int lrow = (i < 4) ? (tr * 4 + i) : (64 + tr * 4 + (i - 4));
        int grow = rowbase + lrow;
        if (grow < Mrows) {
            *(float4*)&Y[(size_t)grow * 256 + colbase + tc * 4] =
                make_float4(acc[i][0], acc[i][1], acc[i][2], acc[i][3]);
            *(float4*)&Y[(size_t)grow * 256 + colbase + 64 + tc * 4] =
                make_float4(acc[i][4], acc[i][5], acc[i][6], acc[i][7]);
        }
    }
}

// ---------------- per-row: [norm] -> channel-attn -> [residual] -> gelu ----------------
template <int NORM, int RES, int SMODE>
__global__ __launch_bounds__(256) void apply_k(const u16* __restrict__ Yin,
                                               u16* __restrict__ Hout,
                                               const u16* __restrict__ Hsc,
                                               const float* __restrict__ W1,
                                               const float* __restrict__ b1,
                                               const float* __restrict__ W2,
                                               const float* __restrict__ b2,
                                               const float* __restrict__ mu,
                                               const float* __restrict__ rs,
                                               float* __restrict__ ssum,
                                               float* __restrict__ ssq) {
    __shared__ float v[16][256];
    __shared__ float tt[16][32];
    const int c = blockIdx.z, n0 = blockIdx.x * 16, tid = threadIdx.x;
    const int d = tid;
    const size_t rowbase = ((size_t)c * N_ + n0) * 256;

    float muv = 0.f, rsv = 1.f;
    if (NORM) { muv = mu[c * 256 + d]; rsv = rs[c * 256 + d]; }
#pragma unroll 4
    for (int g = 0; g < 16; ++g) {
        float x = bf2f(Yin[rowbase + g * 256 + d]);
        v[g][d] = NORM ? (x - muv) * rsv : x;
    }
    __syncthreads();
    {
        const int r = tid & 31, g2 = tid >> 5;
#pragma unroll
        for (int hh = 0; hh < 2; ++hh) {
            const int g = g2 * 2 + hh;
            float acc = b1[r];
#pragma unroll 4
            for (int dd = 0; dd < 256; dd += 4) {
                float4 vv = *(const float4*)&v[g][dd];
                acc = fmaf(vv.x, W1[(dd + 0) * 32 + r], acc);
                acc = fmaf(vv.y, W1[(dd + 1) * 32 + r], acc);
                acc = fmaf(vv.z, W1[(dd + 2) * 32 + r], acc);
                acc = fmaf(vv.w, W1[(dd + 3) * 32 + r], acc);
            }
            tt[g][r] = fmaxf(acc, 0.f);
        }
    }
    __syncthreads();
    float psum = 0.f, psq = 0.f;
    const float b2v = b2[d];
#pragma unroll 2
    for (int g = 0; g < 16; ++g) {
        float s = b2v;
#pragma unroll
        for (int rr = 0; rr < 32; ++rr)
            s = fmaf(tt[g][rr], W2[rr * 256 + d], s);
        float sig = 1.0f / (1.0f + expf(-s));
        float val = sig * v[g][d];
        if (RES) val += bf2f(Hsc[rowbase + g * 256 + d]);
        val = gelu_f(val);
        Hout[rowbase + g * 256 + d] = f2bf(val);
        if (SMODE == 1) { psum += val; psq += val * val; }
        if (SMODE == 2) { psum += val; }
    }
    if (SMODE == 1) {
        atomicAdd(&ssum[c * 256 + d], psum);
        atomicAdd(&ssq[c * 256 + d], psq);
    }
    if (SMODE == 2) {
        atomicAdd(&ssum[c * 256 + d], psum);
    }
}

// ---------------- classifier ----------------
__global__ __launch_bounds__(256) void cls_k(const float* __restrict__ pooled_sum,
                                             const float* __restrict__ clsW,
                                             const float* __restrict__ clsb,
                                             float* __restrict__ out) {
    __shared__ float red[256];
    int c = blockIdx.x, d = threadIdx.x;
    red[d] = pooled_sum[c * 256 + d] * (1.0f / (float)N_) * clsW[d];
    __syncthreads();
    for (int s = 128; s > 0; s >>= 1) {
        if (d < s) red[d] += red[d + s];
        __syncthreads();
    }
    if (d == 0) out[c] = red[0] + clsb[0];
}

// ---------------- host launch ----------------
static inline size_t alup(size_t x) { return (x + 255) & ~(size_t)255; }

extern "C" void kernel_launch(void* const* d_in, const int* in_sizes, int n_in,
                              void* d_out, int out_size, void* d_ws, size_t ws_size,
                              hipStream_t stream) {
    const int*   xcfg   = (const int*)d_in[0];
    const float* xfeat  = (const float*)d_in[1];
    const int*   xlay   = (const int*)d_in[2];
    const int*   xop    = (const int*)d_in[3];
    const int*   ei     = (const int*)d_in[4];
    const int*   ncid   = (const int*)d_in[5];
    const float* embO   = (const float*)d_in[6];
    const float* embL   = (const float*)d_in[7];
    const float* lin1W  = (const float*)d_in[8];
    const float* lin1b  = (const float*)d_in[9];
    const float* ca1W1  = (const float*)d_in[10];
    const float* ca1b1  = (const float*)d_in[11];
    const float* ca1W2  = (const float*)d_in[12];
    const float* ca1b2  = (const float*)d_in[13];
    const float* lin2W  = (const float*)d_in[14];
    const float* lin2b  = (const float*)d_in[15];
    const float* ca2W1  = (const float*)d_in[16];
    const float* ca2b1  = (const float*)d_in[17];
    const float* ca2W2  = (const float*)d_in[18];
    const float* ca2b2  = (const float*)d_in[19];
    const float* sageWl = (const float*)d_in[20];
    const float* sagebl = (const float*)d_in[21];
    const float* sageWr = (const float*)d_in[22];
    const float* scaW1  = (const float*)d_in[23];
    const float* scab1  = (const float*)d_in[24];
    const float* scaW2  = (const float*)d_in[25];
    const float* scab2  = (const float*)d_in[26];
    const float* clsW   = (const float*)d_in[27];
    const float* clsb   = (const float*)d_in[28];
    float* out = (float*)d_out;

    // ---- workspace carve-up: fixed buffers first, then config-chunk slabs ----
    char* w = (char*)d_ws;
    size_t o = 0;
    auto take = [&](size_t bytes) { char* p = w + o; o = alup(o + bytes); return p; };
    float* base    = (float*)take((size_t)N_ * 256 * 4);
    float* feat162 = (float*)take((size_t)N_ * 176 * 4);
    float* W162    = (float*)take((size_t)176 * 256 * 4);
    float* T       = (float*)take((size_t)18 * 8 * 256 * 4);
    float* stats   = (float*)take((size_t)6 * 8192 * 4);
    float* MU      = (float*)take((size_t)5 * 4096 * 4);
    float* RS      = (float*)take((size_t)5 * 4096 * 4);
    float* invcnt  = (float*)take((size_t)N_ * 4);
    int*   cnt     = (int*)take((size_t)N_ * 4);
    int*   off     = (int*)take((size_t)(N_ + 1) * 4);
    int*   cursor  = (int*)take((size_t)N_ * 4);
    int*   csr     = (int*)take((size_t)E_ * 4);
    int*   cfgpos  = (int*)take((size_t)N_ * 4);
    u16*   Wt2     = (u16*)take((size_t)256 * 256 * 2);
    u16*   Wfold   = (u16*)take((size_t)C_ * 256 * 512 * 2);   // 4 MB
    float* biasF   = (float*)take((size_t)C_ * 256 * 4);

    const size_t slab = (size_t)SZ_ * 2;                       // bf16: 5.12 MB
    size_t avail = (ws_size > o) ? (ws_size - o) : 0;
    int Cc = (int)(avail / (3 * slab + 768));
    if (Cc > C_) Cc = C_;
    if (Cc < 1) Cc = 1;
    u16* BufH = (u16*)take((size_t)Cc * slab);
    u16* BufY = (u16*)take((size_t)Cc * slab);
    u16* BufA = (u16*)take((size_t)Cc * slab);
    (void)in_sizes; (void)n_in; (void)out_size;

    auto S = [&](int s) { return stats + (size_t)s * 8192; };
    auto Q = [&](int s) { return stats + (size_t)s * 8192 + 4096; };

    hipMemsetAsync(stats, 0, 6 * 8192 * 4, stream);
    hipMemsetAsync(cnt, 0, N_ * 4, stream);
    hipMemsetAsync(cfgpos, 0xFF, N_ * 4, stream);

    // shared prep
    tbl_k<<<144, 256, 0, stream>>>(embL, lin1W, T);
    feat_k<<<N_, 192, 0, stream>>>(xfeat, xlay, xop, embL, embO, feat162);
    wpack_k<<<176, 256, 0, stream>>>(lin1W, W162);
    wt2_k<<<256, 256, 0, stream>>>(lin2W, Wt2);
    cfgpos_k<<<(NC_ + 255) / 256, 256, 0, stream>>>(ncid, cfgpos);
    hist_k<<<(E_ + 255) / 256, 256, 0, stream>>>(ei, cnt);
    scan_k<<<1, 1024, 0, stream>>>(cnt, off, cursor, invcnt);
    fill_k<<<(E_ + 255) / 256, 256, 0, stream>>>(ei, cursor, csr);

    // base = feat162 @ W162 + lin1_b (fp32, one-time)
    gemm_k<<<dim3(2, 79, 1), 256, 0, stream>>>(feat162, 176, W162, 176, lin1b, base, N_);

    // ---- per-config-chunk pipeline ----
    for (int c0 = 0; c0 < C_; c0 += Cc) {
        const int nc = (C_ - c0 < Cc) ? (C_ - c0) : Cc;
        const int co = c0 * 256;

        lin1_k<<<dim3(625, 1, nc), 256, 0, stream>>>(
            base, T, cfgpos, xcfg + (size_t)c0 * NC_ * 18, BufH, S(0) + co, Q(0) + co);
        finstat_k<<<nc, 256, 0, stream>>>(S(0) + co, Q(0) + co, MU + co, RS + co);

        apply_k<1, 0, 0><<<dim3(625, 1, nc), 256, 0, stream>>>(
            BufH, BufH, nullptr, ca1W1, ca1b1, ca1W2, ca1b2,
            MU + co, RS + co, nullptr, nullptr);

        mgemm_k<1><<<dim3(2, 79, nc), 256, 0, stream>>>(
            BufH, SZ_, nullptr, 0, Wt2, 0, 256, 256,
            lin2b, 0, BufY, SZ_, N_, S(1) + co, Q(1) + co);
        finstat_k<<<nc, 256, 0, stream>>>(S(1) + co, Q(1) + co, MU + 4096 + co, RS + 4096 + co);

        apply_k<1, 0, 1><<<dim3(625, 1, nc), 256, 0, stream>>>(
            BufY, BufY, nullptr, ca2W1, ca2b1, ca2W2, ca2b2,
            MU + 4096 + co, RS + 4096 + co, S(2) + co, Q(2) + co);

        for (int i = 0; i < 3; ++i) {
            const int set = 2 + i;
            finstat_k<<<nc, 256, 0, stream>>>(S(set) + co, Q(set) + co,
                                              MU + set * 4096 + co, RS + set * 4096 + co);
            foldw_k<<<dim3(256, nc), 256, 0, stream>>>(
                sageWl + (size_t)i * 65536, sageWr + (size_t)i * 65536, sagebl + i * 256,
                MU + set * 4096 + co, RS + set * 4096 + co,
                Wfold + (size_t)c0 * 256 * 512, biasF + co);
            agg_k<<<nc * 2500, 256, 0, stream>>>(BufY, off, csr, invcnt,
                                                 MU + set * 4096 + co, BufA);
            mgemm_k<0><<<dim3(2, 79, nc), 256, 0, stream>>>(
                BufA, SZ_, BufY, SZ_, Wfold + (size_t)c0 * 256 * 512, 256 * 512, 256, 512,
                biasF + co, 256, BufH, SZ_, N_, nullptr, nullptr);
            if (i < 2) {
                apply_k<0, 1, 1><<<dim3(625, 1, nc), 256, 0, stream>>>(
                    BufH, BufY, BufY,
                    scaW1 + (size_t)i * 8192, scab1 + i * 32,
                    scaW2 + (size_t)i * 8192, scab2 + i * 256,
                    nullptr, nullptr, S(3 + i) + co, Q(3 + i) + co);
            } else {
                apply_k<0, 1, 2><<<dim3(625, 1, nc), 256, 0, stream>>>(
                    BufH, BufY, BufY,
                    scaW1 + (size_t)i * 8192, scab1 + i * 32,
                    scaW2 + (size_t)i * 8192, scab2 + i * 256,
                    nullptr, nullptr, S(5) + co, nullptr);
            }
        }
    }

    cls_k<<<16, 256, 0, stream>>>(S(5), clsW, clsb, out);
}

// Round 4
// 1629.215 us; speedup vs baseline: 2.3298x; 1.3500x over previous
//
#include <hip/hip_runtime.h>
#include <math.h>

// ---------------- problem constants ----------------
constexpr int C_  = 16;
constexpr int N_  = 10000;
constexpr int NC_ = 2000;
constexpr int E_  = 50000;
constexpr int D_  = 256;
constexpr int SZ_ = N_ * D_;          // per-config slab (elements)
constexpr float EPS_ = 1e-5f;

typedef unsigned short u16;
typedef __attribute__((ext_vector_type(8))) unsigned short us8v;
typedef __attribute__((ext_vector_type(4))) unsigned short us4v;
typedef __attribute__((ext_vector_type(8))) short s16x8;
typedef __attribute__((ext_vector_type(4))) float f32x4;

__device__ __forceinline__ float gelu_f(float x) {
    return 0.5f * x * (1.0f + erff(x * 0.70710678118654752f));
}
__device__ __forceinline__ u16 f2bf(float f) {
    unsigned u = __float_as_uint(f);
    u += 0x7fffu + ((u >> 16) & 1u);
    return (u16)(u >> 16);
}
__device__ __forceinline__ float bf2f(u16 h) {
    return __uint_as_float(((unsigned)h) << 16);
}

// ---------------- tiny prep kernels ----------------

__global__ __launch_bounds__(256) void tbl_k(const float* __restrict__ embL,
                                             const float* __restrict__ W,
                                             float* __restrict__ T) {
    int b = blockIdx.x;            // 0..143
    int s = b >> 3, i = b & 7, d = threadIdx.x;
    float acc = 0.f;
#pragma unroll
    for (int k = 0; k < 4; ++k)
        acc = fmaf(embL[i * 4 + k], W[(134 + s * 4 + k) * 256 + d], acc);
    T[(s * 8 + i) * 256 + d] = acc;
}

__global__ __launch_bounds__(192) void feat_k(const float* __restrict__ xf,
                                              const int* __restrict__ xlay,
                                              const int* __restrict__ xop,
                                              const float* __restrict__ embL,
                                              const float* __restrict__ embO,
                                              float* __restrict__ f) {
    int n = blockIdx.x, j = threadIdx.x;
    if (j >= 176) return;
    float v;
    if (j < 134) v = xf[n * 134 + j];
    else if (j < 158) { int q = j - 134; int t = q >> 2, k = q & 3; v = embL[(xlay[n * 6 + t] + 2) * 4 + k]; }
    else if (j < 162) { int k = j - 158; v = embO[xop[n] * 4 + k]; }
    else v = 0.f;
    f[n * 176 + j] = v;
}

__global__ __launch_bounds__(256) void wpack_k(const float* __restrict__ W,
                                               float* __restrict__ Wp) {
    int j = blockIdx.x, d = threadIdx.x;
    float v = 0.f;
    if (j < 134) v = W[j * 256 + d];
    else if (j < 158) v = W[(206 + j - 134) * 256 + d];
    else if (j < 162) v = W[(230 + j - 158) * 256 + d];
    Wp[j * 256 + d] = v;
}

__global__ __launch_bounds__(256) void packbf_k(const float* __restrict__ src,
                                                u16* __restrict__ dst, int n) {
    int i = blockIdx.x * 256 + threadIdx.x;
    if (i < n) dst[i] = f2bf(src[i]);
}

__global__ __launch_bounds__(256) void cfgpos_k(const int* __restrict__ ncid,
                                                int* __restrict__ cfgpos) {
    int i = blockIdx.x * 256 + threadIdx.x;
    if (i < NC_) cfgpos[ncid[i]] = i;
}

__global__ __launch_bounds__(256) void hist_k(const int* __restrict__ ei, int* __restrict__ cnt) {
    int e = blockIdx.x * 256 + threadIdx.x;
    if (e < E_) atomicAdd(&cnt[ei[E_ + e]], 1);
}

__global__ __launch_bounds__(1024) void scan_k(const int* __restrict__ cnt,
                                               int* __restrict__ off,
                                               int* __restrict__ cursor,
                                               float* __restrict__ invcnt) {
    __shared__ int s[1024];
    int t = threadIdx.x;
    int base = t * 10;
    int local[10];
    int part = 0;
#pragma unroll
    for (int k = 0; k < 10; ++k) {
        int idx = base + k;
        int v = (idx < N_) ? cnt[idx] : 0;
        local[k] = v; part += v;
    }
    s[t] = part;
    __syncthreads();
    for (int o = 1; o < 1024; o <<= 1) {
        int val = (t >= o) ? s[t - o] : 0;
        __syncthreads();
        s[t] += val;
        __syncthreads();
    }
    int pre = s[t] - part;
#pragma unroll
    for (int k = 0; k < 10; ++k) {
        int idx = base + k;
        if (idx < N_) {
            off[idx] = pre;
            cursor[idx] = pre;
            invcnt[idx] = 1.0f / (float)(local[k] > 1 ? local[k] : 1);
            pre += local[k];
        }
    }
    if (t == 1023) off[N_] = s[1023];
}

__global__ __launch_bounds__(256) void fill_k(const int* __restrict__ ei,
                                              int* __restrict__ cursor,
                                              int* __restrict__ csr) {
    int e = blockIdx.x * 256 + threadIdx.x;
    if (e < E_) {
        int t = ei[E_ + e];
        int p = atomicAdd(&cursor[t], 1);
        csr[p] = ei[e];
    }
}

// transpose lin2_W -> Wt2[j][k] bf16
__global__ __launch_bounds__(256) void wt2_k(const float* __restrict__ W,
                                             u16* __restrict__ Wt) {
    int j = blockIdx.x, k = threadIdx.x;
    Wt[j * 256 + k] = f2bf(W[k * 256 + j]);
}

// fold instance-norm into sage weights (per config)
__global__ __launch_bounds__(256) void foldw_k(const float* __restrict__ Wl,
                                               const float* __restrict__ Wr,
                                               const float* __restrict__ bl,
                                               const float* __restrict__ mu,
                                               const float* __restrict__ rs,
                                               u16* __restrict__ Wt,
                                               float* __restrict__ biasF) {
    __shared__ float red[256];
    int c = blockIdx.y, j = blockIdx.x, k = threadIdx.x;
    float rsv = rs[c * 256 + k], muv = mu[c * 256 + k];
    float fl = rsv * Wl[k * 256 + j];
    float fr = rsv * Wr[k * 256 + j];
    size_t wb = ((size_t)c * 256 + j) * 512;
    Wt[wb + k] = f2bf(fl);
    Wt[wb + 256 + k] = f2bf(fr);
    red[k] = muv * (fl + fr);
    __syncthreads();
    for (int s = 128; s > 0; s >>= 1) {
        if (k < s) red[k] += red[k + s];
        __syncthreads();
    }
    if (k == 0) biasF[c * 256 + j] = bl[j] - red[0];
}

// ---------------- lin1: h = base + table-sum, bf16 out, fp32 stats ----------------
__global__ __launch_bounds__(256) void lin1_k(const float* __restrict__ base,
                                              const float* __restrict__ T,
                                              const int* __restrict__ cfgpos,
                                              const int* __restrict__ xcfg,
                                              u16* __restrict__ H,
                                              float* __restrict__ ssum,
                                              float* __restrict__ ssq) {
    const int c = blockIdx.z, n0 = blockIdx.x * 16, d = threadIdx.x;
    float psum = 0.f, psq = 0.f;
    for (int g = 0; g < 16; ++g) {
        int n = n0 + g;
        float acc = base[n * 256 + d];
        int j = cfgpos[n];
        if (j >= 0) {
            const int* ip = &xcfg[((size_t)c * NC_ + j) * 18];
#pragma unroll
            for (int s = 0; s < 18; ++s)
                acc += T[(s * 8 + ip[s] + 2) * 256 + d];
        } else {
#pragma unroll
            for (int s = 0; s < 18; ++s)
                acc += T[(s * 8) * 256 + d];
        }
        H[((size_t)c * N_ + n) * 256 + d] = f2bf(acc);
        psum += acc; psq += acc * acc;
    }
    atomicAdd(&ssum[c * 256 + d], psum);
    atomicAdd(&ssq[c * 256 + d], psq);
}

__global__ __launch_bounds__(256) void finstat_k(const float* __restrict__ ssum,
                                                 const float* __restrict__ ssq,
                                                 float* __restrict__ mu,
                                                 float* __restrict__ rs) {
    int i = blockIdx.x * 256 + threadIdx.x;
    float m = ssum[i] * (1.0f / (float)N_);
    float v = ssq[i] * (1.0f / (float)N_) - m * m;
    mu[i] = m;
    rs[i] = rsqrtf(v + EPS_);
}

// ---------------- CSR gather-mean (raw mean; mu for deg-0 rows) ----------------
__global__ __launch_bounds__(256) void agg_k(const u16* __restrict__ H,
                                             const int* __restrict__ off,
                                             const int* __restrict__ csr,
                                             const float* __restrict__ invcnt,
                                             const float* __restrict__ mu,
                                             u16* __restrict__ Agg) {
    int wave = threadIdx.x >> 6, lane = threadIdx.x & 63;
    int pair = blockIdx.x * 4 + wave;
    int c = pair / N_, t = pair - c * N_;
    int d4 = lane * 4;
    int o0 = off[t], o1 = off[t + 1];
    float ax = 0.f, ay = 0.f, az = 0.f, aw = 0.f;
    for (int i = o0; i < o1; ++i) {
        int s = csr[i];
        us4v hv = *(const us4v*)&H[((size_t)c * N_ + s) * 256 + d4];
        ax += bf2f(hv.x); ay += bf2f(hv.y); az += bf2f(hv.z); aw += bf2f(hv.w);
    }
    us4v o;
    if (o1 > o0) {
        float inv = invcnt[t];
        o.x = f2bf(ax * inv); o.y = f2bf(ay * inv);
        o.z = f2bf(az * inv); o.w = f2bf(aw * inv);
    } else {
        o.x = f2bf(mu[c * 256 + d4 + 0]);
        o.y = f2bf(mu[c * 256 + d4 + 1]);
        o.z = f2bf(mu[c * 256 + d4 + 2]);
        o.w = f2bf(mu[c * 256 + d4 + 3]);
    }
    *(us4v*)&Agg[((size_t)c * N_ + t) * 256 + d4] = o;
}

// ---------------- bf16 MFMA GEMM: Y = [A1|A2] @ Wt^T + bias ----------------
template <int STATS>
__global__ __launch_bounds__(256) void mgemm_k(
    const u16* __restrict__ A1, size_t sA1,
    const u16* __restrict__ A2, size_t sA2,
    const u16* __restrict__ Wt, size_t sW, int K1, int Ktot,
    const float* __restrict__ bias, size_t sBias,
    u16* __restrict__ Y, size_t sY, int Mrows,
    float* __restrict__ ssum, float* __restrict__ ssq)
{
    __shared__ u16 Asm[128 * 64];
    __shared__ u16 Bsm[128 * 64];
    const int tid = threadIdx.x;
    const int lane = tid & 63, wid = tid >> 6;
    const int wr = wid >> 1, wc = wid & 1;
    const int c = blockIdx.z;
    const int rowbase = blockIdx.y * 128, colbase = blockIdx.x * 128;

    const u16* A1p = A1 + (size_t)c * sA1;
    const u16* A2p = A2 ? (A2 + (size_t)c * sA2) : nullptr;
    const u16* Wp  = Wt + (size_t)c * sW;

    f32x4 acc[4][4];
#pragma unroll
    for (int i = 0; i < 4; ++i)
#pragma unroll
        for (int j = 0; j < 4; ++j) acc[i][j] = (f32x4)0.f;

    const int srow = tid >> 1;
    const int scol = (tid & 1) * 32;
    const int sgrow = rowbase + srow;

    for (int k0 = 0; k0 < Ktot; k0 += 64) {
        const u16* asrc; int ak;
        if (k0 < K1) { asrc = A1p; ak = k0; } else { asrc = A2p; ak = k0 - K1; }
        const u16* ag = asrc + (size_t)sgrow * 256 + ak + scol;
        const u16* bg = Wp + (size_t)(colbase + srow) * Ktot + k0 + scol;
#pragma unroll
        for (int i = 0; i < 4; ++i) {
            us8v av = (us8v)0;
            if (sgrow < Mrows) av = *(const us8v*)(ag + i * 8);
            *(us8v*)&Asm[(srow * 64 + scol + i * 8) ^ ((srow & 7) << 3)] = av;
            us8v bv = *(const us8v*)(bg + i * 8);
            *(us8v*)&Bsm[(srow * 64 + scol + i * 8) ^ ((srow & 7) << 3)] = bv;
        }
        __syncthreads();
#pragma unroll
        for (int ks = 0; ks < 2; ++ks) {
            s16x8 aF[4], bF[4];
            const int kk = ks * 32 + ((lane >> 4) << 3);
#pragma unroll
            for (int f = 0; f < 4; ++f) {
                int ar = wr * 64 + f * 16 + (lane & 15);
                aF[f] = *(const s16x8*)&Asm[(ar * 64 + kk) ^ ((ar & 7) << 3)];
                int br = wc * 64 + f * 16 + (lane & 15);
                bF[f] = *(const s16x8*)&Bsm[(br * 64 + kk) ^ ((br & 7) << 3)];
            }
#pragma unroll
            for (int fr = 0; fr < 4; ++fr)
#pragma unroll
                for (int fc = 0; fc < 4; ++fc)
                    acc[fr][fc] = __builtin_amdgcn_mfma_f32_16x16x32_bf16(
                        aF[fr], bF[fc], acc[fr][fc], 0, 0, 0);
        }
        __syncthreads();
    }

    float bcol[4];
#pragma unroll
    for (int fc = 0; fc < 4; ++fc)
        bcol[fc] = bias[(size_t)c * sBias + colbase + wc * 64 + fc * 16 + (lane & 15)];
    u16* Yp = Y + (size_t)c * sY;
    float ps[4] = {0, 0, 0, 0}, pq[4] = {0, 0, 0, 0};
#pragma unroll
    for (int fr = 0; fr < 4; ++fr) {
#pragma unroll
        for (int i = 0; i < 4; ++i) {
            int grow = rowbase + wr * 64 + fr * 16 + ((lane >> 4) << 2) + i;
            if (grow < Mrows) {
                size_t rb = (size_t)grow * 256 + colbase + wc * 64 + (lane & 15);
#pragma unroll
                for (int fc = 0; fc < 4; ++fc) {
                    float v = acc[fr][fc][i] + bcol[fc];
                    Yp[rb + fc * 16] = f2bf(v);
                    if (STATS) { ps[fc] += v; pq[fc] += v * v; }
                }
            }
        }
    }
    if (STATS) {
#pragma unroll
        for (int fc = 0; fc < 4; ++fc) {
            float s = ps[fc], q = pq[fc];
            s += __shfl_xor(s, 16); s += __shfl_xor(s, 32);
            q += __shfl_xor(q, 16); q += __shfl_xor(q, 32);
            if (lane < 16) {
                int col = colbase + wc * 64 + fc * 16 + lane;
                atomicAdd(&ssum[c * 256 + col], s);
                atomicAdd(&ssq[c * 256 + col], q);
            }
        }
    }
}

// ---------------- fp32 tiled GEMM (one-time base GEMM) ----------------
__global__ __launch_bounds__(256) void gemm_k(const float* __restrict__ A1, int lda1,
                                              const float* __restrict__ W1, int K1,
                                              const float* __restrict__ bias,
                                              float* __restrict__ Y, int Mrows) {
    __shared__ float As[16][132];
    __shared__ float Bs[16][132];
    float acc[8][8];
#pragma unroll
    for (int i = 0; i < 8; ++i)
#pragma unroll
        for (int j = 0; j < 8; ++j) acc[i][j] = 0.f;

    const int tid = threadIdx.x;
    const int tr = tid >> 4, tc = tid & 15;
    const int rowbase = blockIdx.y * 128, colbase = blockIdx.x * 128;

    for (int k0 = 0; k0 < K1; k0 += 16) {
#pragma unroll
        for (int ii = 0; ii < 2; ++ii) {
            int i = tid + ii * 256;
            int rr = i >> 2, qq = i & 3;
            int grow = rowbase + rr;
            float4 vv = make_float4(0.f, 0.f, 0.f, 0.f);
            if (grow < Mrows) vv = *(const float4*)&A1[(size_t)grow * lda1 + k0 + qq * 4];
            As[qq * 4 + 0][rr] = vv.x;
            As[qq * 4 + 1][rr] = vv.y;
            As[qq * 4 + 2][rr] = vv.z;
            As[qq * 4 + 3][rr] = vv.w;
        }
#pragma unroll
        for (int ii = 0; ii < 2; ++ii) {
            int i = tid + ii * 256;
            int rr = i >> 5, qq = i & 31;
            float4 vv = *(const float4*)&W1[(size_t)(k0 + rr) * 256 + colbase + qq * 4];
            *(float4*)&Bs[rr][qq * 4] = vv;
        }
        __syncthreads();
#pragma unroll
        for (int kk = 0; kk < 16; ++kk) {
            float a[8], b[8];
            *(float4*)&a[0] = *(const float4*)&As[kk][tr * 4];
            *(float4*)&a[4] = *(const float4*)&As[kk][64 + tr * 4];
            *(float4*)&b[0] = *(const float4*)&Bs[kk][tc * 4];
            *(float4*)&b[4] = *(const float4*)&Bs[kk][64 + tc * 4];
#pragma unroll
            for (int i = 0; i < 8; ++i)
#pragma unroll
                for (int j = 0; j < 8; ++j)
                    acc[i][j] = fmaf(a[i], b[j], acc[i][j]);
        }
        __syncthreads();
    }

    float4 blo = *(const float4*)&bias[colbase + tc * 4];
    float4 bhi = *(const float4*)&bias[colbase + 64 + tc * 4];
    float bb[8] = {blo.x, blo.y, blo.z, blo.w, bhi.x, bhi.y, bhi.z, bhi.w};
#pragma unroll
    for (int i = 0; i < 8; ++i)
#pragma unroll
        for (int j = 0; j < 8; ++j) acc[i][j] += bb[j];

#pragma unroll
    for (int i = 0; i < 8; ++i) {
        int lrow = (i < 4) ? (tr * 4 + i) : (64 + tr * 4 + (i - 4));
        int grow = rowbase + lrow;
        if (grow < Mrows) {
            *(float4*)&Y[(size_t)grow * 256 + colbase + tc * 4] =
                make_float4(acc[i][0], acc[i][1], acc[i][2], acc[i][3]);
            *(float4*)&Y[(size_t)grow * 256 + colbase + 64 + tc * 4] =
                make_float4(acc[i][4], acc[i][5], acc[i][6], acc[i][7]);
        }
    }
}

// ---------------- per-row epilogue with MFMA channel-attention ----------------
// phases: A load+norm -> B t=relu(x@W1+b1) via MFMA (wave K-split) ->
//         C y=t@W2 via MFMA fused sigmoid*x (+res) gelu -> D coalesced store+stats
template <int NORM, int RES, int SMODE>
__global__ __launch_bounds__(256) void apply_k(const u16* __restrict__ Yin,
                                               u16* __restrict__ Hout,
                                               const u16* __restrict__ Hsc,
                                               const u16* __restrict__ W1bf,
                                               const float* __restrict__ b1,
                                               const u16* __restrict__ W2bf,
                                               const float* __restrict__ b2,
                                               const float* __restrict__ mu,
                                               const float* __restrict__ rs,
                                               float* __restrict__ ssum,
                                               float* __restrict__ ssq) {
    __shared__ u16 vbf[16 * 264];
    __shared__ u16 scs[(RES ? 16 : 1) * 264];
    __shared__ float tpart[4 * 512];
    __shared__ u16 tbf[16 * 40];
    const int c = blockIdx.z, n0 = blockIdx.x * 16, tid = threadIdx.x;
    const int lane = tid & 63, wid = tid >> 6;
    const size_t rowbase = ((size_t)c * N_ + n0) * 256;

    // phase A: load + normalize (coalesced)
    {
        const int d = tid;
        float muv = 0.f, rsv = 1.f;
        if (NORM) { muv = mu[c * 256 + d]; rsv = rs[c * 256 + d]; }
#pragma unroll 4
        for (int g = 0; g < 16; ++g) {
            float x = bf2f(Yin[rowbase + g * 256 + d]);
            if (NORM) x = (x - muv) * rsv;
            vbf[g * 264 + d] = f2bf(x);
            if (RES) scs[g * 264 + d] = Hsc[rowbase + g * 256 + d];
        }
    }
    __syncthreads();

    // phase B: t_partial = x(K-slice) @ W1, wave w owns K in [w*64, w*64+64)
    {
        const int row = lane & 15, kq = lane >> 4;
        f32x4 at0 = (f32x4)0.f, at1 = (f32x4)0.f;
        const int wk = wid * 64;
#pragma unroll
        for (int ks = 0; ks < 2; ++ks) {
            const int k = wk + ks * 32 + kq * 8;
            s16x8 aF = *(const s16x8*)&vbf[row * 264 + k];
            s16x8 bF0, bF1;
#pragma unroll
            for (int j = 0; j < 8; ++j) {
                bF0[j] = (short)W1bf[(k + j) * 32 + row];
                bF1[j] = (short)W1bf[(k + j) * 32 + 16 + row];
            }
            at0 = __builtin_amdgcn_mfma_f32_16x16x32_bf16(aF, bF0, at0, 0, 0, 0);
            at1 = __builtin_amdgcn_mfma_f32_16x16x32_bf16(aF, bF1, at1, 0, 0, 0);
        }
#pragma unroll
        for (int i = 0; i < 4; ++i) {
            tpart[wid * 512 + (kq * 4 + i) * 32 + (lane & 15)] = at0[i];
            tpart[wid * 512 + (kq * 4 + i) * 32 + 16 + (lane & 15)] = at1[i];
        }
    }
    __syncthreads();

    // reduce partials across waves, +b1, relu -> tbf
    {
#pragma unroll
        for (int ii = 0; ii < 2; ++ii) {
            int idx = tid + ii * 256;
            float s = tpart[idx] + tpart[512 + idx] + tpart[1024 + idx] + tpart[1536 + idx];
            int col = idx & 31;
            s += b1[col];
            tbf[(idx >> 5) * 40 + col] = f2bf(fmaxf(s, 0.f));
        }
    }
    __syncthreads();

    // phase C: y = t @ W2, fused sigmoid * x (+res), gelu; write back to vbf
    {
        const int cl = lane & 15, kq = lane >> 4;
        s16x8 aF = *(const s16x8*)&tbf[cl * 40 + kq * 8];
#pragma unroll
        for (int q = 0; q < 4; ++q) {
            const int colb = (wid * 4 + q) * 16;
            s16x8 bF;
#pragma unroll
            for (int j = 0; j < 8; ++j)
                bF[j] = (short)W2bf[(kq * 8 + j) * 256 + colb + cl];
            f32x4 acc = __builtin_amdgcn_mfma_f32_16x16x32_bf16(aF, bF, (f32x4)0.f, 0, 0, 0);
            const float b2v = b2[colb + cl];
#pragma unroll
            for (int i = 0; i < 4; ++i) {
                const int row = kq * 4 + i;
                float s = acc[i] + b2v;
                float sig = 1.0f / (1.0f + expf(-s));
                float val = sig * bf2f(vbf[row * 264 + colb + cl]);
                if (RES) val += bf2f(scs[row * 264 + colb + cl]);
                val = gelu_f(val);
                vbf[row * 264 + colb + cl] = f2bf(val);
            }
        }
    }
    __syncthreads();

    // phase D: coalesced store + stats
    {
        const int d = tid;
        float psum = 0.f, psq = 0.f;
#pragma unroll 4
        for (int g = 0; g < 16; ++g) {
            u16 h = vbf[g * 264 + d];
            Hout[rowbase + g * 256 + d] = h;
            if (SMODE) {
                float v = bf2f(h);
                psum += v;
                if (SMODE == 1) psq += v * v;
            }
        }
        if (SMODE == 1) {
            atomicAdd(&ssum[c * 256 + d], psum);
            atomicAdd(&ssq[c * 256 + d], psq);
        }
        if (SMODE == 2) {
            atomicAdd(&ssum[c * 256 + d], psum);
        }
    }
}

// ---------------- classifier ----------------
__global__ __launch_bounds__(256) void cls_k(const float* __restrict__ pooled_sum,
                                             const float* __restrict__ clsW,
                                             const float* __restrict__ clsb,
                                             float* __restrict__ out) {
    __shared__ float red[256];
    int c = blockIdx.x, d = threadIdx.x;
    red[d] = pooled_sum[c * 256 + d] * (1.0f / (float)N_) * clsW[d];
    __syncthreads();
    for (int s = 128; s > 0; s >>= 1) {
        if (d < s) red[d] += red[d + s];
        __syncthreads();
    }
    if (d == 0) out[c] = red[0] + clsb[0];
}

// ---------------- host launch ----------------
static inline size_t alup(size_t x) { return (x + 255) & ~(size_t)255; }

extern "C" void kernel_launch(void* const* d_in, const int* in_sizes, int n_in,
                              void* d_out, int out_size, void* d_ws, size_t ws_size,
                              hipStream_t stream) {
    const int*   xcfg   = (const int*)d_in[0];
    const float* xfeat  = (const float*)d_in[1];
    const int*   xlay   = (const int*)d_in[2];
    const int*   xop    = (const int*)d_in[3];
    const int*   ei     = (const int*)d_in[4];
    const int*   ncid   = (const int*)d_in[5];
    const float* embO   = (const float*)d_in[6];
    const float* embL   = (const float*)d_in[7];
    const float* lin1W  = (const float*)d_in[8];
    const float* lin1b  = (const float*)d_in[9];
    const float* ca1W1  = (const float*)d_in[10];
    const float* ca1b1  = (const float*)d_in[11];
    const float* ca1W2  = (const float*)d_in[12];
    const float* ca1b2  = (const float*)d_in[13];
    const float* lin2W  = (const float*)d_in[14];
    const float* lin2b  = (const float*)d_in[15];
    const float* ca2W1  = (const float*)d_in[16];
    const float* ca2b1  = (const float*)d_in[17];
    const float* ca2W2  = (const float*)d_in[18];
    const float* ca2b2  = (const float*)d_in[19];
    const float* sageWl = (const float*)d_in[20];
    const float* sagebl = (const float*)d_in[21];
    const float* sageWr = (const float*)d_in[22];
    const float* scaW1  = (const float*)d_in[23];
    const float* scab1  = (const float*)d_in[24];
    const float* scaW2  = (const float*)d_in[25];
    const float* scab2  = (const float*)d_in[26];
    const float* clsW   = (const float*)d_in[27];
    const float* clsb   = (const float*)d_in[28];
    float* out = (float*)d_out;

    // ---- workspace carve-up ----
    char* w = (char*)d_ws;
    size_t o = 0;
    auto take = [&](size_t bytes) { char* p = w + o; o = alup(o + bytes); return p; };
    float* base    = (float*)take((size_t)N_ * 256 * 4);
    float* feat162 = (float*)take((size_t)N_ * 176 * 4);
    float* W162    = (float*)take((size_t)176 * 256 * 4);
    float* T       = (float*)take((size_t)18 * 8 * 256 * 4);
    float* stats   = (float*)take((size_t)6 * 8192 * 4);
    float* MU      = (float*)take((size_t)5 * 4096 * 4);
    float* RS      = (float*)take((size_t)5 * 4096 * 4);
    float* invcnt  = (float*)take((size_t)N_ * 4);
    int*   cnt     = (int*)take((size_t)N_ * 4);
    int*   off     = (int*)take((size_t)(N_ + 1) * 4);
    int*   cursor  = (int*)take((size_t)N_ * 4);
    int*   csr     = (int*)take((size_t)E_ * 4);
    int*   cfgpos  = (int*)take((size_t)N_ * 4);
    u16*   Wt2     = (u16*)take((size_t)256 * 256 * 2);
    u16*   Wfold   = (u16*)take((size_t)C_ * 256 * 512 * 2);   // 4 MB
    float* biasF   = (float*)take((size_t)C_ * 256 * 4);
    u16*   CAW1    = (u16*)take((size_t)5 * 8192 * 2);         // bf16 [5][256][32]
    u16*   CAW2    = (u16*)take((size_t)5 * 8192 * 2);         // bf16 [5][32][256]

    const size_t slab = (size_t)SZ_ * 2;                       // bf16: 5.12 MB
    size_t avail = (ws_size > o) ? (ws_size - o) : 0;
    int Cc = (int)(avail / (3 * slab + 768));
    if (Cc > C_) Cc = C_;
    if (Cc < 1) Cc = 1;
    u16* BufH = (u16*)take((size_t)Cc * slab);
    u16* BufY = (u16*)take((size_t)Cc * slab);
    u16* BufA = (u16*)take((size_t)Cc * slab);
    (void)in_sizes; (void)n_in; (void)out_size;

    auto S = [&](int s) { return stats + (size_t)s * 8192; };
    auto Q = [&](int s) { return stats + (size_t)s * 8192 + 4096; };

    hipMemsetAsync(stats, 0, 6 * 8192 * 4, stream);
    hipMemsetAsync(cnt, 0, N_ * 4, stream);
    hipMemsetAsync(cfgpos, 0xFF, N_ * 4, stream);

    // shared prep
    tbl_k<<<144, 256, 0, stream>>>(embL, lin1W, T);
    feat_k<<<N_, 192, 0, stream>>>(xfeat, xlay, xop, embL, embO, feat162);
    wpack_k<<<176, 256, 0, stream>>>(lin1W, W162);
    wt2_k<<<256, 256, 0, stream>>>(lin2W, Wt2);
    packbf_k<<<32, 256, 0, stream>>>(ca1W1, CAW1 + 0 * 8192, 8192);
    packbf_k<<<32, 256, 0, stream>>>(ca2W1, CAW1 + 1 * 8192, 8192);
    packbf_k<<<32, 256, 0, stream>>>(scaW1 + 0 * 8192, CAW1 + 2 * 8192, 8192);
    packbf_k<<<32, 256, 0, stream>>>(scaW1 + 1 * 8192, CAW1 + 3 * 8192, 8192);
    packbf_k<<<32, 256, 0, stream>>>(scaW1 + 2 * 8192, CAW1 + 4 * 8192, 8192);
    packbf_k<<<32, 256, 0, stream>>>(ca1W2, CAW2 + 0 * 8192, 8192);
    packbf_k<<<32, 256, 0, stream>>>(ca2W2, CAW2 + 1 * 8192, 8192);
    packbf_k<<<32, 256, 0, stream>>>(scaW2 + 0 * 8192, CAW2 + 2 * 8192, 8192);
    packbf_k<<<32, 256, 0, stream>>>(scaW2 + 1 * 8192, CAW2 + 3 * 8192, 8192);
    packbf_k<<<32, 256, 0, stream>>>(scaW2 + 2 * 8192, CAW2 + 4 * 8192, 8192);
    cfgpos_k<<<(NC_ + 255) / 256, 256, 0, stream>>>(ncid, cfgpos);
    hist_k<<<(E_ + 255) / 256, 256, 0, stream>>>(ei, cnt);
    scan_k<<<1, 1024, 0, stream>>>(cnt, off, cursor, invcnt);
    fill_k<<<(E_ + 255) / 256, 256, 0, stream>>>(ei, cursor, csr);

    // base = feat162 @ W162 + lin1_b (fp32, one-time)
    gemm_k<<<dim3(2, 79, 1), 256, 0, stream>>>(feat162, 176, W162, 176, lin1b, base, N_);

    // ---- per-config-chunk pipeline ----
    for (int c0 = 0; c0 < C_; c0 += Cc) {
        const int nc = (C_ - c0 < Cc) ? (C_ - c0) : Cc;
        const int co = c0 * 256;

        lin1_k<<<dim3(625, 1, nc), 256, 0, stream>>>(
            base, T, cfgpos, xcfg + (size_t)c0 * NC_ * 18, BufH, S(0) + co, Q(0) + co);
        finstat_k<<<nc, 256, 0, stream>>>(S(0) + co, Q(0) + co, MU + co, RS + co);

        apply_k<1, 0, 0><<<dim3(625, 1, nc), 256, 0, stream>>>(
            BufH, BufH, nullptr, CAW1 + 0 * 8192, ca1b1, CAW2 + 0 * 8192, ca1b2,
            MU + co, RS + co, nullptr, nullptr);

        mgemm_k<1><<<dim3(2, 79, nc), 256, 0, stream>>>(
            BufH, SZ_, nullptr, 0, Wt2, 0, 256, 256,
            lin2b, 0, BufY, SZ_, N_, S(1) + co, Q(1) + co);
        finstat_k<<<nc, 256, 0, stream>>>(S(1) + co, Q(1) + co, MU + 4096 + co, RS + 4096 + co);

        apply_k<1, 0, 1><<<dim3(625, 1, nc), 256, 0, stream>>>(
            BufY, BufY, nullptr, CAW1 + 1 * 8192, ca2b1, CAW2 + 1 * 8192, ca2b2,
            MU + 4096 + co, RS + 4096 + co, S(2) + co, Q(2) + co);

        for (int i = 0; i < 3; ++i) {
            const int set = 2 + i;
            finstat_k<<<nc, 256, 0, stream>>>(S(set) + co, Q(set) + co,
                                              MU + set * 4096 + co, RS + set * 4096 + co);
            foldw_k<<<dim3(256, nc), 256, 0, stream>>>(
                sageWl + (size_t)i * 65536, sageWr + (size_t)i * 65536, sagebl + i * 256,
                MU + set * 4096 + co, RS + set * 4096 + co,
                Wfold + (size_t)c0 * 256 * 512, biasF + co);
            agg_k<<<nc * 2500, 256, 0, stream>>>(BufY, off, csr, invcnt,
                                                 MU + set * 4096 + co, BufA);
            mgemm_k<0><<<dim3(2, 79, nc), 256, 0, stream>>>(
                BufA, SZ_, BufY, SZ_, Wfold + (size_t)c0 * 256 * 512, 256 * 512, 256, 512,
                biasF + co, 256, BufH, SZ_, N_, nullptr, nullptr);
            if (i < 2) {
                apply_k<0, 1, 1><<<dim3(625, 1, nc), 256, 0, stream>>>(
                    BufH, BufY, BufY,
                    CAW1 + (2 + i) * 8192, scab1 + i * 32,
                    CAW2 + (2 + i) * 8192, scab2 + i * 256,
                    nullptr, nullptr, S(3 + i) + co, Q(3 + i) + co);
            } else {
                apply_k<0, 1, 2><<<dim3(625, 1, nc), 256, 0, stream>>>(
                    BufH, BufY, BufY,
                    CAW1 + (2 + i) * 8192, scab1 + i * 32,
                    CAW2 + (2 + i) * 8192, scab2 + i * 256,
                    nullptr, nullptr, S(5) + co, nullptr);
            }
        }
    }

    cls_k<<<16, 256, 0, stream>>>(S(5), clsW, clsb, out);
}

// Round 5
// 1552.432 us; speedup vs baseline: 2.4450x; 1.0495x over previous
//
#include <hip/hip_runtime.h>
#include <math.h>

// ---------------- problem constants ----------------
constexpr int C_  = 16;
constexpr int N_  = 10000;
constexpr int NC_ = 2000;
constexpr int E_  = 50000;
constexpr int D_  = 256;
constexpr int SZ_ = N_ * D_;          // per-config slab (elements)
constexpr float EPS_ = 1e-5f;

typedef unsigned short u16;
typedef __attribute__((ext_vector_type(8))) unsigned short us8v;
typedef __attribute__((ext_vector_type(4))) unsigned short us4v;
typedef __attribute__((ext_vector_type(8))) short s16x8;
typedef __attribute__((ext_vector_type(4))) float f32x4;

__device__ __forceinline__ u16 f2bf(float f) {
    unsigned u = __float_as_uint(f);
    u += 0x7fffu + ((u >> 16) & 1u);
    return (u16)(u >> 16);
}
__device__ __forceinline__ float bf2f(u16 h) {
    return __uint_as_float(((unsigned)h) << 16);
}
// fast gelu: erf via Abramowitz-Stegun 7.1.26 (|err|<=1.5e-7) + hw exp
__device__ __forceinline__ float gelu_f(float x) {
    float z = x * 0.70710678118654752f;
    float az = fabsf(z);
    float t = 1.f / fmaf(0.3275911f, az, 1.f);
    float p = t * (0.254829592f + t * (-0.284496736f + t * (1.421413741f +
              t * (-1.453152027f + t * 1.061405429f))));
    float e = p * __expf(-z * z);
    float erfv = (z >= 0.f) ? (1.f - e) : (e - 1.f);
    return 0.5f * x * (1.f + erfv);
}

// ---------------- tiny prep kernels ----------------

__global__ __launch_bounds__(256) void tbl_k(const float* __restrict__ embL,
                                             const float* __restrict__ W,
                                             float* __restrict__ T) {
    int b = blockIdx.x;            // 0..143
    int s = b >> 3, i = b & 7, d = threadIdx.x;
    float acc = 0.f;
#pragma unroll
    for (int k = 0; k < 4; ++k)
        acc = fmaf(embL[i * 4 + k], W[(134 + s * 4 + k) * 256 + d], acc);
    T[(s * 8 + i) * 256 + d] = acc;
}

// csum[d] = sum_s T[s][0][d]  (the table-sum for unconfigured nodes)
__global__ __launch_bounds__(256) void csum_k(const float* __restrict__ T,
                                              float* __restrict__ cs) {
    int d = threadIdx.x;
    float a = 0.f;
#pragma unroll
    for (int s = 0; s < 18; ++s) a += T[(s * 8) * 256 + d];
    cs[d] = a;
}

__global__ __launch_bounds__(192) void feat_k(const float* __restrict__ xf,
                                              const int* __restrict__ xlay,
                                              const int* __restrict__ xop,
                                              const float* __restrict__ embL,
                                              const float* __restrict__ embO,
                                              float* __restrict__ f) {
    int n = blockIdx.x, j = threadIdx.x;
    if (j >= 176) return;
    float v;
    if (j < 134) v = xf[n * 134 + j];
    else if (j < 158) { int q = j - 134; int t = q >> 2, k = q & 3; v = embL[(xlay[n * 6 + t] + 2) * 4 + k]; }
    else if (j < 162) { int k = j - 158; v = embO[xop[n] * 4 + k]; }
    else v = 0.f;
    f[n * 176 + j] = v;
}

__global__ __launch_bounds__(256) void wpack_k(const float* __restrict__ W,
                                               float* __restrict__ Wp) {
    int j = blockIdx.x, d = threadIdx.x;
    float v = 0.f;
    if (j < 134) v = W[j * 256 + d];
    else if (j < 158) v = W[(206 + j - 134) * 256 + d];
    else if (j < 162) v = W[(230 + j - 158) * 256 + d];
    Wp[j * 256 + d] = v;
}

// pack channel-attn W1 [256][32] into MFMA fragment order (see apply_k phase B)
__global__ __launch_bounds__(256) void packw1_k(const float* __restrict__ W1,
                                                u16* __restrict__ dst) {
    int i = blockIdx.x * 256 + threadIdx.x;    // 0..8191
    int j = i & 7, lane = (i >> 3) & 63, half = (i >> 9) & 1, ks = (i >> 10) & 1, wid = (i >> 11) & 3;
    int k = wid * 64 + ks * 32 + ((lane >> 4) << 3) + j;
    int col = half * 16 + (lane & 15);
    dst[i] = f2bf(W1[k * 32 + col]);
}
// pack channel-attn W2 [32][256] into MFMA fragment order (see apply_k phase C)
__global__ __launch_bounds__(256) void packw2_k(const float* __restrict__ W2,
                                                u16* __restrict__ dst) {
    int i = blockIdx.x * 256 + threadIdx.x;    // 0..8191
    int j = i & 7, lane = (i >> 3) & 63, q = (i >> 9) & 3, wid = (i >> 11) & 3;
    int kq = lane >> 4, cl = lane & 15;
    dst[i] = f2bf(W2[(kq * 8 + j) * 256 + (wid * 4 + q) * 16 + cl]);
}

__global__ __launch_bounds__(256) void cfgpos_k(const int* __restrict__ ncid,
                                                int* __restrict__ cfgpos) {
    int i = blockIdx.x * 256 + threadIdx.x;
    if (i < NC_) cfgpos[ncid[i]] = i;
}

__global__ __launch_bounds__(256) void hist_k(const int* __restrict__ ei, int* __restrict__ cnt) {
    int e = blockIdx.x * 256 + threadIdx.x;
    if (e < E_) atomicAdd(&cnt[ei[E_ + e]], 1);
}

__global__ __launch_bounds__(1024) void scan_k(const int* __restrict__ cnt,
                                               int* __restrict__ off,
                                               int* __restrict__ cursor,
                                               float* __restrict__ invcnt) {
    __shared__ int s[1024];
    int t = threadIdx.x;
    int base = t * 10;
    int local[10];
    int part = 0;
#pragma unroll
    for (int k = 0; k < 10; ++k) {
        int idx = base + k;
        int v = (idx < N_) ? cnt[idx] : 0;
        local[k] = v; part += v;
    }
    s[t] = part;
    __syncthreads();
    for (int o = 1; o < 1024; o <<= 1) {
        int val = (t >= o) ? s[t - o] : 0;
        __syncthreads();
        s[t] += val;
        __syncthreads();
    }
    int pre = s[t] - part;
#pragma unroll
    for (int k = 0; k < 10; ++k) {
        int idx = base + k;
        if (idx < N_) {
            off[idx] = pre;
            cursor[idx] = pre;
            invcnt[idx] = 1.0f / (float)(local[k] > 1 ? local[k] : 1);
            pre += local[k];
        }
    }
    if (t == 1023) off[N_] = s[1023];
}

__global__ __launch_bounds__(256) void fill_k(const int* __restrict__ ei,
                                              int* __restrict__ cursor,
                                              int* __restrict__ csr) {
    int e = blockIdx.x * 256 + threadIdx.x;
    if (e < E_) {
        int t = ei[E_ + e];
        int p = atomicAdd(&cursor[t], 1);
        csr[p] = ei[e];
    }
}

// transpose lin2_W -> Wt2[j][k] bf16
__global__ __launch_bounds__(256) void wt2_k(const float* __restrict__ W,
                                             u16* __restrict__ Wt) {
    int j = blockIdx.x, k = threadIdx.x;
    Wt[j * 256 + k] = f2bf(W[k * 256 + j]);
}

// fold instance-norm into sage weights (per config)
__global__ __launch_bounds__(256) void foldw_k(const float* __restrict__ Wl,
                                               const float* __restrict__ Wr,
                                               const float* __restrict__ bl,
                                               const float* __restrict__ mu,
                                               const float* __restrict__ rs,
                                               u16* __restrict__ Wt,
                                               float* __restrict__ biasF) {
    __shared__ float red[256];
    int c = blockIdx.y, j = blockIdx.x, k = threadIdx.x;
    float rsv = rs[c * 256 + k], muv = mu[c * 256 + k];
    float fl = rsv * Wl[k * 256 + j];
    float fr = rsv * Wr[k * 256 + j];
    size_t wb = ((size_t)c * 256 + j) * 512;
    Wt[wb + k] = f2bf(fl);
    Wt[wb + 256 + k] = f2bf(fr);
    red[k] = muv * (fl + fr);
    __syncthreads();
    for (int s = 128; s > 0; s >>= 1) {
        if (k < s) red[k] += red[k + s];
        __syncthreads();
    }
    if (k == 0) biasF[c * 256 + j] = bl[j] - red[0];
}

// ---------------- lin1 (configured nodes): via ncid list, LDS idx, 4-row ILP ----------------
__global__ __launch_bounds__(256) void lin1_cfg_k(const float* __restrict__ base,
                                                  const float* __restrict__ T,
                                                  const int* __restrict__ ncid,
                                                  const int* __restrict__ xcfg,
                                                  u16* __restrict__ H,
                                                  float* __restrict__ ssum,
                                                  float* __restrict__ ssq) {
    __shared__ int idxs[16][18];   // premultiplied by 256
    __shared__ int nid[16];
    const int c = blockIdx.z, j0 = blockIdx.x * 16, tid = threadIdx.x;
    if (tid < 16) nid[tid] = ncid[j0 + tid];
    for (int t = tid; t < 288; t += 256) {
        int row = t / 18, s = t - row * 18;
        idxs[row][s] = (xcfg[((size_t)c * NC_ + j0 + row) * 18 + s] + 2) * 256;
    }
    __syncthreads();
    const int d = tid;
    float psum = 0.f, psq = 0.f;
    for (int g = 0; g < 16; g += 4) {
        float acc[4];
#pragma unroll
        for (int gg = 0; gg < 4; ++gg) acc[gg] = base[(size_t)nid[g + gg] * 256 + d];
#pragma unroll
        for (int s = 0; s < 18; ++s) {
            const float* Ts = &T[s * 2048 + d];
#pragma unroll
            for (int gg = 0; gg < 4; ++gg)
                acc[gg] += Ts[idxs[g + gg][s]];
        }
#pragma unroll
        for (int gg = 0; gg < 4; ++gg) {
            H[((size_t)c * N_ + nid[g + gg]) * 256 + d] = f2bf(acc[gg]);
            psum += acc[gg]; psq += acc[gg] * acc[gg];
        }
    }
    atomicAdd(&ssum[c * 256 + d], psum);
    atomicAdd(&ssq[c * 256 + d], psq);
}

// ---------------- lin1 (unconfigured nodes): base+csum broadcast to all configs ----------------
__global__ __launch_bounds__(256) void lin1_unc_k(const float* __restrict__ base,
                                                  const float* __restrict__ csum,
                                                  const int* __restrict__ cfgpos,
                                                  int nc,
                                                  u16* __restrict__ H,
                                                  float* __restrict__ ssum,
                                                  float* __restrict__ ssq) {
    __shared__ float red[2048];
    const int n0 = blockIdx.x * 16, tid = threadIdx.x;
    float ps[8] = {0, 0, 0, 0, 0, 0, 0, 0}, pq[8] = {0, 0, 0, 0, 0, 0, 0, 0};
#pragma unroll
    for (int it = 0; it < 2; ++it) {
        const int flat = tid + it * 256;
        const int row = flat >> 5, cb = (flat & 31) * 8;
        const int n = n0 + row;
        if (cfgpos[n] >= 0) continue;
        us8v b;
#pragma unroll
        for (int j = 0; j < 8; ++j) {
            float v = base[(size_t)n * 256 + cb + j] + csum[cb + j];
            b[j] = f2bf(v);
            ps[j] += v; pq[j] += v * v;
        }
        for (int c = 0; c < nc; ++c)
            *(us8v*)&H[((size_t)c * N_ + n) * 256 + cb] = b;
    }
#pragma unroll
    for (int j = 0; j < 8; ++j)
        red[((tid >> 5) * 32 + (tid & 31)) * 8 + j] = ps[j];
    __syncthreads();
    {
        const int cb2 = tid >> 3, j2 = tid & 7;
        float s = 0.f;
#pragma unroll
        for (int r8 = 0; r8 < 8; ++r8) s += red[(r8 * 32 + cb2) * 8 + j2];
        for (int c = 0; c < nc; ++c) atomicAdd(&ssum[c * 256 + tid], s);
    }
    __syncthreads();
#pragma unroll
    for (int j = 0; j < 8; ++j)
        red[((tid >> 5) * 32 + (tid & 31)) * 8 + j] = pq[j];
    __syncthreads();
    {
        const int cb2 = tid >> 3, j2 = tid & 7;
        float s = 0.f;
#pragma unroll
        for (int r8 = 0; r8 < 8; ++r8) s += red[(r8 * 32 + cb2) * 8 + j2];
        for (int c = 0; c < nc; ++c) atomicAdd(&ssq[c * 256 + tid], s);
    }
}

__global__ __launch_bounds__(256) void finstat_k(const float* __restrict__ ssum,
                                                 const float* __restrict__ ssq,
                                                 float* __restrict__ mu,
                                                 float* __restrict__ rs) {
    int i = blockIdx.x * 256 + threadIdx.x;
    float m = ssum[i] * (1.0f / (float)N_);
    float v = ssq[i] * (1.0f / (float)N_) - m * m;
    mu[i] = m;
    rs[i] = rsqrtf(v + EPS_);
}

// ---------------- CSR gather-mean (raw mean; mu for deg-0 rows) ----------------
__global__ __launch_bounds__(256) void agg_k(const u16* __restrict__ H,
                                             const int* __restrict__ off,
                                             const int* __restrict__ csr,
                                             const float* __restrict__ invcnt,
                                             const float* __restrict__ mu,
                                             u16* __restrict__ Agg) {
    int wave = threadIdx.x >> 6, lane = threadIdx.x & 63;
    int pair = blockIdx.x * 4 + wave;
    int c = pair / N_, t = pair - c * N_;
    int d4 = lane * 4;
    int o0 = off[t], o1 = off[t + 1];
    float ax = 0.f, ay = 0.f, az = 0.f, aw = 0.f;
    for (int i = o0; i < o1; ++i) {
        int s = csr[i];
        us4v hv = *(const us4v*)&H[((size_t)c * N_ + s) * 256 + d4];
        ax += bf2f(hv.x); ay += bf2f(hv.y); az += bf2f(hv.z); aw += bf2f(hv.w);
    }
    us4v o;
    if (o1 > o0) {
        float inv = invcnt[t];
        o.x = f2bf(ax * inv); o.y = f2bf(ay * inv);
        o.z = f2bf(az * inv); o.w = f2bf(aw * inv);
    } else {
        o.x = f2bf(mu[c * 256 + d4 + 0]);
        o.y = f2bf(mu[c * 256 + d4 + 1]);
        o.z = f2bf(mu[c * 256 + d4 + 2]);
        o.w = f2bf(mu[c * 256 + d4 + 3]);
    }
    *(us4v*)&Agg[((size_t)c * N_ + t) * 256 + d4] = o;
}

// ---------------- bf16 MFMA GEMM: Y = [A1|A2] @ Wt^T + bias ----------------
template <int STATS>
__global__ __launch_bounds__(256) void mgemm_k(
    const u16* __restrict__ A1, size_t sA1,
    const u16* __restrict__ A2, size_t sA2,
    const u16* __restrict__ Wt, size_t sW, int K1, int Ktot,
    const float* __restrict__ bias, size_t sBias,
    u16* __restrict__ Y, size_t sY, int Mrows,
    float* __restrict__ ssum, float* __restrict__ ssq)
{
    __shared__ u16 Asm[128 * 64];
    __shared__ u16 Bsm[128 * 64];
    const int tid = threadIdx.x;
    const int lane = tid & 63, wid = tid >> 6;
    const int wr = wid >> 1, wc = wid & 1;
    const int c = blockIdx.z;
    const int rowbase = blockIdx.y * 128, colbase = blockIdx.x * 128;

    const u16* A1p = A1 + (size_t)c * sA1;
    const u16* A2p = A2 ? (A2 + (size_t)c * sA2) : nullptr;
    const u16* Wp  = Wt + (size_t)c * sW;

    f32x4 acc[4][4];
#pragma unroll
    for (int i = 0; i < 4; ++i)
#pragma unroll
        for (int j = 0; j < 4; ++j) acc[i][j] = (f32x4)0.f;

    const int srow = tid >> 1;
    const int scol = (tid & 1) * 32;
    const int sgrow = rowbase + srow;

    for (int k0 = 0; k0 < Ktot; k0 += 64) {
        const u16* asrc; int ak;
        if (k0 < K1) { asrc = A1p; ak = k0; } else { asrc = A2p; ak = k0 - K1; }
        const u16* ag = asrc + (size_t)sgrow * 256 + ak + scol;
        const u16* bg = Wp + (size_t)(colbase + srow) * Ktot + k0 + scol;
#pragma unroll
        for (int i = 0; i < 4; ++i) {
            us8v av = (us8v)0;
            if (sgrow < Mrows) av = *(const us8v*)(ag + i * 8);
            *(us8v*)&Asm[(srow * 64 + scol + i * 8) ^ ((srow & 7) << 3)] = av;
            us8v bv = *(const us8v*)(bg + i * 8);
            *(us8v*)&Bsm[(srow * 64 + scol + i * 8) ^ ((srow & 7) << 3)] = bv;
        }
        __syncthreads();
#pragma unroll
        for (int ks = 0; ks < 2; ++ks) {
            s16x8 aF[4], bF[4];
            const int kk = ks * 32 + ((lane >> 4) << 3);
#pragma unroll
            for (int f = 0; f < 4; ++f) {
                int ar = wr * 64 + f * 16 + (lane & 15);
                aF[f] = *(const s16x8*)&Asm[(ar * 64 + kk) ^ ((ar & 7) << 3)];
                int br = wc * 64 + f * 16 + (lane & 15);
                bF[f] = *(const s16x8*)&Bsm[(br * 64 + kk) ^ ((br & 7) << 3)];
            }
#pragma unroll
            for (int fr = 0; fr < 4; ++fr)
#pragma unroll
                for (int fc = 0; fc < 4; ++fc)
                    acc[fr][fc] = __builtin_amdgcn_mfma_f32_16x16x32_bf16(
                        aF[fr], bF[fc], acc[fr][fc], 0, 0, 0);
        }
        __syncthreads();
    }

    float bcol[4];
#pragma unroll
    for (int fc = 0; fc < 4; ++fc)
        bcol[fc] = bias[(size_t)c * sBias + colbase + wc * 64 + fc * 16 + (lane & 15)];
    u16* Yp = Y + (size_t)c * sY;
    float ps[4] = {0, 0, 0, 0}, pq[4] = {0, 0, 0, 0};
#pragma unroll
    for (int fr = 0; fr < 4; ++fr) {
#pragma unroll
        for (int i = 0; i < 4; ++i) {
            int grow = rowbase + wr * 64 + fr * 16 + ((lane >> 4) << 2) + i;
            if (grow < Mrows) {
                size_t rb = (size_t)grow * 256 + colbase + wc * 64 + (lane & 15);
#pragma unroll
                for (int fc = 0; fc < 4; ++fc) {
                    float v = acc[fr][fc][i] + bcol[fc];
                    Yp[rb + fc * 16] = f2bf(v);
                    if (STATS) { ps[fc] += v; pq[fc] += v * v; }
                }
            }
        }
    }
    if (STATS) {
#pragma unroll
        for (int fc = 0; fc < 4; ++fc) {
            float s = ps[fc], q = pq[fc];
            s += __shfl_xor(s, 16); s += __shfl_xor(s, 32);
            q += __shfl_xor(q, 16); q += __shfl_xor(q, 32);
            if (lane < 16) {
                int col = colbase + wc * 64 + fc * 16 + lane;
                atomicAdd(&ssum[c * 256 + col], s);
                atomicAdd(&ssq[c * 256 + col], q);
            }
        }
    }
}

// ---------------- fp32 tiled GEMM (one-time base GEMM) ----------------
__global__ __launch_bounds__(256) void gemm_k(const float* __restrict__ A1, int lda1,
                                              const float* __restrict__ W1, int K1,
                                              const float* __restrict__ bias,
                                              float* __restrict__ Y, int Mrows) {
    __shared__ float As[16][132];
    __shared__ float Bs[16][132];
    float acc[8][8];
#pragma unroll
    for (int i = 0; i < 8; ++i)
#pragma unroll
        for (int j = 0; j < 8; ++j) acc[i][j] = 0.f;

    const int tid = threadIdx.x;
    const int tr = tid >> 4, tc = tid & 15;
    const int rowbase = blockIdx.y * 128, colbase = blockIdx.x * 128;

    for (int k0 = 0; k0 < K1; k0 += 16) {
#pragma unroll
        for (int ii = 0; ii < 2; ++ii) {
            int i = tid + ii * 256;
            int rr = i >> 2, qq = i & 3;
            int grow = rowbase + rr;
            float4 vv = make_float4(0.f, 0.f, 0.f, 0.f);
            if (grow < Mrows) vv = *(const float4*)&A1[(size_t)grow * lda1 + k0 + qq * 4];
            As[qq * 4 + 0][rr] = vv.x;
            As[qq * 4 + 1][rr] = vv.y;
            As[qq * 4 + 2][rr] = vv.z;
            As[qq * 4 + 3][rr] = vv.w;
        }
#pragma unroll
        for (int ii = 0; ii < 2; ++ii) {
            int i = tid + ii * 256;
            int rr = i >> 5, qq = i & 31;
            float4 vv = *(const float4*)&W1[(size_t)(k0 + rr) * 256 + colbase + qq * 4];
            *(float4*)&Bs[rr][qq * 4] = vv;
        }
        __syncthreads();
#pragma unroll
        for (int kk = 0; kk < 16; ++kk) {
            float a[8], b[8];
            *(float4*)&a[0] = *(const float4*)&As[kk][tr * 4];
            *(float4*)&a[4] = *(const float4*)&As[kk][64 + tr * 4];
            *(float4*)&b[0] = *(const float4*)&Bs[kk][tc * 4];
            *(float4*)&b[4] = *(const float4*)&Bs[kk][64 + tc * 4];
#pragma unroll
            for (int i = 0; i < 8; ++i)
#pragma unroll
                for (int j = 0; j < 8; ++j)
                    acc[i][j] = fmaf(a[i], b[j], acc[i][j]);
        }
        __syncthreads();
    }

    float4 blo = *(const float4*)&bias[colbase + tc * 4];
    float4 bhi = *(const float4*)&bias[colbase + 64 + tc * 4];
    float bb[8] = {blo.x, blo.y, blo.z, blo.w, bhi.x, bhi.y, bhi.z, bhi.w};
#pragma unroll
    for (int i = 0; i < 8; ++i)
#pragma unroll
        for (int j = 0; j < 8; ++j) acc[i][j] += bb[j];

#pragma unroll
    for (int i = 0; i < 8; ++i) {
        int lrow = (i < 4) ? (tr * 4 + i) : (64 + tr * 4 + (i - 4));
        int grow = rowbase + lrow;
        if (grow < Mrows) {
            *(float4*)&Y[(size_t)grow * 256 + colbase + tc * 4] =
                make_float4(acc[i][0], acc[i][1], acc[i][2], acc[i][3]);
            *(float4*)&Y[(size_t)grow * 256 + colbase + 64 + tc * 4] =
                make_float4(acc[i][4], acc[i][5], acc[i][6], acc[i][7]);
        }
    }
}

// ---------------- per-row epilogue with MFMA channel-attention ----------------
// A: vectorized load+norm -> B: t=relu(x@W1+b1) MFMA (packed frags) ->
// C: y=t@W2 MFMA fused sigmoid*x (+res) gelu -> D: vectorized store+stats
template <int NORM, int RES, int SMODE>
__global__ __launch_bounds__(256) void apply_k(const u16* __restrict__ Yin,
                                               u16* __restrict__ Hout,
                                               const u16* __restrict__ Hsc,
                                               const u16* __restrict__ W1p,
                                               const float* __restrict__ b1,
                                               const u16* __restrict__ W2p,
                                               const float* __restrict__ b2,
                                               const float* __restrict__ mu,
                                               const float* __restrict__ rs,
                                               float* __restrict__ ssum,
                                               float* __restrict__ ssq) {
    __shared__ u16 vbf[16 * 264];
    __shared__ u16 scs[(RES ? 16 : 1) * 264];
    __shared__ float tpart[4 * 512];
    __shared__ u16 tbf[16 * 40];
    const int c = blockIdx.z, n0 = blockIdx.x * 16, tid = threadIdx.x;
    const int lane = tid & 63, wid = tid >> 6;
    const size_t rowbase = ((size_t)c * N_ + n0) * 256;

    // phase A: vectorized load + normalize
#pragma unroll
    for (int it = 0; it < 2; ++it) {
        const int flat = tid + it * 256;
        const int row = flat >> 5, cb = (flat & 31) * 8;
        us8v x = *(const us8v*)&Yin[rowbase + row * 256 + cb];
        if (NORM) {
            us8v y;
#pragma unroll
            for (int j = 0; j < 8; ++j)
                y[j] = f2bf((bf2f(x[j]) - mu[c * 256 + cb + j]) * rs[c * 256 + cb + j]);
            *(us8v*)&vbf[row * 264 + cb] = y;
        } else {
            *(us8v*)&vbf[row * 264 + cb] = x;
        }
        if (RES) *(us8v*)&scs[row * 264 + cb] = *(const us8v*)&Hsc[rowbase + row * 256 + cb];
    }
    __syncthreads();

    // phase B: t_partial = x(K-slice) @ W1, wave w owns K in [w*64, w*64+64)
    {
        const int row = lane & 15;
        const int kq = lane >> 4;
        f32x4 at0 = (f32x4)0.f, at1 = (f32x4)0.f;
#pragma unroll
        for (int ks = 0; ks < 2; ++ks) {
            const int k = wid * 64 + ks * 32 + kq * 8;
            s16x8 aF = *(const s16x8*)&vbf[row * 264 + k];
            s16x8 bF0 = *(const s16x8*)&W1p[(((wid * 2 + ks) * 2 + 0) * 64 + lane) * 8];
            s16x8 bF1 = *(const s16x8*)&W1p[(((wid * 2 + ks) * 2 + 1) * 64 + lane) * 8];
            at0 = __builtin_amdgcn_mfma_f32_16x16x32_bf16(aF, bF0, at0, 0, 0, 0);
            at1 = __builtin_amdgcn_mfma_f32_16x16x32_bf16(aF, bF1, at1, 0, 0, 0);
        }
#pragma unroll
        for (int i = 0; i < 4; ++i) {
            tpart[wid * 512 + (kq * 4 + i) * 32 + (lane & 15)] = at0[i];
            tpart[wid * 512 + (kq * 4 + i) * 32 + 16 + (lane & 15)] = at1[i];
        }
    }
    __syncthreads();

    // reduce partials across waves, +b1, relu -> tbf
#pragma unroll
    for (int ii = 0; ii < 2; ++ii) {
        int idx = tid + ii * 256;
        float s = tpart[idx] + tpart[512 + idx] + tpart[1024 + idx] + tpart[1536 + idx];
        int col = idx & 31;
        s += b1[col];
        tbf[(idx >> 5) * 40 + col] = f2bf(fmaxf(s, 0.f));
    }
    __syncthreads();

    // phase C: y = t @ W2, fused sigmoid * x (+res), gelu; write back to vbf
    {
        const int cl = lane & 15, kq = lane >> 4;
        s16x8 aF = *(const s16x8*)&tbf[cl * 40 + kq * 8];
#pragma unroll
        for (int q = 0; q < 4; ++q) {
            const int colb = (wid * 4 + q) * 16;
            s16x8 bF = *(const s16x8*)&W2p[((wid * 4 + q) * 64 + lane) * 8];
            f32x4 acc = __builtin_amdgcn_mfma_f32_16x16x32_bf16(aF, bF, (f32x4)0.f, 0, 0, 0);
            const float b2v = b2[colb + cl];
#pragma unroll
            for (int i = 0; i < 4; ++i) {
                const int row = kq * 4 + i;
                float s = acc[i] + b2v;
                float sig = 1.0f / (1.0f + __expf(-s));
                float val = sig * bf2f(vbf[row * 264 + colb + cl]);
                if (RES) val += bf2f(scs[row * 264 + colb + cl]);
                val = gelu_f(val);
                vbf[row * 264 + colb + cl] = f2bf(val);
            }
        }
    }
    __syncthreads();

    // phase D: vectorized store + per-column stats (LDS reduce)
    {
        float ps[8] = {0, 0, 0, 0, 0, 0, 0, 0}, pq[8] = {0, 0, 0, 0, 0, 0, 0, 0};
#pragma unroll
        for (int it = 0; it < 2; ++it) {
            const int flat = tid + it * 256;
            const int row = flat >> 5, cb = (flat & 31) * 8;
            us8v h = *(const us8v*)&vbf[row * 264 + cb];
            *(us8v*)&Hout[rowbase + row * 256 + cb] = h;
            if (SMODE) {
#pragma unroll
                for (int j = 0; j < 8; ++j) {
                    float v = bf2f(h[j]);
                    ps[j] += v;
                    if (SMODE == 1) pq[j] += v * v;
                }
            }
        }
        if (SMODE) {
#pragma unroll
            for (int j = 0; j < 8; ++j)
                tpart[((tid >> 5) * 32 + (tid & 31)) * 8 + j] = ps[j];
            __syncthreads();
            {
                const int cb2 = tid >> 3, j2 = tid & 7;
                float s = 0.f;
#pragma unroll
                for (int r8 = 0; r8 < 8; ++r8) s += tpart[(r8 * 32 + cb2) * 8 + j2];
                atomicAdd(&ssum[c * 256 + tid], s);
            }
            if (SMODE == 1) {
                __syncthreads();
#pragma unroll
                for (int j = 0; j < 8; ++j)
                    tpart[((tid >> 5) * 32 + (tid & 31)) * 8 + j] = pq[j];
                __syncthreads();
                const int cb2 = tid >> 3, j2 = tid & 7;
                float s = 0.f;
#pragma unroll
                for (int r8 = 0; r8 < 8; ++r8) s += tpart[(r8 * 32 + cb2) * 8 + j2];
                atomicAdd(&ssq[c * 256 + tid], s);
            }
        }
    }
}

// ---------------- classifier ----------------
__global__ __launch_bounds__(256) void cls_k(const float* __restrict__ pooled_sum,
                                             const float* __restrict__ clsW,
                                             const float* __restrict__ clsb,
                                             float* __restrict__ out) {
    __shared__ float red[256];
    int c = blockIdx.x, d = threadIdx.x;
    red[d] = pooled_sum[c * 256 + d] * (1.0f / (float)N_) * clsW[d];
    __syncthreads();
    for (int s = 128; s > 0; s >>= 1) {
        if (d < s) red[d] += red[d + s];
        __syncthreads();
    }
    if (d == 0) out[c] = red[0] + clsb[0];
}

// ---------------- host launch ----------------
static inline size_t alup(size_t x) { return (x + 255) & ~(size_t)255; }

extern "C" void kernel_launch(void* const* d_in, const int* in_sizes, int n_in,
                              void* d_out, int out_size, void* d_ws, size_t ws_size,
                              hipStream_t stream) {
    const int*   xcfg   = (const int*)d_in[0];
    const float* xfeat  = (const float*)d_in[1];
    const int*   xlay   = (const int*)d_in[2];
    const int*   xop    = (const int*)d_in[3];
    const int*   ei     = (const int*)d_in[4];
    const int*   ncid   = (const int*)d_in[5];
    const float* embO   = (const float*)d_in[6];
    const float* embL   = (const float*)d_in[7];
    const float* lin1W  = (const float*)d_in[8];
    const float* lin1b  = (const float*)d_in[9];
    const float* ca1W1  = (const float*)d_in[10];
    const float* ca1b1  = (const float*)d_in[11];
    const float* ca1W2  = (const float*)d_in[12];
    const float* ca1b2  = (const float*)d_in[13];
    const float* lin2W  = (const float*)d_in[14];
    const float* lin2b  = (const float*)d_in[15];
    const float* ca2W1  = (const float*)d_in[16];
    const float* ca2b1  = (const float*)d_in[17];
    const float* ca2W2  = (const float*)d_in[18];
    const float* ca2b2  = (const float*)d_in[19];
    const float* sageWl = (const float*)d_in[20];
    const float* sagebl = (const float*)d_in[21];
    const float* sageWr = (const float*)d_in[22];
    const float* scaW1  = (const float*)d_in[23];
    const float* scab1  = (const float*)d_in[24];
    const float* scaW2  = (const float*)d_in[25];
    const float* scab2  = (const float*)d_in[26];
    const float* clsW   = (const float*)d_in[27];
    const float* clsb   = (const float*)d_in[28];
    float* out = (float*)d_out;

    // ---- workspace carve-up ----
    char* w = (char*)d_ws;
    size_t o = 0;
    auto take = [&](size_t bytes) { char* p = w + o; o = alup(o + bytes); return p; };
    float* base    = (float*)take((size_t)N_ * 256 * 4);
    float* feat162 = (float*)take((size_t)N_ * 176 * 4);
    float* W162    = (float*)take((size_t)176 * 256 * 4);
    float* T       = (float*)take((size_t)18 * 8 * 256 * 4);
    float* csum    = (float*)take((size_t)256 * 4);
    float* stats   = (float*)take((size_t)6 * 8192 * 4);
    float* MU      = (float*)take((size_t)5 * 4096 * 4);
    float* RS      = (float*)take((size_t)5 * 4096 * 4);
    float* invcnt  = (float*)take((size_t)N_ * 4);
    int*   cnt     = (int*)take((size_t)N_ * 4);
    int*   off     = (int*)take((size_t)(N_ + 1) * 4);
    int*   cursor  = (int*)take((size_t)N_ * 4);
    int*   csr     = (int*)take((size_t)E_ * 4);
    int*   cfgpos  = (int*)take((size_t)N_ * 4);
    u16*   Wt2     = (u16*)take((size_t)256 * 256 * 2);
    u16*   Wfold   = (u16*)take((size_t)C_ * 256 * 512 * 2);   // 4 MB
    float* biasF   = (float*)take((size_t)C_ * 256 * 4);
    u16*   CAW1    = (u16*)take((size_t)5 * 8192 * 2);         // packed frag order
    u16*   CAW2    = (u16*)take((size_t)5 * 8192 * 2);

    const size_t slab = (size_t)SZ_ * 2;                       // bf16: 5.12 MB
    size_t avail = (ws_size > o) ? (ws_size - o) : 0;
    int Cc = (int)(avail / (3 * slab + 768));
    if (Cc > C_) Cc = C_;
    if (Cc < 1) Cc = 1;
    u16* BufH = (u16*)take((size_t)Cc * slab);
    u16* BufY = (u16*)take((size_t)Cc * slab);
    u16* BufA = (u16*)take((size_t)Cc * slab);
    (void)in_sizes; (void)n_in; (void)out_size;

    auto S = [&](int s) { return stats + (size_t)s * 8192; };
    auto Q = [&](int s) { return stats + (size_t)s * 8192 + 4096; };

    hipMemsetAsync(stats, 0, 6 * 8192 * 4, stream);
    hipMemsetAsync(cnt, 0, N_ * 4, stream);
    hipMemsetAsync(cfgpos, 0xFF, N_ * 4, stream);

    // shared prep
    tbl_k<<<144, 256, 0, stream>>>(embL, lin1W, T);
    csum_k<<<1, 256, 0, stream>>>(T, csum);
    feat_k<<<N_, 192, 0, stream>>>(xfeat, xlay, xop, embL, embO, feat162);
    wpack_k<<<176, 256, 0, stream>>>(lin1W, W162);
    wt2_k<<<256, 256, 0, stream>>>(lin2W, Wt2);
    packw1_k<<<32, 256, 0, stream>>>(ca1W1, CAW1 + 0 * 8192);
    packw1_k<<<32, 256, 0, stream>>>(ca2W1, CAW1 + 1 * 8192);
    packw1_k<<<32, 256, 0, stream>>>(scaW1 + 0 * 8192, CAW1 + 2 * 8192);
    packw1_k<<<32, 256, 0, stream>>>(scaW1 + 1 * 8192, CAW1 + 3 * 8192);
    packw1_k<<<32, 256, 0, stream>>>(scaW1 + 2 * 8192, CAW1 + 4 * 8192);
    packw2_k<<<32, 256, 0, stream>>>(ca1W2, CAW2 + 0 * 8192);
    packw2_k<<<32, 256, 0, stream>>>(ca2W2, CAW2 + 1 * 8192);
    packw2_k<<<32, 256, 0, stream>>>(scaW2 + 0 * 8192, CAW2 + 2 * 8192);
    packw2_k<<<32, 256, 0, stream>>>(scaW2 + 1 * 8192, CAW2 + 3 * 8192);
    packw2_k<<<32, 256, 0, stream>>>(scaW2 + 2 * 8192, CAW2 + 4 * 8192);
    cfgpos_k<<<(NC_ + 255) / 256, 256, 0, stream>>>(ncid, cfgpos);
    hist_k<<<(E_ + 255) / 256, 256, 0, stream>>>(ei, cnt);
    scan_k<<<1, 1024, 0, stream>>>(cnt, off, cursor, invcnt);
    fill_k<<<(E_ + 255) / 256, 256, 0, stream>>>(ei, cursor, csr);

    // base = feat162 @ W162 + lin1_b (fp32, one-time)
    gemm_k<<<dim3(2, 79, 1), 256, 0, stream>>>(feat162, 176, W162, 176, lin1b, base, N_);

    // ---- per-config-chunk pipeline ----
    for (int c0 = 0; c0 < C_; c0 += Cc) {
        const int nc = (C_ - c0 < Cc) ? (C_ - c0) : Cc;
        const int co = c0 * 256;

        lin1_cfg_k<<<dim3(NC_ / 16, 1, nc), 256, 0, stream>>>(
            base, T, ncid, xcfg + (size_t)c0 * NC_ * 18, BufH, S(0) + co, Q(0) + co);
        lin1_unc_k<<<625, 256, 0, stream>>>(
            base, csum, cfgpos, nc, BufH, S(0) + co, Q(0) + co);
        finstat_k<<<nc, 256, 0, stream>>>(S(0) + co, Q(0) + co, MU + co, RS + co);

        apply_k<1, 0, 0><<<dim3(625, 1, nc), 256, 0, stream>>>(
            BufH, BufH, nullptr, CAW1 + 0 * 8192, ca1b1, CAW2 + 0 * 8192, ca1b2,
            MU + co, RS + co, nullptr, nullptr);

        mgemm_k<1><<<dim3(2, 79, nc), 256, 0, stream>>>(
            BufH, SZ_, nullptr, 0, Wt2, 0, 256, 256,
            lin2b, 0, BufY, SZ_, N_, S(1) + co, Q(1) + co);
        finstat_k<<<nc, 256, 0, stream>>>(S(1) + co, Q(1) + co, MU + 4096 + co, RS + 4096 + co);

        apply_k<1, 0, 1><<<dim3(625, 1, nc), 256, 0, stream>>>(
            BufY, BufY, nullptr, CAW1 + 1 * 8192, ca2b1, CAW2 + 1 * 8192, ca2b2,
            MU + 4096 + co, RS + 4096 + co, S(2) + co, Q(2) + co);

        for (int i = 0; i < 3; ++i) {
            const int set = 2 + i;
            finstat_k<<<nc, 256, 0, stream>>>(S(set) + co, Q(set) + co,
                                              MU + set * 4096 + co, RS + set * 4096 + co);
            foldw_k<<<dim3(256, nc), 256, 0, stream>>>(
                sageWl + (size_t)i * 65536, sageWr + (size_t)i * 65536, sagebl + i * 256,
                MU + set * 4096 + co, RS + set * 4096 + co,
                Wfold + (size_t)c0 * 256 * 512, biasF + co);
            agg_k<<<nc * 2500, 256, 0, stream>>>(BufY, off, csr, invcnt,
                                                 MU + set * 4096 + co, BufA);
            mgemm_k<0><<<dim3(2, 79, nc), 256, 0, stream>>>(
                BufA, SZ_, BufY, SZ_, Wfold + (size_t)c0 * 256 * 512, 256 * 512, 256, 512,
                biasF + co, 256, BufH, SZ_, N_, nullptr, nullptr);
            if (i < 2) {
                apply_k<0, 1, 1><<<dim3(625, 1, nc), 256, 0, stream>>>(
                    BufH, BufY, BufY,
                    CAW1 + (2 + i) * 8192, scab1 + i * 32,
                    CAW2 + (2 + i) * 8192, scab2 + i * 256,
                    nullptr, nullptr, S(3 + i) + co, Q(3 + i) + co);
            } else {
                apply_k<0, 1, 2><<<dim3(625, 1, nc), 256, 0, stream>>>(
                    BufH, BufY, BufY,
                    CAW1 + (2 + i) * 8192, scab1 + i * 32,
                    CAW2 + (2 + i) * 8192, scab2 + i * 256,
                    nullptr, nullptr, S(5) + co, nullptr);
            }
        }
    }

    cls_k<<<16, 256, 0, stream>>>(S(5), clsW, clsb, out);
}

// Round 6
// 1455.698 us; speedup vs baseline: 2.6075x; 1.0665x over previous
//
#include <hip/hip_runtime.h>
#include <math.h>

// ---------------- problem constants ----------------
constexpr int C_  = 16;
constexpr int N_  = 10000;
constexpr int NC_ = 2000;
constexpr int E_  = 50000;
constexpr int D_  = 256;
constexpr int SZ_ = N_ * D_;          // per-config slab (elements)
constexpr float EPS_ = 1e-5f;

typedef unsigned short u16;
typedef __attribute__((ext_vector_type(8))) unsigned short us8v;
typedef __attribute__((ext_vector_type(4))) unsigned short us4v;
typedef __attribute__((ext_vector_type(8))) short s16x8;
typedef __attribute__((ext_vector_type(4))) float f32x4;

typedef __attribute__((address_space(3))) unsigned int lds_uint;
typedef const __attribute__((address_space(1))) unsigned int glb_uint;

__device__ __forceinline__ u16 f2bf(float f) {
    unsigned u = __float_as_uint(f);
    u += 0x7fffu + ((u >> 16) & 1u);
    return (u16)(u >> 16);
}
__device__ __forceinline__ float bf2f(u16 h) {
    return __uint_as_float(((unsigned)h) << 16);
}
// fast gelu: erf via Abramowitz-Stegun 7.1.26 (|err|<=1.5e-7) + hw exp
__device__ __forceinline__ float gelu_f(float x) {
    float z = x * 0.70710678118654752f;
    float az = fabsf(z);
    float t = 1.f / fmaf(0.3275911f, az, 1.f);
    float p = t * (0.254829592f + t * (-0.284496736f + t * (1.421413741f +
              t * (-1.453152027f + t * 1.061405429f))));
    float e = p * __expf(-z * z);
    float erfv = (z >= 0.f) ? (1.f - e) : (e - 1.f);
    return 0.5f * x * (1.f + erfv);
}

// ---------------- tiny prep kernels ----------------

__global__ __launch_bounds__(256) void tbl_k(const float* __restrict__ embL,
                                             const float* __restrict__ W,
                                             float* __restrict__ T) {
    int b = blockIdx.x;            // 0..143
    int s = b >> 3, i = b & 7, d = threadIdx.x;
    float acc = 0.f;
#pragma unroll
    for (int k = 0; k < 4; ++k)
        acc = fmaf(embL[i * 4 + k], W[(134 + s * 4 + k) * 256 + d], acc);
    T[(s * 8 + i) * 256 + d] = acc;
}

// csum[d] = sum_s T[s][0][d]  (the table-sum for unconfigured nodes)
__global__ __launch_bounds__(256) void csum_k(const float* __restrict__ T,
                                              float* __restrict__ cs) {
    int d = threadIdx.x;
    float a = 0.f;
#pragma unroll
    for (int s = 0; s < 18; ++s) a += T[(s * 8) * 256 + d];
    cs[d] = a;
}

__global__ __launch_bounds__(192) void feat_k(const float* __restrict__ xf,
                                              const int* __restrict__ xlay,
                                              const int* __restrict__ xop,
                                              const float* __restrict__ embL,
                                              const float* __restrict__ embO,
                                              float* __restrict__ f) {
    int n = blockIdx.x, j = threadIdx.x;
    if (j >= 176) return;
    float v;
    if (j < 134) v = xf[n * 134 + j];
    else if (j < 158) { int q = j - 134; int t = q >> 2, k = q & 3; v = embL[(xlay[n * 6 + t] + 2) * 4 + k]; }
    else if (j < 162) { int k = j - 158; v = embO[xop[n] * 4 + k]; }
    else v = 0.f;
    f[n * 176 + j] = v;
}

__global__ __launch_bounds__(256) void wpack_k(const float* __restrict__ W,
                                               float* __restrict__ Wp) {
    int j = blockIdx.x, d = threadIdx.x;
    float v = 0.f;
    if (j < 134) v = W[j * 256 + d];
    else if (j < 158) v = W[(206 + j - 134) * 256 + d];
    else if (j < 162) v = W[(230 + j - 158) * 256 + d];
    Wp[j * 256 + d] = v;
}

// pack channel-attn W1 [256][32] into MFMA fragment order (see apply_k phase B)
__global__ __launch_bounds__(256) void packw1_k(const float* __restrict__ W1,
                                                u16* __restrict__ dst) {
    int i = blockIdx.x * 256 + threadIdx.x;    // 0..8191
    int j = i & 7, lane = (i >> 3) & 63, half = (i >> 9) & 1, ks = (i >> 10) & 1, wid = (i >> 11) & 3;
    int k = wid * 64 + ks * 32 + ((lane >> 4) << 3) + j;
    int col = half * 16 + (lane & 15);
    dst[i] = f2bf(W1[k * 32 + col]);
}
// pack channel-attn W2 [32][256] into MFMA fragment order (see apply_k phase C)
__global__ __launch_bounds__(256) void packw2_k(const float* __restrict__ W2,
                                                u16* __restrict__ dst) {
    int i = blockIdx.x * 256 + threadIdx.x;    // 0..8191
    int j = i & 7, lane = (i >> 3) & 63, q = (i >> 9) & 3, wid = (i >> 11) & 3;
    int kq = lane >> 4, cl = lane & 15;
    dst[i] = f2bf(W2[(kq * 8 + j) * 256 + (wid * 4 + q) * 16 + cl]);
}

__global__ __launch_bounds__(256) void cfgpos_k(const int* __restrict__ ncid,
                                                int* __restrict__ cfgpos) {
    int i = blockIdx.x * 256 + threadIdx.x;
    if (i < NC_) cfgpos[ncid[i]] = i;
}

__global__ __launch_bounds__(256) void hist_k(const int* __restrict__ ei, int* __restrict__ cnt) {
    int e = blockIdx.x * 256 + threadIdx.x;
    if (e < E_) atomicAdd(&cnt[ei[E_ + e]], 1);
}

__global__ __launch_bounds__(1024) void scan_k(const int* __restrict__ cnt,
                                               int* __restrict__ off,
                                               int* __restrict__ cursor,
                                               float* __restrict__ invcnt) {
    __shared__ int s[1024];
    int t = threadIdx.x;
    int base = t * 10;
    int local[10];
    int part = 0;
#pragma unroll
    for (int k = 0; k < 10; ++k) {
        int idx = base + k;
        int v = (idx < N_) ? cnt[idx] : 0;
        local[k] = v; part += v;
    }
    s[t] = part;
    __syncthreads();
    for (int o = 1; o < 1024; o <<= 1) {
        int val = (t >= o) ? s[t - o] : 0;
        __syncthreads();
        s[t] += val;
        __syncthreads();
    }
    int pre = s[t] - part;
#pragma unroll
    for (int k = 0; k < 10; ++k) {
        int idx = base + k;
        if (idx < N_) {
            off[idx] = pre;
            cursor[idx] = pre;
            invcnt[idx] = 1.0f / (float)(local[k] > 1 ? local[k] : 1);
            pre += local[k];
        }
    }
    if (t == 1023) off[N_] = s[1023];
}

__global__ __launch_bounds__(256) void fill_k(const int* __restrict__ ei,
                                              int* __restrict__ cursor,
                                              int* __restrict__ csr) {
    int e = blockIdx.x * 256 + threadIdx.x;
    if (e < E_) {
        int t = ei[E_ + e];
        int p = atomicAdd(&cursor[t], 1);
        csr[p] = ei[e];
    }
}

// transpose lin2_W -> Wt2[j][k] bf16
__global__ __launch_bounds__(256) void wt2_k(const float* __restrict__ W,
                                             u16* __restrict__ Wt) {
    int j = blockIdx.x, k = threadIdx.x;
    Wt[j * 256 + k] = f2bf(W[k * 256 + j]);
}

// fold instance-norm into sage weights (per config)
__global__ __launch_bounds__(256) void foldw_k(const float* __restrict__ Wl,
                                               const float* __restrict__ Wr,
                                               const float* __restrict__ bl,
                                               const float* __restrict__ mu,
                                               const float* __restrict__ rs,
                                               u16* __restrict__ Wt,
                                               float* __restrict__ biasF) {
    __shared__ float red[256];
    int c = blockIdx.y, j = blockIdx.x, k = threadIdx.x;
    float rsv = rs[c * 256 + k], muv = mu[c * 256 + k];
    float fl = rsv * Wl[k * 256 + j];
    float fr = rsv * Wr[k * 256 + j];
    size_t wb = ((size_t)c * 256 + j) * 512;
    Wt[wb + k] = f2bf(fl);
    Wt[wb + 256 + k] = f2bf(fr);
    red[k] = muv * (fl + fr);
    __syncthreads();
    for (int s = 128; s > 0; s >>= 1) {
        if (k < s) red[k] += red[k + s];
        __syncthreads();
    }
    if (k == 0) biasF[c * 256 + j] = bl[j] - red[0];
}

// ---------------- lin1 (configured nodes): via ncid list, LDS idx, 4-row ILP ----------------
__global__ __launch_bounds__(256) void lin1_cfg_k(const float* __restrict__ base,
                                                  const float* __restrict__ T,
                                                  const int* __restrict__ ncid,
                                                  const int* __restrict__ xcfg,
                                                  u16* __restrict__ H,
                                                  float* __restrict__ ssum,
                                                  float* __restrict__ ssq) {
    __shared__ int idxs[16][18];   // premultiplied by 256
    __shared__ int nid[16];
    const int c = blockIdx.z, j0 = blockIdx.x * 16, tid = threadIdx.x;
    if (tid < 16) nid[tid] = ncid[j0 + tid];
    for (int t = tid; t < 288; t += 256) {
        int row = t / 18, s = t - row * 18;
        idxs[row][s] = (xcfg[((size_t)c * NC_ + j0 + row) * 18 + s] + 2) * 256;
    }
    __syncthreads();
    const int d = tid;
    float psum = 0.f, psq = 0.f;
    for (int g = 0; g < 16; g += 4) {
        float acc[4];
#pragma unroll
        for (int gg = 0; gg < 4; ++gg) acc[gg] = base[(size_t)nid[g + gg] * 256 + d];
#pragma unroll
        for (int s = 0; s < 18; ++s) {
            const float* Ts = &T[s * 2048 + d];
#pragma unroll
            for (int gg = 0; gg < 4; ++gg)
                acc[gg] += Ts[idxs[g + gg][s]];
        }
#pragma unroll
        for (int gg = 0; gg < 4; ++gg) {
            H[((size_t)c * N_ + nid[g + gg]) * 256 + d] = f2bf(acc[gg]);
            psum += acc[gg]; psq += acc[gg] * acc[gg];
        }
    }
    atomicAdd(&ssum[c * 256 + d], psum);
    atomicAdd(&ssq[c * 256 + d], psq);
}

// ---------------- lin1 (unconfigured nodes): base+csum broadcast to all configs ----------------
__global__ __launch_bounds__(256) void lin1_unc_k(const float* __restrict__ base,
                                                  const float* __restrict__ csum,
                                                  const int* __restrict__ cfgpos,
                                                  int nc,
                                                  u16* __restrict__ H,
                                                  float* __restrict__ ssum,
                                                  float* __restrict__ ssq) {
    __shared__ float red[2048];
    const int n0 = blockIdx.x * 16, tid = threadIdx.x;
    float ps[8] = {0, 0, 0, 0, 0, 0, 0, 0}, pq[8] = {0, 0, 0, 0, 0, 0, 0, 0};
#pragma unroll
    for (int it = 0; it < 2; ++it) {
        const int flat = tid + it * 256;
        const int row = flat >> 5, cb = (flat & 31) * 8;
        const int n = n0 + row;
        if (cfgpos[n] >= 0) continue;
        us8v b;
#pragma unroll
        for (int j = 0; j < 8; ++j) {
            float v = base[(size_t)n * 256 + cb + j] + csum[cb + j];
            b[j] = f2bf(v);
            ps[j] += v; pq[j] += v * v;
        }
        for (int c = 0; c < nc; ++c)
            *(us8v*)&H[((size_t)c * N_ + n) * 256 + cb] = b;
    }
#pragma unroll
    for (int j = 0; j < 8; ++j)
        red[((tid >> 5) * 32 + (tid & 31)) * 8 + j] = ps[j];
    __syncthreads();
    {
        const int cb2 = tid >> 3, j2 = tid & 7;
        float s = 0.f;
#pragma unroll
        for (int r8 = 0; r8 < 8; ++r8) s += red[(r8 * 32 + cb2) * 8 + j2];
        for (int c = 0; c < nc; ++c) atomicAdd(&ssum[c * 256 + tid], s);
    }
    __syncthreads();
#pragma unroll
    for (int j = 0; j < 8; ++j)
        red[((tid >> 5) * 32 + (tid & 31)) * 8 + j] = pq[j];
    __syncthreads();
    {
        const int cb2 = tid >> 3, j2 = tid & 7;
        float s = 0.f;
#pragma unroll
        for (int r8 = 0; r8 < 8; ++r8) s += red[(r8 * 32 + cb2) * 8 + j2];
        for (int c = 0; c < nc; ++c) atomicAdd(&ssq[c * 256 + tid], s);
    }
}

__global__ __launch_bounds__(256) void finstat_k(const float* __restrict__ ssum,
                                                 const float* __restrict__ ssq,
                                                 float* __restrict__ mu,
                                                 float* __restrict__ rs) {
    int i = blockIdx.x * 256 + threadIdx.x;
    float m = ssum[i] * (1.0f / (float)N_);
    float v = ssq[i] * (1.0f / (float)N_) - m * m;
    mu[i] = m;
    rs[i] = rsqrtf(v + EPS_);
}

// ---------------- CSR gather-mean (raw mean; mu for deg-0 rows) ----------------
__global__ __launch_bounds__(256) void agg_k(const u16* __restrict__ H,
                                             const int* __restrict__ off,
                                             const int* __restrict__ csr,
                                             const float* __restrict__ invcnt,
                                             const float* __restrict__ mu,
                                             u16* __restrict__ Agg) {
    int wave = threadIdx.x >> 6, lane = threadIdx.x & 63;
    int pair = blockIdx.x * 4 + wave;
    int c = pair / N_, t = pair - c * N_;
    int d4 = lane * 4;
    int o0 = off[t], o1 = off[t + 1];
    float ax = 0.f, ay = 0.f, az = 0.f, aw = 0.f;
    for (int i = o0; i < o1; ++i) {
        int s = csr[i];
        us4v hv = *(const us4v*)&H[((size_t)c * N_ + s) * 256 + d4];
        ax += bf2f(hv.x); ay += bf2f(hv.y); az += bf2f(hv.z); aw += bf2f(hv.w);
    }
    us4v o;
    if (o1 > o0) {
        float inv = invcnt[t];
        o.x = f2bf(ax * inv); o.y = f2bf(ay * inv);
        o.z = f2bf(az * inv); o.w = f2bf(aw * inv);
    } else {
        o.x = f2bf(mu[c * 256 + d4 + 0]);
        o.y = f2bf(mu[c * 256 + d4 + 1]);
        o.z = f2bf(mu[c * 256 + d4 + 2]);
        o.w = f2bf(mu[c * 256 + d4 + 3]);
    }
    *(us4v*)&Agg[((size_t)c * N_ + t) * 256 + d4] = o;
}

// ---------------- bf16 MFMA GEMM: Y = [A1|A2] @ Wt^T + bias ----------------
// global_load_lds(16B) staging with pre-swizzled source chunks (linear LDS dest);
// read side applies the XOR swizzle. XCD-aware bijective block remap.
template <int STATS>
__global__ __launch_bounds__(256) void mgemm_k(
    const u16* __restrict__ A1, size_t sA1,
    const u16* __restrict__ A2, size_t sA2,
    const u16* __restrict__ Wt, size_t sW, int K1, int Ktot,
    const float* __restrict__ bias, size_t sBias,
    u16* __restrict__ Y, size_t sY, int Mrows,
    float* __restrict__ ssum, float* __restrict__ ssq)
{
    __shared__ u16 Asm[128 * 64];
    __shared__ u16 Bsm[128 * 64];
    const int tid = threadIdx.x;
    const int lane = tid & 63, wid = tid >> 6;
    const int wr = wid >> 1, wc = wid & 1;

    // XCD-aware bijective remap of the flattened block id (m204 variant)
    const int gx = gridDim.x, gy = gridDim.y;
    int nwg = gx * gy * gridDim.z;
    int orig = blockIdx.x + gx * (blockIdx.y + gy * blockIdx.z);
    int q = nwg >> 3, r = nwg & 7;
    int xcd = orig & 7, idx = orig >> 3;
    int swz = (xcd < r ? xcd * (q + 1) : r * (q + 1) + (xcd - r) * q) + idx;
    const int bx = swz % gx;
    const int tmp = swz / gx;
    const int by = tmp % gy;
    const int c  = tmp / gy;

    const int rowbase = by * 128, colbase = bx * 128;

    const u16* A1p = A1 + (size_t)c * sA1;
    const u16* A2p = A2 ? (A2 + (size_t)c * sA2) : nullptr;
    const u16* Wp  = Wt + (size_t)c * sW;

    f32x4 acc[4][4];
#pragma unroll
    for (int i = 0; i < 4; ++i)
#pragma unroll
        for (int j = 0; j < 4; ++j) acc[i][j] = (f32x4)0.f;

    const int lrow = lane >> 3;        // row within the wave's 8-row group
    const int lchunk = lane & 7;       // 16B chunk within the row

    for (int k0 = 0; k0 < Ktot; k0 += 64) {
        const u16* asrc; int ak;
        if (k0 < K1) { asrc = A1p; ak = k0; } else { asrc = A2p; ak = k0 - K1; }
#pragma unroll
        for (int i = 0; i < 4; ++i) {
            const int row = (wid * 4 + i) * 8 + lrow;          // 0..127
            const int srcchunk = lchunk ^ (row & 7);           // inverse of read-side XOR
            int garow = rowbase + row;
            if (garow >= Mrows) garow = Mrows - 1;             // clamp: values unused
            const u16* ga = asrc + (size_t)garow * 256 + ak + srcchunk * 8;
            __builtin_amdgcn_global_load_lds((glb_uint*)ga,
                (lds_uint*)(Asm + (wid * 4 + i) * 512), 16, 0, 0);
            const u16* gb = Wp + (size_t)(colbase + row) * Ktot + k0 + srcchunk * 8;
            __builtin_amdgcn_global_load_lds((glb_uint*)gb,
                (lds_uint*)(Bsm + (wid * 4 + i) * 512), 16, 0, 0);
        }
        __syncthreads();
#pragma unroll
        for (int ks = 0; ks < 2; ++ks) {
            s16x8 aF[4], bF[4];
            const int kk = ks * 32 + ((lane >> 4) << 3);
#pragma unroll
            for (int f = 0; f < 4; ++f) {
                int ar = wr * 64 + f * 16 + (lane & 15);
                aF[f] = *(const s16x8*)&Asm[(ar * 64 + kk) ^ ((ar & 7) << 3)];
                int br = wc * 64 + f * 16 + (lane & 15);
                bF[f] = *(const s16x8*)&Bsm[(br * 64 + kk) ^ ((br & 7) << 3)];
            }
#pragma unroll
            for (int fr = 0; fr < 4; ++fr)
#pragma unroll
                for (int fc = 0; fc < 4; ++fc)
                    acc[fr][fc] = __builtin_amdgcn_mfma_f32_16x16x32_bf16(
                        aF[fr], bF[fc], acc[fr][fc], 0, 0, 0);
        }
        __syncthreads();
    }

    float bcol[4];
#pragma unroll
    for (int fc = 0; fc < 4; ++fc)
        bcol[fc] = bias[(size_t)c * sBias + colbase + wc * 64 + fc * 16 + (lane & 15)];
    u16* Yp = Y + (size_t)c * sY;
    float ps[4] = {0, 0, 0, 0}, pq[4] = {0, 0, 0, 0};
#pragma unroll
    for (int fr = 0; fr < 4; ++fr) {
#pragma unroll
        for (int i = 0; i < 4; ++i) {
            int grow = rowbase + wr * 64 + fr * 16 + ((lane >> 4) << 2) + i;
            if (grow < Mrows) {
                size_t rb = (size_t)grow * 256 + colbase + wc * 64 + (lane & 15);
#pragma unroll
                for (int fc = 0; fc < 4; ++fc) {
                    float v = acc[fr][fc][i] + bcol[fc];
                    Yp[rb + fc * 16] = f2bf(v);
                    if (STATS) { ps[fc] += v; pq[fc] += v * v; }
                }
            }
        }
    }
    if (STATS) {
#pragma unroll
        for (int fc = 0; fc < 4; ++fc) {
            float s = ps[fc], q2 = pq[fc];
            s += __shfl_xor(s, 16); s += __shfl_xor(s, 32);
            q2 += __shfl_xor(q2, 16); q2 += __shfl_xor(q2, 32);
            if (lane < 16) {
                int col = colbase + wc * 64 + fc * 16 + lane;
                atomicAdd(&ssum[c * 256 + col], s);
                atomicAdd(&ssq[c * 256 + col], q2);
            }
        }
    }
}

// ---------------- fp32 tiled GEMM (one-time base GEMM) ----------------
__global__ __launch_bounds__(256) void gemm_k(const float* __restrict__ A1, int lda1,
                                              const float* __restrict__ W1, int K1,
                                              const float* __restrict__ bias,
                                              float* __restrict__ Y, int Mrows) {
    __shared__ float As[16][132];
    __shared__ float Bs[16][132];
    float acc[8][8];
#pragma unroll
    for (int i = 0; i < 8; ++i)
#pragma unroll
        for (int j = 0; j < 8; ++j) acc[i][j] = 0.f;

    const int tid = threadIdx.x;
    const int tr = tid >> 4, tc = tid & 15;
    const int rowbase = blockIdx.y * 128, colbase = blockIdx.x * 128;

    for (int k0 = 0; k0 < K1; k0 += 16) {
#pragma unroll
        for (int ii = 0; ii < 2; ++ii) {
            int i = tid + ii * 256;
            int rr = i >> 2, qq = i & 3;
            int grow = rowbase + rr;
            float4 vv = make_float4(0.f, 0.f, 0.f, 0.f);
            if (grow < Mrows) vv = *(const float4*)&A1[(size_t)grow * lda1 + k0 + qq * 4];
            As[qq * 4 + 0][rr] = vv.x;
            As[qq * 4 + 1][rr] = vv.y;
            As[qq * 4 + 2][rr] = vv.z;
            As[qq * 4 + 3][rr] = vv.w;
        }
#pragma unroll
        for (int ii = 0; ii < 2; ++ii) {
            int i = tid + ii * 256;
            int rr = i >> 5, qq = i & 31;
            float4 vv = *(const float4*)&W1[(size_t)(k0 + rr) * 256 + colbase + qq * 4];
            *(float4*)&Bs[rr][qq * 4] = vv;
        }
        __syncthreads();
#pragma unroll
        for (int kk = 0; kk < 16; ++kk) {
            float a[8], b[8];
            *(float4*)&a[0] = *(const float4*)&As[kk][tr * 4];
            *(float4*)&a[4] = *(const float4*)&As[kk][64 + tr * 4];
            *(float4*)&b[0] = *(const float4*)&Bs[kk][tc * 4];
            *(float4*)&b[4] = *(const float4*)&Bs[kk][64 + tc * 4];
#pragma unroll
            for (int i = 0; i < 8; ++i)
#pragma unroll
                for (int j = 0; j < 8; ++j)
                    acc[i][j] = fmaf(a[i], b[j], acc[i][j]);
        }
        __syncthreads();
    }

    float4 blo = *(const float4*)&bias[colbase + tc * 4];
    float4 bhi = *(const float4*)&bias[colbase + 64 + tc * 4];
    float bb[8] = {blo.x, blo.y, blo.z, blo.w, bhi.x, bhi.y, bhi.z, bhi.w};
#pragma unroll
    for (int i = 0; i < 8; ++i)
#pragma unroll
        for (int j = 0; j < 8; ++j) acc[i][j] += bb[j];

#pragma unroll
    for (int i = 0; i < 8; ++i) {
        int lrow = (i < 4) ? (tr * 4 + i) : (64 + tr * 4 + (i - 4));
        int grow = rowbase + lrow;
        if (grow < Mrows) {
            *(float4*)&Y[(size_t)grow * 256 + colbase + tc * 4] =
                make_float4(acc[i][0], acc[i][1], acc[i][2], acc[i][3]);
            *(float4*)&Y[(size_t)grow * 256 + colbase + 64 + tc * 4] =
                make_float4(acc[i][4], acc[i][5], acc[i][6], acc[i][7]);
        }
    }
}

// ---------------- per-row epilogue with MFMA channel-attention ----------------
template <int NORM, int RES, int SMODE>
__global__ __launch_bounds__(256) void apply_k(const u16* __restrict__ Yin,
                                               u16* __restrict__ Hout,
                                               const u16* __restrict__ Hsc,
                                               const u16* __restrict__ W1p,
                                               const float* __restrict__ b1,
                                               const u16* __restrict__ W2p,
                                               const float* __restrict__ b2,
                                               const float* __restrict__ mu,
                                               const float* __restrict__ rs,
                                               float* __restrict__ ssum,
                                               float* __restrict__ ssq) {
    __shared__ u16 vbf[16 * 264];
    __shared__ u16 scs[(RES ? 16 : 1) * 264];
    __shared__ float tpart[4 * 512];
    __shared__ u16 tbf[16 * 40];
    const int c = blockIdx.z, n0 = blockIdx.x * 16, tid = threadIdx.x;
    const int lane = tid & 63, wid = tid >> 6;
    const size_t rowbase = ((size_t)c * N_ + n0) * 256;

    // phase A: vectorized load + normalize
#pragma unroll
    for (int it = 0; it < 2; ++it) {
        const int flat = tid + it * 256;
        const int row = flat >> 5, cb = (flat & 31) * 8;
        us8v x = *(const us8v*)&Yin[rowbase + row * 256 + cb];
        if (NORM) {
            us8v y;
#pragma unroll
            for (int j = 0; j < 8; ++j)
                y[j] = f2bf((bf2f(x[j]) - mu[c * 256 + cb + j]) * rs[c * 256 + cb + j]);
            *(us8v*)&vbf[row * 264 + cb] = y;
        } else {
            *(us8v*)&vbf[row * 264 + cb] = x;
        }
        if (RES) *(us8v*)&scs[row * 264 + cb] = *(const us8v*)&Hsc[rowbase + row * 256 + cb];
    }
    __syncthreads();

    // phase B: t_partial = x(K-slice) @ W1, wave w owns K in [w*64, w*64+64)
    {
        const int row = lane & 15;
        const int kq = lane >> 4;
        f32x4 at0 = (f32x4)0.f, at1 = (f32x4)0.f;
#pragma unroll
        for (int ks = 0; ks < 2; ++ks) {
            const int k = wid * 64 + ks * 32 + kq * 8;
            s16x8 aF = *(const s16x8*)&vbf[row * 264 + k];
            s16x8 bF0 = *(const s16x8*)&W1p[(((wid * 2 + ks) * 2 + 0) * 64 + lane) * 8];
            s16x8 bF1 = *(const s16x8*)&W1p[(((wid * 2 + ks) * 2 + 1) * 64 + lane) * 8];
            at0 = __builtin_amdgcn_mfma_f32_16x16x32_bf16(aF, bF0, at0, 0, 0, 0);
            at1 = __builtin_amdgcn_mfma_f32_16x16x32_bf16(aF, bF1, at1, 0, 0, 0);
        }
#pragma unroll
        for (int i = 0; i < 4; ++i) {
            tpart[wid * 512 + (kq * 4 + i) * 32 + (lane & 15)] = at0[i];
            tpart[wid * 512 + (kq * 4 + i) * 32 + 16 + (lane & 15)] = at1[i];
        }
    }
    __syncthreads();

    // reduce partials across waves, +b1, relu -> tbf
#pragma unroll
    for (int ii = 0; ii < 2; ++ii) {
        int idx = tid + ii * 256;
        float s = tpart[idx] + tpart[512 + idx] + tpart[1024 + idx] + tpart[1536 + idx];
        int col = idx & 31;
        s += b1[col];
        tbf[(idx >> 5) * 40 + col] = f2bf(fmaxf(s, 0.f));
    }
    __syncthreads();

    // phase C: y = t @ W2, fused sigmoid * x (+res), gelu; write back to vbf
    {
        const int cl = lane & 15, kq = lane >> 4;
        s16x8 aF = *(const s16x8*)&tbf[cl * 40 + kq * 8];
#pragma unroll
        for (int q = 0; q < 4; ++q) {
            const int colb = (wid * 4 + q) * 16;
            s16x8 bF = *(const s16x8*)&W2p[((wid * 4 + q) * 64 + lane) * 8];
            f32x4 acc = __builtin_amdgcn_mfma_f32_16x16x32_bf16(aF, bF, (f32x4)0.f, 0, 0, 0);
            const float b2v = b2[colb + cl];
#pragma unroll
            for (int i = 0; i < 4; ++i) {
                const int row = kq * 4 + i;
                float s = acc[i] + b2v;
                float sig = 1.0f / (1.0f + __expf(-s));
                float val = sig * bf2f(vbf[row * 264 + colb + cl]);
                if (RES) val += bf2f(scs[row * 264 + colb + cl]);
                val = gelu_f(val);
                vbf[row * 264 + colb + cl] = f2bf(val);
            }
        }
    }
    __syncthreads();

    // phase D: vectorized store + per-column stats (LDS reduce)
    {
        float ps[8] = {0, 0, 0, 0, 0, 0, 0, 0}, pq[8] = {0, 0, 0, 0, 0, 0, 0, 0};
#pragma unroll
        for (int it = 0; it < 2; ++it) {
            const int flat = tid + it * 256;
            const int row = flat >> 5, cb = (flat & 31) * 8;
            us8v h = *(const us8v*)&vbf[row * 264 + cb];
            *(us8v*)&Hout[rowbase + row * 256 + cb] = h;
            if (SMODE) {
#pragma unroll
                for (int j = 0; j < 8; ++j) {
                    float v = bf2f(h[j]);
                    ps[j] += v;
                    if (SMODE == 1) pq[j] += v * v;
                }
            }
        }
        if (SMODE) {
#pragma unroll
            for (int j = 0; j < 8; ++j)
                tpart[((tid >> 5) * 32 + (tid & 31)) * 8 + j] = ps[j];
            __syncthreads();
            {
                const int cb2 = tid >> 3, j2 = tid & 7;
                float s = 0.f;
#pragma unroll
                for (int r8 = 0; r8 < 8; ++r8) s += tpart[(r8 * 32 + cb2) * 8 + j2];
                atomicAdd(&ssum[c * 256 + tid], s);
            }
            if (SMODE == 1) {
                __syncthreads();
#pragma unroll
                for (int j = 0; j < 8; ++j)
                    tpart[((tid >> 5) * 32 + (tid & 31)) * 8 + j] = pq[j];
                __syncthreads();
                const int cb2 = tid >> 3, j2 = tid & 7;
                float s = 0.f;
#pragma unroll
                for (int r8 = 0; r8 < 8; ++r8) s += tpart[(r8 * 32 + cb2) * 8 + j2];
                atomicAdd(&ssq[c * 256 + tid], s);
            }
        }
    }
}

// ---------------- classifier ----------------
__global__ __launch_bounds__(256) void cls_k(const float* __restrict__ pooled_sum,
                                             const float* __restrict__ clsW,
                                             const float* __restrict__ clsb,
                                             float* __restrict__ out) {
    __shared__ float red[256];
    int c = blockIdx.x, d = threadIdx.x;
    red[d] = pooled_sum[c * 256 + d] * (1.0f / (float)N_) * clsW[d];
    __syncthreads();
    for (int s = 128; s > 0; s >>= 1) {
        if (d < s) red[d] += red[d + s];
        __syncthreads();
    }
    if (d == 0) out[c] = red[0] + clsb[0];
}

// ---------------- host launch ----------------
static inline size_t alup(size_t x) { return (x + 255) & ~(size_t)255; }

extern "C" void kernel_launch(void* const* d_in, const int* in_sizes, int n_in,
                              void* d_out, int out_size, void* d_ws, size_t ws_size,
                              hipStream_t stream) {
    const int*   xcfg   = (const int*)d_in[0];
    const float* xfeat  = (const float*)d_in[1];
    const int*   xlay   = (const int*)d_in[2];
    const int*   xop    = (const int*)d_in[3];
    const int*   ei     = (const int*)d_in[4];
    const int*   ncid   = (const int*)d_in[5];
    const float* embO   = (const float*)d_in[6];
    const float* embL   = (const float*)d_in[7];
    const float* lin1W  = (const float*)d_in[8];
    const float* lin1b  = (const float*)d_in[9];
    const float* ca1W1  = (const float*)d_in[10];
    const float* ca1b1  = (const float*)d_in[11];
    const float* ca1W2  = (const float*)d_in[12];
    const float* ca1b2  = (const float*)d_in[13];
    const float* lin2W  = (const float*)d_in[14];
    const float* lin2b  = (const float*)d_in[15];
    const float* ca2W1  = (const float*)d_in[16];
    const float* ca2b1  = (const float*)d_in[17];
    const float* ca2W2  = (const float*)d_in[18];
    const float* ca2b2  = (const float*)d_in[19];
    const float* sageWl = (const float*)d_in[20];
    const float* sagebl = (const float*)d_in[21];
    const float* sageWr = (const float*)d_in[22];
    const float* scaW1  = (const float*)d_in[23];
    const float* scab1  = (const float*)d_in[24];
    const float* scaW2  = (const float*)d_in[25];
    const float* scab2  = (const float*)d_in[26];
    const float* clsW   = (const float*)d_in[27];
    const float* clsb   = (const float*)d_in[28];
    float* out = (float*)d_out;

    // ---- workspace carve-up ----
    char* w = (char*)d_ws;
    size_t o = 0;
    auto take = [&](size_t bytes) { char* p = w + o; o = alup(o + bytes); return p; };
    float* base    = (float*)take((size_t)N_ * 256 * 4);
    float* feat162 = (float*)take((size_t)N_ * 176 * 4);
    float* W162    = (float*)take((size_t)176 * 256 * 4);
    float* T       = (float*)take((size_t)18 * 8 * 256 * 4);
    float* csum    = (float*)take((size_t)256 * 4);
    float* stats   = (float*)take((size_t)6 * 8192 * 4);
    float* MU      = (float*)take((size_t)5 * 4096 * 4);
    float* RS      = (float*)take((size_t)5 * 4096 * 4);
    float* invcnt  = (float*)take((size_t)N_ * 4);
    int*   cnt     = (int*)take((size_t)N_ * 4);
    int*   off     = (int*)take((size_t)(N_ + 1) * 4);
    int*   cursor  = (int*)take((size_t)N_ * 4);
    int*   csr     = (int*)take((size_t)E_ * 4);
    int*   cfgpos  = (int*)take((size_t)N_ * 4);
    u16*   Wt2     = (u16*)take((size_t)256 * 256 * 2);
    u16*   Wfold   = (u16*)take((size_t)C_ * 256 * 512 * 2);   // 4 MB
    float* biasF   = (float*)take((size_t)C_ * 256 * 4);
    u16*   CAW1    = (u16*)take((size_t)5 * 8192 * 2);         // packed frag order
    u16*   CAW2    = (u16*)take((size_t)5 * 8192 * 2);

    const size_t slab = (size_t)SZ_ * 2;                       // bf16: 5.12 MB
    size_t avail = (ws_size > o) ? (ws_size - o) : 0;
    int Cc = (int)(avail / (3 * slab + 768));
    if (Cc > C_) Cc = C_;
    if (Cc < 1) Cc = 1;
    u16* BufH = (u16*)take((size_t)Cc * slab);
    u16* BufY = (u16*)take((size_t)Cc * slab);
    u16* BufA = (u16*)take((size_t)Cc * slab);
    (void)in_sizes; (void)n_in; (void)out_size;

    auto S = [&](int s) { return stats + (size_t)s * 8192; };
    auto Q = [&](int s) { return stats + (size_t)s * 8192 + 4096; };

    hipMemsetAsync(stats, 0, 6 * 8192 * 4, stream);
    hipMemsetAsync(cnt, 0, N_ * 4, stream);
    hipMemsetAsync(cfgpos, 0xFF, N_ * 4, stream);

    // shared prep
    tbl_k<<<144, 256, 0, stream>>>(embL, lin1W, T);
    csum_k<<<1, 256, 0, stream>>>(T, csum);
    feat_k<<<N_, 192, 0, stream>>>(xfeat, xlay, xop, embL, embO, feat162);
    wpack_k<<<176, 256, 0, stream>>>(lin1W, W162);
    wt2_k<<<256, 256, 0, stream>>>(lin2W, Wt2);
    packw1_k<<<32, 256, 0, stream>>>(ca1W1, CAW1 + 0 * 8192);
    packw1_k<<<32, 256, 0, stream>>>(ca2W1, CAW1 + 1 * 8192);
    packw1_k<<<32, 256, 0, stream>>>(scaW1 + 0 * 8192, CAW1 + 2 * 8192);
    packw1_k<<<32, 256, 0, stream>>>(scaW1 + 1 * 8192, CAW1 + 3 * 8192);
    packw1_k<<<32, 256, 0, stream>>>(scaW1 + 2 * 8192, CAW1 + 4 * 8192);
    packw2_k<<<32, 256, 0, stream>>>(ca1W2, CAW2 + 0 * 8192);
    packw2_k<<<32, 256, 0, stream>>>(ca2W2, CAW2 + 1 * 8192);
    packw2_k<<<32, 256, 0, stream>>>(scaW2 + 0 * 8192, CAW2 + 2 * 8192);
    packw2_k<<<32, 256, 0, stream>>>(scaW2 + 1 * 8192, CAW2 + 3 * 8192);
    packw2_k<<<32, 256, 0, stream>>>(scaW2 + 2 * 8192, CAW2 + 4 * 8192);
    cfgpos_k<<<(NC_ + 255) / 256, 256, 0, stream>>>(ncid, cfgpos);
    hist_k<<<(E_ + 255) / 256, 256, 0, stream>>>(ei, cnt);
    scan_k<<<1, 1024, 0, stream>>>(cnt, off, cursor, invcnt);
    fill_k<<<(E_ + 255) / 256, 256, 0, stream>>>(ei, cursor, csr);

    // base = feat162 @ W162 + lin1_b (fp32, one-time)
    gemm_k<<<dim3(2, 79, 1), 256, 0, stream>>>(feat162, 176, W162, 176, lin1b, base, N_);

    // ---- per-config-chunk pipeline ----
    for (int c0 = 0; c0 < C_; c0 += Cc) {
        const int nc = (C_ - c0 < Cc) ? (C_ - c0) : Cc;
        const int co = c0 * 256;

        lin1_cfg_k<<<dim3(NC_ / 16, 1, nc), 256, 0, stream>>>(
            base, T, ncid, xcfg + (size_t)c0 * NC_ * 18, BufH, S(0) + co, Q(0) + co);
        lin1_unc_k<<<625, 256, 0, stream>>>(
            base, csum, cfgpos, nc, BufH, S(0) + co, Q(0) + co);
        finstat_k<<<nc, 256, 0, stream>>>(S(0) + co, Q(0) + co, MU + co, RS + co);

        apply_k<1, 0, 0><<<dim3(625, 1, nc), 256, 0, stream>>>(
            BufH, BufH, nullptr, CAW1 + 0 * 8192, ca1b1, CAW2 + 0 * 8192, ca1b2,
            MU + co, RS + co, nullptr, nullptr);

        mgemm_k<1><<<dim3(2, 79, nc), 256, 0, stream>>>(
            BufH, SZ_, nullptr, 0, Wt2, 0, 256, 256,
            lin2b, 0, BufY, SZ_, N_, S(1) + co, Q(1) + co);
        finstat_k<<<nc, 256, 0, stream>>>(S(1) + co, Q(1) + co, MU + 4096 + co, RS + 4096 + co);

        apply_k<1, 0, 1><<<dim3(625, 1, nc), 256, 0, stream>>>(
            BufY, BufY, nullptr, CAW1 + 1 * 8192, ca2b1, CAW2 + 1 * 8192, ca2b2,
            MU + 4096 + co, RS + 4096 + co, S(2) + co, Q(2) + co);

        for (int i = 0; i < 3; ++i) {
            const int set = 2 + i;
            finstat_k<<<nc, 256, 0, stream>>>(S(set) + co, Q(set) + co,
                                              MU + set * 4096 + co, RS + set * 4096 + co);
            foldw_k<<<dim3(256, nc), 256, 0, stream>>>(
                sageWl + (size_t)i * 65536, sageWr + (size_t)i * 65536, sagebl + i * 256,
                MU + set * 4096 + co, RS + set * 4096 + co,
                Wfold + (size_t)c0 * 256 * 512, biasF + co);
            agg_k<<<nc * 2500, 256, 0, stream>>>(BufY, off, csr, invcnt,
                                                 MU + set * 4096 + co, BufA);
            mgemm_k<0><<<dim3(2, 79, nc), 256, 0, stream>>>(
                BufA, SZ_, BufY, SZ_, Wfold + (size_t)c0 * 256 * 512, 256 * 512, 256, 512,
                biasF + co, 256, BufH, SZ_, N_, nullptr, nullptr);
            if (i < 2) {
                apply_k<0, 1, 1><<<dim3(625, 1, nc), 256, 0, stream>>>(
                    BufH, BufY, BufY,
                    CAW1 + (2 + i) * 8192, scab1 + i * 32,
                    CAW2 + (2 + i) * 8192, scab2 + i * 256,
                    nullptr, nullptr, S(3 + i) + co, Q(3 + i) + co);
            } else {
                apply_k<0, 1, 2><<<dim3(625, 1, nc), 256, 0, stream>>>(
                    BufH, BufY, BufY,
                    CAW1 + (2 + i) * 8192, scab1 + i * 32,
                    CAW2 + (2 + i) * 8192, scab2 + i * 256,
                    nullptr, nullptr, S(5) + co, nullptr);
            }
        }
    }

    cls_k<<<16, 256, 0, stream>>>(S(5), clsW, clsb, out);
}

// Round 7
// 1373.472 us; speedup vs baseline: 2.7636x; 1.0599x over previous
//
#include <hip/hip_runtime.h>
#include <math.h>

// ---------------- problem constants ----------------
constexpr int C_  = 16;
constexpr int N_  = 10000;
constexpr int NC_ = 2000;
constexpr int E_  = 50000;
constexpr int D_  = 256;
constexpr int SZ_ = N_ * D_;          // per-config slab (elements)
constexpr float EPS_ = 1e-5f;

typedef unsigned short u16;
typedef __attribute__((ext_vector_type(8))) unsigned short us8v;
typedef __attribute__((ext_vector_type(4))) unsigned short us4v;
typedef __attribute__((ext_vector_type(8))) short s16x8;
typedef __attribute__((ext_vector_type(4))) float f32x4;

typedef __attribute__((address_space(3))) unsigned int lds_uint;
typedef const __attribute__((address_space(1))) unsigned int glb_uint;

__device__ __forceinline__ u16 f2bf(float f) {
    unsigned u = __float_as_uint(f);
    u += 0x7fffu + ((u >> 16) & 1u);
    return (u16)(u >> 16);
}
__device__ __forceinline__ float bf2f(u16 h) {
    return __uint_as_float(((unsigned)h) << 16);
}
// fast gelu: erf via Abramowitz-Stegun 7.1.26 (|err|<=1.5e-7) + hw exp
__device__ __forceinline__ float gelu_f(float x) {
    float z = x * 0.70710678118654752f;
    float az = fabsf(z);
    float t = 1.f / fmaf(0.3275911f, az, 1.f);
    float p = t * (0.254829592f + t * (-0.284496736f + t * (1.421413741f +
              t * (-1.453152027f + t * 1.061405429f))));
    float e = p * __expf(-z * z);
    float erfv = (z >= 0.f) ? (1.f - e) : (e - 1.f);
    return 0.5f * x * (1.f + erfv);
}

// vbf/scs swizzled chunk address: 16 rows x 264 u16, 8-elem chunks XOR'd by row
__device__ __forceinline__ int vswz(int row, int chunk) {
    return row * 264 + ((chunk ^ (row & 7)) << 3);
}

// ---------------- tiny prep kernels ----------------

__global__ __launch_bounds__(256) void tbl_k(const float* __restrict__ embL,
                                             const float* __restrict__ W,
                                             float* __restrict__ T) {
    int b = blockIdx.x;            // 0..143
    int s = b >> 3, i = b & 7, d = threadIdx.x;
    float acc = 0.f;
#pragma unroll
    for (int k = 0; k < 4; ++k)
        acc = fmaf(embL[i * 4 + k], W[(134 + s * 4 + k) * 256 + d], acc);
    T[(s * 8 + i) * 256 + d] = acc;
}

// csum[d] = sum_s T[s][0][d]
__global__ __launch_bounds__(256) void csum_k(const float* __restrict__ T,
                                              float* __restrict__ cs) {
    int d = threadIdx.x;
    float a = 0.f;
#pragma unroll
    for (int s = 0; s < 18; ++s) a += T[(s * 8) * 256 + d];
    cs[d] = a;
}

__global__ __launch_bounds__(192) void feat_k(const float* __restrict__ xf,
                                              const int* __restrict__ xlay,
                                              const int* __restrict__ xop,
                                              const float* __restrict__ embL,
                                              const float* __restrict__ embO,
                                              float* __restrict__ f) {
    int n = blockIdx.x, j = threadIdx.x;
    if (j >= 176) return;
    float v;
    if (j < 134) v = xf[n * 134 + j];
    else if (j < 158) { int q = j - 134; int t = q >> 2, k = q & 3; v = embL[(xlay[n * 6 + t] + 2) * 4 + k]; }
    else if (j < 162) { int k = j - 158; v = embO[xop[n] * 4 + k]; }
    else v = 0.f;
    f[n * 176 + j] = v;
}

__global__ __launch_bounds__(256) void wpack_k(const float* __restrict__ W,
                                               float* __restrict__ Wp) {
    int j = blockIdx.x, d = threadIdx.x;
    float v = 0.f;
    if (j < 134) v = W[j * 256 + d];
    else if (j < 158) v = W[(206 + j - 134) * 256 + d];
    else if (j < 162) v = W[(230 + j - 158) * 256 + d];
    Wp[j * 256 + d] = v;
}

// pack channel-attn W1 [256][32] into MFMA fragment order
__global__ __launch_bounds__(256) void packw1_k(const float* __restrict__ W1,
                                                u16* __restrict__ dst) {
    int i = blockIdx.x * 256 + threadIdx.x;    // 0..8191
    int j = i & 7, lane = (i >> 3) & 63, half = (i >> 9) & 1, ks = (i >> 10) & 1, wid = (i >> 11) & 3;
    int k = wid * 64 + ks * 32 + ((lane >> 4) << 3) + j;
    int col = half * 16 + (lane & 15);
    dst[i] = f2bf(W1[k * 32 + col]);
}
// pack channel-attn W2 [32][256] into MFMA fragment order
__global__ __launch_bounds__(256) void packw2_k(const float* __restrict__ W2,
                                                u16* __restrict__ dst) {
    int i = blockIdx.x * 256 + threadIdx.x;    // 0..8191
    int j = i & 7, lane = (i >> 3) & 63, q = (i >> 9) & 3, wid = (i >> 11) & 3;
    int kq = lane >> 4, cl = lane & 15;
    dst[i] = f2bf(W2[(kq * 8 + j) * 256 + (wid * 4 + q) * 16 + cl]);
}

__global__ __launch_bounds__(256) void cfgpos_k(const int* __restrict__ ncid,
                                                int* __restrict__ cfgpos) {
    int i = blockIdx.x * 256 + threadIdx.x;
    if (i < NC_) cfgpos[ncid[i]] = i;
}

__global__ __launch_bounds__(256) void hist_k(const int* __restrict__ ei, int* __restrict__ cnt) {
    int e = blockIdx.x * 256 + threadIdx.x;
    if (e < E_) atomicAdd(&cnt[ei[E_ + e]], 1);
}

__global__ __launch_bounds__(1024) void scan_k(const int* __restrict__ cnt,
                                               int* __restrict__ off,
                                               int* __restrict__ cursor,
                                               float* __restrict__ invcnt) {
    __shared__ int s[1024];
    int t = threadIdx.x;
    int base = t * 10;
    int local[10];
    int part = 0;
#pragma unroll
    for (int k = 0; k < 10; ++k) {
        int idx = base + k;
        int v = (idx < N_) ? cnt[idx] : 0;
        local[k] = v; part += v;
    }
    s[t] = part;
    __syncthreads();
    for (int o = 1; o < 1024; o <<= 1) {
        int val = (t >= o) ? s[t - o] : 0;
        __syncthreads();
        s[t] += val;
        __syncthreads();
    }
    int pre = s[t] - part;
#pragma unroll
    for (int k = 0; k < 10; ++k) {
        int idx = base + k;
        if (idx < N_) {
            off[idx] = pre;
            cursor[idx] = pre;
            invcnt[idx] = 1.0f / (float)(local[k] > 1 ? local[k] : 1);
            pre += local[k];
        }
    }
    if (t == 1023) off[N_] = s[1023];
}

__global__ __launch_bounds__(256) void fill_k(const int* __restrict__ ei,
                                              int* __restrict__ cursor,
                                              int* __restrict__ csr) {
    int e = blockIdx.x * 256 + threadIdx.x;
    if (e < E_) {
        int t = ei[E_ + e];
        int p = atomicAdd(&cursor[t], 1);
        csr[p] = ei[e];
    }
}

// transpose lin2_W -> Wt2[j][k] bf16
__global__ __launch_bounds__(256) void wt2_k(const float* __restrict__ W,
                                             u16* __restrict__ Wt) {
    int j = blockIdx.x, k = threadIdx.x;
    Wt[j * 256 + k] = f2bf(W[k * 256 + j]);
}

// fold instance-norm into sage weights (per config)
__global__ __launch_bounds__(256) void foldw_k(const float* __restrict__ Wl,
                                               const float* __restrict__ Wr,
                                               const float* __restrict__ bl,
                                               const float* __restrict__ mu,
                                               const float* __restrict__ rs,
                                               u16* __restrict__ Wt,
                                               float* __restrict__ biasF) {
    __shared__ float red[256];
    int c = blockIdx.y, j = blockIdx.x, k = threadIdx.x;
    float rsv = rs[c * 256 + k], muv = mu[c * 256 + k];
    float fl = rsv * Wl[k * 256 + j];
    float fr = rsv * Wr[k * 256 + j];
    size_t wb = ((size_t)c * 256 + j) * 512;
    Wt[wb + k] = f2bf(fl);
    Wt[wb + 256 + k] = f2bf(fr);
    red[k] = muv * (fl + fr);
    __syncthreads();
    for (int s = 128; s > 0; s >>= 1) {
        if (k < s) red[k] += red[k + s];
        __syncthreads();
    }
    if (k == 0) biasF[c * 256 + j] = bl[j] - red[0];
}

// ---------------- lin1 (configured nodes) ----------------
__global__ __launch_bounds__(256) void lin1_cfg_k(const float* __restrict__ base,
                                                  const float* __restrict__ T,
                                                  const int* __restrict__ ncid,
                                                  const int* __restrict__ xcfg,
                                                  u16* __restrict__ H,
                                                  float* __restrict__ ssum,
                                                  float* __restrict__ ssq) {
    __shared__ int idxs[16][18];   // premultiplied by 256
    __shared__ int nid[16];
    const int c = blockIdx.z, j0 = blockIdx.x * 16, tid = threadIdx.x;
    if (tid < 16) nid[tid] = ncid[j0 + tid];
    for (int t = tid; t < 288; t += 256) {
        int row = t / 18, s = t - row * 18;
        idxs[row][s] = (xcfg[((size_t)c * NC_ + j0 + row) * 18 + s] + 2) * 256;
    }
    __syncthreads();
    const int d = tid;
    float psum = 0.f, psq = 0.f;
    for (int g = 0; g < 16; g += 4) {
        float acc[4];
#pragma unroll
        for (int gg = 0; gg < 4; ++gg) acc[gg] = base[(size_t)nid[g + gg] * 256 + d];
#pragma unroll
        for (int s = 0; s < 18; ++s) {
            const float* Ts = &T[s * 2048 + d];
#pragma unroll
            for (int gg = 0; gg < 4; ++gg)
                acc[gg] += Ts[idxs[g + gg][s]];
        }
#pragma unroll
        for (int gg = 0; gg < 4; ++gg) {
            H[((size_t)c * N_ + nid[g + gg]) * 256 + d] = f2bf(acc[gg]);
            psum += acc[gg]; psq += acc[gg] * acc[gg];
        }
    }
    atomicAdd(&ssum[c * 256 + d], psum);
    atomicAdd(&ssq[c * 256 + d], psq);
}

// ---------------- lin1 (unconfigured nodes) ----------------
__global__ __launch_bounds__(256) void lin1_unc_k(const float* __restrict__ base,
                                                  const float* __restrict__ csum,
                                                  const int* __restrict__ cfgpos,
                                                  int nc,
                                                  u16* __restrict__ H,
                                                  float* __restrict__ ssum,
                                                  float* __restrict__ ssq) {
    __shared__ float red[2048];
    const int n0 = blockIdx.x * 16, tid = threadIdx.x;
    float ps[8] = {0, 0, 0, 0, 0, 0, 0, 0}, pq[8] = {0, 0, 0, 0, 0, 0, 0, 0};
#pragma unroll
    for (int it = 0; it < 2; ++it) {
        const int flat = tid + it * 256;
        const int row = flat >> 5, cb = (flat & 31) * 8;
        const int n = n0 + row;
        if (cfgpos[n] >= 0) continue;
        us8v b;
#pragma unroll
        for (int j = 0; j < 8; ++j) {
            float v = base[(size_t)n * 256 + cb + j] + csum[cb + j];
            b[j] = f2bf(v);
            ps[j] += v; pq[j] += v * v;
        }
        for (int c = 0; c < nc; ++c)
            *(us8v*)&H[((size_t)c * N_ + n) * 256 + cb] = b;
    }
#pragma unroll
    for (int j = 0; j < 8; ++j)
        red[((tid >> 5) * 32 + (tid & 31)) * 8 + j] = ps[j];
    __syncthreads();
    {
        const int cb2 = tid >> 3, j2 = tid & 7;
        float s = 0.f;
#pragma unroll
        for (int r8 = 0; r8 < 8; ++r8) s += red[(r8 * 32 + cb2) * 8 + j2];
        for (int c = 0; c < nc; ++c) atomicAdd(&ssum[c * 256 + tid], s);
    }
    __syncthreads();
#pragma unroll
    for (int j = 0; j < 8; ++j)
        red[((tid >> 5) * 32 + (tid & 31)) * 8 + j] = pq[j];
    __syncthreads();
    {
        const int cb2 = tid >> 3, j2 = tid & 7;
        float s = 0.f;
#pragma unroll
        for (int r8 = 0; r8 < 8; ++r8) s += red[(r8 * 32 + cb2) * 8 + j2];
        for (int c = 0; c < nc; ++c) atomicAdd(&ssq[c * 256 + tid], s);
    }
}

__global__ __launch_bounds__(256) void finstat_k(const float* __restrict__ ssum,
                                                 const float* __restrict__ ssq,
                                                 float* __restrict__ mu,
                                                 float* __restrict__ rs) {
    int i = blockIdx.x * 256 + threadIdx.x;
    float m = ssum[i] * (1.0f / (float)N_);
    float v = ssq[i] * (1.0f / (float)N_) - m * m;
    mu[i] = m;
    rs[i] = rsqrtf(v + EPS_);
}

// ---------------- CSR gather-mean: vector index load + shfl broadcast ----------------
__global__ __launch_bounds__(256) void agg_k(const u16* __restrict__ H,
                                             const int* __restrict__ off,
                                             const int* __restrict__ csr,
                                             const float* __restrict__ invcnt,
                                             const float* __restrict__ mu,
                                             u16* __restrict__ Agg) {
    int wave = threadIdx.x >> 6, lane = threadIdx.x & 63;
    int pair = blockIdx.x * 4 + wave;
    int c = pair / N_, t = pair - c * N_;
    int d4 = lane * 4;
    int o0 = off[t], o1 = off[t + 1];
    int deg = o1 - o0;
    us4v o;
    if (deg > 0) {
        // one coalesced load grabs up to 64 edge indices for this target
        int myidx = (lane < deg) ? csr[o0 + lane] : 0;
        const u16* Hc = H + (size_t)c * SZ_ + d4;
        float ax = 0.f, ay = 0.f, az = 0.f, aw = 0.f;
        int lim = deg < 64 ? deg : 64;
        int i = 0;
        for (; i + 4 <= lim; i += 4) {
            int s0 = __shfl(myidx, i), s1 = __shfl(myidx, i + 1);
            int s2 = __shfl(myidx, i + 2), s3 = __shfl(myidx, i + 3);
            us4v h0 = *(const us4v*)&Hc[(size_t)s0 * 256];
            us4v h1 = *(const us4v*)&Hc[(size_t)s1 * 256];
            us4v h2 = *(const us4v*)&Hc[(size_t)s2 * 256];
            us4v h3 = *(const us4v*)&Hc[(size_t)s3 * 256];
            ax += (bf2f(h0.x) + bf2f(h1.x)) + (bf2f(h2.x) + bf2f(h3.x));
            ay += (bf2f(h0.y) + bf2f(h1.y)) + (bf2f(h2.y) + bf2f(h3.y));
            az += (bf2f(h0.z) + bf2f(h1.z)) + (bf2f(h2.z) + bf2f(h3.z));
            aw += (bf2f(h0.w) + bf2f(h1.w)) + (bf2f(h2.w) + bf2f(h3.w));
        }
        for (; i < lim; ++i) {
            int s = __shfl(myidx, i);
            us4v h = *(const us4v*)&Hc[(size_t)s * 256];
            ax += bf2f(h.x); ay += bf2f(h.y); az += bf2f(h.z); aw += bf2f(h.w);
        }
        for (int j = o0 + 64; j < o1; ++j) {     // rare: degree > 64
            int s = csr[j];
            us4v h = *(const us4v*)&Hc[(size_t)s * 256];
            ax += bf2f(h.x); ay += bf2f(h.y); az += bf2f(h.z); aw += bf2f(h.w);
        }
        float inv = invcnt[t];
        o.x = f2bf(ax * inv); o.y = f2bf(ay * inv);
        o.z = f2bf(az * inv); o.w = f2bf(aw * inv);
    } else {
        o.x = f2bf(mu[c * 256 + d4 + 0]);
        o.y = f2bf(mu[c * 256 + d4 + 1]);
        o.z = f2bf(mu[c * 256 + d4 + 2]);
        o.w = f2bf(mu[c * 256 + d4 + 3]);
    }
    *(us4v*)&Agg[((size_t)c * N_ + t) * 256 + d4] = o;
}

// ---------------- bf16 MFMA GEMM: Y = [A1|A2] @ Wt^T + bias ----------------
template <int STATS>
__global__ __launch_bounds__(256) void mgemm_k(
    const u16* __restrict__ A1, size_t sA1,
    const u16* __restrict__ A2, size_t sA2,
    const u16* __restrict__ Wt, size_t sW, int K1, int Ktot,
    const float* __restrict__ bias, size_t sBias,
    u16* __restrict__ Y, size_t sY, int Mrows,
    float* __restrict__ ssum, float* __restrict__ ssq)
{
    __shared__ u16 Asm[128 * 64];
    __shared__ u16 Bsm[128 * 64];
    const int tid = threadIdx.x;
    const int lane = tid & 63, wid = tid >> 6;
    const int wr = wid >> 1, wc = wid & 1;

    // XCD-aware bijective remap of the flattened block id
    const int gx = gridDim.x, gy = gridDim.y;
    int nwg = gx * gy * gridDim.z;
    int orig = blockIdx.x + gx * (blockIdx.y + gy * blockIdx.z);
    int q = nwg >> 3, r = nwg & 7;
    int xcd = orig & 7, idx = orig >> 3;
    int swz = (xcd < r ? xcd * (q + 1) : r * (q + 1) + (xcd - r) * q) + idx;
    const int bx = swz % gx;
    const int tmp = swz / gx;
    const int by = tmp % gy;
    const int c  = tmp / gy;

    const int rowbase = by * 128, colbase = bx * 128;

    const u16* A1p = A1 + (size_t)c * sA1;
    const u16* A2p = A2 ? (A2 + (size_t)c * sA2) : nullptr;
    const u16* Wp  = Wt + (size_t)c * sW;

    f32x4 acc[4][4];
#pragma unroll
    for (int i = 0; i < 4; ++i)
#pragma unroll
        for (int j = 0; j < 4; ++j) acc[i][j] = (f32x4)0.f;

    const int lrow = lane >> 3;        // row within the wave's 8-row group
    const int lchunk = lane & 7;       // 16B chunk within the row

    for (int k0 = 0; k0 < Ktot; k0 += 64) {
        const u16* asrc; int ak;
        if (k0 < K1) { asrc = A1p; ak = k0; } else { asrc = A2p; ak = k0 - K1; }
#pragma unroll
        for (int i = 0; i < 4; ++i) {
            const int row = (wid * 4 + i) * 8 + lrow;          // 0..127
            const int srcchunk = lchunk ^ (row & 7);           // inverse of read-side XOR
            int garow = rowbase + row;
            if (garow >= Mrows) garow = Mrows - 1;             // clamp: values unused
            const u16* ga = asrc + (size_t)garow * 256 + ak + srcchunk * 8;
            __builtin_amdgcn_global_load_lds((glb_uint*)ga,
                (lds_uint*)(Asm + (wid * 4 + i) * 512), 16, 0, 0);
            const u16* gb = Wp + (size_t)(colbase + row) * Ktot + k0 + srcchunk * 8;
            __builtin_amdgcn_global_load_lds((glb_uint*)gb,
                (lds_uint*)(Bsm + (wid * 4 + i) * 512), 16, 0, 0);
        }
        __syncthreads();
#pragma unroll
        for (int ks = 0; ks < 2; ++ks) {
            s16x8 aF[4], bF[4];
            const int kk = ks * 32 + ((lane >> 4) << 3);
#pragma unroll
            for (int f = 0; f < 4; ++f) {
                int ar = wr * 64 + f * 16 + (lane & 15);
                aF[f] = *(const s16x8*)&Asm[(ar * 64 + kk) ^ ((ar & 7) << 3)];
                int br = wc * 64 + f * 16 + (lane & 15);
                bF[f] = *(const s16x8*)&Bsm[(br * 64 + kk) ^ ((br & 7) << 3)];
            }
#pragma unroll
            for (int fr = 0; fr < 4; ++fr)
#pragma unroll
                for (int fc = 0; fc < 4; ++fc)
                    acc[fr][fc] = __builtin_amdgcn_mfma_f32_16x16x32_bf16(
                        aF[fr], bF[fc], acc[fr][fc], 0, 0, 0);
        }
        __syncthreads();
    }

    float bcol[4];
#pragma unroll
    for (int fc = 0; fc < 4; ++fc)
        bcol[fc] = bias[(size_t)c * sBias + colbase + wc * 64 + fc * 16 + (lane & 15)];
    u16* Yp = Y + (size_t)c * sY;
    float ps[4] = {0, 0, 0, 0}, pq[4] = {0, 0, 0, 0};
#pragma unroll
    for (int fr = 0; fr < 4; ++fr) {
#pragma unroll
        for (int i = 0; i < 4; ++i) {
            int grow = rowbase + wr * 64 + fr * 16 + ((lane >> 4) << 2) + i;
            if (grow < Mrows) {
                size_t rb = (size_t)grow * 256 + colbase + wc * 64 + (lane & 15);
#pragma unroll
                for (int fc = 0; fc < 4; ++fc) {
                    float v = acc[fr][fc][i] + bcol[fc];
                    Yp[rb + fc * 16] = f2bf(v);
                    if (STATS) { ps[fc] += v; pq[fc] += v * v; }
                }
            }
        }
    }
    if (STATS) {
#pragma unroll
        for (int fc = 0; fc < 4; ++fc) {
            float s = ps[fc], q2 = pq[fc];
            s += __shfl_xor(s, 16); s += __shfl_xor(s, 32);
            q2 += __shfl_xor(q2, 16); q2 += __shfl_xor(q2, 32);
            if (lane < 16) {
                int col = colbase + wc * 64 + fc * 16 + lane;
                atomicAdd(&ssum[c * 256 + col], s);
                atomicAdd(&ssq[c * 256 + col], q2);
            }
        }
    }
}

// ---------------- fp32 tiled GEMM (one-time base GEMM) ----------------
__global__ __launch_bounds__(256) void gemm_k(const float* __restrict__ A1, int lda1,
                                              const float* __restrict__ W1, int K1,
                                              const float* __restrict__ bias,
                                              float* __restrict__ Y, int Mrows) {
    __shared__ float As[16][132];
    __shared__ float Bs[16][132];
    float acc[8][8];
#pragma unroll
    for (int i = 0; i < 8; ++i)
#pragma unroll
        for (int j = 0; j < 8; ++j) acc[i][j] = 0.f;

    const int tid = threadIdx.x;
    const int tr = tid >> 4, tc = tid & 15;
    const int rowbase = blockIdx.y * 128, colbase = blockIdx.x * 128;

    for (int k0 = 0; k0 < K1; k0 += 16) {
#pragma unroll
        for (int ii = 0; ii < 2; ++ii) {
            int i = tid + ii * 256;
            int rr = i >> 2, qq = i & 3;
            int grow = rowbase + rr;
            float4 vv = make_float4(0.f, 0.f, 0.f, 0.f);
            if (grow < Mrows) vv = *(const float4*)&A1[(size_t)grow * lda1 + k0 + qq * 4];
            As[qq * 4 + 0][rr] = vv.x;
            As[qq * 4 + 1][rr] = vv.y;
            As[qq * 4 + 2][rr] = vv.z;
            As[qq * 4 + 3][rr] = vv.w;
        }
#pragma unroll
        for (int ii = 0; ii < 2; ++ii) {
            int i = tid + ii * 256;
            int rr = i >> 5, qq = i & 31;
            float4 vv = *(const float4*)&W1[(size_t)(k0 + rr) * 256 + colbase + qq * 4];
            *(float4*)&Bs[rr][qq * 4] = vv;
        }
        __syncthreads();
#pragma unroll
        for (int kk = 0; kk < 16; ++kk) {
            float a[8], b[8];
            *(float4*)&a[0] = *(const float4*)&As[kk][tr * 4];
            *(float4*)&a[4] = *(const float4*)&As[kk][64 + tr * 4];
            *(float4*)&b[0] = *(const float4*)&Bs[kk][tc * 4];
            *(float4*)&b[4] = *(const float4*)&Bs[kk][64 + tc * 4];
#pragma unroll
            for (int i = 0; i < 8; ++i)
#pragma unroll
                for (int j = 0; j < 8; ++j)
                    acc[i][j] = fmaf(a[i], b[j], acc[i][j]);
        }
        __syncthreads();
    }

    float4 blo = *(const float4*)&bias[colbase + tc * 4];
    float4 bhi = *(const float4*)&bias[colbase + 64 + tc * 4];
    float bb[8] = {blo.x, blo.y, blo.z, blo.w, bhi.x, bhi.y, bhi.z, bhi.w};
#pragma unroll
    for (int i = 0; i < 8; ++i)
#pragma unroll
        for (int j = 0; j < 8; ++j) acc[i][j] += bb[j];

#pragma unroll
    for (int i = 0; i < 8; ++i) {
        int lrow = (i < 4) ? (tr * 4 + i) : (64 + tr * 4 + (i - 4));
        int grow = rowbase + lrow;
        if (grow < Mrows) {
            *(float4*)&Y[(size_t)grow * 256 + colbase + tc * 4] =
                make_float4(acc[i][0], acc[i][1], acc[i][2], acc[i][3]);
            *(float4*)&Y[(size_t)grow * 256 + colbase + 64 + tc * 4] =
                make_float4(acc[i][4], acc[i][5], acc[i][6], acc[i][7]);
        }
    }
}

// ---------------- per-row epilogue with MFMA channel-attention ----------------
// A: vectorized load+norm (LDS mu/rs) -> B: t=relu(x@W1+b1) MFMA ->
// C: y=t@W2 MFMA fused sigmoid*x (+res) gelu + shfl stats -> D: vectorized store
template <int NORM, int RES, int SMODE>
__global__ __launch_bounds__(256) void apply_k(const u16* __restrict__ Yin,
                                               u16* __restrict__ Hout,
                                               const u16* __restrict__ Hsc,
                                               const u16* __restrict__ W1p,
                                               const float* __restrict__ b1,
                                               const u16* __restrict__ W2p,
                                               const float* __restrict__ b2,
                                               const float* __restrict__ mu,
                                               const float* __restrict__ rs,
                                               float* __restrict__ ssum,
                                               float* __restrict__ ssq) {
    __shared__ u16 vbf[16 * 264];
    __shared__ u16 scs[(RES ? 16 : 1) * 264];
    __shared__ float tpart[4 * 528];           // stride 33 per 16-col row group
    __shared__ u16 tbf[16 * 40];
    __shared__ float smu[NORM ? 256 : 1], srs[NORM ? 256 : 1];
    const int c = blockIdx.z, n0 = blockIdx.x * 16, tid = threadIdx.x;
    const int lane = tid & 63, wid = tid >> 6;
    const size_t rowbase = ((size_t)c * N_ + n0) * 256;

    // phase A: vectorized load + normalize (mu/rs staged in LDS)
    if (NORM) { smu[tid] = mu[c * 256 + tid]; srs[tid] = rs[c * 256 + tid]; }
    {
        us8v x0, x1, r0, r1;
        {
            const int row = tid >> 5, cb = (tid & 31) * 8;
            x0 = *(const us8v*)&Yin[rowbase + row * 256 + cb];
            if (RES) r0 = *(const us8v*)&Hsc[rowbase + row * 256 + cb];
        }
        {
            const int flat = tid + 256;
            const int row = flat >> 5, cb = (flat & 31) * 8;
            x1 = *(const us8v*)&Yin[rowbase + row * 256 + cb];
            if (RES) r1 = *(const us8v*)&Hsc[rowbase + row * 256 + cb];
        }
        if (NORM) __syncthreads();   // smu/srs ready
        {
            const int row = tid >> 5, ch = tid & 31, cb = ch * 8;
            if (NORM) {
                us8v y;
#pragma unroll
                for (int j = 0; j < 8; ++j)
                    y[j] = f2bf((bf2f(x0[j]) - smu[cb + j]) * srs[cb + j]);
                *(us8v*)&vbf[vswz(row, ch)] = y;
            } else {
                *(us8v*)&vbf[vswz(row, ch)] = x0;
            }
            if (RES) *(us8v*)&scs[vswz(row, ch)] = r0;
        }
        {
            const int flat = tid + 256;
            const int row = flat >> 5, ch = flat & 31, cb = ch * 8;
            if (NORM) {
                us8v y;
#pragma unroll
                for (int j = 0; j < 8; ++j)
                    y[j] = f2bf((bf2f(x1[j]) - smu[cb + j]) * srs[cb + j]);
                *(us8v*)&vbf[vswz(row, ch)] = y;
            } else {
                *(us8v*)&vbf[vswz(row, ch)] = x1;
            }
            if (RES) *(us8v*)&scs[vswz(row, ch)] = r1;
        }
    }
    __syncthreads();

    // phase B: t_partial = x(K-slice) @ W1, wave w owns K in [w*64, w*64+64)
    {
        const int row = lane & 15;
        const int kq = lane >> 4;
        f32x4 at0 = (f32x4)0.f, at1 = (f32x4)0.f;
#pragma unroll
        for (int ks = 0; ks < 2; ++ks) {
            const int chunk = wid * 8 + ks * 4 + kq;
            s16x8 aF = *(const s16x8*)&vbf[vswz(row, chunk)];
            s16x8 bF0 = *(const s16x8*)&W1p[(((wid * 2 + ks) * 2 + 0) * 64 + lane) * 8];
            s16x8 bF1 = *(const s16x8*)&W1p[(((wid * 2 + ks) * 2 + 1) * 64 + lane) * 8];
            at0 = __builtin_amdgcn_mfma_f32_16x16x32_bf16(aF, bF0, at0, 0, 0, 0);
            at1 = __builtin_amdgcn_mfma_f32_16x16x32_bf16(aF, bF1, at1, 0, 0, 0);
        }
#pragma unroll
        for (int i = 0; i < 4; ++i) {
            tpart[wid * 528 + (kq * 4 + i) * 33 + (lane & 15)] = at0[i];
            tpart[wid * 528 + (kq * 4 + i) * 33 + 16 + (lane & 15)] = at1[i];
        }
    }
    __syncthreads();

    // reduce partials across waves, +b1, relu -> tbf
#pragma unroll
    for (int ii = 0; ii < 2; ++ii) {
        int idx = tid + ii * 256;
        int nr = idx >> 5, col = idx & 31;
        float s = tpart[nr * 33 + col] + tpart[528 + nr * 33 + col] +
                  tpart[1056 + nr * 33 + col] + tpart[1584 + nr * 33 + col];
        s += b1[col];
        tbf[nr * 40 + col] = f2bf(fmaxf(s, 0.f));
    }
    __syncthreads();

    // phase C: y = t @ W2, fused sigmoid * x (+res), gelu; stats via shfl
    {
        const int cl = lane & 15, kq = lane >> 4;
        s16x8 aF = *(const s16x8*)&tbf[cl * 40 + kq * 8];
        float ps[4] = {0, 0, 0, 0}, pq[4] = {0, 0, 0, 0};
#pragma unroll
        for (int q = 0; q < 4; ++q) {
            const int colb = (wid * 4 + q) * 16;
            const int chunk = (colb + cl) >> 3, within = cl & 7;
            s16x8 bF = *(const s16x8*)&W2p[((wid * 4 + q) * 64 + lane) * 8];
            f32x4 acc = __builtin_amdgcn_mfma_f32_16x16x32_bf16(aF, bF, (f32x4)0.f, 0, 0, 0);
            const float b2v = b2[colb + cl];
#pragma unroll
            for (int i = 0; i < 4; ++i) {
                const int row = kq * 4 + i;
                const int ea = vswz(row, chunk) + within;
                float s = acc[i] + b2v;
                float sig = 1.0f / (1.0f + __expf(-s));
                float val = sig * bf2f(vbf[ea]);
                if (RES) val += bf2f(scs[ea]);
                val = gelu_f(val);
                vbf[ea] = f2bf(val);
                if (SMODE) { ps[q] += val; if (SMODE == 1) pq[q] += val * val; }
            }
        }
        if (SMODE) {
#pragma unroll
            for (int q = 0; q < 4; ++q) {
                float s = ps[q];
                s += __shfl_xor(s, 16); s += __shfl_xor(s, 32);
                if (SMODE == 1) {
                    float q2 = pq[q];
                    q2 += __shfl_xor(q2, 16); q2 += __shfl_xor(q2, 32);
                    if (lane < 16) atomicAdd(&ssq[c * 256 + (wid * 4 + q) * 16 + lane], q2);
                }
                if (lane < 16) atomicAdd(&ssum[c * 256 + (wid * 4 + q) * 16 + lane], s);
            }
        }
    }
    __syncthreads();

    // phase D: vectorized store
#pragma unroll
    for (int it = 0; it < 2; ++it) {
        const int flat = tid + it * 256;
        const int row = flat >> 5, ch = flat & 31;
        us8v h = *(const us8v*)&vbf[vswz(row, ch)];
        *(us8v*)&Hout[rowbase + row * 256 + ch * 8] = h;
    }
}

// ---------------- classifier ----------------
__global__ __launch_bounds__(256) void cls_k(const float* __restrict__ pooled_sum,
                                             const float* __restrict__ clsW,
                                             const float* __restrict__ clsb,
                                             float* __restrict__ out) {
    __shared__ float red[256];
    int c = blockIdx.x, d = threadIdx.x;
    red[d] = pooled_sum[c * 256 + d] * (1.0f / (float)N_) * clsW[d];
    __syncthreads();
    for (int s = 128; s > 0; s >>= 1) {
        if (d < s) red[d] += red[d + s];
        __syncthreads();
    }
    if (d == 0) out[c] = red[0] + clsb[0];
}

// ---------------- host launch ----------------
static inline size_t alup(size_t x) { return (x + 255) & ~(size_t)255; }

extern "C" void kernel_launch(void* const* d_in, const int* in_sizes, int n_in,
                              void* d_out, int out_size, void* d_ws, size_t ws_size,
                              hipStream_t stream) {
    const int*   xcfg   = (const int*)d_in[0];
    const float* xfeat  = (const float*)d_in[1];
    const int*   xlay   = (const int*)d_in[2];
    const int*   xop    = (const int*)d_in[3];
    const int*   ei     = (const int*)d_in[4];
    const int*   ncid   = (const int*)d_in[5];
    const float* embO   = (const float*)d_in[6];
    const float* embL   = (const float*)d_in[7];
    const float* lin1W  = (const float*)d_in[8];
    const float* lin1b  = (const float*)d_in[9];
    const float* ca1W1  = (const float*)d_in[10];
    const float* ca1b1  = (const float*)d_in[11];
    const float* ca1W2  = (const float*)d_in[12];
    const float* ca1b2  = (const float*)d_in[13];
    const float* lin2W  = (const float*)d_in[14];
    const float* lin2b  = (const float*)d_in[15];
    const float* ca2W1  = (const float*)d_in[16];
    const float* ca2b1  = (const float*)d_in[17];
    const float* ca2W2  = (const float*)d_in[18];
    const float* ca2b2  = (const float*)d_in[19];
    const float* sageWl = (const float*)d_in[20];
    const float* sagebl = (const float*)d_in[21];
    const float* sageWr = (const float*)d_in[22];
    const float* scaW1  = (const float*)d_in[23];
    const float* scab1  = (const float*)d_in[24];
    const float* scaW2  = (const float*)d_in[25];
    const float* scab2  = (const float*)d_in[26];
    const float* clsW   = (const float*)d_in[27];
    const float* clsb   = (const float*)d_in[28];
    float* out = (float*)d_out;

    // ---- workspace carve-up ----
    char* w = (char*)d_ws;
    size_t o = 0;
    auto take = [&](size_t bytes) { char* p = w + o; o = alup(o + bytes); return p; };
    float* base    = (float*)take((size_t)N_ * 256 * 4);
    float* feat162 = (float*)take((size_t)N_ * 176 * 4);
    float* W162    = (float*)take((size_t)176 * 256 * 4);
    float* T       = (float*)take((size_t)18 * 8 * 256 * 4);
    float* csum    = (float*)take((size_t)256 * 4);
    float* stats   = (float*)take((size_t)6 * 8192 * 4);
    float* MU      = (float*)take((size_t)5 * 4096 * 4);
    float* RS      = (float*)take((size_t)5 * 4096 * 4);
    float* invcnt  = (float*)take((size_t)N_ * 4);
    int*   cnt     = (int*)take((size_t)N_ * 4);
    int*   off     = (int*)take((size_t)(N_ + 1) * 4);
    int*   cursor  = (int*)take((size_t)N_ * 4);
    int*   csr     = (int*)take((size_t)E_ * 4);
    int*   cfgpos  = (int*)take((size_t)N_ * 4);
    u16*   Wt2     = (u16*)take((size_t)256 * 256 * 2);
    u16*   Wfold   = (u16*)take((size_t)C_ * 256 * 512 * 2);   // 4 MB
    float* biasF   = (float*)take((size_t)C_ * 256 * 4);
    u16*   CAW1    = (u16*)take((size_t)5 * 8192 * 2);         // packed frag order
    u16*   CAW2    = (u16*)take((size_t)5 * 8192 * 2);

    const size_t slab = (size_t)SZ_ * 2;                       // bf16: 5.12 MB
    size_t avail = (ws_size > o) ? (ws_size - o) : 0;
    int Cc = (int)(avail / (3 * slab + 768));
    if (Cc > C_) Cc = C_;
    if (Cc < 1) Cc = 1;
    u16* BufH = (u16*)take((size_t)Cc * slab);
    u16* BufY = (u16*)take((size_t)Cc * slab);
    u16* BufA = (u16*)take((size_t)Cc * slab);
    (void)in_sizes; (void)n_in; (void)out_size;

    auto S = [&](int s) { return stats + (size_t)s * 8192; };
    auto Q = [&](int s) { return stats + (size_t)s * 8192 + 4096; };

    hipMemsetAsync(stats, 0, 6 * 8192 * 4, stream);
    hipMemsetAsync(cnt, 0, N_ * 4, stream);
    hipMemsetAsync(cfgpos, 0xFF, N_ * 4, stream);

    // shared prep
    tbl_k<<<144, 256, 0, stream>>>(embL, lin1W, T);
    csum_k<<<1, 256, 0, stream>>>(T, csum);
    feat_k<<<N_, 192, 0, stream>>>(xfeat, xlay, xop, embL, embO, feat162);
    wpack_k<<<176, 256, 0, stream>>>(lin1W, W162);
    wt2_k<<<256, 256, 0, stream>>>(lin2W, Wt2);
    packw1_k<<<32, 256, 0, stream>>>(ca1W1, CAW1 + 0 * 8192);
    packw1_k<<<32, 256, 0, stream>>>(ca2W1, CAW1 + 1 * 8192);
    packw1_k<<<32, 256, 0, stream>>>(scaW1 + 0 * 8192, CAW1 + 2 * 8192);
    packw1_k<<<32, 256, 0, stream>>>(scaW1 + 1 * 8192, CAW1 + 3 * 8192);
    packw1_k<<<32, 256, 0, stream>>>(scaW1 + 2 * 8192, CAW1 + 4 * 8192);
    packw2_k<<<32, 256, 0, stream>>>(ca1W2, CAW2 + 0 * 8192);
    packw2_k<<<32, 256, 0, stream>>>(ca2W2, CAW2 + 1 * 8192);
    packw2_k<<<32, 256, 0, stream>>>(scaW2 + 0 * 8192, CAW2 + 2 * 8192);
    packw2_k<<<32, 256, 0, stream>>>(scaW2 + 1 * 8192, CAW2 + 3 * 8192);
    packw2_k<<<32, 256, 0, stream>>>(scaW2 + 2 * 8192, CAW2 + 4 * 8192);
    cfgpos_k<<<(NC_ + 255) / 256, 256, 0, stream>>>(ncid, cfgpos);
    hist_k<<<(E_ + 255) / 256, 256, 0, stream>>>(ei, cnt);
    scan_k<<<1, 1024, 0, stream>>>(cnt, off, cursor, invcnt);
    fill_k<<<(E_ + 255) / 256, 256, 0, stream>>>(ei, cursor, csr);

    // base = feat162 @ W162 + lin1_b (fp32, one-time)
    gemm_k<<<dim3(2, 79, 1), 256, 0, stream>>>(feat162, 176, W162, 176, lin1b, base, N_);

    // ---- per-config-chunk pipeline ----
    for (int c0 = 0; c0 < C_; c0 += Cc) {
        const int nc = (C_ - c0 < Cc) ? (C_ - c0) : Cc;
        const int co = c0 * 256;

        lin1_cfg_k<<<dim3(NC_ / 16, 1, nc), 256, 0, stream>>>(
            base, T, ncid, xcfg + (size_t)c0 * NC_ * 18, BufH, S(0) + co, Q(0) + co);
        lin1_unc_k<<<625, 256, 0, stream>>>(
            base, csum, cfgpos, nc, BufH, S(0) + co, Q(0) + co);
        finstat_k<<<nc, 256, 0, stream>>>(S(0) + co, Q(0) + co, MU + co, RS + co);

        apply_k<1, 0, 0><<<dim3(625, 1, nc), 256, 0, stream>>>(
            BufH, BufH, nullptr, CAW1 + 0 * 8192, ca1b1, CAW2 + 0 * 8192, ca1b2,
            MU + co, RS + co, nullptr, nullptr);

        mgemm_k<1><<<dim3(2, 79, nc), 256, 0, stream>>>(
            BufH, SZ_, nullptr, 0, Wt2, 0, 256, 256,
            lin2b, 0, BufY, SZ_, N_, S(1) + co, Q(1) + co);
        finstat_k<<<nc, 256, 0, stream>>>(S(1) + co, Q(1) + co, MU + 4096 + co, RS + 4096 + co);

        apply_k<1, 0, 1><<<dim3(625, 1, nc), 256, 0, stream>>>(
            BufY, BufY, nullptr, CAW1 + 1 * 8192, ca2b1, CAW2 + 1 * 8192, ca2b2,
            MU + 4096 + co, RS + 4096 + co, S(2) + co, Q(2) + co);

        for (int i = 0; i < 3; ++i) {
            const int set = 2 + i;
            finstat_k<<<nc, 256, 0, stream>>>(S(set) + co, Q(set) + co,
                                              MU + set * 4096 + co, RS + set * 4096 + co);
            foldw_k<<<dim3(256, nc), 256, 0, stream>>>(
                sageWl + (size_t)i * 65536, sageWr + (size_t)i * 65536, sagebl + i * 256,
                MU + set * 4096 + co, RS + set * 4096 + co,
                Wfold + (size_t)c0 * 256 * 512, biasF + co);
            agg_k<<<nc * 2500, 256, 0, stream>>>(BufY, off, csr, invcnt,
                                                 MU + set * 4096 + co, BufA);
            mgemm_k<0><<<dim3(2, 79, nc), 256, 0, stream>>>(
                BufA, SZ_, BufY, SZ_, Wfold + (size_t)c0 * 256 * 512, 256 * 512, 256, 512,
                biasF + co, 256, BufH, SZ_, N_, nullptr, nullptr);
            if (i < 2) {
                apply_k<0, 1, 1><<<dim3(625, 1, nc), 256, 0, stream>>>(
                    BufH, BufY, BufY,
                    CAW1 + (2 + i) * 8192, scab1 + i * 32,
                    CAW2 + (2 + i) * 8192, scab2 + i * 256,
                    nullptr, nullptr, S(3 + i) + co, Q(3 + i) + co);
            } else {
                apply_k<0, 1, 2><<<dim3(625, 1, nc), 256, 0, stream>>>(
                    BufH, BufY, BufY,
                    CAW1 + (2 + i) * 8192, scab1 + i * 32,
                    CAW2 + (2 + i) * 8192, scab2 + i * 256,
                    nullptr, nullptr, S(5) + co, nullptr);
            }
        }
    }

    cls_k<<<16, 256, 0, stream>>>(S(5), clsW, clsb, out);
}

// Round 8
// 1367.069 us; speedup vs baseline: 2.7765x; 1.0047x over previous
//
#include <hip/hip_runtime.h>
#include <hip/hip_bf16.h>
#include <math.h>

// ---------------- problem constants ----------------
constexpr int C_  = 16;
constexpr int N_  = 10000;
constexpr int NC_ = 2000;
constexpr int E_  = 50000;
constexpr int D_  = 256;
constexpr int SZ_ = N_ * D_;          // per-config slab (elements)
constexpr float EPS_ = 1e-5f;

typedef unsigned short u16;
typedef __attribute__((ext_vector_type(8))) unsigned short us8v;
typedef __attribute__((ext_vector_type(4))) unsigned short us4v;
typedef __attribute__((ext_vector_type(8))) short s16x8;
typedef __attribute__((ext_vector_type(4))) float f32x4;

typedef __attribute__((address_space(3))) unsigned int lds_uint;
typedef const __attribute__((address_space(1))) unsigned int glb_uint;

__device__ __forceinline__ u16 f2bf(float f) {
    __hip_bfloat16 h = __float2bfloat16(f);   // hw v_cvt (RNE), 1 instr vs 5
    return __builtin_bit_cast(u16, h);
}
__device__ __forceinline__ float bf2f(u16 h) {
    return __uint_as_float(((unsigned)h) << 16);
}
// fast gelu: erf via Abramowitz-Stegun 7.1.26 (|err|<=1.5e-7) + hw exp
__device__ __forceinline__ float gelu_f(float x) {
    float z = x * 0.70710678118654752f;
    float az = fabsf(z);
    float t = 1.f / fmaf(0.3275911f, az, 1.f);
    float p = t * (0.254829592f + t * (-0.284496736f + t * (1.421413741f +
              t * (-1.453152027f + t * 1.061405429f))));
    float e = p * __expf(-z * z);
    float erfv = (z >= 0.f) ? (1.f - e) : (e - 1.f);
    return 0.5f * x * (1.f + erfv);
}

// ---------------- tiny prep kernels ----------------

__global__ __launch_bounds__(256) void tbl_k(const float* __restrict__ embL,
                                             const float* __restrict__ W,
                                             float* __restrict__ T) {
    int b = blockIdx.x;            // 0..143
    int s = b >> 3, i = b & 7, d = threadIdx.x;
    float acc = 0.f;
#pragma unroll
    for (int k = 0; k < 4; ++k)
        acc = fmaf(embL[i * 4 + k], W[(134 + s * 4 + k) * 256 + d], acc);
    T[(s * 8 + i) * 256 + d] = acc;
}

// csum[d] = sum_s T[s][0][d]
__global__ __launch_bounds__(256) void csum_k(const float* __restrict__ T,
                                              float* __restrict__ cs) {
    int d = threadIdx.x;
    float a = 0.f;
#pragma unroll
    for (int s = 0; s < 18; ++s) a += T[(s * 8) * 256 + d];
    cs[d] = a;
}

__global__ __launch_bounds__(192) void feat_k(const float* __restrict__ xf,
                                              const int* __restrict__ xlay,
                                              const int* __restrict__ xop,
                                              const float* __restrict__ embL,
                                              const float* __restrict__ embO,
                                              float* __restrict__ f) {
    int n = blockIdx.x, j = threadIdx.x;
    if (j >= 176) return;
    float v;
    if (j < 134) v = xf[n * 134 + j];
    else if (j < 158) { int q = j - 134; int t = q >> 2, k = q & 3; v = embL[(xlay[n * 6 + t] + 2) * 4 + k]; }
    else if (j < 162) { int k = j - 158; v = embO[xop[n] * 4 + k]; }
    else v = 0.f;
    f[n * 176 + j] = v;
}

__global__ __launch_bounds__(256) void wpack_k(const float* __restrict__ W,
                                               float* __restrict__ Wp) {
    int j = blockIdx.x, d = threadIdx.x;
    float v = 0.f;
    if (j < 134) v = W[j * 256 + d];
    else if (j < 158) v = W[(206 + j - 134) * 256 + d];
    else if (j < 162) v = W[(230 + j - 158) * 256 + d];
    Wp[j * 256 + d] = v;
}

// pack channel-attn W1 [256][32] into MFMA fragment order
__global__ __launch_bounds__(256) void packw1_k(const float* __restrict__ W1,
                                                u16* __restrict__ dst) {
    int i = blockIdx.x * 256 + threadIdx.x;    // 0..8191
    int j = i & 7, lane = (i >> 3) & 63, half = (i >> 9) & 1, ks = (i >> 10) & 1, wid = (i >> 11) & 3;
    int k = wid * 64 + ks * 32 + ((lane >> 4) << 3) + j;
    int col = half * 16 + (lane & 15);
    dst[i] = f2bf(W1[k * 32 + col]);
}
// pack channel-attn W2 [32][256] into MFMA fragment order
__global__ __launch_bounds__(256) void packw2_k(const float* __restrict__ W2,
                                                u16* __restrict__ dst) {
    int i = blockIdx.x * 256 + threadIdx.x;    // 0..8191
    int j = i & 7, lane = (i >> 3) & 63, q = (i >> 9) & 3, wid = (i >> 11) & 3;
    int kq = lane >> 4, cl = lane & 15;
    dst[i] = f2bf(W2[(kq * 8 + j) * 256 + (wid * 4 + q) * 16 + cl]);
}

__global__ __launch_bounds__(256) void cfgpos_k(const int* __restrict__ ncid,
                                                int* __restrict__ cfgpos) {
    int i = blockIdx.x * 256 + threadIdx.x;
    if (i < NC_) cfgpos[ncid[i]] = i;
}

__global__ __launch_bounds__(256) void hist_k(const int* __restrict__ ei, int* __restrict__ cnt) {
    int e = blockIdx.x * 256 + threadIdx.x;
    if (e < E_) atomicAdd(&cnt[ei[E_ + e]], 1);
}

__global__ __launch_bounds__(1024) void scan_k(const int* __restrict__ cnt,
                                               int* __restrict__ off,
                                               int* __restrict__ cursor,
                                               float* __restrict__ invcnt) {
    __shared__ int s[1024];
    int t = threadIdx.x;
    int base = t * 10;
    int local[10];
    int part = 0;
#pragma unroll
    for (int k = 0; k < 10; ++k) {
        int idx = base + k;
        int v = (idx < N_) ? cnt[idx] : 0;
        local[k] = v; part += v;
    }
    s[t] = part;
    __syncthreads();
    for (int o = 1; o < 1024; o <<= 1) {
        int val = (t >= o) ? s[t - o] : 0;
        __syncthreads();
        s[t] += val;
        __syncthreads();
    }
    int pre = s[t] - part;
#pragma unroll
    for (int k = 0; k < 10; ++k) {
        int idx = base + k;
        if (idx < N_) {
            off[idx] = pre;
            cursor[idx] = pre;
            invcnt[idx] = 1.0f / (float)(local[k] > 1 ? local[k] : 1);
            pre += local[k];
        }
    }
    if (t == 1023) off[N_] = s[1023];
}

__global__ __launch_bounds__(256) void fill_k(const int* __restrict__ ei,
                                              int* __restrict__ cursor,
                                              int* __restrict__ csr) {
    int e = blockIdx.x * 256 + threadIdx.x;
    if (e < E_) {
        int t = ei[E_ + e];
        int p = atomicAdd(&cursor[t], 1);
        csr[p] = ei[e];
    }
}

// transpose lin2_W -> Wt2[j][k] bf16
__global__ __launch_bounds__(256) void wt2_k(const float* __restrict__ W,
                                             u16* __restrict__ Wt) {
    int j = blockIdx.x, k = threadIdx.x;
    Wt[j * 256 + k] = f2bf(W[k * 256 + j]);
}

// fold instance-norm into sage weights (per config)
__global__ __launch_bounds__(256) void foldw_k(const float* __restrict__ Wl,
                                               const float* __restrict__ Wr,
                                               const float* __restrict__ bl,
                                               const float* __restrict__ mu,
                                               const float* __restrict__ rs,
                                               u16* __restrict__ Wt,
                                               float* __restrict__ biasF) {
    __shared__ float red[256];
    int c = blockIdx.y, j = blockIdx.x, k = threadIdx.x;
    float rsv = rs[c * 256 + k], muv = mu[c * 256 + k];
    float fl = rsv * Wl[k * 256 + j];
    float fr = rsv * Wr[k * 256 + j];
    size_t wb = ((size_t)c * 256 + j) * 512;
    Wt[wb + k] = f2bf(fl);
    Wt[wb + 256 + k] = f2bf(fr);
    red[k] = muv * (fl + fr);
    __syncthreads();
    for (int s = 128; s > 0; s >>= 1) {
        if (k < s) red[k] += red[k + s];
        __syncthreads();
    }
    if (k == 0) biasF[c * 256 + j] = bl[j] - red[0];
}

// ---------------- lin1 (configured nodes) ----------------
__global__ __launch_bounds__(256) void lin1_cfg_k(const float* __restrict__ base,
                                                  const float* __restrict__ T,
                                                  const int* __restrict__ ncid,
                                                  const int* __restrict__ xcfg,
                                                  u16* __restrict__ H,
                                                  float* __restrict__ ssum,
                                                  float* __restrict__ ssq) {
    __shared__ int idxs[16][18];   // premultiplied by 256
    __shared__ int nid[16];
    const int c = blockIdx.z, j0 = blockIdx.x * 16, tid = threadIdx.x;
    if (tid < 16) nid[tid] = ncid[j0 + tid];
    for (int t = tid; t < 288; t += 256) {
        int row = t / 18, s = t - row * 18;
        idxs[row][s] = (xcfg[((size_t)c * NC_ + j0 + row) * 18 + s] + 2) * 256;
    }
    __syncthreads();
    const int d = tid;
    float psum = 0.f, psq = 0.f;
    for (int g = 0; g < 16; g += 4) {
        float acc[4];
#pragma unroll
        for (int gg = 0; gg < 4; ++gg) acc[gg] = base[(size_t)nid[g + gg] * 256 + d];
#pragma unroll
        for (int s = 0; s < 18; ++s) {
            const float* Ts = &T[s * 2048 + d];
#pragma unroll
            for (int gg = 0; gg < 4; ++gg)
                acc[gg] += Ts[idxs[g + gg][s]];
        }
#pragma unroll
        for (int gg = 0; gg < 4; ++gg) {
            H[((size_t)c * N_ + nid[g + gg]) * 256 + d] = f2bf(acc[gg]);
            psum += acc[gg]; psq += acc[gg] * acc[gg];
        }
    }
    atomicAdd(&ssum[c * 256 + d], psum);
    atomicAdd(&ssq[c * 256 + d], psq);
}

// ---------------- lin1 (unconfigured nodes) ----------------
__global__ __launch_bounds__(256) void lin1_unc_k(const float* __restrict__ base,
                                                  const float* __restrict__ csum,
                                                  const int* __restrict__ cfgpos,
                                                  int nc,
                                                  u16* __restrict__ H,
                                                  float* __restrict__ ssum,
                                                  float* __restrict__ ssq) {
    __shared__ float red[2048];
    const int n0 = blockIdx.x * 16, tid = threadIdx.x;
    float ps[8] = {0, 0, 0, 0, 0, 0, 0, 0}, pq[8] = {0, 0, 0, 0, 0, 0, 0, 0};
#pragma unroll
    for (int it = 0; it < 2; ++it) {
        const int flat = tid + it * 256;
        const int row = flat >> 5, cb = (flat & 31) * 8;
        const int n = n0 + row;
        if (cfgpos[n] >= 0) continue;
        us8v b;
#pragma unroll
        for (int j = 0; j < 8; ++j) {
            float v = base[(size_t)n * 256 + cb + j] + csum[cb + j];
            b[j] = f2bf(v);
            ps[j] += v; pq[j] += v * v;
        }
        for (int c = 0; c < nc; ++c)
            *(us8v*)&H[((size_t)c * N_ + n) * 256 + cb] = b;
    }
#pragma unroll
    for (int j = 0; j < 8; ++j)
        red[((tid >> 5) * 32 + (tid & 31)) * 8 + j] = ps[j];
    __syncthreads();
    {
        const int cb2 = tid >> 3, j2 = tid & 7;
        float s = 0.f;
#pragma unroll
        for (int r8 = 0; r8 < 8; ++r8) s += red[(r8 * 32 + cb2) * 8 + j2];
        for (int c = 0; c < nc; ++c) atomicAdd(&ssum[c * 256 + tid], s);
    }
    __syncthreads();
#pragma unroll
    for (int j = 0; j < 8; ++j)
        red[((tid >> 5) * 32 + (tid & 31)) * 8 + j] = pq[j];
    __syncthreads();
    {
        const int cb2 = tid >> 3, j2 = tid & 7;
        float s = 0.f;
#pragma unroll
        for (int r8 = 0; r8 < 8; ++r8) s += red[(r8 * 32 + cb2) * 8 + j2];
        for (int c = 0; c < nc; ++c) atomicAdd(&ssq[c * 256 + tid], s);
    }
}

// finalize stats; also emits mrs = mu*rs for fma-folded normalize
__global__ __launch_bounds__(256) void finstat_k(const float* __restrict__ ssum,
                                                 const float* __restrict__ ssq,
                                                 float* __restrict__ mu,
                                                 float* __restrict__ rs,
                                                 float* __restrict__ mrs) {
    int i = blockIdx.x * 256 + threadIdx.x;
    float m = ssum[i] * (1.0f / (float)N_);
    float v = ssq[i] * (1.0f / (float)N_) - m * m;
    float r = rsqrtf(v + EPS_);
    mu[i] = m;
    rs[i] = r;
    mrs[i] = m * r;
}

// ---------------- CSR gather-mean: vector index load + shfl broadcast ----------------
__global__ __launch_bounds__(256) void agg_k(const u16* __restrict__ H,
                                             const int* __restrict__ off,
                                             const int* __restrict__ csr,
                                             const float* __restrict__ invcnt,
                                             const float* __restrict__ mu,
                                             u16* __restrict__ Agg) {
    int wave = threadIdx.x >> 6, lane = threadIdx.x & 63;
    int pair = blockIdx.x * 4 + wave;
    int c = pair / N_, t = pair - c * N_;
    int d4 = lane * 4;
    int o0 = off[t], o1 = off[t + 1];
    int deg = o1 - o0;
    us4v o;
    if (deg > 0) {
        int myidx = (lane < deg) ? csr[o0 + lane] : 0;
        const u16* Hc = H + (size_t)c * SZ_ + d4;
        float ax = 0.f, ay = 0.f, az = 0.f, aw = 0.f;
        int lim = deg < 64 ? deg : 64;
        int i = 0;
        for (; i + 4 <= lim; i += 4) {
            int s0 = __shfl(myidx, i), s1 = __shfl(myidx, i + 1);
            int s2 = __shfl(myidx, i + 2), s3 = __shfl(myidx, i + 3);
            us4v h0 = *(const us4v*)&Hc[(size_t)s0 * 256];
            us4v h1 = *(const us4v*)&Hc[(size_t)s1 * 256];
            us4v h2 = *(const us4v*)&Hc[(size_t)s2 * 256];
            us4v h3 = *(const us4v*)&Hc[(size_t)s3 * 256];
            ax += (bf2f(h0.x) + bf2f(h1.x)) + (bf2f(h2.x) + bf2f(h3.x));
            ay += (bf2f(h0.y) + bf2f(h1.y)) + (bf2f(h2.y) + bf2f(h3.y));
            az += (bf2f(h0.z) + bf2f(h1.z)) + (bf2f(h2.z) + bf2f(h3.z));
            aw += (bf2f(h0.w) + bf2f(h1.w)) + (bf2f(h2.w) + bf2f(h3.w));
        }
        for (; i < lim; ++i) {
            int s = __shfl(myidx, i);
            us4v h = *(const us4v*)&Hc[(size_t)s * 256];
            ax += bf2f(h.x); ay += bf2f(h.y); az += bf2f(h.z); aw += bf2f(h.w);
        }
        for (int j = o0 + 64; j < o1; ++j) {     // rare: degree > 64
            int s = csr[j];
            us4v h = *(const us4v*)&Hc[(size_t)s * 256];
            ax += bf2f(h.x); ay += bf2f(h.y); az += bf2f(h.z); aw += bf2f(h.w);
        }
        float inv = invcnt[t];
        o.x = f2bf(ax * inv); o.y = f2bf(ay * inv);
        o.z = f2bf(az * inv); o.w = f2bf(aw * inv);
    } else {
        o.x = f2bf(mu[c * 256 + d4 + 0]);
        o.y = f2bf(mu[c * 256 + d4 + 1]);
        o.z = f2bf(mu[c * 256 + d4 + 2]);
        o.w = f2bf(mu[c * 256 + d4 + 3]);
    }
    *(us4v*)&Agg[((size_t)c * N_ + t) * 256 + d4] = o;
}

// ---------------- bf16 MFMA GEMM: Y = [A1|A2] @ Wt^T + bias ----------------
template <int STATS>
__global__ __launch_bounds__(256) void mgemm_k(
    const u16* __restrict__ A1, size_t sA1,
    const u16* __restrict__ A2, size_t sA2,
    const u16* __restrict__ Wt, size_t sW, int K1, int Ktot,
    const float* __restrict__ bias, size_t sBias,
    u16* __restrict__ Y, size_t sY, int Mrows,
    float* __restrict__ ssum, float* __restrict__ ssq)
{
    __shared__ u16 Asm[128 * 64];
    __shared__ u16 Bsm[128 * 64];
    const int tid = threadIdx.x;
    const int lane = tid & 63, wid = tid >> 6;
    const int wr = wid >> 1, wc = wid & 1;

    // XCD-aware bijective remap of the flattened block id
    const int gx = gridDim.x, gy = gridDim.y;
    int nwg = gx * gy * gridDim.z;
    int orig = blockIdx.x + gx * (blockIdx.y + gy * blockIdx.z);
    int q = nwg >> 3, r = nwg & 7;
    int xcd = orig & 7, idx = orig >> 3;
    int swz = (xcd < r ? xcd * (q + 1) : r * (q + 1) + (xcd - r) * q) + idx;
    const int bx = swz % gx;
    const int tmp = swz / gx;
    const int by = tmp % gy;
    const int c  = tmp / gy;

    const int rowbase = by * 128, colbase = bx * 128;

    const u16* A1p = A1 + (size_t)c * sA1;
    const u16* A2p = A2 ? (A2 + (size_t)c * sA2) : nullptr;
    const u16* Wp  = Wt + (size_t)c * sW;

    f32x4 acc[4][4];
#pragma unroll
    for (int i = 0; i < 4; ++i)
#pragma unroll
        for (int j = 0; j < 4; ++j) acc[i][j] = (f32x4)0.f;

    const int lrow = lane >> 3;        // row within the wave's 8-row group
    const int lchunk = lane & 7;       // 16B chunk within the row

    for (int k0 = 0; k0 < Ktot; k0 += 64) {
        const u16* asrc; int ak;
        if (k0 < K1) { asrc = A1p; ak = k0; } else { asrc = A2p; ak = k0 - K1; }
#pragma unroll
        for (int i = 0; i < 4; ++i) {
            const int row = (wid * 4 + i) * 8 + lrow;          // 0..127
            const int srcchunk = lchunk ^ (row & 7);           // inverse of read-side XOR
            int garow = rowbase + row;
            if (garow >= Mrows) garow = Mrows - 1;             // clamp: values unused
            const u16* ga = asrc + (size_t)garow * 256 + ak + srcchunk * 8;
            __builtin_amdgcn_global_load_lds((glb_uint*)ga,
                (lds_uint*)(Asm + (wid * 4 + i) * 512), 16, 0, 0);
            const u16* gb = Wp + (size_t)(colbase + row) * Ktot + k0 + srcchunk * 8;
            __builtin_amdgcn_global_load_lds((glb_uint*)gb,
                (lds_uint*)(Bsm + (wid * 4 + i) * 512), 16, 0, 0);
        }
        __syncthreads();
#pragma unroll
        for (int ks = 0; ks < 2; ++ks) {
            s16x8 aF[4], bF[4];
            const int kk = ks * 32 + ((lane >> 4) << 3);
#pragma unroll
            for (int f = 0; f < 4; ++f) {
                int ar = wr * 64 + f * 16 + (lane & 15);
                aF[f] = *(const s16x8*)&Asm[(ar * 64 + kk) ^ ((ar & 7) << 3)];
                int br = wc * 64 + f * 16 + (lane & 15);
                bF[f] = *(const s16x8*)&Bsm[(br * 64 + kk) ^ ((br & 7) << 3)];
            }
#pragma unroll
            for (int fr = 0; fr < 4; ++fr)
#pragma unroll
                for (int fc = 0; fc < 4; ++fc)
                    acc[fr][fc] = __builtin_amdgcn_mfma_f32_16x16x32_bf16(
                        aF[fr], bF[fc], acc[fr][fc], 0, 0, 0);
        }
        __syncthreads();
    }

    float bcol[4];
#pragma unroll
    for (int fc = 0; fc < 4; ++fc)
        bcol[fc] = bias[(size_t)c * sBias + colbase + wc * 64 + fc * 16 + (lane & 15)];
    u16* Yp = Y + (size_t)c * sY;
    float ps[4] = {0, 0, 0, 0}, pq[4] = {0, 0, 0, 0};
#pragma unroll
    for (int fr = 0; fr < 4; ++fr) {
#pragma unroll
        for (int i = 0; i < 4; ++i) {
            int grow = rowbase + wr * 64 + fr * 16 + ((lane >> 4) << 2) + i;
            if (grow < Mrows) {
                size_t rb = (size_t)grow * 256 + colbase + wc * 64 + (lane & 15);
#pragma unroll
                for (int fc = 0; fc < 4; ++fc) {
                    float v = acc[fr][fc][i] + bcol[fc];
                    Yp[rb + fc * 16] = f2bf(v);
                    if (STATS) { ps[fc] += v; pq[fc] += v * v; }
                }
            }
        }
    }
    if (STATS) {
#pragma unroll
        for (int fc = 0; fc < 4; ++fc) {
            float s = ps[fc], q2 = pq[fc];
            s += __shfl_xor(s, 16); s += __shfl_xor(s, 32);
            q2 += __shfl_xor(q2, 16); q2 += __shfl_xor(q2, 32);
            if (lane < 16) {
                int col = colbase + wc * 64 + fc * 16 + lane;
                atomicAdd(&ssum[c * 256 + col], s);
                atomicAdd(&ssq[c * 256 + col], q2);
            }
        }
    }
}

// ---------------- fp32 tiled GEMM (one-time base GEMM) ----------------
__global__ __launch_bounds__(256) void gemm_k(const float* __restrict__ A1, int lda1,
                                              const float* __restrict__ W1, int K1,
                                              const float* __restrict__ bias,
                                              float* __restrict__ Y, int Mrows) {
    __shared__ float As[16][132];
    __shared__ float Bs[16][132];
    float acc[8][8];
#pragma unroll
    for (int i = 0; i < 8; ++i)
#pragma unroll
        for (int j = 0; j < 8; ++j) acc[i][j] = 0.f;

    const int tid = threadIdx.x;
    const int tr = tid >> 4, tc = tid & 15;
    const int rowbase = blockIdx.y * 128, colbase = blockIdx.x * 128;

    for (int k0 = 0; k0 < K1; k0 += 16) {
#pragma unroll
        for (int ii = 0; ii < 2; ++ii) {
            int i = tid + ii * 256;
            int rr = i >> 2, qq = i & 3;
            int grow = rowbase + rr;
            float4 vv = make_float4(0.f, 0.f, 0.f, 0.f);
            if (grow < Mrows) vv = *(const float4*)&A1[(size_t)grow * lda1 + k0 + qq * 4];
            As[qq * 4 + 0][rr] = vv.x;
            As[qq * 4 + 1][rr] = vv.y;
            As[qq * 4 + 2][rr] = vv.z;
            As[qq * 4 + 3][rr] = vv.w;
        }
#pragma unroll
        for (int ii = 0; ii < 2; ++ii) {
            int i = tid + ii * 256;
            int rr = i >> 5, qq = i & 31;
            float4 vv = *(const float4*)&W1[(size_t)(k0 + rr) * 256 + colbase + qq * 4];
            *(float4*)&Bs[rr][qq * 4] = vv;
        }
        __syncthreads();
#pragma unroll
        for (int kk = 0; kk < 16; ++kk) {
            float a[8], b[8];
            *(float4*)&a[0] = *(const float4*)&As[kk][tr * 4];
            *(float4*)&a[4] = *(const float4*)&As[kk][64 + tr * 4];
            *(float4*)&b[0] = *(const float4*)&Bs[kk][tc * 4];
            *(float4*)&b[4] = *(const float4*)&Bs[kk][64 + tc * 4];
#pragma unroll
            for (int i = 0; i < 8; ++i)
#pragma unroll
                for (int j = 0; j < 8; ++j)
                    acc[i][j] = fmaf(a[i], b[j], acc[i][j]);
        }
        __syncthreads();
    }

    float4 blo = *(const float4*)&bias[colbase + tc * 4];
    float4 bhi = *(const float4*)&bias[colbase + 64 + tc * 4];
    float bb[8] = {blo.x, blo.y, blo.z, blo.w, bhi.x, bhi.y, bhi.z, bhi.w};
#pragma unroll
    for (int i = 0; i < 8; ++i)
#pragma unroll
        for (int j = 0; j < 8; ++j) acc[i][j] += bb[j];

#pragma unroll
    for (int i = 0; i < 8; ++i) {
        int lrow = (i < 4) ? (tr * 4 + i) : (64 + tr * 4 + (i - 4));
        int grow = rowbase + lrow;
        if (grow < Mrows) {
            *(float4*)&Y[(size_t)grow * 256 + colbase + tc * 4] =
                make_float4(acc[i][0], acc[i][1], acc[i][2], acc[i][3]);
            *(float4*)&Y[(size_t)grow * 256 + colbase + 64 + tc * 4] =
                make_float4(acc[i][4], acc[i][5], acc[i][6], acc[i][7]);
        }
    }
}

// ---------------- per-row epilogue with MFMA channel-attention ----------------
// A: vectorized load+fma-norm (LDS rs/mrs) -> B: t=relu(x@W1+b1) MFMA ->
// C: y=t@W2 MFMA fused sigmoid*x (+res) gelu + shfl stats -> D: vectorized store
// vbf layout LINEAR (row stride 264 is odd-in-banks: phase-B reads are 2-way=free);
// tpart stride 33 (f32) to de-conflict the partial-sum stores.
template <int NORM, int RES, int SMODE>
__global__ __launch_bounds__(256) void apply_k(const u16* __restrict__ Yin,
                                               u16* __restrict__ Hout,
                                               const u16* __restrict__ Hsc,
                                               const u16* __restrict__ W1p,
                                               const float* __restrict__ b1,
                                               const u16* __restrict__ W2p,
                                               const float* __restrict__ b2,
                                               const float* __restrict__ rs,
                                               const float* __restrict__ mrs,
                                               float* __restrict__ ssum,
                                               float* __restrict__ ssq) {
    __shared__ u16 vbf[16 * 264];
    __shared__ u16 scs[(RES ? 16 : 1) * 264];
    __shared__ float tpart[4 * 528];           // stride 33 per 16-col row group
    __shared__ u16 tbf[16 * 40];
    __shared__ float srs[NORM ? 256 : 1], smrs[NORM ? 256 : 1];
    const int c = blockIdx.z, n0 = blockIdx.x * 16, tid = threadIdx.x;
    const int lane = tid & 63, wid = tid >> 6;
    const size_t rowbase = ((size_t)c * N_ + n0) * 256;

    // phase A: vectorized load + fma-normalize (rs/mrs staged in LDS)
    if (NORM) { srs[tid] = rs[c * 256 + tid]; smrs[tid] = mrs[c * 256 + tid]; }
    {
        us8v x0, x1, r0, r1;
        {
            const int row = tid >> 5, cb = (tid & 31) * 8;
            x0 = *(const us8v*)&Yin[rowbase + row * 256 + cb];
            if (RES) r0 = *(const us8v*)&Hsc[rowbase + row * 256 + cb];
        }
        {
            const int flat = tid + 256;
            const int row = flat >> 5, cb = (flat & 31) * 8;
            x1 = *(const us8v*)&Yin[rowbase + row * 256 + cb];
            if (RES) r1 = *(const us8v*)&Hsc[rowbase + row * 256 + cb];
        }
        if (NORM) __syncthreads();   // srs/smrs ready
        {
            const int row = tid >> 5, cb = (tid & 31) * 8;
            if (NORM) {
                us8v y;
#pragma unroll
                for (int j = 0; j < 8; ++j)
                    y[j] = f2bf(fmaf(bf2f(x0[j]), srs[cb + j], -smrs[cb + j]));
                *(us8v*)&vbf[row * 264 + cb] = y;
            } else {
                *(us8v*)&vbf[row * 264 + cb] = x0;
            }
            if (RES) *(us8v*)&scs[row * 264 + cb] = r0;
        }
        {
            const int flat = tid + 256;
            const int row = flat >> 5, cb = (flat & 31) * 8;
            if (NORM) {
                us8v y;
#pragma unroll
                for (int j = 0; j < 8; ++j)
                    y[j] = f2bf(fmaf(bf2f(x1[j]), srs[cb + j], -smrs[cb + j]));
                *(us8v*)&vbf[row * 264 + cb] = y;
            } else {
                *(us8v*)&vbf[row * 264 + cb] = x1;
            }
            if (RES) *(us8v*)&scs[row * 264 + cb] = r1;
        }
    }
    __syncthreads();

    // phase B: t_partial = x(K-slice) @ W1, wave w owns K in [w*64, w*64+64)
    {
        const int row = lane & 15;
        const int kq = lane >> 4;
        f32x4 at0 = (f32x4)0.f, at1 = (f32x4)0.f;
#pragma unroll
        for (int ks = 0; ks < 2; ++ks) {
            const int k = wid * 64 + ks * 32 + kq * 8;
            s16x8 aF = *(const s16x8*)&vbf[row * 264 + k];
            s16x8 bF0 = *(const s16x8*)&W1p[(((wid * 2 + ks) * 2 + 0) * 64 + lane) * 8];
            s16x8 bF1 = *(const s16x8*)&W1p[(((wid * 2 + ks) * 2 + 1) * 64 + lane) * 8];
            at0 = __builtin_amdgcn_mfma_f32_16x16x32_bf16(aF, bF0, at0, 0, 0, 0);
            at1 = __builtin_amdgcn_mfma_f32_16x16x32_bf16(aF, bF1, at1, 0, 0, 0);
        }
#pragma unroll
        for (int i = 0; i < 4; ++i) {
            tpart[wid * 528 + (kq * 4 + i) * 33 + (lane & 15)] = at0[i];
            tpart[wid * 528 + (kq * 4 + i) * 33 + 16 + (lane & 15)] = at1[i];
        }
    }
    __syncthreads();

    // reduce partials across waves, +b1, relu -> tbf
#pragma unroll
    for (int ii = 0; ii < 2; ++ii) {
        int idx = tid + ii * 256;
        int nr = idx >> 5, col = idx & 31;
        float s = tpart[nr * 33 + col] + tpart[528 + nr * 33 + col] +
                  tpart[1056 + nr * 33 + col] + tpart[1584 + nr * 33 + col];
        s += b1[col];
        tbf[nr * 40 + col] = f2bf(fmaxf(s, 0.f));
    }
    __syncthreads();

    // phase C: y = t @ W2, fused sigmoid * x (+res), gelu; stats via shfl
    {
        const int cl = lane & 15, kq = lane >> 4;
        s16x8 aF = *(const s16x8*)&tbf[cl * 40 + kq * 8];
        float ps[4] = {0, 0, 0, 0}, pq[4] = {0, 0, 0, 0};
#pragma unroll
        for (int q = 0; q < 4; ++q) {
            const int colb = (wid * 4 + q) * 16;
            s16x8 bF = *(const s16x8*)&W2p[((wid * 4 + q) * 64 + lane) * 8];
            f32x4 acc = __builtin_amdgcn_mfma_f32_16x16x32_bf16(aF, bF, (f32x4)0.f, 0, 0, 0);
            const float b2v = b2[colb + cl];
#pragma unroll
            for (int i = 0; i < 4; ++i) {
                const int row = kq * 4 + i;
                const int ea = row * 264 + colb + cl;
                float s = acc[i] + b2v;
                float sig = 1.0f / (1.0f + __expf(-s));
                float val = sig * bf2f(vbf[ea]);
                if (RES) val += bf2f(scs[ea]);
                val = gelu_f(val);
                vbf[ea] = f2bf(val);
                if (SMODE) { ps[q] += val; if (SMODE == 1) pq[q] += val * val; }
            }
        }
        if (SMODE) {
#pragma unroll
            for (int q = 0; q < 4; ++q) {
                float s = ps[q];
                s += __shfl_xor(s, 16); s += __shfl_xor(s, 32);
                if (SMODE == 1) {
                    float q2 = pq[q];
                    q2 += __shfl_xor(q2, 16); q2 += __shfl_xor(q2, 32);
                    if (lane < 16) atomicAdd(&ssq[c * 256 + (wid * 4 + q) * 16 + lane], q2);
                }
                if (lane < 16) atomicAdd(&ssum[c * 256 + (wid * 4 + q) * 16 + lane], s);
            }
        }
    }
    __syncthreads();

    // phase D: vectorized store
#pragma unroll
    for (int it = 0; it < 2; ++it) {
        const int flat = tid + it * 256;
        const int row = flat >> 5, cb = (flat & 31) * 8;
        us8v h = *(const us8v*)&vbf[row * 264 + cb];
        *(us8v*)&Hout[rowbase + row * 256 + cb] = h;
    }
}

// ---------------- classifier ----------------
__global__ __launch_bounds__(256) void cls_k(const float* __restrict__ pooled_sum,
                                             const float* __restrict__ clsW,
                                             const float* __restrict__ clsb,
                                             float* __restrict__ out) {
    __shared__ float red[256];
    int c = blockIdx.x, d = threadIdx.x;
    red[d] = pooled_sum[c * 256 + d] * (1.0f / (float)N_) * clsW[d];
    __syncthreads();
    for (int s = 128; s > 0; s >>= 1) {
        if (d < s) red[d] += red[d + s];
        __syncthreads();
    }
    if (d == 0) out[c] = red[0] + clsb[0];
}

// ---------------- host launch ----------------
static inline size_t alup(size_t x) { return (x + 255) & ~(size_t)255; }

extern "C" void kernel_launch(void* const* d_in, const int* in_sizes, int n_in,
                              void* d_out, int out_size, void* d_ws, size_t ws_size,
                              hipStream_t stream) {
    const int*   xcfg   = (const int*)d_in[0];
    const float* xfeat  = (const float*)d_in[1];
    const int*   xlay   = (const int*)d_in[2];
    const int*   xop    = (const int*)d_in[3];
    const int*   ei     = (const int*)d_in[4];
    const int*   ncid   = (const int*)d_in[5];
    const float* embO   = (const float*)d_in[6];
    const float* embL   = (const float*)d_in[7];
    const float* lin1W  = (const float*)d_in[8];
    const float* lin1b  = (const float*)d_in[9];
    const float* ca1W1  = (const float*)d_in[10];
    const float* ca1b1  = (const float*)d_in[11];
    const float* ca1W2  = (const float*)d_in[12];
    const float* ca1b2  = (const float*)d_in[13];
    const float* lin2W  = (const float*)d_in[14];
    const float* lin2b  = (const float*)d_in[15];
    const float* ca2W1  = (const float*)d_in[16];
    const float* ca2b1  = (const float*)d_in[17];
    const float* ca2W2  = (const float*)d_in[18];
    const float* ca2b2  = (const float*)d_in[19];
    const float* sageWl = (const float*)d_in[20];
    const float* sagebl = (const float*)d_in[21];
    const float* sageWr = (const float*)d_in[22];
    const float* scaW1  = (const float*)d_in[23];
    const float* scab1  = (const float*)d_in[24];
    const float* scaW2  = (const float*)d_in[25];
    const float* scab2  = (const float*)d_in[26];
    const float* clsW   = (const float*)d_in[27];
    const float* clsb   = (const float*)d_in[28];
    float* out = (float*)d_out;

    // ---- workspace carve-up ----
    char* w = (char*)d_ws;
    size_t o = 0;
    auto take = [&](size_t bytes) { char* p = w + o; o = alup(o + bytes); return p; };
    float* base    = (float*)take((size_t)N_ * 256 * 4);
    float* feat162 = (float*)take((size_t)N_ * 176 * 4);
    float* W162    = (float*)take((size_t)176 * 256 * 4);
    float* T       = (float*)take((size_t)18 * 8 * 256 * 4);
    float* csum    = (float*)take((size_t)256 * 4);
    float* stats   = (float*)take((size_t)6 * 8192 * 4);
    float* MU      = (float*)take((size_t)5 * 4096 * 4);
    float* RS      = (float*)take((size_t)5 * 4096 * 4);
    float* MRS     = (float*)take((size_t)5 * 4096 * 4);
    float* invcnt  = (float*)take((size_t)N_ * 4);
    int*   cnt     = (int*)take((size_t)N_ * 4);
    int*   off     = (int*)take((size_t)(N_ + 1) * 4);
    int*   cursor  = (int*)take((size_t)N_ * 4);
    int*   csr     = (int*)take((size_t)E_ * 4);
    int*   cfgpos  = (int*)take((size_t)N_ * 4);
    u16*   Wt2     = (u16*)take((size_t)256 * 256 * 2);
    u16*   Wfold   = (u16*)take((size_t)C_ * 256 * 512 * 2);   // 4 MB
    float* biasF   = (float*)take((size_t)C_ * 256 * 4);
    u16*   CAW1    = (u16*)take((size_t)5 * 8192 * 2);         // packed frag order
    u16*   CAW2    = (u16*)take((size_t)5 * 8192 * 2);

    const size_t slab = (size_t)SZ_ * 2;                       // bf16: 5.12 MB
    size_t avail = (ws_size > o) ? (ws_size - o) : 0;
    int Cc = (int)(avail / (3 * slab + 768));
    if (Cc > C_) Cc = C_;
    if (Cc < 1) Cc = 1;
    u16* BufH = (u16*)take((size_t)Cc * slab);
    u16* BufY = (u16*)take((size_t)Cc * slab);
    u16* BufA = (u16*)take((size_t)Cc * slab);
    (void)in_sizes; (void)n_in; (void)out_size;

    auto S = [&](int s) { return stats + (size_t)s * 8192; };
    auto Q = [&](int s) { return stats + (size_t)s * 8192 + 4096; };

    hipMemsetAsync(stats, 0, 6 * 8192 * 4, stream);
    hipMemsetAsync(cnt, 0, N_ * 4, stream);
    hipMemsetAsync(cfgpos, 0xFF, N_ * 4, stream);

    // shared prep
    tbl_k<<<144, 256, 0, stream>>>(embL, lin1W, T);
    csum_k<<<1, 256, 0, stream>>>(T, csum);
    feat_k<<<N_, 192, 0, stream>>>(xfeat, xlay, xop, embL, embO, feat162);
    wpack_k<<<176, 256, 0, stream>>>(lin1W, W162);
    wt2_k<<<256, 256, 0, stream>>>(lin2W, Wt2);
    packw1_k<<<32, 256, 0, stream>>>(ca1W1, CAW1 + 0 * 8192);
    packw1_k<<<32, 256, 0, stream>>>(ca2W1, CAW1 + 1 * 8192);
    packw1_k<<<32, 256, 0, stream>>>(scaW1 + 0 * 8192, CAW1 + 2 * 8192);
    packw1_k<<<32, 256, 0, stream>>>(scaW1 + 1 * 8192, CAW1 + 3 * 8192);
    packw1_k<<<32, 256, 0, stream>>>(scaW1 + 2 * 8192, CAW1 + 4 * 8192);
    packw2_k<<<32, 256, 0, stream>>>(ca1W2, CAW2 + 0 * 8192);
    packw2_k<<<32, 256, 0, stream>>>(ca2W2, CAW2 + 1 * 8192);
    packw2_k<<<32, 256, 0, stream>>>(scaW2 + 0 * 8192, CAW2 + 2 * 8192);
    packw2_k<<<32, 256, 0, stream>>>(scaW2 + 1 * 8192, CAW2 + 3 * 8192);
    packw2_k<<<32, 256, 0, stream>>>(scaW2 + 2 * 8192, CAW2 + 4 * 8192);
    cfgpos_k<<<(NC_ + 255) / 256, 256, 0, stream>>>(ncid, cfgpos);
    hist_k<<<(E_ + 255) / 256, 256, 0, stream>>>(ei, cnt);
    scan_k<<<1, 1024, 0, stream>>>(cnt, off, cursor, invcnt);
    fill_k<<<(E_ + 255) / 256, 256, 0, stream>>>(ei, cursor, csr);

    // base = feat162 @ W162 + lin1_b (fp32, one-time)
    gemm_k<<<dim3(2, 79, 1), 256, 0, stream>>>(feat162, 176, W162, 176, lin1b, base, N_);

    // ---- per-config-chunk pipeline ----
    for (int c0 = 0; c0 < C_; c0 += Cc) {
        const int nc = (C_ - c0 < Cc) ? (C_ - c0) : Cc;
        const int co = c0 * 256;

        lin1_cfg_k<<<dim3(NC_ / 16, 1, nc), 256, 0, stream>>>(
            base, T, ncid, xcfg + (size_t)c0 * NC_ * 18, BufH, S(0) + co, Q(0) + co);
        lin1_unc_k<<<625, 256, 0, stream>>>(
            base, csum, cfgpos, nc, BufH, S(0) + co, Q(0) + co);
        finstat_k<<<nc, 256, 0, stream>>>(S(0) + co, Q(0) + co,
                                          MU + co, RS + co, MRS + co);

        apply_k<1, 0, 0><<<dim3(625, 1, nc), 256, 0, stream>>>(
            BufH, BufH, nullptr, CAW1 + 0 * 8192, ca1b1, CAW2 + 0 * 8192, ca1b2,
            RS + co, MRS + co, nullptr, nullptr);

        mgemm_k<1><<<dim3(2, 79, nc), 256, 0, stream>>>(
            BufH, SZ_, nullptr, 0, Wt2, 0, 256, 256,
            lin2b, 0, BufY, SZ_, N_, S(1) + co, Q(1) + co);
        finstat_k<<<nc, 256, 0, stream>>>(S(1) + co, Q(1) + co,
                                          MU + 4096 + co, RS + 4096 + co, MRS + 4096 + co);

        apply_k<1, 0, 1><<<dim3(625, 1, nc), 256, 0, stream>>>(
            BufY, BufY, nullptr, CAW1 + 1 * 8192, ca2b1, CAW2 + 1 * 8192, ca2b2,
            RS + 4096 + co, MRS + 4096 + co, S(2) + co, Q(2) + co);

        for (int i = 0; i < 3; ++i) {
            const int set = 2 + i;
            finstat_k<<<nc, 256, 0, stream>>>(S(set) + co, Q(set) + co,
                                              MU + set * 4096 + co, RS + set * 4096 + co,
                                              MRS + set * 4096 + co);
            foldw_k<<<dim3(256, nc), 256, 0, stream>>>(
                sageWl + (size_t)i * 65536, sageWr + (size_t)i * 65536, sagebl + i * 256,
                MU + set * 4096 + co, RS + set * 4096 + co,
                Wfold + (size_t)c0 * 256 * 512, biasF + co);
            agg_k<<<nc * 2500, 256, 0, stream>>>(BufY, off, csr, invcnt,
                                                 MU + set * 4096 + co, BufA);
            mgemm_k<0><<<dim3(2, 79, nc), 256, 0, stream>>>(
                BufA, SZ_, BufY, SZ_, Wfold + (size_t)c0 * 256 * 512, 256 * 512, 256, 512,
                biasF + co, 256, BufH, SZ_, N_, nullptr, nullptr);
            if (i < 2) {
                apply_k<0, 1, 1><<<dim3(625, 1, nc), 256, 0, stream>>>(
                    BufH, BufY, BufY,
                    CAW1 + (2 + i) * 8192, scab1 + i * 32,
                    CAW2 + (2 + i) * 8192, scab2 + i * 256,
                    nullptr, nullptr, S(3 + i) + co, Q(3 + i) + co);
            } else {
                apply_k<0, 1, 2><<<dim3(625, 1, nc), 256, 0, stream>>>(
                    BufH, BufY, BufY,
                    CAW1 + (2 + i) * 8192, scab1 + i * 32,
                    CAW2 + (2 + i) * 8192, scab2 + i * 256,
                    nullptr, nullptr, S(5) + co, nullptr);
            }
        }
    }

    cls_k<<<16, 256, 0, stream>>>(S(5), clsW, clsb, out);
}

// Round 9
// 1358.679 us; speedup vs baseline: 2.7936x; 1.0062x over previous
//
#include <hip/hip_runtime.h>
#include <hip/hip_bf16.h>
#include <math.h>

// ---------------- problem constants ----------------
constexpr int C_  = 16;
constexpr int N_  = 10000;
constexpr int NC_ = 2000;
constexpr int E_  = 50000;
constexpr int D_  = 256;
constexpr int SZ_ = N_ * D_;          // per-config slab (elements)
constexpr float EPS_ = 1e-5f;

typedef unsigned short u16;
typedef __attribute__((ext_vector_type(8))) unsigned short us8v;
typedef __attribute__((ext_vector_type(4))) unsigned short us4v;
typedef __attribute__((ext_vector_type(8))) short s16x8;
typedef __attribute__((ext_vector_type(4))) float f32x4;

typedef __attribute__((address_space(3))) unsigned int lds_uint;
typedef const __attribute__((address_space(1))) unsigned int glb_uint;

__device__ __forceinline__ u16 f2bf(float f) {
    __hip_bfloat16 h = __float2bfloat16(f);   // hw v_cvt (RNE)
    return __builtin_bit_cast(u16, h);
}
__device__ __forceinline__ float bf2f(u16 h) {
    return __uint_as_float(((unsigned)h) << 16);
}
// fast gelu: erf via Abramowitz-Stegun 7.1.26 (|err|<=1.5e-7) + hw exp
__device__ __forceinline__ float gelu_f(float x) {
    float z = x * 0.70710678118654752f;
    float az = fabsf(z);
    float t = 1.f / fmaf(0.3275911f, az, 1.f);
    float p = t * (0.254829592f + t * (-0.284496736f + t * (1.421413741f +
              t * (-1.453152027f + t * 1.061405429f))));
    float e = p * __expf(-z * z);
    float erfv = (z >= 0.f) ? (1.f - e) : (e - 1.f);
    return 0.5f * x * (1.f + erfv);
}

// ---------------- tiny prep kernels ----------------

__global__ __launch_bounds__(256) void tbl_k(const float* __restrict__ embL,
                                             const float* __restrict__ W,
                                             float* __restrict__ T) {
    int b = blockIdx.x;            // 0..143
    int s = b >> 3, i = b & 7, d = threadIdx.x;
    float acc = 0.f;
#pragma unroll
    for (int k = 0; k < 4; ++k)
        acc = fmaf(embL[i * 4 + k], W[(134 + s * 4 + k) * 256 + d], acc);
    T[(s * 8 + i) * 256 + d] = acc;
}

// csum[d] = sum_s T[s][0][d]
__global__ __launch_bounds__(256) void csum_k(const float* __restrict__ T,
                                              float* __restrict__ cs) {
    int d = threadIdx.x;
    float a = 0.f;
#pragma unroll
    for (int s = 0; s < 18; ++s) a += T[(s * 8) * 256 + d];
    cs[d] = a;
}

__global__ __launch_bounds__(192) void feat_k(const float* __restrict__ xf,
                                              const int* __restrict__ xlay,
                                              const int* __restrict__ xop,
                                              const float* __restrict__ embL,
                                              const float* __restrict__ embO,
                                              float* __restrict__ f) {
    int n = blockIdx.x, j = threadIdx.x;
    if (j >= 176) return;
    float v;
    if (j < 134) v = xf[n * 134 + j];
    else if (j < 158) { int q = j - 134; int t = q >> 2, k = q & 3; v = embL[(xlay[n * 6 + t] + 2) * 4 + k]; }
    else if (j < 162) { int k = j - 158; v = embO[xop[n] * 4 + k]; }
    else v = 0.f;
    f[n * 176 + j] = v;
}

__global__ __launch_bounds__(256) void wpack_k(const float* __restrict__ W,
                                               float* __restrict__ Wp) {
    int j = blockIdx.x, d = threadIdx.x;
    float v = 0.f;
    if (j < 134) v = W[j * 256 + d];
    else if (j < 158) v = W[(206 + j - 134) * 256 + d];
    else if (j < 162) v = W[(230 + j - 158) * 256 + d];
    Wp[j * 256 + d] = v;
}

// pack channel-attn W1 [256][32] into MFMA fragment order
__global__ __launch_bounds__(256) void packw1_k(const float* __restrict__ W1,
                                                u16* __restrict__ dst) {
    int i = blockIdx.x * 256 + threadIdx.x;    // 0..8191
    int j = i & 7, lane = (i >> 3) & 63, half = (i >> 9) & 1, ks = (i >> 10) & 1, wid = (i >> 11) & 3;
    int k = wid * 64 + ks * 32 + ((lane >> 4) << 3) + j;
    int col = half * 16 + (lane & 15);
    dst[i] = f2bf(W1[k * 32 + col]);
}
// pack channel-attn W2 [32][256] into MFMA fragment order
__global__ __launch_bounds__(256) void packw2_k(const float* __restrict__ W2,
                                                u16* __restrict__ dst) {
    int i = blockIdx.x * 256 + threadIdx.x;    // 0..8191
    int j = i & 7, lane = (i >> 3) & 63, q = (i >> 9) & 3, wid = (i >> 11) & 3;
    int kq = lane >> 4, cl = lane & 15;
    dst[i] = f2bf(W2[(kq * 8 + j) * 256 + (wid * 4 + q) * 16 + cl]);
}

__global__ __launch_bounds__(256) void cfgpos_k(const int* __restrict__ ncid,
                                                int* __restrict__ cfgpos) {
    int i = blockIdx.x * 256 + threadIdx.x;
    if (i < NC_) cfgpos[ncid[i]] = i;
}

__global__ __launch_bounds__(256) void hist_k(const int* __restrict__ ei, int* __restrict__ cnt) {
    int e = blockIdx.x * 256 + threadIdx.x;
    if (e < E_) atomicAdd(&cnt[ei[E_ + e]], 1);
}

__global__ __launch_bounds__(1024) void scan_k(const int* __restrict__ cnt,
                                               int* __restrict__ off,
                                               int* __restrict__ cursor,
                                               float* __restrict__ invcnt) {
    __shared__ int s[1024];
    int t = threadIdx.x;
    int base = t * 10;
    int local[10];
    int part = 0;
#pragma unroll
    for (int k = 0; k < 10; ++k) {
        int idx = base + k;
        int v = (idx < N_) ? cnt[idx] : 0;
        local[k] = v; part += v;
    }
    s[t] = part;
    __syncthreads();
    for (int o = 1; o < 1024; o <<= 1) {
        int val = (t >= o) ? s[t - o] : 0;
        __syncthreads();
        s[t] += val;
        __syncthreads();
    }
    int pre = s[t] - part;
#pragma unroll
    for (int k = 0; k < 10; ++k) {
        int idx = base + k;
        if (idx < N_) {
            off[idx] = pre;
            cursor[idx] = pre;
            invcnt[idx] = 1.0f / (float)(local[k] > 1 ? local[k] : 1);
            pre += local[k];
        }
    }
    if (t == 1023) off[N_] = s[1023];
}

__global__ __launch_bounds__(256) void fill_k(const int* __restrict__ ei,
                                              int* __restrict__ cursor,
                                              int* __restrict__ csr) {
    int e = blockIdx.x * 256 + threadIdx.x;
    if (e < E_) {
        int t = ei[E_ + e];
        int p = atomicAdd(&cursor[t], 1);
        csr[p] = ei[e];
    }
}

// transpose lin2_W -> Wt2[j][k] bf16
__global__ __launch_bounds__(256) void wt2_k(const float* __restrict__ W,
                                             u16* __restrict__ Wt) {
    int j = blockIdx.x, k = threadIdx.x;
    Wt[j * 256 + k] = f2bf(W[k * 256 + j]);
}

// fold instance-norm into sage weights (per config)
__global__ __launch_bounds__(256) void foldw_k(const float* __restrict__ Wl,
                                               const float* __restrict__ Wr,
                                               const float* __restrict__ bl,
                                               const float* __restrict__ mu,
                                               const float* __restrict__ rs,
                                               u16* __restrict__ Wt,
                                               float* __restrict__ biasF) {
    __shared__ float red[256];
    int c = blockIdx.y, j = blockIdx.x, k = threadIdx.x;
    float rsv = rs[c * 256 + k], muv = mu[c * 256 + k];
    float fl = rsv * Wl[k * 256 + j];
    float fr = rsv * Wr[k * 256 + j];
    size_t wb = ((size_t)c * 256 + j) * 512;
    Wt[wb + k] = f2bf(fl);
    Wt[wb + 256 + k] = f2bf(fr);
    red[k] = muv * (fl + fr);
    __syncthreads();
    for (int s = 128; s > 0; s >>= 1) {
        if (k < s) red[k] += red[k + s];
        __syncthreads();
    }
    if (k == 0) biasF[c * 256 + j] = bl[j] - red[0];
}

// ---------------- lin1 (configured nodes) ----------------
__global__ __launch_bounds__(256) void lin1_cfg_k(const float* __restrict__ base,
                                                  const float* __restrict__ T,
                                                  const int* __restrict__ ncid,
                                                  const int* __restrict__ xcfg,
                                                  u16* __restrict__ H,
                                                  float* __restrict__ ssum,
                                                  float* __restrict__ ssq) {
    __shared__ int idxs[16][18];   // premultiplied by 256
    __shared__ int nid[16];
    const int c = blockIdx.z, j0 = blockIdx.x * 16, tid = threadIdx.x;
    if (tid < 16) nid[tid] = ncid[j0 + tid];
    for (int t = tid; t < 288; t += 256) {
        int row = t / 18, s = t - row * 18;
        idxs[row][s] = (xcfg[((size_t)c * NC_ + j0 + row) * 18 + s] + 2) * 256;
    }
    __syncthreads();
    const int d = tid;
    float psum = 0.f, psq = 0.f;
    for (int g = 0; g < 16; g += 4) {
        float acc[4];
#pragma unroll
        for (int gg = 0; gg < 4; ++gg) acc[gg] = base[(size_t)nid[g + gg] * 256 + d];
#pragma unroll
        for (int s = 0; s < 18; ++s) {
            const float* Ts = &T[s * 2048 + d];
#pragma unroll
            for (int gg = 0; gg < 4; ++gg)
                acc[gg] += Ts[idxs[g + gg][s]];
        }
#pragma unroll
        for (int gg = 0; gg < 4; ++gg) {
            H[((size_t)c * N_ + nid[g + gg]) * 256 + d] = f2bf(acc[gg]);
            psum += acc[gg]; psq += acc[gg] * acc[gg];
        }
    }
    atomicAdd(&ssum[c * 256 + d], psum);
    atomicAdd(&ssq[c * 256 + d], psq);
}

// ---------------- lin1 (unconfigured nodes) ----------------
__global__ __launch_bounds__(256) void lin1_unc_k(const float* __restrict__ base,
                                                  const float* __restrict__ csum,
                                                  const int* __restrict__ cfgpos,
                                                  int nc,
                                                  u16* __restrict__ H,
                                                  float* __restrict__ ssum,
                                                  float* __restrict__ ssq) {
    __shared__ float red[2048];
    const int n0 = blockIdx.x * 16, tid = threadIdx.x;
    float ps[8] = {0, 0, 0, 0, 0, 0, 0, 0}, pq[8] = {0, 0, 0, 0, 0, 0, 0, 0};
#pragma unroll
    for (int it = 0; it < 2; ++it) {
        const int flat = tid + it * 256;
        const int row = flat >> 5, cb = (flat & 31) * 8;
        const int n = n0 + row;
        if (cfgpos[n] >= 0) continue;
        us8v b;
#pragma unroll
        for (int j = 0; j < 8; ++j) {
            float v = base[(size_t)n * 256 + cb + j] + csum[cb + j];
            b[j] = f2bf(v);
            ps[j] += v; pq[j] += v * v;
        }
        for (int c = 0; c < nc; ++c)
            *(us8v*)&H[((size_t)c * N_ + n) * 256 + cb] = b;
    }
#pragma unroll
    for (int j = 0; j < 8; ++j)
        red[((tid >> 5) * 32 + (tid & 31)) * 8 + j] = ps[j];
    __syncthreads();
    {
        const int cb2 = tid >> 3, j2 = tid & 7;
        float s = 0.f;
#pragma unroll
        for (int r8 = 0; r8 < 8; ++r8) s += red[(r8 * 32 + cb2) * 8 + j2];
        for (int c = 0; c < nc; ++c) atomicAdd(&ssum[c * 256 + tid], s);
    }
    __syncthreads();
#pragma unroll
    for (int j = 0; j < 8; ++j)
        red[((tid >> 5) * 32 + (tid & 31)) * 8 + j] = pq[j];
    __syncthreads();
    {
        const int cb2 = tid >> 3, j2 = tid & 7;
        float s = 0.f;
#pragma unroll
        for (int r8 = 0; r8 < 8; ++r8) s += red[(r8 * 32 + cb2) * 8 + j2];
        for (int c = 0; c < nc; ++c) atomicAdd(&ssq[c * 256 + tid], s);
    }
}

// finalize stats; also emits mrs = mu*rs for fma-folded normalize
__global__ __launch_bounds__(256) void finstat_k(const float* __restrict__ ssum,
                                                 const float* __restrict__ ssq,
                                                 float* __restrict__ mu,
                                                 float* __restrict__ rs,
                                                 float* __restrict__ mrs) {
    int i = blockIdx.x * 256 + threadIdx.x;
    float m = ssum[i] * (1.0f / (float)N_);
    float v = ssq[i] * (1.0f / (float)N_) - m * m;
    float r = rsqrtf(v + EPS_);
    mu[i] = m;
    rs[i] = r;
    mrs[i] = m * r;
}

// ---------------- CSR gather-mean: vector index load + shfl broadcast ----------------
__global__ __launch_bounds__(256) void agg_k(const u16* __restrict__ H,
                                             const int* __restrict__ off,
                                             const int* __restrict__ csr,
                                             const float* __restrict__ invcnt,
                                             const float* __restrict__ mu,
                                             u16* __restrict__ Agg) {
    int wave = threadIdx.x >> 6, lane = threadIdx.x & 63;
    int pair = blockIdx.x * 4 + wave;
    int c = pair / N_, t = pair - c * N_;
    int d4 = lane * 4;
    int o0 = off[t], o1 = off[t + 1];
    int deg = o1 - o0;
    us4v o;
    if (deg > 0) {
        int myidx = (lane < deg) ? csr[o0 + lane] : 0;
        const u16* Hc = H + (size_t)c * SZ_ + d4;
        float ax = 0.f, ay = 0.f, az = 0.f, aw = 0.f;
        int lim = deg < 64 ? deg : 64;
        int i = 0;
        for (; i + 4 <= lim; i += 4) {
            int s0 = __shfl(myidx, i), s1 = __shfl(myidx, i + 1);
            int s2 = __shfl(myidx, i + 2), s3 = __shfl(myidx, i + 3);
            us4v h0 = *(const us4v*)&Hc[(size_t)s0 * 256];
            us4v h1 = *(const us4v*)&Hc[(size_t)s1 * 256];
            us4v h2 = *(const us4v*)&Hc[(size_t)s2 * 256];
            us4v h3 = *(const us4v*)&Hc[(size_t)s3 * 256];
            ax += (bf2f(h0.x) + bf2f(h1.x)) + (bf2f(h2.x) + bf2f(h3.x));
            ay += (bf2f(h0.y) + bf2f(h1.y)) + (bf2f(h2.y) + bf2f(h3.y));
            az += (bf2f(h0.z) + bf2f(h1.z)) + (bf2f(h2.z) + bf2f(h3.z));
            aw += (bf2f(h0.w) + bf2f(h1.w)) + (bf2f(h2.w) + bf2f(h3.w));
        }
        for (; i < lim; ++i) {
            int s = __shfl(myidx, i);
            us4v h = *(const us4v*)&Hc[(size_t)s * 256];
            ax += bf2f(h.x); ay += bf2f(h.y); az += bf2f(h.z); aw += bf2f(h.w);
        }
        for (int j = o0 + 64; j < o1; ++j) {     // rare: degree > 64
            int s = csr[j];
            us4v h = *(const us4v*)&Hc[(size_t)s * 256];
            ax += bf2f(h.x); ay += bf2f(h.y); az += bf2f(h.z); aw += bf2f(h.w);
        }
        float inv = invcnt[t];
        o.x = f2bf(ax * inv); o.y = f2bf(ay * inv);
        o.z = f2bf(az * inv); o.w = f2bf(aw * inv);
    } else {
        o.x = f2bf(mu[c * 256 + d4 + 0]);
        o.y = f2bf(mu[c * 256 + d4 + 1]);
        o.z = f2bf(mu[c * 256 + d4 + 2]);
        o.w = f2bf(mu[c * 256 + d4 + 3]);
    }
    *(us4v*)&Agg[((size_t)c * N_ + t) * 256 + d4] = o;
}

// ---------------- bf16 MFMA GEMM: Y = [A1|A2] @ Wt^T + bias ----------------
template <int STATS>
__global__ __launch_bounds__(256) void mgemm_k(
    const u16* __restrict__ A1, size_t sA1,
    const u16* __restrict__ A2, size_t sA2,
    const u16* __restrict__ Wt, size_t sW, int K1, int Ktot,
    const float* __restrict__ bias, size_t sBias,
    u16* __restrict__ Y, size_t sY, int Mrows,
    float* __restrict__ ssum, float* __restrict__ ssq)
{
    __shared__ u16 Asm[128 * 64];
    __shared__ u16 Bsm[128 * 64];
    const int tid = threadIdx.x;
    const int lane = tid & 63, wid = tid >> 6;
    const int wr = wid >> 1, wc = wid & 1;

    // XCD-aware bijective remap of the flattened block id
    const int gx = gridDim.x, gy = gridDim.y;
    int nwg = gx * gy * gridDim.z;
    int orig = blockIdx.x + gx * (blockIdx.y + gy * blockIdx.z);
    int q = nwg >> 3, r = nwg & 7;
    int xcd = orig & 7, idx = orig >> 3;
    int swz = (xcd < r ? xcd * (q + 1) : r * (q + 1) + (xcd - r) * q) + idx;
    const int bx = swz % gx;
    const int tmp = swz / gx;
    const int by = tmp % gy;
    const int c  = tmp / gy;

    const int rowbase = by * 128, colbase = bx * 128;

    const u16* A1p = A1 + (size_t)c * sA1;
    const u16* A2p = A2 ? (A2 + (size_t)c * sA2) : nullptr;
    const u16* Wp  = Wt + (size_t)c * sW;

    f32x4 acc[4][4];
#pragma unroll
    for (int i = 0; i < 4; ++i)
#pragma unroll
        for (int j = 0; j < 4; ++j) acc[i][j] = (f32x4)0.f;

    const int lrow = lane >> 3;        // row within the wave's 8-row group
    const int lchunk = lane & 7;       // 16B chunk within the row

    for (int k0 = 0; k0 < Ktot; k0 += 64) {
        const u16* asrc; int ak;
        if (k0 < K1) { asrc = A1p; ak = k0; } else { asrc = A2p; ak = k0 - K1; }
#pragma unroll
        for (int i = 0; i < 4; ++i) {
            const int row = (wid * 4 + i) * 8 + lrow;          // 0..127
            const int srcchunk = lchunk ^ (row & 7);           // inverse of read-side XOR
            int garow = rowbase + row;
            if (garow >= Mrows) garow = Mrows - 1;             // clamp: values unused
            const u16* ga = asrc + (size_t)garow * 256 + ak + srcchunk * 8;
            __builtin_amdgcn_global_load_lds((glb_uint*)ga,
                (lds_uint*)(Asm + (wid * 4 + i) * 512), 16, 0, 0);
            const u16* gb = Wp + (size_t)(colbase + row) * Ktot + k0 + srcchunk * 8;
            __builtin_amdgcn_global_load_lds((glb_uint*)gb,
                (lds_uint*)(Bsm + (wid * 4 + i) * 512), 16, 0, 0);
        }
        __syncthreads();
#pragma unroll
        for (int ks = 0; ks < 2; ++ks) {
            s16x8 aF[4], bF[4];
            const int kk = ks * 32 + ((lane >> 4) << 3);
#pragma unroll
            for (int f = 0; f < 4; ++f) {
                int ar = wr * 64 + f * 16 + (lane & 15);
                aF[f] = *(const s16x8*)&Asm[(ar * 64 + kk) ^ ((ar & 7) << 3)];
                int br = wc * 64 + f * 16 + (lane & 15);
                bF[f] = *(const s16x8*)&Bsm[(br * 64 + kk) ^ ((br & 7) << 3)];
            }
#pragma unroll
            for (int fr = 0; fr < 4; ++fr)
#pragma unroll
                for (int fc = 0; fc < 4; ++fc)
                    acc[fr][fc] = __builtin_amdgcn_mfma_f32_16x16x32_bf16(
                        aF[fr], bF[fc], acc[fr][fc], 0, 0, 0);
        }
        __syncthreads();
    }

    float bcol[4];
#pragma unroll
    for (int fc = 0; fc < 4; ++fc)
        bcol[fc] = bias[(size_t)c * sBias + colbase + wc * 64 + fc * 16 + (lane & 15)];
    u16* Yp = Y + (size_t)c * sY;
    float ps[4] = {0, 0, 0, 0}, pq[4] = {0, 0, 0, 0};
#pragma unroll
    for (int fr = 0; fr < 4; ++fr) {
#pragma unroll
        for (int i = 0; i < 4; ++i) {
            int grow = rowbase + wr * 64 + fr * 16 + ((lane >> 4) << 2) + i;
            if (grow < Mrows) {
                size_t rb = (size_t)grow * 256 + colbase + wc * 64 + (lane & 15);
#pragma unroll
                for (int fc = 0; fc < 4; ++fc) {
                    float v = acc[fr][fc][i] + bcol[fc];
                    Yp[rb + fc * 16] = f2bf(v);
                    if (STATS) { ps[fc] += v; pq[fc] += v * v; }
                }
            }
        }
    }
    if (STATS) {
#pragma unroll
        for (int fc = 0; fc < 4; ++fc) {
            float s = ps[fc], q2 = pq[fc];
            s += __shfl_xor(s, 16); s += __shfl_xor(s, 32);
            q2 += __shfl_xor(q2, 16); q2 += __shfl_xor(q2, 32);
            if (lane < 16) {
                int col = colbase + wc * 64 + fc * 16 + lane;
                atomicAdd(&ssum[c * 256 + col], s);
                atomicAdd(&ssq[c * 256 + col], q2);
            }
        }
    }
}

// ---------------- fp32 tiled GEMM (one-time base GEMM) ----------------
__global__ __launch_bounds__(256) void gemm_k(const float* __restrict__ A1, int lda1,
                                              const float* __restrict__ W1, int K1,
                                              const float* __restrict__ bias,
                                              float* __restrict__ Y, int Mrows) {
    __shared__ float As[16][132];
    __shared__ float Bs[16][132];
    float acc[8][8];
#pragma unroll
    for (int i = 0; i < 8; ++i)
#pragma unroll
        for (int j = 0; j < 8; ++j) acc[i][j] = 0.f;

    const int tid = threadIdx.x;
    const int tr = tid >> 4, tc = tid & 15;
    const int rowbase = blockIdx.y * 128, colbase = blockIdx.x * 128;

    for (int k0 = 0; k0 < K1; k0 += 16) {
#pragma unroll
        for (int ii = 0; ii < 2; ++ii) {
            int i = tid + ii * 256;
            int rr = i >> 2, qq = i & 3;
            int grow = rowbase + rr;
            float4 vv = make_float4(0.f, 0.f, 0.f, 0.f);
            if (grow < Mrows) vv = *(const float4*)&A1[(size_t)grow * lda1 + k0 + qq * 4];
            As[qq * 4 + 0][rr] = vv.x;
            As[qq * 4 + 1][rr] = vv.y;
            As[qq * 4 + 2][rr] = vv.z;
            As[qq * 4 + 3][rr] = vv.w;
        }
#pragma unroll
        for (int ii = 0; ii < 2; ++ii) {
            int i = tid + ii * 256;
            int rr = i >> 5, qq = i & 31;
            float4 vv = *(const float4*)&W1[(size_t)(k0 + rr) * 256 + colbase + qq * 4];
            *(float4*)&Bs[rr][qq * 4] = vv;
        }
        __syncthreads();
#pragma unroll
        for (int kk = 0; kk < 16; ++kk) {
            float a[8], b[8];
            *(float4*)&a[0] = *(const float4*)&As[kk][tr * 4];
            *(float4*)&a[4] = *(const float4*)&As[kk][64 + tr * 4];
            *(float4*)&b[0] = *(const float4*)&Bs[kk][tc * 4];
            *(float4*)&b[4] = *(const float4*)&Bs[kk][64 + tc * 4];
#pragma unroll
            for (int i = 0; i < 8; ++i)
#pragma unroll
                for (int j = 0; j < 8; ++j)
                    acc[i][j] = fmaf(a[i], b[j], acc[i][j]);
        }
        __syncthreads();
    }

    float4 blo = *(const float4*)&bias[colbase + tc * 4];
    float4 bhi = *(const float4*)&bias[colbase + 64 + tc * 4];
    float bb[8] = {blo.x, blo.y, blo.z, blo.w, bhi.x, bhi.y, bhi.z, bhi.w};
#pragma unroll
    for (int i = 0; i < 8; ++i)
#pragma unroll
        for (int j = 0; j < 8; ++j) acc[i][j] += bb[j];

#pragma unroll
    for (int i = 0; i < 8; ++i) {
        int lrow = (i < 4) ? (tr * 4 + i) : (64 + tr * 4 + (i - 4));
        int grow = rowbase + lrow;
        if (grow < Mrows) {
            *(float4*)&Y[(size_t)grow * 256 + colbase + tc * 4] =
                make_float4(acc[i][0], acc[i][1], acc[i][2], acc[i][3]);
            *(float4*)&Y[(size_t)grow * 256 + colbase + 64 + tc * 4] =
                make_float4(acc[i][4], acc[i][5], acc[i][6], acc[i][7]);
        }
    }
}

// ---------------- per-row epilogue with MFMA channel-attention (512 thr, 8 waves) ----------------
// A: vectorized load+fma-norm -> B: t=relu(x@W1+b1), wave w owns K-slice of 32 ->
// C: y=t@W2 fused sigmoid*x (+res) gelu + shfl stats (2 col-frags/wave) -> D: store
template <int NORM, int RES, int SMODE>
__global__ __launch_bounds__(512) void apply_k(const u16* __restrict__ Yin,
                                               u16* __restrict__ Hout,
                                               const u16* __restrict__ Hsc,
                                               const u16* __restrict__ W1p,
                                               const float* __restrict__ b1,
                                               const u16* __restrict__ W2p,
                                               const float* __restrict__ b2,
                                               const float* __restrict__ rs,
                                               const float* __restrict__ mrs,
                                               float* __restrict__ ssum,
                                               float* __restrict__ ssq) {
    __shared__ u16 vbf[16 * 264];
    __shared__ u16 scs[(RES ? 16 : 1) * 264];
    __shared__ float tpart[8 * 528];           // 8 wave slabs, stride 33 per row
    __shared__ u16 tbf[16 * 40];
    __shared__ float srs[NORM ? 256 : 1], smrs[NORM ? 256 : 1];
    const int c = blockIdx.z, n0 = blockIdx.x * 16, tid = threadIdx.x;
    const int lane = tid & 63, wid = tid >> 6;   // wid 0..7
    const size_t rowbase = ((size_t)c * N_ + n0) * 256;

    // phase A: one 8-elem chunk per thread (512 = 16 rows x 32 chunks)
    if (NORM && tid < 256) { srs[tid] = rs[c * 256 + tid]; smrs[tid] = mrs[c * 256 + tid]; }
    {
        const int row = tid >> 5, cb = (tid & 31) * 8;
        us8v x = *(const us8v*)&Yin[rowbase + row * 256 + cb];
        us8v r;
        if (RES) r = *(const us8v*)&Hsc[rowbase + row * 256 + cb];
        if (NORM) {
            __syncthreads();   // srs/smrs ready
            us8v y;
#pragma unroll
            for (int j = 0; j < 8; ++j)
                y[j] = f2bf(fmaf(bf2f(x[j]), srs[cb + j], -smrs[cb + j]));
            *(us8v*)&vbf[row * 264 + cb] = y;
        } else {
            *(us8v*)&vbf[row * 264 + cb] = x;
        }
        if (RES) *(us8v*)&scs[row * 264 + cb] = r;
    }
    __syncthreads();

    // phase B: wave w owns K in [w*32, w*32+32): one MFMA per col-half
    {
        const int arow = lane & 15, kq = lane >> 4;
        const int k = wid * 32 + kq * 8;
        s16x8 aF = *(const s16x8*)&vbf[arow * 264 + k];
        s16x8 bF0 = *(const s16x8*)&W1p[((wid * 2 + 0) * 64 + lane) * 8];
        s16x8 bF1 = *(const s16x8*)&W1p[((wid * 2 + 1) * 64 + lane) * 8];
        f32x4 at0 = __builtin_amdgcn_mfma_f32_16x16x32_bf16(aF, bF0, (f32x4)0.f, 0, 0, 0);
        f32x4 at1 = __builtin_amdgcn_mfma_f32_16x16x32_bf16(aF, bF1, (f32x4)0.f, 0, 0, 0);
#pragma unroll
        for (int i = 0; i < 4; ++i) {
            tpart[wid * 528 + (kq * 4 + i) * 33 + (lane & 15)] = at0[i];
            tpart[wid * 528 + (kq * 4 + i) * 33 + 16 + (lane & 15)] = at1[i];
        }
    }
    __syncthreads();

    // reduce 8 wave-partials, +b1, relu -> tbf (512 threads, 1 entry each)
    {
        const int nr = tid >> 5, col = tid & 31;
        float s = b1[col];
#pragma unroll
        for (int w8 = 0; w8 < 8; ++w8)
            s += tpart[w8 * 528 + nr * 33 + col];
        tbf[nr * 40 + col] = f2bf(fmaxf(s, 0.f));
    }
    __syncthreads();

    // phase C: y = t @ W2 (2 col-frags/wave), fused sigmoid*x (+res), gelu; shfl stats
    {
        const int cl = lane & 15, kq = lane >> 4;
        s16x8 aF = *(const s16x8*)&tbf[cl * 40 + kq * 8];
        float ps[2] = {0, 0}, pq[2] = {0, 0};
#pragma unroll
        for (int q = 0; q < 2; ++q) {
            const int colb = (wid * 2 + q) * 16;
            s16x8 bF = *(const s16x8*)&W2p[((wid * 2 + q) * 64 + lane) * 8];
            f32x4 acc = __builtin_amdgcn_mfma_f32_16x16x32_bf16(aF, bF, (f32x4)0.f, 0, 0, 0);
            const float b2v = b2[colb + cl];
#pragma unroll
            for (int i = 0; i < 4; ++i) {
                const int row = kq * 4 + i;
                const int ea = row * 264 + colb + cl;
                float s = acc[i] + b2v;
                float sig = 1.0f / (1.0f + __expf(-s));
                float val = sig * bf2f(vbf[ea]);
                if (RES) val += bf2f(scs[ea]);
                val = gelu_f(val);
                vbf[ea] = f2bf(val);
                if (SMODE) { ps[q] += val; if (SMODE == 1) pq[q] += val * val; }
            }
        }
        if (SMODE) {
#pragma unroll
            for (int q = 0; q < 2; ++q) {
                float s = ps[q];
                s += __shfl_xor(s, 16); s += __shfl_xor(s, 32);
                if (SMODE == 1) {
                    float q2 = pq[q];
                    q2 += __shfl_xor(q2, 16); q2 += __shfl_xor(q2, 32);
                    if (lane < 16) atomicAdd(&ssq[c * 256 + (wid * 2 + q) * 16 + lane], q2);
                }
                if (lane < 16) atomicAdd(&ssum[c * 256 + (wid * 2 + q) * 16 + lane], s);
            }
        }
    }
    __syncthreads();

    // phase D: one chunk per thread
    {
        const int row = tid >> 5, cb = (tid & 31) * 8;
        us8v h = *(const us8v*)&vbf[row * 264 + cb];
        *(us8v*)&Hout[rowbase + row * 256 + cb] = h;
    }
}

// ---------------- classifier ----------------
__global__ __launch_bounds__(256) void cls_k(const float* __restrict__ pooled_sum,
                                             const float* __restrict__ clsW,
                                             const float* __restrict__ clsb,
                                             float* __restrict__ out) {
    __shared__ float red[256];
    int c = blockIdx.x, d = threadIdx.x;
    red[d] = pooled_sum[c * 256 + d] * (1.0f / (float)N_) * clsW[d];
    __syncthreads();
    for (int s = 128; s > 0; s >>= 1) {
        if (d < s) red[d] += red[d + s];
        __syncthreads();
    }
    if (d == 0) out[c] = red[0] + clsb[0];
}

// ---------------- host launch ----------------
static inline size_t alup(size_t x) { return (x + 255) & ~(size_t)255; }

extern "C" void kernel_launch(void* const* d_in, const int* in_sizes, int n_in,
                              void* d_out, int out_size, void* d_ws, size_t ws_size,
                              hipStream_t stream) {
    const int*   xcfg   = (const int*)d_in[0];
    const float* xfeat  = (const float*)d_in[1];
    const int*   xlay   = (const int*)d_in[2];
    const int*   xop    = (const int*)d_in[3];
    const int*   ei     = (const int*)d_in[4];
    const int*   ncid   = (const int*)d_in[5];
    const float* embO   = (const float*)d_in[6];
    const float* embL   = (const float*)d_in[7];
    const float* lin1W  = (const float*)d_in[8];
    const float* lin1b  = (const float*)d_in[9];
    const float* ca1W1  = (const float*)d_in[10];
    const float* ca1b1  = (const float*)d_in[11];
    const float* ca1W2  = (const float*)d_in[12];
    const float* ca1b2  = (const float*)d_in[13];
    const float* lin2W  = (const float*)d_in[14];
    const float* lin2b  = (const float*)d_in[15];
    const float* ca2W1  = (const float*)d_in[16];
    const float* ca2b1  = (const float*)d_in[17];
    const float* ca2W2  = (const float*)d_in[18];
    const float* ca2b2  = (const float*)d_in[19];
    const float* sageWl = (const float*)d_in[20];
    const float* sagebl = (const float*)d_in[21];
    const float* sageWr = (const float*)d_in[22];
    const float* scaW1  = (const float*)d_in[23];
    const float* scab1  = (const float*)d_in[24];
    const float* scaW2  = (const float*)d_in[25];
    const float* scab2  = (const float*)d_in[26];
    const float* clsW   = (const float*)d_in[27];
    const float* clsb   = (const float*)d_in[28];
    float* out = (float*)d_out;

    // ---- workspace carve-up ----
    char* w = (char*)d_ws;
    size_t o = 0;
    auto take = [&](size_t bytes) { char* p = w + o; o = alup(o + bytes); return p; };
    float* base    = (float*)take((size_t)N_ * 256 * 4);
    float* feat162 = (float*)take((size_t)N_ * 176 * 4);
    float* W162    = (float*)take((size_t)176 * 256 * 4);
    float* T       = (float*)take((size_t)18 * 8 * 256 * 4);
    float* csum    = (float*)take((size_t)256 * 4);
    float* stats   = (float*)take((size_t)6 * 8192 * 4);
    float* MU      = (float*)take((size_t)5 * 4096 * 4);
    float* RS      = (float*)take((size_t)5 * 4096 * 4);
    float* MRS     = (float*)take((size_t)5 * 4096 * 4);
    float* invcnt  = (float*)take((size_t)N_ * 4);
    int*   cnt     = (int*)take((size_t)N_ * 4);
    int*   off     = (int*)take((size_t)(N_ + 1) * 4);
    int*   cursor  = (int*)take((size_t)N_ * 4);
    int*   csr     = (int*)take((size_t)E_ * 4);
    int*   cfgpos  = (int*)take((size_t)N_ * 4);
    u16*   Wt2     = (u16*)take((size_t)256 * 256 * 2);
    u16*   Wfold   = (u16*)take((size_t)C_ * 256 * 512 * 2);   // 4 MB
    float* biasF   = (float*)take((size_t)C_ * 256 * 4);
    u16*   CAW1    = (u16*)take((size_t)5 * 8192 * 2);         // packed frag order
    u16*   CAW2    = (u16*)take((size_t)5 * 8192 * 2);

    const size_t slab = (size_t)SZ_ * 2;                       // bf16: 5.12 MB
    size_t avail = (ws_size > o) ? (ws_size - o) : 0;
    int Cc = (int)(avail / (3 * slab + 768));
    if (Cc > C_) Cc = C_;
    if (Cc < 1) Cc = 1;
    u16* BufH = (u16*)take((size_t)Cc * slab);
    u16* BufY = (u16*)take((size_t)Cc * slab);
    u16* BufA = (u16*)take((size_t)Cc * slab);
    (void)in_sizes; (void)n_in; (void)out_size;

    auto S = [&](int s) { return stats + (size_t)s * 8192; };
    auto Q = [&](int s) { return stats + (size_t)s * 8192 + 4096; };

    hipMemsetAsync(stats, 0, 6 * 8192 * 4, stream);
    hipMemsetAsync(cnt, 0, N_ * 4, stream);
    hipMemsetAsync(cfgpos, 0xFF, N_ * 4, stream);

    // shared prep
    tbl_k<<<144, 256, 0, stream>>>(embL, lin1W, T);
    csum_k<<<1, 256, 0, stream>>>(T, csum);
    feat_k<<<N_, 192, 0, stream>>>(xfeat, xlay, xop, embL, embO, feat162);
    wpack_k<<<176, 256, 0, stream>>>(lin1W, W162);
    wt2_k<<<256, 256, 0, stream>>>(lin2W, Wt2);
    packw1_k<<<32, 256, 0, stream>>>(ca1W1, CAW1 + 0 * 8192);
    packw1_k<<<32, 256, 0, stream>>>(ca2W1, CAW1 + 1 * 8192);
    packw1_k<<<32, 256, 0, stream>>>(scaW1 + 0 * 8192, CAW1 + 2 * 8192);
    packw1_k<<<32, 256, 0, stream>>>(scaW1 + 1 * 8192, CAW1 + 3 * 8192);
    packw1_k<<<32, 256, 0, stream>>>(scaW1 + 2 * 8192, CAW1 + 4 * 8192);
    packw2_k<<<32, 256, 0, stream>>>(ca1W2, CAW2 + 0 * 8192);
    packw2_k<<<32, 256, 0, stream>>>(ca2W2, CAW2 + 1 * 8192);
    packw2_k<<<32, 256, 0, stream>>>(scaW2 + 0 * 8192, CAW2 + 2 * 8192);
    packw2_k<<<32, 256, 0, stream>>>(scaW2 + 1 * 8192, CAW2 + 3 * 8192);
    packw2_k<<<32, 256, 0, stream>>>(scaW2 + 2 * 8192, CAW2 + 4 * 8192);
    cfgpos_k<<<(NC_ + 255) / 256, 256, 0, stream>>>(ncid, cfgpos);
    hist_k<<<(E_ + 255) / 256, 256, 0, stream>>>(ei, cnt);
    scan_k<<<1, 1024, 0, stream>>>(cnt, off, cursor, invcnt);
    fill_k<<<(E_ + 255) / 256, 256, 0, stream>>>(ei, cursor, csr);

    // base = feat162 @ W162 + lin1_b (fp32, one-time)
    gemm_k<<<dim3(2, 79, 1), 256, 0, stream>>>(feat162, 176, W162, 176, lin1b, base, N_);

    // ---- per-config-chunk pipeline ----
    for (int c0 = 0; c0 < C_; c0 += Cc) {
        const int nc = (C_ - c0 < Cc) ? (C_ - c0) : Cc;
        const int co = c0 * 256;

        lin1_cfg_k<<<dim3(NC_ / 16, 1, nc), 256, 0, stream>>>(
            base, T, ncid, xcfg + (size_t)c0 * NC_ * 18, BufH, S(0) + co, Q(0) + co);
        lin1_unc_k<<<625, 256, 0, stream>>>(
            base, csum, cfgpos, nc, BufH, S(0) + co, Q(0) + co);
        finstat_k<<<nc, 256, 0, stream>>>(S(0) + co, Q(0) + co,
                                          MU + co, RS + co, MRS + co);

        apply_k<1, 0, 0><<<dim3(625, 1, nc), 512, 0, stream>>>(
            BufH, BufH, nullptr, CAW1 + 0 * 8192, ca1b1, CAW2 + 0 * 8192, ca1b2,
            RS + co, MRS + co, nullptr, nullptr);

        mgemm_k<1><<<dim3(2, 79, nc), 256, 0, stream>>>(
            BufH, SZ_, nullptr, 0, Wt2, 0, 256, 256,
            lin2b, 0, BufY, SZ_, N_, S(1) + co, Q(1) + co);
        finstat_k<<<nc, 256, 0, stream>>>(S(1) + co, Q(1) + co,
                                          MU + 4096 + co, RS + 4096 + co, MRS + 4096 + co);

        apply_k<1, 0, 1><<<dim3(625, 1, nc), 512, 0, stream>>>(
            BufY, BufY, nullptr, CAW1 + 1 * 8192, ca2b1, CAW2 + 1 * 8192, ca2b2,
            RS + 4096 + co, MRS + 4096 + co, S(2) + co, Q(2) + co);

        for (int i = 0; i < 3; ++i) {
            const int set = 2 + i;
            finstat_k<<<nc, 256, 0, stream>>>(S(set) + co, Q(set) + co,
                                              MU + set * 4096 + co, RS + set * 4096 + co,
                                              MRS + set * 4096 + co);
            foldw_k<<<dim3(256, nc), 256, 0, stream>>>(
                sageWl + (size_t)i * 65536, sageWr + (size_t)i * 65536, sagebl + i * 256,
                MU + set * 4096 + co, RS + set * 4096 + co,
                Wfold + (size_t)c0 * 256 * 512, biasF + co);
            agg_k<<<nc * 2500, 256, 0, stream>>>(BufY, off, csr, invcnt,
                                                 MU + set * 4096 + co, BufA);
            mgemm_k<0><<<dim3(2, 79, nc), 256, 0, stream>>>(
                BufA, SZ_, BufY, SZ_, Wfold + (size_t)c0 * 256 * 512, 256 * 512, 256, 512,
                biasF + co, 256, BufH, SZ_, N_, nullptr, nullptr);
            if (i < 2) {
                apply_k<0, 1, 1><<<dim3(625, 1, nc), 512, 0, stream>>>(
                    BufH, BufY, BufY,
                    CAW1 + (2 + i) * 8192, scab1 + i * 32,
                    CAW2 + (2 + i) * 8192, scab2 + i * 256,
                    nullptr, nullptr, S(3 + i) + co, Q(3 + i) + co);
            } else {
                apply_k<0, 1, 2><<<dim3(625, 1, nc), 512, 0, stream>>>(
                    BufH, BufY, BufY,
                    CAW1 + (2 + i) * 8192, scab1 + i * 32,
                    CAW2 + (2 + i) * 8192, scab2 + i * 256,
                    nullptr, nullptr, S(5) + co, nullptr);
            }
        }
    }

    cls_k<<<16, 256, 0, stream>>>(S(5), clsW, clsb, out);
}

// Round 10
// 1307.057 us; speedup vs baseline: 2.9040x; 1.0395x over previous
//
#include <hip/hip_runtime.h>
#include <hip/hip_bf16.h>
#include <math.h>

// ---------------- problem constants ----------------
constexpr int C_  = 16;
constexpr int N_  = 10000;
constexpr int NC_ = 2000;
constexpr int E_  = 50000;
constexpr int D_  = 256;
constexpr int SZ_ = N_ * D_;          // per-config slab (elements)
constexpr float EPS_ = 1e-5f;

typedef unsigned short u16;
typedef __attribute__((ext_vector_type(8))) unsigned short us8v;
typedef __attribute__((ext_vector_type(4))) unsigned short us4v;
typedef __attribute__((ext_vector_type(8))) short s16x8;
typedef __attribute__((ext_vector_type(4))) float f32x4;

typedef __attribute__((address_space(3))) unsigned int lds_uint;
typedef const __attribute__((address_space(1))) unsigned int glb_uint;

__device__ __forceinline__ u16 f2bf(float f) {
    __hip_bfloat16 h = __float2bfloat16(f);   // hw v_cvt (RNE)
    return __builtin_bit_cast(u16, h);
}
__device__ __forceinline__ float bf2f(u16 h) {
    return __uint_as_float(((unsigned)h) << 16);
}
// fast gelu: erf via Abramowitz-Stegun 7.1.26 (|err|<=1.5e-7) + hw exp
__device__ __forceinline__ float gelu_f(float x) {
    float z = x * 0.70710678118654752f;
    float az = fabsf(z);
    float t = 1.f / fmaf(0.3275911f, az, 1.f);
    float p = t * (0.254829592f + t * (-0.284496736f + t * (1.421413741f +
              t * (-1.453152027f + t * 1.061405429f))));
    float e = p * __expf(-z * z);
    float erfv = (z >= 0.f) ? (1.f - e) : (e - 1.f);
    return 0.5f * x * (1.f + erfv);
}

// ---------------- tiny prep kernels ----------------

__global__ __launch_bounds__(256) void tbl_k(const float* __restrict__ embL,
                                             const float* __restrict__ W,
                                             float* __restrict__ T) {
    int b = blockIdx.x;            // 0..143
    int s = b >> 3, i = b & 7, d = threadIdx.x;
    float acc = 0.f;
#pragma unroll
    for (int k = 0; k < 4; ++k)
        acc = fmaf(embL[i * 4 + k], W[(134 + s * 4 + k) * 256 + d], acc);
    T[(s * 8 + i) * 256 + d] = acc;
}

// csum[d] = sum_s T[s][0][d]
__global__ __launch_bounds__(256) void csum_k(const float* __restrict__ T,
                                              float* __restrict__ cs) {
    int d = threadIdx.x;
    float a = 0.f;
#pragma unroll
    for (int s = 0; s < 18; ++s) a += T[(s * 8) * 256 + d];
    cs[d] = a;
}

__global__ __launch_bounds__(192) void feat_k(const float* __restrict__ xf,
                                              const int* __restrict__ xlay,
                                              const int* __restrict__ xop,
                                              const float* __restrict__ embL,
                                              const float* __restrict__ embO,
                                              float* __restrict__ f) {
    int n = blockIdx.x, j = threadIdx.x;
    if (j >= 176) return;
    float v;
    if (j < 134) v = xf[n * 134 + j];
    else if (j < 158) { int q = j - 134; int t = q >> 2, k = q & 3; v = embL[(xlay[n * 6 + t] + 2) * 4 + k]; }
    else if (j < 162) { int k = j - 158; v = embO[xop[n] * 4 + k]; }
    else v = 0.f;
    f[n * 176 + j] = v;
}

__global__ __launch_bounds__(256) void wpack_k(const float* __restrict__ W,
                                               float* __restrict__ Wp) {
    int j = blockIdx.x, d = threadIdx.x;
    float v = 0.f;
    if (j < 134) v = W[j * 256 + d];
    else if (j < 158) v = W[(206 + j - 134) * 256 + d];
    else if (j < 162) v = W[(230 + j - 158) * 256 + d];
    Wp[j * 256 + d] = v;
}

// pack channel-attn W1 [256][32] into MFMA fragment order
__global__ __launch_bounds__(256) void packw1_k(const float* __restrict__ W1,
                                                u16* __restrict__ dst) {
    int i = blockIdx.x * 256 + threadIdx.x;    // 0..8191
    int j = i & 7, lane = (i >> 3) & 63, half = (i >> 9) & 1, ks = (i >> 10) & 1, wid = (i >> 11) & 3;
    int k = wid * 64 + ks * 32 + ((lane >> 4) << 3) + j;
    int col = half * 16 + (lane & 15);
    dst[i] = f2bf(W1[k * 32 + col]);
}
// pack channel-attn W2 [32][256] into MFMA fragment order
__global__ __launch_bounds__(256) void packw2_k(const float* __restrict__ W2,
                                                u16* __restrict__ dst) {
    int i = blockIdx.x * 256 + threadIdx.x;    // 0..8191
    int j = i & 7, lane = (i >> 3) & 63, q = (i >> 9) & 3, wid = (i >> 11) & 3;
    int kq = lane >> 4, cl = lane & 15;
    dst[i] = f2bf(W2[(kq * 8 + j) * 256 + (wid * 4 + q) * 16 + cl]);
}

__global__ __launch_bounds__(256) void cfgpos_k(const int* __restrict__ ncid,
                                                int* __restrict__ cfgpos) {
    int i = blockIdx.x * 256 + threadIdx.x;
    if (i < NC_) cfgpos[ncid[i]] = i;
}

__global__ __launch_bounds__(256) void hist_k(const int* __restrict__ ei, int* __restrict__ cnt) {
    int e = blockIdx.x * 256 + threadIdx.x;
    if (e < E_) atomicAdd(&cnt[ei[E_ + e]], 1);
}

__global__ __launch_bounds__(1024) void scan_k(const int* __restrict__ cnt,
                                               int* __restrict__ off,
                                               int* __restrict__ cursor,
                                               float* __restrict__ invcnt) {
    __shared__ int s[1024];
    int t = threadIdx.x;
    int base = t * 10;
    int local[10];
    int part = 0;
#pragma unroll
    for (int k = 0; k < 10; ++k) {
        int idx = base + k;
        int v = (idx < N_) ? cnt[idx] : 0;
        local[k] = v; part += v;
    }
    s[t] = part;
    __syncthreads();
    for (int o = 1; o < 1024; o <<= 1) {
        int val = (t >= o) ? s[t - o] : 0;
        __syncthreads();
        s[t] += val;
        __syncthreads();
    }
    int pre = s[t] - part;
#pragma unroll
    for (int k = 0; k < 10; ++k) {
        int idx = base + k;
        if (idx < N_) {
            off[idx] = pre;
            cursor[idx] = pre;
            invcnt[idx] = 1.0f / (float)(local[k] > 1 ? local[k] : 1);
            pre += local[k];
        }
    }
    if (t == 1023) off[N_] = s[1023];
}

__global__ __launch_bounds__(256) void fill_k(const int* __restrict__ ei,
                                              int* __restrict__ cursor,
                                              int* __restrict__ csr) {
    int e = blockIdx.x * 256 + threadIdx.x;
    if (e < E_) {
        int t = ei[E_ + e];
        int p = atomicAdd(&cursor[t], 1);
        csr[p] = ei[e];
    }
}

// transpose lin2_W -> Wt2[j][k] bf16
__global__ __launch_bounds__(256) void wt2_k(const float* __restrict__ W,
                                             u16* __restrict__ Wt) {
    int j = blockIdx.x, k = threadIdx.x;
    Wt[j * 256 + k] = f2bf(W[k * 256 + j]);
}

// fold instance-norm into sage weights (per config)
__global__ __launch_bounds__(256) void foldw_k(const float* __restrict__ Wl,
                                               const float* __restrict__ Wr,
                                               const float* __restrict__ bl,
                                               const float* __restrict__ mu,
                                               const float* __restrict__ rs,
                                               u16* __restrict__ Wt,
                                               float* __restrict__ biasF) {
    __shared__ float red[256];
    int c = blockIdx.y, j = blockIdx.x, k = threadIdx.x;
    float rsv = rs[c * 256 + k], muv = mu[c * 256 + k];
    float fl = rsv * Wl[k * 256 + j];
    float fr = rsv * Wr[k * 256 + j];
    size_t wb = ((size_t)c * 256 + j) * 512;
    Wt[wb + k] = f2bf(fl);
    Wt[wb + 256 + k] = f2bf(fr);
    red[k] = muv * (fl + fr);
    __syncthreads();
    for (int s = 128; s > 0; s >>= 1) {
        if (k < s) red[k] += red[k + s];
        __syncthreads();
    }
    if (k == 0) biasF[c * 256 + j] = bl[j] - red[0];
}

// ---------------- lin1 (configured nodes) ----------------
__global__ __launch_bounds__(256) void lin1_cfg_k(const float* __restrict__ base,
                                                  const float* __restrict__ T,
                                                  const int* __restrict__ ncid,
                                                  const int* __restrict__ xcfg,
                                                  u16* __restrict__ H,
                                                  float* __restrict__ ssum,
                                                  float* __restrict__ ssq) {
    __shared__ int idxs[16][18];   // premultiplied by 256
    __shared__ int nid[16];
    const int c = blockIdx.z, j0 = blockIdx.x * 16, tid = threadIdx.x;
    if (tid < 16) nid[tid] = ncid[j0 + tid];
    for (int t = tid; t < 288; t += 256) {
        int row = t / 18, s = t - row * 18;
        idxs[row][s] = (xcfg[((size_t)c * NC_ + j0 + row) * 18 + s] + 2) * 256;
    }
    __syncthreads();
    const int d = tid;
    float psum = 0.f, psq = 0.f;
    for (int g = 0; g < 16; g += 4) {
        float acc[4];
#pragma unroll
        for (int gg = 0; gg < 4; ++gg) acc[gg] = base[(size_t)nid[g + gg] * 256 + d];
#pragma unroll
        for (int s = 0; s < 18; ++s) {
            const float* Ts = &T[s * 2048 + d];
#pragma unroll
            for (int gg = 0; gg < 4; ++gg)
                acc[gg] += Ts[idxs[g + gg][s]];
        }
#pragma unroll
        for (int gg = 0; gg < 4; ++gg) {
            H[((size_t)c * N_ + nid[g + gg]) * 256 + d] = f2bf(acc[gg]);
            psum += acc[gg]; psq += acc[gg] * acc[gg];
        }
    }
    atomicAdd(&ssum[c * 256 + d], psum);
    atomicAdd(&ssq[c * 256 + d], psq);
}

// ---------------- lin1 (unconfigured nodes) ----------------
__global__ __launch_bounds__(256) void lin1_unc_k(const float* __restrict__ base,
                                                  const float* __restrict__ csum,
                                                  const int* __restrict__ cfgpos,
                                                  int nc,
                                                  u16* __restrict__ H,
                                                  float* __restrict__ ssum,
                                                  float* __restrict__ ssq) {
    __shared__ float red[2048];
    const int n0 = blockIdx.x * 16, tid = threadIdx.x;
    float ps[8] = {0, 0, 0, 0, 0, 0, 0, 0}, pq[8] = {0, 0, 0, 0, 0, 0, 0, 0};
#pragma unroll
    for (int it = 0; it < 2; ++it) {
        const int flat = tid + it * 256;
        const int row = flat >> 5, cb = (flat & 31) * 8;
        const int n = n0 + row;
        if (cfgpos[n] >= 0) continue;
        us8v b;
#pragma unroll
        for (int j = 0; j < 8; ++j) {
            float v = base[(size_t)n * 256 + cb + j] + csum[cb + j];
            b[j] = f2bf(v);
            ps[j] += v; pq[j] += v * v;
        }
        for (int c = 0; c < nc; ++c)
            *(us8v*)&H[((size_t)c * N_ + n) * 256 + cb] = b;
    }
#pragma unroll
    for (int j = 0; j < 8; ++j)
        red[((tid >> 5) * 32 + (tid & 31)) * 8 + j] = ps[j];
    __syncthreads();
    {
        const int cb2 = tid >> 3, j2 = tid & 7;
        float s = 0.f;
#pragma unroll
        for (int r8 = 0; r8 < 8; ++r8) s += red[(r8 * 32 + cb2) * 8 + j2];
        for (int c = 0; c < nc; ++c) atomicAdd(&ssum[c * 256 + tid], s);
    }
    __syncthreads();
#pragma unroll
    for (int j = 0; j < 8; ++j)
        red[((tid >> 5) * 32 + (tid & 31)) * 8 + j] = pq[j];
    __syncthreads();
    {
        const int cb2 = tid >> 3, j2 = tid & 7;
        float s = 0.f;
#pragma unroll
        for (int r8 = 0; r8 < 8; ++r8) s += red[(r8 * 32 + cb2) * 8 + j2];
        for (int c = 0; c < nc; ++c) atomicAdd(&ssq[c * 256 + tid], s);
    }
}

// finalize stats; also emits mrs = mu*rs for fma-folded normalize
__global__ __launch_bounds__(256) void finstat_k(const float* __restrict__ ssum,
                                                 const float* __restrict__ ssq,
                                                 float* __restrict__ mu,
                                                 float* __restrict__ rs,
                                                 float* __restrict__ mrs) {
    int i = blockIdx.x * 256 + threadIdx.x;
    float m = ssum[i] * (1.0f / (float)N_);
    float v = ssq[i] * (1.0f / (float)N_) - m * m;
    float r = rsqrtf(v + EPS_);
    mu[i] = m;
    rs[i] = r;
    mrs[i] = m * r;
}

// ---------------- CSR gather-mean: vector index load + shfl broadcast ----------------
__global__ __launch_bounds__(256) void agg_k(const u16* __restrict__ H,
                                             const int* __restrict__ off,
                                             const int* __restrict__ csr,
                                             const float* __restrict__ invcnt,
                                             const float* __restrict__ mu,
                                             u16* __restrict__ Agg) {
    int wave = threadIdx.x >> 6, lane = threadIdx.x & 63;
    int pair = blockIdx.x * 4 + wave;
    int c = pair / N_, t = pair - c * N_;
    int d4 = lane * 4;
    int o0 = off[t], o1 = off[t + 1];
    int deg = o1 - o0;
    us4v o;
    if (deg > 0) {
        int myidx = (lane < deg) ? csr[o0 + lane] : 0;
        const u16* Hc = H + (size_t)c * SZ_ + d4;
        float ax = 0.f, ay = 0.f, az = 0.f, aw = 0.f;
        int lim = deg < 64 ? deg : 64;
        int i = 0;
        for (; i + 4 <= lim; i += 4) {
            int s0 = __shfl(myidx, i), s1 = __shfl(myidx, i + 1);
            int s2 = __shfl(myidx, i + 2), s3 = __shfl(myidx, i + 3);
            us4v h0 = *(const us4v*)&Hc[(size_t)s0 * 256];
            us4v h1 = *(const us4v*)&Hc[(size_t)s1 * 256];
            us4v h2 = *(const us4v*)&Hc[(size_t)s2 * 256];
            us4v h3 = *(const us4v*)&Hc[(size_t)s3 * 256];
            ax += (bf2f(h0.x) + bf2f(h1.x)) + (bf2f(h2.x) + bf2f(h3.x));
            ay += (bf2f(h0.y) + bf2f(h1.y)) + (bf2f(h2.y) + bf2f(h3.y));
            az += (bf2f(h0.z) + bf2f(h1.z)) + (bf2f(h2.z) + bf2f(h3.z));
            aw += (bf2f(h0.w) + bf2f(h1.w)) + (bf2f(h2.w) + bf2f(h3.w));
        }
        for (; i < lim; ++i) {
            int s = __shfl(myidx, i);
            us4v h = *(const us4v*)&Hc[(size_t)s * 256];
            ax += bf2f(h.x); ay += bf2f(h.y); az += bf2f(h.z); aw += bf2f(h.w);
        }
        for (int j = o0 + 64; j < o1; ++j) {     // rare: degree > 64
            int s = csr[j];
            us4v h = *(const us4v*)&Hc[(size_t)s * 256];
            ax += bf2f(h.x); ay += bf2f(h.y); az += bf2f(h.z); aw += bf2f(h.w);
        }
        float inv = invcnt[t];
        o.x = f2bf(ax * inv); o.y = f2bf(ay * inv);
        o.z = f2bf(az * inv); o.w = f2bf(aw * inv);
    } else {
        o.x = f2bf(mu[c * 256 + d4 + 0]);
        o.y = f2bf(mu[c * 256 + d4 + 1]);
        o.z = f2bf(mu[c * 256 + d4 + 2]);
        o.w = f2bf(mu[c * 256 + d4 + 3]);
    }
    *(us4v*)&Agg[((size_t)c * N_ + t) * 256 + d4] = o;
}

// ---------------- bf16 MFMA GEMM (128x128 tile): Y = [A1|A2] @ Wt^T + bias ----------------
template <int STATS>
__global__ __launch_bounds__(256) void mgemm_k(
    const u16* __restrict__ A1, size_t sA1,
    const u16* __restrict__ A2, size_t sA2,
    const u16* __restrict__ Wt, size_t sW, int K1, int Ktot,
    const float* __restrict__ bias, size_t sBias,
    u16* __restrict__ Y, size_t sY, int Mrows,
    float* __restrict__ ssum, float* __restrict__ ssq)
{
    __shared__ u16 Asm[128 * 64];
    __shared__ u16 Bsm[128 * 64];
    const int tid = threadIdx.x;
    const int lane = tid & 63, wid = tid >> 6;
    const int wr = wid >> 1, wc = wid & 1;

    // XCD-aware bijective remap of the flattened block id
    const int gx = gridDim.x, gy = gridDim.y;
    int nwg = gx * gy * gridDim.z;
    int orig = blockIdx.x + gx * (blockIdx.y + gy * blockIdx.z);
    int q = nwg >> 3, r = nwg & 7;
    int xcd = orig & 7, idx = orig >> 3;
    int swz = (xcd < r ? xcd * (q + 1) : r * (q + 1) + (xcd - r) * q) + idx;
    const int bx = swz % gx;
    const int tmp = swz / gx;
    const int by = tmp % gy;
    const int c  = tmp / gy;

    const int rowbase = by * 128, colbase = bx * 128;

    const u16* A1p = A1 + (size_t)c * sA1;
    const u16* A2p = A2 ? (A2 + (size_t)c * sA2) : nullptr;
    const u16* Wp  = Wt + (size_t)c * sW;

    f32x4 acc[4][4];
#pragma unroll
    for (int i = 0; i < 4; ++i)
#pragma unroll
        for (int j = 0; j < 4; ++j) acc[i][j] = (f32x4)0.f;

    const int lrow = lane >> 3;        // row within the wave's 8-row group
    const int lchunk = lane & 7;       // 16B chunk within the row

    for (int k0 = 0; k0 < Ktot; k0 += 64) {
        const u16* asrc; int ak;
        if (k0 < K1) { asrc = A1p; ak = k0; } else { asrc = A2p; ak = k0 - K1; }
#pragma unroll
        for (int i = 0; i < 4; ++i) {
            const int row = (wid * 4 + i) * 8 + lrow;          // 0..127
            const int srcchunk = lchunk ^ (row & 7);           // inverse of read-side XOR
            int garow = rowbase + row;
            if (garow >= Mrows) garow = Mrows - 1;             // clamp: values unused
            const u16* ga = asrc + (size_t)garow * 256 + ak + srcchunk * 8;
            __builtin_amdgcn_global_load_lds((glb_uint*)ga,
                (lds_uint*)(Asm + (wid * 4 + i) * 512), 16, 0, 0);
            const u16* gb = Wp + (size_t)(colbase + row) * Ktot + k0 + srcchunk * 8;
            __builtin_amdgcn_global_load_lds((glb_uint*)gb,
                (lds_uint*)(Bsm + (wid * 4 + i) * 512), 16, 0, 0);
        }
        __syncthreads();
#pragma unroll
        for (int ks = 0; ks < 2; ++ks) {
            s16x8 aF[4], bF[4];
            const int kk = ks * 32 + ((lane >> 4) << 3);
#pragma unroll
            for (int f = 0; f < 4; ++f) {
                int ar = wr * 64 + f * 16 + (lane & 15);
                aF[f] = *(const s16x8*)&Asm[(ar * 64 + kk) ^ ((ar & 7) << 3)];
                int br = wc * 64 + f * 16 + (lane & 15);
                bF[f] = *(const s16x8*)&Bsm[(br * 64 + kk) ^ ((br & 7) << 3)];
            }
#pragma unroll
            for (int fr = 0; fr < 4; ++fr)
#pragma unroll
                for (int fc = 0; fc < 4; ++fc)
                    acc[fr][fc] = __builtin_amdgcn_mfma_f32_16x16x32_bf16(
                        aF[fr], bF[fc], acc[fr][fc], 0, 0, 0);
        }
        __syncthreads();
    }

    float bcol[4];
#pragma unroll
    for (int fc = 0; fc < 4; ++fc)
        bcol[fc] = bias[(size_t)c * sBias + colbase + wc * 64 + fc * 16 + (lane & 15)];
    u16* Yp = Y + (size_t)c * sY;
    float ps[4] = {0, 0, 0, 0}, pq[4] = {0, 0, 0, 0};
#pragma unroll
    for (int fr = 0; fr < 4; ++fr) {
#pragma unroll
        for (int i = 0; i < 4; ++i) {
            int grow = rowbase + wr * 64 + fr * 16 + ((lane >> 4) << 2) + i;
            if (grow < Mrows) {
                size_t rb = (size_t)grow * 256 + colbase + wc * 64 + (lane & 15);
#pragma unroll
                for (int fc = 0; fc < 4; ++fc) {
                    float v = acc[fr][fc][i] + bcol[fc];
                    Yp[rb + fc * 16] = f2bf(v);
                    if (STATS) { ps[fc] += v; pq[fc] += v * v; }
                }
            }
        }
    }
    if (STATS) {
#pragma unroll
        for (int fc = 0; fc < 4; ++fc) {
            float s = ps[fc], q2 = pq[fc];
            s += __shfl_xor(s, 16); s += __shfl_xor(s, 32);
            q2 += __shfl_xor(q2, 16); q2 += __shfl_xor(q2, 32);
            if (lane < 16) {
                int col = colbase + wc * 64 + fc * 16 + lane;
                atomicAdd(&ssum[c * 256 + col], s);
                atomicAdd(&ssq[c * 256 + col], q2);
            }
        }
    }
}

// ---------------- FUSED sage: Y = gelu(chattn([Agg|H] @ Wfold^T + biasF) + H) ----------------
// 128 rows x 256 cols tile, K=512, 8 waves (wr=wid>>2 row-half, wc=wid&3 col-quarter).
// Epilogue per 64-row half: acc -> xbf (LDS) -> t=relu(x@W1+b1) -> y'=sig(t@W2+b2)*x
// -> gelu(y'+res) coalesced store + stats. In-place on Yout (disjoint row tiles).
template <int SMODE>   // 1: sum+sumsq, 2: sum only
__global__ __launch_bounds__(512) void msage_k(
    const u16* __restrict__ A1,                 // Agg slabs
    const u16* __restrict__ A2,                 // H slabs (also residual, in-place out)
    const u16* __restrict__ Wt, size_t sW,      // folded weights [256][512] per config
    const float* __restrict__ biasF,            // [nc][256]
    const u16* __restrict__ W1p, const float* __restrict__ b1,
    const u16* __restrict__ W2p, const float* __restrict__ b2,
    u16* __restrict__ Yout, int Mrows,
    float* __restrict__ ssum, float* __restrict__ ssq)
{
    __shared__ __align__(16) char SM[56320];
    u16*   Asm   = (u16*)SM;                    // 128x64   (K loop)
    u16*   Bsm   = (u16*)(SM + 16384);          // 256x64   (K loop)
    u16*   xbf   = (u16*)SM;                    // 64x264   (attention)
    float* tpart = (float*)(SM + 33792);        // 8x528
    u16*   tbf   = (u16*)(SM + 50688);          // 64x40
    float* red   = tpart;                       // stats reduce (16KB)

    const int tid = threadIdx.x;
    const int lane = tid & 63, wid = tid >> 6;
    const int wr = wid >> 2, wc = wid & 3;
    const int cl = lane & 15, kq = lane >> 4;

    // XCD-aware bijective remap over (bx, c)
    int nwg = gridDim.x * gridDim.y;
    int orig = blockIdx.x + gridDim.x * blockIdx.y;
    int q = nwg >> 3, r = nwg & 7;
    int xcd = orig & 7, idx = orig >> 3;
    int swz = (xcd < r ? xcd * (q + 1) : r * (q + 1) + (xcd - r) * q) + idx;
    const int by = swz % gridDim.x;
    const int c  = swz / gridDim.x;
    const int rowbase = by * 128;

    const u16* A1p = A1 + (size_t)c * SZ_;
    const u16* A2p = A2 + (size_t)c * SZ_;
    const u16* Wp  = Wt + (size_t)c * sW;

    f32x4 acc[4][4];
#pragma unroll
    for (int i = 0; i < 4; ++i)
#pragma unroll
        for (int j = 0; j < 4; ++j) acc[i][j] = (f32x4)0.f;

    // ---- K loop: Ktot = 512 ----
    for (int k0 = 0; k0 < 512; k0 += 64) {
        const u16* asrc = (k0 < 256) ? A1p : A2p;
        const int ak = (k0 < 256) ? k0 : (k0 - 256);
        // A tile: 128 rows x 64k = 1024 16B units, 2/thread
#pragma unroll
        for (int jj = 0; jj < 2; ++jj) {
            const int u = tid + jj * 512;
            const int row = u >> 3, chunk = u & 7;
            const int sc2 = chunk ^ (row & 7);
            int garow = rowbase + row;
            if (garow >= Mrows) garow = Mrows - 1;
            __builtin_amdgcn_global_load_lds(
                (glb_uint*)(asrc + (size_t)garow * 256 + ak + sc2 * 8),
                (lds_uint*)(Asm + (jj * 512 + wid * 64) * 8), 16, 0, 0);
        }
        // B tile: 256 wcols x 64k = 2048 units, 4/thread
#pragma unroll
        for (int jj = 0; jj < 4; ++jj) {
            const int u = tid + jj * 512;
            const int wcol = u >> 3, chunk = u & 7;
            const int sc2 = chunk ^ (wcol & 7);
            __builtin_amdgcn_global_load_lds(
                (glb_uint*)(Wp + (size_t)wcol * 512 + k0 + sc2 * 8),
                (lds_uint*)(Bsm + (jj * 512 + wid * 64) * 8), 16, 0, 0);
        }
        __syncthreads();
#pragma unroll
        for (int ks = 0; ks < 2; ++ks) {
            s16x8 aF[4], bF[4];
            const int kk = ks * 32 + kq * 8;
#pragma unroll
            for (int f = 0; f < 4; ++f) {
                const int ar = wr * 64 + f * 16 + cl;
                aF[f] = *(const s16x8*)&Asm[(ar * 64 + kk) ^ ((ar & 7) << 3)];
                const int bc = wc * 64 + f * 16 + cl;
                bF[f] = *(const s16x8*)&Bsm[(bc * 64 + kk) ^ ((bc & 7) << 3)];
            }
#pragma unroll
            for (int fr = 0; fr < 4; ++fr)
#pragma unroll
                for (int fc = 0; fc < 4; ++fc)
                    acc[fr][fc] = __builtin_amdgcn_mfma_f32_16x16x32_bf16(
                        aF[fr], bF[fc], acc[fr][fc], 0, 0, 0);
        }
        __syncthreads();
    }

    float bcol[4];
#pragma unroll
    for (int fc = 0; fc < 4; ++fc)
        bcol[fc] = biasF[c * 256 + wc * 64 + fc * 16 + cl];

    // ---- attention epilogue: two 64-row halves ----
    for (int h = 0; h < 2; ++h) {
        __syncthreads();                 // xbf region free (staging / prev half done)
        if (wr == h) {
#pragma unroll
            for (int fr = 0; fr < 4; ++fr)
#pragma unroll
                for (int i = 0; i < 4; ++i) {
                    const int rloc = fr * 16 + kq * 4 + i;
#pragma unroll
                    for (int fc = 0; fc < 4; ++fc)
                        xbf[rloc * 264 + wc * 64 + fc * 16 + cl] =
                            f2bf(acc[fr][fc][i] + bcol[fc]);
                }
        }
        __syncthreads();
        // t partials: wave = (rb = wid>>1, kh = wid&1), K-slice of 128
        {
            const int rb = wid >> 1, kh = wid & 1;
            f32x4 at0 = (f32x4)0.f, at1 = (f32x4)0.f;
#pragma unroll
            for (int ks = 0; ks < 4; ++ks) {
                const int s = kh * 4 + ks;
                s16x8 aF = *(const s16x8*)&xbf[(rb * 16 + cl) * 264 + s * 32 + kq * 8];
                s16x8 bF0 = *(const s16x8*)&W1p[((s * 2 + 0) * 64 + lane) * 8];
                s16x8 bF1 = *(const s16x8*)&W1p[((s * 2 + 1) * 64 + lane) * 8];
                at0 = __builtin_amdgcn_mfma_f32_16x16x32_bf16(aF, bF0, at0, 0, 0, 0);
                at1 = __builtin_amdgcn_mfma_f32_16x16x32_bf16(aF, bF1, at1, 0, 0, 0);
            }
#pragma unroll
            for (int i = 0; i < 4; ++i) {
                tpart[(rb * 2 + kh) * 528 + (kq * 4 + i) * 33 + cl] = at0[i];
                tpart[(rb * 2 + kh) * 528 + (kq * 4 + i) * 33 + 16 + cl] = at1[i];
            }
        }
        __syncthreads();
        // reduce 2 partials, +b1, relu -> tbf
#pragma unroll
        for (int it = 0; it < 4; ++it) {
            const int e = tid + it * 512;
            const int row = e >> 5, col = e & 31;
            const int rb = row >> 4, rr = row & 15;
            float s = tpart[(rb * 2) * 528 + rr * 33 + col] +
                      tpart[(rb * 2 + 1) * 528 + rr * 33 + col] + b1[col];
            tbf[row * 40 + col] = f2bf(fmaxf(s, 0.f));
        }
        __syncthreads();
        // y' = sigmoid(t@W2 + b2) * x  -> back into xbf
        {
            s16x8 aF[4];
#pragma unroll
            for (int rg = 0; rg < 4; ++rg)
                aF[rg] = *(const s16x8*)&tbf[(rg * 16 + cl) * 40 + kq * 8];
#pragma unroll
            for (int q2 = 0; q2 < 2; ++q2) {
                const int colb = (wid * 2 + q2) * 16;
                s16x8 bF = *(const s16x8*)&W2p[((wid * 2 + q2) * 64 + lane) * 8];
                const float b2v = b2[colb + cl];
#pragma unroll
                for (int rg = 0; rg < 4; ++rg) {
                    f32x4 a2 = __builtin_amdgcn_mfma_f32_16x16x32_bf16(
                        aF[rg], bF, (f32x4)0.f, 0, 0, 0);
#pragma unroll
                    for (int i = 0; i < 4; ++i) {
                        const int ea = (rg * 16 + kq * 4 + i) * 264 + colb + cl;
                        float s = a2[i] + b2v;
                        float sig = 1.f / (1.f + __expf(-s));
                        xbf[ea] = f2bf(sig * bf2f(xbf[ea]));
                    }
                }
            }
        }
        __syncthreads();
        // gelu(y' + res), coalesced store + stats
        float ps[8] = {0, 0, 0, 0, 0, 0, 0, 0}, pq[8] = {0, 0, 0, 0, 0, 0, 0, 0};
#pragma unroll
        for (int it = 0; it < 4; ++it) {
            const int e = tid + it * 512;
            const int row = e >> 5, cb = (e & 31) * 8;
            const int grow = rowbase + h * 64 + row;
            if (grow < Mrows) {
                us8v xv = *(const us8v*)&xbf[row * 264 + cb];
                us8v rv = *(const us8v*)&Yout[((size_t)c * N_ + grow) * 256 + cb];
                us8v ov;
#pragma unroll
                for (int j = 0; j < 8; ++j) {
                    float v = gelu_f(bf2f(xv[j]) + bf2f(rv[j]));
                    ov[j] = f2bf(v);
                    ps[j] += v;
                    if (SMODE == 1) pq[j] += v * v;
                }
                *(us8v*)&Yout[((size_t)c * N_ + grow) * 256 + cb] = ov;
            }
        }
#pragma unroll
        for (int j = 0; j < 8; ++j)
            red[((tid >> 5) * 32 + (tid & 31)) * 8 + j] = ps[j];
        __syncthreads();
        if (tid < 256) {
            const int cb2 = tid >> 3, j2 = tid & 7;
            float s = 0.f;
#pragma unroll
            for (int r16 = 0; r16 < 16; ++r16) s += red[(r16 * 32 + cb2) * 8 + j2];
            atomicAdd(&ssum[c * 256 + cb2 * 8 + j2], s);
        }
        if (SMODE == 1) {
            __syncthreads();
#pragma unroll
            for (int j = 0; j < 8; ++j)
                red[((tid >> 5) * 32 + (tid & 31)) * 8 + j] = pq[j];
            __syncthreads();
            if (tid < 256) {
                const int cb2 = tid >> 3, j2 = tid & 7;
                float s = 0.f;
#pragma unroll
                for (int r16 = 0; r16 < 16; ++r16) s += red[(r16 * 32 + cb2) * 8 + j2];
                atomicAdd(&ssq[c * 256 + cb2 * 8 + j2], s);
            }
        }
    }
}

// ---------------- fp32 tiled GEMM (one-time base GEMM) ----------------
__global__ __launch_bounds__(256) void gemm_k(const float* __restrict__ A1, int lda1,
                                              const float* __restrict__ W1, int K1,
                                              const float* __restrict__ bias,
                                              float* __restrict__ Y, int Mrows) {
    __shared__ float As[16][132];
    __shared__ float Bs[16][132];
    float acc[8][8];
#pragma unroll
    for (int i = 0; i < 8; ++i)
#pragma unroll
        for (int j = 0; j < 8; ++j) acc[i][j] = 0.f;

    const int tid = threadIdx.x;
    const int tr = tid >> 4, tc = tid & 15;
    const int rowbase = blockIdx.y * 128, colbase = blockIdx.x * 128;

    for (int k0 = 0; k0 < K1; k0 += 16) {
#pragma unroll
        for (int ii = 0; ii < 2; ++ii) {
            int i = tid + ii * 256;
            int rr = i >> 2, qq = i & 3;
            int grow = rowbase + rr;
            float4 vv = make_float4(0.f, 0.f, 0.f, 0.f);
            if (grow < Mrows) vv = *(const float4*)&A1[(size_t)grow * lda1 + k0 + qq * 4];
            As[qq * 4 + 0][rr] = vv.x;
            As[qq * 4 + 1][rr] = vv.y;
            As[qq * 4 + 2][rr] = vv.z;
            As[qq * 4 + 3][rr] = vv.w;
        }
#pragma unroll
        for (int ii = 0; ii < 2; ++ii) {
            int i = tid + ii * 256;
            int rr = i >> 5, qq = i & 31;
            float4 vv = *(const float4*)&W1[(size_t)(k0 + rr) * 256 + colbase + qq * 4];
            *(float4*)&Bs[rr][qq * 4] = vv;
        }
        __syncthreads();
#pragma unroll
        for (int kk = 0; kk < 16; ++kk) {
            float a[8], b[8];
            *(float4*)&a[0] = *(const float4*)&As[kk][tr * 4];
            *(float4*)&a[4] = *(const float4*)&As[kk][64 + tr * 4];
            *(float4*)&b[0] = *(const float4*)&Bs[kk][tc * 4];
            *(float4*)&b[4] = *(const float4*)&Bs[kk][64 + tc * 4];
#pragma unroll
            for (int i = 0; i < 8; ++i)
#pragma unroll
                for (int j = 0; j < 8; ++j)
                    acc[i][j] = fmaf(a[i], b[j], acc[i][j]);
        }
        __syncthreads();
    }

    float4 blo = *(const float4*)&bias[colbase + tc * 4];
    float4 bhi = *(const float4*)&bias[colbase + 64 + tc * 4];
    float bb[8] = {blo.x, blo.y, blo.z, blo.w, bhi.x, bhi.y, bhi.z, bhi.w};
#pragma unroll
    for (int i = 0; i < 8; ++i)
#pragma unroll
        for (int j = 0; j < 8; ++j) acc[i][j] += bb[j];

#pragma unroll
    for (int i = 0; i < 8; ++i) {
        int lrow = (i < 4) ? (tr * 4 + i) : (64 + tr * 4 + (i - 4));
        int grow = rowbase + lrow;
        if (grow < Mrows) {
            *(float4*)&Y[(size_t)grow * 256 + colbase + tc * 4] =
                make_float4(acc[i][0], acc[i][1], acc[i][2], acc[i][3]);
            *(float4*)&Y[(size_t)grow * 256 + colbase + 64 + tc * 4] =
                make_float4(acc[i][4], acc[i][5], acc[i][6], acc[i][7]);
        }
    }
}

// ---------------- per-row epilogue with MFMA channel-attention (512 thr, 8 waves) ----------------
template <int NORM, int RES, int SMODE>
__global__ __launch_bounds__(512) void apply_k(const u16* __restrict__ Yin,
                                               u16* __restrict__ Hout,
                                               const u16* __restrict__ Hsc,
                                               const u16* __restrict__ W1p,
                                               const float* __restrict__ b1,
                                               const u16* __restrict__ W2p,
                                               const float* __restrict__ b2,
                                               const float* __restrict__ rs,
                                               const float* __restrict__ mrs,
                                               float* __restrict__ ssum,
                                               float* __restrict__ ssq) {
    __shared__ u16 vbf[16 * 264];
    __shared__ u16 scs[(RES ? 16 : 1) * 264];
    __shared__ float tpart[8 * 528];
    __shared__ u16 tbf[16 * 40];
    __shared__ float srs[NORM ? 256 : 1], smrs[NORM ? 256 : 1];
    const int c = blockIdx.z, n0 = blockIdx.x * 16, tid = threadIdx.x;
    const int lane = tid & 63, wid = tid >> 6;   // wid 0..7
    const size_t rowbase = ((size_t)c * N_ + n0) * 256;

    if (NORM && tid < 256) { srs[tid] = rs[c * 256 + tid]; smrs[tid] = mrs[c * 256 + tid]; }
    {
        const int row = tid >> 5, cb = (tid & 31) * 8;
        us8v x = *(const us8v*)&Yin[rowbase + row * 256 + cb];
        us8v r;
        if (RES) r = *(const us8v*)&Hsc[rowbase + row * 256 + cb];
        if (NORM) {
            __syncthreads();
            us8v y;
#pragma unroll
            for (int j = 0; j < 8; ++j)
                y[j] = f2bf(fmaf(bf2f(x[j]), srs[cb + j], -smrs[cb + j]));
            *(us8v*)&vbf[row * 264 + cb] = y;
        } else {
            *(us8v*)&vbf[row * 264 + cb] = x;
        }
        if (RES) *(us8v*)&scs[row * 264 + cb] = r;
    }
    __syncthreads();

    {
        const int arow = lane & 15, kq = lane >> 4;
        const int k = wid * 32 + kq * 8;
        s16x8 aF = *(const s16x8*)&vbf[arow * 264 + k];
        s16x8 bF0 = *(const s16x8*)&W1p[((wid * 2 + 0) * 64 + lane) * 8];
        s16x8 bF1 = *(const s16x8*)&W1p[((wid * 2 + 1) * 64 + lane) * 8];
        f32x4 at0 = __builtin_amdgcn_mfma_f32_16x16x32_bf16(aF, bF0, (f32x4)0.f, 0, 0, 0);
        f32x4 at1 = __builtin_amdgcn_mfma_f32_16x16x32_bf16(aF, bF1, (f32x4)0.f, 0, 0, 0);
#pragma unroll
        for (int i = 0; i < 4; ++i) {
            tpart[wid * 528 + (kq * 4 + i) * 33 + (lane & 15)] = at0[i];
            tpart[wid * 528 + (kq * 4 + i) * 33 + 16 + (lane & 15)] = at1[i];
        }
    }
    __syncthreads();

    {
        const int nr = tid >> 5, col = tid & 31;
        float s = b1[col];
#pragma unroll
        for (int w8 = 0; w8 < 8; ++w8)
            s += tpart[w8 * 528 + nr * 33 + col];
        tbf[nr * 40 + col] = f2bf(fmaxf(s, 0.f));
    }
    __syncthreads();

    {
        const int cl = lane & 15, kq = lane >> 4;
        s16x8 aF = *(const s16x8*)&tbf[cl * 40 + kq * 8];
        float ps[2] = {0, 0}, pq[2] = {0, 0};
#pragma unroll
        for (int q = 0; q < 2; ++q) {
            const int colb = (wid * 2 + q) * 16;
            s16x8 bF = *(const s16x8*)&W2p[((wid * 2 + q) * 64 + lane) * 8];
            f32x4 acc = __builtin_amdgcn_mfma_f32_16x16x32_bf16(aF, bF, (f32x4)0.f, 0, 0, 0);
            const float b2v = b2[colb + cl];
#pragma unroll
            for (int i = 0; i < 4; ++i) {
                const int row = kq * 4 + i;
                const int ea = row * 264 + colb + cl;
                float s = acc[i] + b2v;
                float sig = 1.0f / (1.0f + __expf(-s));
                float val = sig * bf2f(vbf[ea]);
                if (RES) val += bf2f(scs[ea]);
                val = gelu_f(val);
                vbf[ea] = f2bf(val);
                if (SMODE) { ps[q] += val; if (SMODE == 1) pq[q] += val * val; }
            }
        }
        if (SMODE) {
#pragma unroll
            for (int q = 0; q < 2; ++q) {
                float s = ps[q];
                s += __shfl_xor(s, 16); s += __shfl_xor(s, 32);
                if (SMODE == 1) {
                    float q2 = pq[q];
                    q2 += __shfl_xor(q2, 16); q2 += __shfl_xor(q2, 32);
                    if (lane < 16) atomicAdd(&ssq[c * 256 + (wid * 2 + q) * 16 + lane], q2);
                }
                if (lane < 16) atomicAdd(&ssum[c * 256 + (wid * 2 + q) * 16 + lane], s);
            }
        }
    }
    __syncthreads();

    {
        const int row = tid >> 5, cb = (tid & 31) * 8;
        us8v h = *(const us8v*)&vbf[row * 264 + cb];
        *(us8v*)&Hout[rowbase + row * 256 + cb] = h;
    }
}

// ---------------- classifier ----------------
__global__ __launch_bounds__(256) void cls_k(const float* __restrict__ pooled_sum,
                                             const float* __restrict__ clsW,
                                             const float* __restrict__ clsb,
                                             float* __restrict__ out) {
    __shared__ float red[256];
    int c = blockIdx.x, d = threadIdx.x;
    red[d] = pooled_sum[c * 256 + d] * (1.0f / (float)N_) * clsW[d];
    __syncthreads();
    for (int s = 128; s > 0; s >>= 1) {
        if (d < s) red[d] += red[d + s];
        __syncthreads();
    }
    if (d == 0) out[c] = red[0] + clsb[0];
}

// ---------------- host launch ----------------
static inline size_t alup(size_t x) { return (x + 255) & ~(size_t)255; }

extern "C" void kernel_launch(void* const* d_in, const int* in_sizes, int n_in,
                              void* d_out, int out_size, void* d_ws, size_t ws_size,
                              hipStream_t stream) {
    const int*   xcfg   = (const int*)d_in[0];
    const float* xfeat  = (const float*)d_in[1];
    const int*   xlay   = (const int*)d_in[2];
    const int*   xop    = (const int*)d_in[3];
    const int*   ei     = (const int*)d_in[4];
    const int*   ncid   = (const int*)d_in[5];
    const float* embO   = (const float*)d_in[6];
    const float* embL   = (const float*)d_in[7];
    const float* lin1W  = (const float*)d_in[8];
    const float* lin1b  = (const float*)d_in[9];
    const float* ca1W1  = (const float*)d_in[10];
    const float* ca1b1  = (const float*)d_in[11];
    const float* ca1W2  = (const float*)d_in[12];
    const float* ca1b2  = (const float*)d_in[13];
    const float* lin2W  = (const float*)d_in[14];
    const float* lin2b  = (const float*)d_in[15];
    const float* ca2W1  = (const float*)d_in[16];
    const float* ca2b1  = (const float*)d_in[17];
    const float* ca2W2  = (const float*)d_in[18];
    const float* ca2b2  = (const float*)d_in[19];
    const float* sageWl = (const float*)d_in[20];
    const float* sagebl = (const float*)d_in[21];
    const float* sageWr = (const float*)d_in[22];
    const float* scaW1  = (const float*)d_in[23];
    const float* scab1  = (const float*)d_in[24];
    const float* scaW2  = (const float*)d_in[25];
    const float* scab2  = (const float*)d_in[26];
    const float* clsW   = (const float*)d_in[27];
    const float* clsb   = (const float*)d_in[28];
    float* out = (float*)d_out;

    // ---- workspace carve-up ----
    char* w = (char*)d_ws;
    size_t o = 0;
    auto take = [&](size_t bytes) { char* p = w + o; o = alup(o + bytes); return p; };
    float* base    = (float*)take((size_t)N_ * 256 * 4);
    float* feat162 = (float*)take((size_t)N_ * 176 * 4);
    float* W162    = (float*)take((size_t)176 * 256 * 4);
    float* T       = (float*)take((size_t)18 * 8 * 256 * 4);
    float* csum    = (float*)take((size_t)256 * 4);
    float* stats   = (float*)take((size_t)6 * 8192 * 4);
    float* MU      = (float*)take((size_t)5 * 4096 * 4);
    float* RS      = (float*)take((size_t)5 * 4096 * 4);
    float* MRS     = (float*)take((size_t)5 * 4096 * 4);
    float* invcnt  = (float*)take((size_t)N_ * 4);
    int*   cnt     = (int*)take((size_t)N_ * 4);
    int*   off     = (int*)take((size_t)(N_ + 1) * 4);
    int*   cursor  = (int*)take((size_t)N_ * 4);
    int*   csr     = (int*)take((size_t)E_ * 4);
    int*   cfgpos  = (int*)take((size_t)N_ * 4);
    u16*   Wt2     = (u16*)take((size_t)256 * 256 * 2);
    u16*   Wfold   = (u16*)take((size_t)C_ * 256 * 512 * 2);   // 4 MB
    float* biasF   = (float*)take((size_t)C_ * 256 * 4);
    u16*   CAW1    = (u16*)take((size_t)5 * 8192 * 2);         // packed frag order
    u16*   CAW2    = (u16*)take((size_t)5 * 8192 * 2);

    const size_t slab = (size_t)SZ_ * 2;                       // bf16: 5.12 MB
    size_t avail = (ws_size > o) ? (ws_size - o) : 0;
    int Cc = (int)(avail / (3 * slab + 768));
    if (Cc > C_) Cc = C_;
    if (Cc < 1) Cc = 1;
    u16* BufH = (u16*)take((size_t)Cc * slab);
    u16* BufY = (u16*)take((size_t)Cc * slab);
    u16* BufA = (u16*)take((size_t)Cc * slab);
    (void)in_sizes; (void)n_in; (void)out_size;

    auto S = [&](int s) { return stats + (size_t)s * 8192; };
    auto Q = [&](int s) { return stats + (size_t)s * 8192 + 4096; };

    hipMemsetAsync(stats, 0, 6 * 8192 * 4, stream);
    hipMemsetAsync(cnt, 0, N_ * 4, stream);
    hipMemsetAsync(cfgpos, 0xFF, N_ * 4, stream);

    // shared prep
    tbl_k<<<144, 256, 0, stream>>>(embL, lin1W, T);
    csum_k<<<1, 256, 0, stream>>>(T, csum);
    feat_k<<<N_, 192, 0, stream>>>(xfeat, xlay, xop, embL, embO, feat162);
    wpack_k<<<176, 256, 0, stream>>>(lin1W, W162);
    wt2_k<<<256, 256, 0, stream>>>(lin2W, Wt2);
    packw1_k<<<32, 256, 0, stream>>>(ca1W1, CAW1 + 0 * 8192);
    packw1_k<<<32, 256, 0, stream>>>(ca2W1, CAW1 + 1 * 8192);
    packw1_k<<<32, 256, 0, stream>>>(scaW1 + 0 * 8192, CAW1 + 2 * 8192);
    packw1_k<<<32, 256, 0, stream>>>(scaW1 + 1 * 8192, CAW1 + 3 * 8192);
    packw1_k<<<32, 256, 0, stream>>>(scaW1 + 2 * 8192, CAW1 + 4 * 8192);
    packw2_k<<<32, 256, 0, stream>>>(ca1W2, CAW2 + 0 * 8192);
    packw2_k<<<32, 256, 0, stream>>>(ca2W2, CAW2 + 1 * 8192);
    packw2_k<<<32, 256, 0, stream>>>(scaW2 + 0 * 8192, CAW2 + 2 * 8192);
    packw2_k<<<32, 256, 0, stream>>>(scaW2 + 1 * 8192, CAW2 + 3 * 8192);
    packw2_k<<<32, 256, 0, stream>>>(scaW2 + 2 * 8192, CAW2 + 4 * 8192);
    cfgpos_k<<<(NC_ + 255) / 256, 256, 0, stream>>>(ncid, cfgpos);
    hist_k<<<(E_ + 255) / 256, 256, 0, stream>>>(ei, cnt);
    scan_k<<<1, 1024, 0, stream>>>(cnt, off, cursor, invcnt);
    fill_k<<<(E_ + 255) / 256, 256, 0, stream>>>(ei, cursor, csr);

    // base = feat162 @ W162 + lin1_b (fp32, one-time)
    gemm_k<<<dim3(2, 79, 1), 256, 0, stream>>>(feat162, 176, W162, 176, lin1b, base, N_);

    // ---- per-config-chunk pipeline ----
    for (int c0 = 0; c0 < C_; c0 += Cc) {
        const int nc = (C_ - c0 < Cc) ? (C_ - c0) : Cc;
        const int co = c0 * 256;

        lin1_cfg_k<<<dim3(NC_ / 16, 1, nc), 256, 0, stream>>>(
            base, T, ncid, xcfg + (size_t)c0 * NC_ * 18, BufH, S(0) + co, Q(0) + co);
        lin1_unc_k<<<625, 256, 0, stream>>>(
            base, csum, cfgpos, nc, BufH, S(0) + co, Q(0) + co);
        finstat_k<<<nc, 256, 0, stream>>>(S(0) + co, Q(0) + co,
                                          MU + co, RS + co, MRS + co);

        apply_k<1, 0, 0><<<dim3(625, 1, nc), 512, 0, stream>>>(
            BufH, BufH, nullptr, CAW1 + 0 * 8192, ca1b1, CAW2 + 0 * 8192, ca1b2,
            RS + co, MRS + co, nullptr, nullptr);

        mgemm_k<1><<<dim3(2, 79, nc), 256, 0, stream>>>(
            BufH, SZ_, nullptr, 0, Wt2, 0, 256, 256,
            lin2b, 0, BufY, SZ_, N_, S(1) + co, Q(1) + co);
        finstat_k<<<nc, 256, 0, stream>>>(S(1) + co, Q(1) + co,
                                          MU + 4096 + co, RS + 4096 + co, MRS + 4096 + co);

        apply_k<1, 0, 1><<<dim3(625, 1, nc), 512, 0, stream>>>(
            BufY, BufY, nullptr, CAW1 + 1 * 8192, ca2b1, CAW2 + 1 * 8192, ca2b2,
            RS + 4096 + co, MRS + 4096 + co, S(2) + co, Q(2) + co);

        for (int i = 0; i < 3; ++i) {
            const int set = 2 + i;
            finstat_k<<<nc, 256, 0, stream>>>(S(set) + co, Q(set) + co,
                                              MU + set * 4096 + co, RS + set * 4096 + co,
                                              MRS + set * 4096 + co);
            foldw_k<<<dim3(256, nc), 256, 0, stream>>>(
                sageWl + (size_t)i * 65536, sageWr + (size_t)i * 65536, sagebl + i * 256,
                MU + set * 4096 + co, RS + set * 4096 + co,
                Wfold + (size_t)c0 * 256 * 512, biasF + co);
            agg_k<<<nc * 2500, 256, 0, stream>>>(BufY, off, csr, invcnt,
                                                 MU + set * 4096 + co, BufA);
            if (i < 2) {
                msage_k<1><<<dim3(79, nc), 512, 0, stream>>>(
                    BufA, BufY, Wfold + (size_t)c0 * 256 * 512, 256 * 512, biasF + co,
                    CAW1 + (2 + i) * 8192, scab1 + i * 32,
                    CAW2 + (2 + i) * 8192, scab2 + i * 256,
                    BufY, N_, S(3 + i) + co, Q(3 + i) + co);
            } else {
                msage_k<2><<<dim3(79, nc), 512, 0, stream>>>(
                    BufA, BufY, Wfold + (size_t)c0 * 256 * 512, 256 * 512, biasF + co,
                    CAW1 + (2 + i) * 8192, scab1 + i * 32,
                    CAW2 + (2 + i) * 8192, scab2 + i * 256,
                    BufY, N_, S(5) + co, nullptr);
            }
        }
    }

    cls_k<<<16, 256, 0, stream>>>(S(5), clsW, clsb, out);
}

// Round 11
// 1299.066 us; speedup vs baseline: 2.9218x; 1.0062x over previous
//
#include <hip/hip_runtime.h>
#include <hip/hip_bf16.h>
#include <math.h>

// ---------------- problem constants ----------------
constexpr int C_  = 16;
constexpr int N_  = 10000;
constexpr int NC_ = 2000;
constexpr int E_  = 50000;
constexpr int D_  = 256;
constexpr int SZ_ = N_ * D_;          // per-config slab (elements)
constexpr float EPS_ = 1e-5f;

typedef unsigned short u16;
typedef __attribute__((ext_vector_type(8))) unsigned short us8v;
typedef __attribute__((ext_vector_type(4))) unsigned short us4v;
typedef __attribute__((ext_vector_type(8))) short s16x8;
typedef __attribute__((ext_vector_type(4))) float f32x4;

typedef __attribute__((address_space(3))) unsigned int lds_uint;
typedef const __attribute__((address_space(1))) unsigned int glb_uint;

__device__ __forceinline__ u16 f2bf(float f) {
    __hip_bfloat16 h = __float2bfloat16(f);   // hw v_cvt (RNE)
    return __builtin_bit_cast(u16, h);
}
__device__ __forceinline__ float bf2f(u16 h) {
    return __uint_as_float(((unsigned)h) << 16);
}
// fast gelu: erf via Abramowitz-Stegun 7.1.26 (|err|<=1.5e-7) + hw exp
__device__ __forceinline__ float gelu_f(float x) {
    float z = x * 0.70710678118654752f;
    float az = fabsf(z);
    float t = 1.f / fmaf(0.3275911f, az, 1.f);
    float p = t * (0.254829592f + t * (-0.284496736f + t * (1.421413741f +
              t * (-1.453152027f + t * 1.061405429f))));
    float e = p * __expf(-z * z);
    float erfv = (z >= 0.f) ? (1.f - e) : (e - 1.f);
    return 0.5f * x * (1.f + erfv);
}

// ---------------- tiny prep kernels ----------------

__global__ __launch_bounds__(256) void tbl_k(const float* __restrict__ embL,
                                             const float* __restrict__ W,
                                             float* __restrict__ T) {
    int b = blockIdx.x;            // 0..143
    int s = b >> 3, i = b & 7, d = threadIdx.x;
    float acc = 0.f;
#pragma unroll
    for (int k = 0; k < 4; ++k)
        acc = fmaf(embL[i * 4 + k], W[(134 + s * 4 + k) * 256 + d], acc);
    T[(s * 8 + i) * 256 + d] = acc;
}

// csum[d] = sum_s T[s][0][d]
__global__ __launch_bounds__(256) void csum_k(const float* __restrict__ T,
                                              float* __restrict__ cs) {
    int d = threadIdx.x;
    float a = 0.f;
#pragma unroll
    for (int s = 0; s < 18; ++s) a += T[(s * 8) * 256 + d];
    cs[d] = a;
}

__global__ __launch_bounds__(192) void feat_k(const float* __restrict__ xf,
                                              const int* __restrict__ xlay,
                                              const int* __restrict__ xop,
                                              const float* __restrict__ embL,
                                              const float* __restrict__ embO,
                                              float* __restrict__ f) {
    int n = blockIdx.x, j = threadIdx.x;
    if (j >= 176) return;
    float v;
    if (j < 134) v = xf[n * 134 + j];
    else if (j < 158) { int q = j - 134; int t = q >> 2, k = q & 3; v = embL[(xlay[n * 6 + t] + 2) * 4 + k]; }
    else if (j < 162) { int k = j - 158; v = embO[xop[n] * 4 + k]; }
    else v = 0.f;
    f[n * 176 + j] = v;
}

__global__ __launch_bounds__(256) void wpack_k(const float* __restrict__ W,
                                               float* __restrict__ Wp) {
    int j = blockIdx.x, d = threadIdx.x;
    float v = 0.f;
    if (j < 134) v = W[j * 256 + d];
    else if (j < 158) v = W[(206 + j - 134) * 256 + d];
    else if (j < 162) v = W[(230 + j - 158) * 256 + d];
    Wp[j * 256 + d] = v;
}

// pack channel-attn W1 [256][32] into MFMA fragment order
__global__ __launch_bounds__(256) void packw1_k(const float* __restrict__ W1,
                                                u16* __restrict__ dst) {
    int i = blockIdx.x * 256 + threadIdx.x;    // 0..8191
    int j = i & 7, lane = (i >> 3) & 63, half = (i >> 9) & 1, ks = (i >> 10) & 1, wid = (i >> 11) & 3;
    int k = wid * 64 + ks * 32 + ((lane >> 4) << 3) + j;
    int col = half * 16 + (lane & 15);
    dst[i] = f2bf(W1[k * 32 + col]);
}
// pack channel-attn W2 [32][256] into MFMA fragment order
__global__ __launch_bounds__(256) void packw2_k(const float* __restrict__ W2,
                                                u16* __restrict__ dst) {
    int i = blockIdx.x * 256 + threadIdx.x;    // 0..8191
    int j = i & 7, lane = (i >> 3) & 63, q = (i >> 9) & 3, wid = (i >> 11) & 3;
    int kq = lane >> 4, cl = lane & 15;
    dst[i] = f2bf(W2[(kq * 8 + j) * 256 + (wid * 4 + q) * 16 + cl]);
}

__global__ __launch_bounds__(256) void cfgpos_k(const int* __restrict__ ncid,
                                                int* __restrict__ cfgpos) {
    int i = blockIdx.x * 256 + threadIdx.x;
    if (i < NC_) cfgpos[ncid[i]] = i;
}

__global__ __launch_bounds__(256) void hist_k(const int* __restrict__ ei, int* __restrict__ cnt) {
    int e = blockIdx.x * 256 + threadIdx.x;
    if (e < E_) atomicAdd(&cnt[ei[E_ + e]], 1);
}

__global__ __launch_bounds__(1024) void scan_k(const int* __restrict__ cnt,
                                               int* __restrict__ off,
                                               int* __restrict__ cursor,
                                               float* __restrict__ invcnt) {
    __shared__ int s[1024];
    int t = threadIdx.x;
    int base = t * 10;
    int local[10];
    int part = 0;
#pragma unroll
    for (int k = 0; k < 10; ++k) {
        int idx = base + k;
        int v = (idx < N_) ? cnt[idx] : 0;
        local[k] = v; part += v;
    }
    s[t] = part;
    __syncthreads();
    for (int o = 1; o < 1024; o <<= 1) {
        int val = (t >= o) ? s[t - o] : 0;
        __syncthreads();
        s[t] += val;
        __syncthreads();
    }
    int pre = s[t] - part;
#pragma unroll
    for (int k = 0; k < 10; ++k) {
        int idx = base + k;
        if (idx < N_) {
            off[idx] = pre;
            cursor[idx] = pre;
            invcnt[idx] = 1.0f / (float)(local[k] > 1 ? local[k] : 1);
            pre += local[k];
        }
    }
    if (t == 1023) off[N_] = s[1023];
}

__global__ __launch_bounds__(256) void fill_k(const int* __restrict__ ei,
                                              int* __restrict__ cursor,
                                              int* __restrict__ csr) {
    int e = blockIdx.x * 256 + threadIdx.x;
    if (e < E_) {
        int t = ei[E_ + e];
        int p = atomicAdd(&cursor[t], 1);
        csr[p] = ei[e];
    }
}

// transpose lin2_W -> Wt2[j][k] bf16
__global__ __launch_bounds__(256) void wt2_k(const float* __restrict__ W,
                                             u16* __restrict__ Wt) {
    int j = blockIdx.x, k = threadIdx.x;
    Wt[j * 256 + k] = f2bf(W[k * 256 + j]);
}

// fold instance-norm into sage weights (per config)
__global__ __launch_bounds__(256) void foldw_k(const float* __restrict__ Wl,
                                               const float* __restrict__ Wr,
                                               const float* __restrict__ bl,
                                               const float* __restrict__ mu,
                                               const float* __restrict__ rs,
                                               u16* __restrict__ Wt,
                                               float* __restrict__ biasF) {
    __shared__ float red[256];
    int c = blockIdx.y, j = blockIdx.x, k = threadIdx.x;
    float rsv = rs[c * 256 + k], muv = mu[c * 256 + k];
    float fl = rsv * Wl[k * 256 + j];
    float fr = rsv * Wr[k * 256 + j];
    size_t wb = ((size_t)c * 256 + j) * 512;
    Wt[wb + k] = f2bf(fl);
    Wt[wb + 256 + k] = f2bf(fr);
    red[k] = muv * (fl + fr);
    __syncthreads();
    for (int s = 128; s > 0; s >>= 1) {
        if (k < s) red[k] += red[k + s];
        __syncthreads();
    }
    if (k == 0) biasF[c * 256 + j] = bl[j] - red[0];
}

// ---------------- lin1 (configured nodes) ----------------
__global__ __launch_bounds__(256) void lin1_cfg_k(const float* __restrict__ base,
                                                  const float* __restrict__ T,
                                                  const int* __restrict__ ncid,
                                                  const int* __restrict__ xcfg,
                                                  u16* __restrict__ H,
                                                  float* __restrict__ ssum,
                                                  float* __restrict__ ssq) {
    __shared__ int idxs[16][18];   // premultiplied by 256
    __shared__ int nid[16];
    const int c = blockIdx.z, j0 = blockIdx.x * 16, tid = threadIdx.x;
    if (tid < 16) nid[tid] = ncid[j0 + tid];
    for (int t = tid; t < 288; t += 256) {
        int row = t / 18, s = t - row * 18;
        idxs[row][s] = (xcfg[((size_t)c * NC_ + j0 + row) * 18 + s] + 2) * 256;
    }
    __syncthreads();
    const int d = tid;
    float psum = 0.f, psq = 0.f;
    for (int g = 0; g < 16; g += 4) {
        float acc[4];
#pragma unroll
        for (int gg = 0; gg < 4; ++gg) acc[gg] = base[(size_t)nid[g + gg] * 256 + d];
#pragma unroll
        for (int s = 0; s < 18; ++s) {
            const float* Ts = &T[s * 2048 + d];
#pragma unroll
            for (int gg = 0; gg < 4; ++gg)
                acc[gg] += Ts[idxs[g + gg][s]];
        }
#pragma unroll
        for (int gg = 0; gg < 4; ++gg) {
            H[((size_t)c * N_ + nid[g + gg]) * 256 + d] = f2bf(acc[gg]);
            psum += acc[gg]; psq += acc[gg] * acc[gg];
        }
    }
    atomicAdd(&ssum[c * 256 + d], psum);
    atomicAdd(&ssq[c * 256 + d], psq);
}

// ---------------- lin1 (unconfigured nodes) ----------------
__global__ __launch_bounds__(256) void lin1_unc_k(const float* __restrict__ base,
                                                  const float* __restrict__ csum,
                                                  const int* __restrict__ cfgpos,
                                                  int nc,
                                                  u16* __restrict__ H,
                                                  float* __restrict__ ssum,
                                                  float* __restrict__ ssq) {
    __shared__ float red[2048];
    const int n0 = blockIdx.x * 16, tid = threadIdx.x;
    float ps[8] = {0, 0, 0, 0, 0, 0, 0, 0}, pq[8] = {0, 0, 0, 0, 0, 0, 0, 0};
#pragma unroll
    for (int it = 0; it < 2; ++it) {
        const int flat = tid + it * 256;
        const int row = flat >> 5, cb = (flat & 31) * 8;
        const int n = n0 + row;
        if (cfgpos[n] >= 0) continue;
        us8v b;
#pragma unroll
        for (int j = 0; j < 8; ++j) {
            float v = base[(size_t)n * 256 + cb + j] + csum[cb + j];
            b[j] = f2bf(v);
            ps[j] += v; pq[j] += v * v;
        }
        for (int c = 0; c < nc; ++c)
            *(us8v*)&H[((size_t)c * N_ + n) * 256 + cb] = b;
    }
#pragma unroll
    for (int j = 0; j < 8; ++j)
        red[((tid >> 5) * 32 + (tid & 31)) * 8 + j] = ps[j];
    __syncthreads();
    {
        const int cb2 = tid >> 3, j2 = tid & 7;
        float s = 0.f;
#pragma unroll
        for (int r8 = 0; r8 < 8; ++r8) s += red[(r8 * 32 + cb2) * 8 + j2];
        for (int c = 0; c < nc; ++c) atomicAdd(&ssum[c * 256 + tid], s);
    }
    __syncthreads();
#pragma unroll
    for (int j = 0; j < 8; ++j)
        red[((tid >> 5) * 32 + (tid & 31)) * 8 + j] = pq[j];
    __syncthreads();
    {
        const int cb2 = tid >> 3, j2 = tid & 7;
        float s = 0.f;
#pragma unroll
        for (int r8 = 0; r8 < 8; ++r8) s += red[(r8 * 32 + cb2) * 8 + j2];
        for (int c = 0; c < nc; ++c) atomicAdd(&ssq[c * 256 + tid], s);
    }
}

// finalize stats; also emits mrs = mu*rs for fma-folded normalize
__global__ __launch_bounds__(256) void finstat_k(const float* __restrict__ ssum,
                                                 const float* __restrict__ ssq,
                                                 float* __restrict__ mu,
                                                 float* __restrict__ rs,
                                                 float* __restrict__ mrs) {
    int i = blockIdx.x * 256 + threadIdx.x;
    float m = ssum[i] * (1.0f / (float)N_);
    float v = ssq[i] * (1.0f / (float)N_) - m * m;
    float r = rsqrtf(v + EPS_);
    mu[i] = m;
    rs[i] = r;
    mrs[i] = m * r;
}

// ---------------- CSR gather-mean: vector index load + shfl broadcast ----------------
__global__ __launch_bounds__(256) void agg_k(const u16* __restrict__ H,
                                             const int* __restrict__ off,
                                             const int* __restrict__ csr,
                                             const float* __restrict__ invcnt,
                                             const float* __restrict__ mu,
                                             u16* __restrict__ Agg) {
    int wave = threadIdx.x >> 6, lane = threadIdx.x & 63;
    int pair = blockIdx.x * 4 + wave;
    int c = pair / N_, t = pair - c * N_;
    int d4 = lane * 4;
    int o0 = off[t], o1 = off[t + 1];
    int deg = o1 - o0;
    us4v o;
    if (deg > 0) {
        int myidx = (lane < deg) ? csr[o0 + lane] : 0;
        const u16* Hc = H + (size_t)c * SZ_ + d4;
        float ax = 0.f, ay = 0.f, az = 0.f, aw = 0.f;
        int lim = deg < 64 ? deg : 64;
        int i = 0;
        for (; i + 4 <= lim; i += 4) {
            int s0 = __shfl(myidx, i), s1 = __shfl(myidx, i + 1);
            int s2 = __shfl(myidx, i + 2), s3 = __shfl(myidx, i + 3);
            us4v h0 = *(const us4v*)&Hc[(size_t)s0 * 256];
            us4v h1 = *(const us4v*)&Hc[(size_t)s1 * 256];
            us4v h2 = *(const us4v*)&Hc[(size_t)s2 * 256];
            us4v h3 = *(const us4v*)&Hc[(size_t)s3 * 256];
            ax += (bf2f(h0.x) + bf2f(h1.x)) + (bf2f(h2.x) + bf2f(h3.x));
            ay += (bf2f(h0.y) + bf2f(h1.y)) + (bf2f(h2.y) + bf2f(h3.y));
            az += (bf2f(h0.z) + bf2f(h1.z)) + (bf2f(h2.z) + bf2f(h3.z));
            aw += (bf2f(h0.w) + bf2f(h1.w)) + (bf2f(h2.w) + bf2f(h3.w));
        }
        for (; i < lim; ++i) {
            int s = __shfl(myidx, i);
            us4v h = *(const us4v*)&Hc[(size_t)s * 256];
            ax += bf2f(h.x); ay += bf2f(h.y); az += bf2f(h.z); aw += bf2f(h.w);
        }
        for (int j = o0 + 64; j < o1; ++j) {     // rare: degree > 64
            int s = csr[j];
            us4v h = *(const us4v*)&Hc[(size_t)s * 256];
            ax += bf2f(h.x); ay += bf2f(h.y); az += bf2f(h.z); aw += bf2f(h.w);
        }
        float inv = invcnt[t];
        o.x = f2bf(ax * inv); o.y = f2bf(ay * inv);
        o.z = f2bf(az * inv); o.w = f2bf(aw * inv);
    } else {
        o.x = f2bf(mu[c * 256 + d4 + 0]);
        o.y = f2bf(mu[c * 256 + d4 + 1]);
        o.z = f2bf(mu[c * 256 + d4 + 2]);
        o.w = f2bf(mu[c * 256 + d4 + 3]);
    }
    *(us4v*)&Agg[((size_t)c * N_ + t) * 256 + d4] = o;
}

// ---------------- bf16 MFMA GEMM (128x128 tile): Y = [A1|A2] @ Wt^T + bias ----------------
template <int STATS>
__global__ __launch_bounds__(256) void mgemm_k(
    const u16* __restrict__ A1, size_t sA1,
    const u16* __restrict__ A2, size_t sA2,
    const u16* __restrict__ Wt, size_t sW, int K1, int Ktot,
    const float* __restrict__ bias, size_t sBias,
    u16* __restrict__ Y, size_t sY, int Mrows,
    float* __restrict__ ssum, float* __restrict__ ssq)
{
    __shared__ u16 Asm[128 * 64];
    __shared__ u16 Bsm[128 * 64];
    const int tid = threadIdx.x;
    const int lane = tid & 63, wid = tid >> 6;
    const int wr = wid >> 1, wc = wid & 1;

    // XCD-aware bijective remap of the flattened block id
    const int gx = gridDim.x, gy = gridDim.y;
    int nwg = gx * gy * gridDim.z;
    int orig = blockIdx.x + gx * (blockIdx.y + gy * blockIdx.z);
    int q = nwg >> 3, r = nwg & 7;
    int xcd = orig & 7, idx = orig >> 3;
    int swz = (xcd < r ? xcd * (q + 1) : r * (q + 1) + (xcd - r) * q) + idx;
    const int bx = swz % gx;
    const int tmp = swz / gx;
    const int by = tmp % gy;
    const int c  = tmp / gy;

    const int rowbase = by * 128, colbase = bx * 128;

    const u16* A1p = A1 + (size_t)c * sA1;
    const u16* A2p = A2 ? (A2 + (size_t)c * sA2) : nullptr;
    const u16* Wp  = Wt + (size_t)c * sW;

    f32x4 acc[4][4];
#pragma unroll
    for (int i = 0; i < 4; ++i)
#pragma unroll
        for (int j = 0; j < 4; ++j) acc[i][j] = (f32x4)0.f;

    const int lrow = lane >> 3;        // row within the wave's 8-row group
    const int lchunk = lane & 7;       // 16B chunk within the row

    for (int k0 = 0; k0 < Ktot; k0 += 64) {
        const u16* asrc; int ak;
        if (k0 < K1) { asrc = A1p; ak = k0; } else { asrc = A2p; ak = k0 - K1; }
#pragma unroll
        for (int i = 0; i < 4; ++i) {
            const int row = (wid * 4 + i) * 8 + lrow;          // 0..127
            const int srcchunk = lchunk ^ (row & 7);           // inverse of read-side XOR
            int garow = rowbase + row;
            if (garow >= Mrows) garow = Mrows - 1;             // clamp: values unused
            const u16* ga = asrc + (size_t)garow * 256 + ak + srcchunk * 8;
            __builtin_amdgcn_global_load_lds((glb_uint*)ga,
                (lds_uint*)(Asm + (wid * 4 + i) * 512), 16, 0, 0);
            const u16* gb = Wp + (size_t)(colbase + row) * Ktot + k0 + srcchunk * 8;
            __builtin_amdgcn_global_load_lds((glb_uint*)gb,
                (lds_uint*)(Bsm + (wid * 4 + i) * 512), 16, 0, 0);
        }
        __syncthreads();
#pragma unroll
        for (int ks = 0; ks < 2; ++ks) {
            s16x8 aF[4], bF[4];
            const int kk = ks * 32 + ((lane >> 4) << 3);
#pragma unroll
            for (int f = 0; f < 4; ++f) {
                int ar = wr * 64 + f * 16 + (lane & 15);
                aF[f] = *(const s16x8*)&Asm[(ar * 64 + kk) ^ ((ar & 7) << 3)];
                int br = wc * 64 + f * 16 + (lane & 15);
                bF[f] = *(const s16x8*)&Bsm[(br * 64 + kk) ^ ((br & 7) << 3)];
            }
#pragma unroll
            for (int fr = 0; fr < 4; ++fr)
#pragma unroll
                for (int fc = 0; fc < 4; ++fc)
                    acc[fr][fc] = __builtin_amdgcn_mfma_f32_16x16x32_bf16(
                        aF[fr], bF[fc], acc[fr][fc], 0, 0, 0);
        }
        __syncthreads();
    }

    float bcol[4];
#pragma unroll
    for (int fc = 0; fc < 4; ++fc)
        bcol[fc] = bias[(size_t)c * sBias + colbase + wc * 64 + fc * 16 + (lane & 15)];
    u16* Yp = Y + (size_t)c * sY;
    float ps[4] = {0, 0, 0, 0}, pq[4] = {0, 0, 0, 0};
#pragma unroll
    for (int fr = 0; fr < 4; ++fr) {
#pragma unroll
        for (int i = 0; i < 4; ++i) {
            int grow = rowbase + wr * 64 + fr * 16 + ((lane >> 4) << 2) + i;
            if (grow < Mrows) {
                size_t rb = (size_t)grow * 256 + colbase + wc * 64 + (lane & 15);
#pragma unroll
                for (int fc = 0; fc < 4; ++fc) {
                    float v = acc[fr][fc][i] + bcol[fc];
                    Yp[rb + fc * 16] = f2bf(v);
                    if (STATS) { ps[fc] += v; pq[fc] += v * v; }
                }
            }
        }
    }
    if (STATS) {
#pragma unroll
        for (int fc = 0; fc < 4; ++fc) {
            float s = ps[fc], q2 = pq[fc];
            s += __shfl_xor(s, 16); s += __shfl_xor(s, 32);
            q2 += __shfl_xor(q2, 16); q2 += __shfl_xor(q2, 32);
            if (lane < 16) {
                int col = colbase + wc * 64 + fc * 16 + lane;
                atomicAdd(&ssum[c * 256 + col], s);
                atomicAdd(&ssq[c * 256 + col], q2);
            }
        }
    }
}

// ---------------- FUSED sage: Y = gelu(chattn([Agg|H] @ Wfold^T + biasF) + H) ----------------
// 128 rows x 256 cols tile, K=512, 8 waves. Epilogue per 64-row half:
// acc -> xbf -> t=relu(x@W1+b1) per-wave 16x16 tiles (K=256 chain, no partials)
// -> y'=sig(t@W2+b2)*x -> gelu(y'+res) store + stats. LDS 48KB -> 3 blocks/CU.
template <int SMODE>   // 1: sum+sumsq, 2: sum only
__global__ __launch_bounds__(512) void msage_k(
    const u16* __restrict__ A1,                 // Agg slabs
    const u16* __restrict__ A2,                 // H slabs (also residual, in-place out)
    const u16* __restrict__ Wt, size_t sW,      // folded weights [256][512] per config
    const float* __restrict__ biasF,            // [nc][256]
    const u16* __restrict__ W1p, const float* __restrict__ b1,
    const u16* __restrict__ W2p, const float* __restrict__ b2,
    u16* __restrict__ Yout, int Mrows,
    float* __restrict__ ssum, float* __restrict__ ssq)
{
    __shared__ __align__(16) char SM[49152];
    u16*   Asm   = (u16*)SM;                    // 128x64   (K loop)
    u16*   Bsm   = (u16*)(SM + 16384);          // 256x64   (K loop)
    u16*   xbf   = (u16*)SM;                    // 64x264   (epilogue)
    u16*   tbf   = (u16*)(SM + 33792);          // 64x40    (epilogue)
    float* red   = (float*)SM;                  // stats reduce (aliases dead xbf)

    const int tid = threadIdx.x;
    const int lane = tid & 63, wid = tid >> 6;
    const int wr = wid >> 2, wc = wid & 3;
    const int cl = lane & 15, kq = lane >> 4;

    // XCD-aware bijective remap over (by, c)
    int nwg = gridDim.x * gridDim.y;
    int orig = blockIdx.x + gridDim.x * blockIdx.y;
    int q = nwg >> 3, r = nwg & 7;
    int xcd = orig & 7, idx = orig >> 3;
    int swz = (xcd < r ? xcd * (q + 1) : r * (q + 1) + (xcd - r) * q) + idx;
    const int by = swz % gridDim.x;
    const int c  = swz / gridDim.x;
    const int rowbase = by * 128;

    const u16* A1p = A1 + (size_t)c * SZ_;
    const u16* A2p = A2 + (size_t)c * SZ_;
    const u16* Wp  = Wt + (size_t)c * sW;

    f32x4 acc[4][4];
#pragma unroll
    for (int i = 0; i < 4; ++i)
#pragma unroll
        for (int j = 0; j < 4; ++j) acc[i][j] = (f32x4)0.f;

    // ---- K loop: Ktot = 512 ----
    for (int k0 = 0; k0 < 512; k0 += 64) {
        const u16* asrc = (k0 < 256) ? A1p : A2p;
        const int ak = (k0 < 256) ? k0 : (k0 - 256);
#pragma unroll
        for (int jj = 0; jj < 2; ++jj) {
            const int u = tid + jj * 512;
            const int row = u >> 3, chunk = u & 7;
            const int sc2 = chunk ^ (row & 7);
            int garow = rowbase + row;
            if (garow >= Mrows) garow = Mrows - 1;
            __builtin_amdgcn_global_load_lds(
                (glb_uint*)(asrc + (size_t)garow * 256 + ak + sc2 * 8),
                (lds_uint*)(Asm + (jj * 512 + wid * 64) * 8), 16, 0, 0);
        }
#pragma unroll
        for (int jj = 0; jj < 4; ++jj) {
            const int u = tid + jj * 512;
            const int wcol = u >> 3, chunk = u & 7;
            const int sc2 = chunk ^ (wcol & 7);
            __builtin_amdgcn_global_load_lds(
                (glb_uint*)(Wp + (size_t)wcol * 512 + k0 + sc2 * 8),
                (lds_uint*)(Bsm + (jj * 512 + wid * 64) * 8), 16, 0, 0);
        }
        __syncthreads();
#pragma unroll
        for (int ks = 0; ks < 2; ++ks) {
            s16x8 aF[4], bF[4];
            const int kk = ks * 32 + kq * 8;
#pragma unroll
            for (int f = 0; f < 4; ++f) {
                const int ar = wr * 64 + f * 16 + cl;
                aF[f] = *(const s16x8*)&Asm[(ar * 64 + kk) ^ ((ar & 7) << 3)];
                const int bc = wc * 64 + f * 16 + cl;
                bF[f] = *(const s16x8*)&Bsm[(bc * 64 + kk) ^ ((bc & 7) << 3)];
            }
#pragma unroll
            for (int fr = 0; fr < 4; ++fr)
#pragma unroll
                for (int fc = 0; fc < 4; ++fc)
                    acc[fr][fc] = __builtin_amdgcn_mfma_f32_16x16x32_bf16(
                        aF[fr], bF[fc], acc[fr][fc], 0, 0, 0);
        }
        __syncthreads();
    }

    float bcol[4];
#pragma unroll
    for (int fc = 0; fc < 4; ++fc)
        bcol[fc] = biasF[c * 256 + wc * 64 + fc * 16 + cl];

    // ---- attention epilogue: two 64-row halves ----
    for (int h = 0; h < 2; ++h) {
        __syncthreads();                 // xbf region free
        if (wr == h) {
#pragma unroll
            for (int fr = 0; fr < 4; ++fr)
#pragma unroll
                for (int i = 0; i < 4; ++i) {
                    const int rloc = fr * 16 + kq * 4 + i;
#pragma unroll
                    for (int fc = 0; fc < 4; ++fc)
                        xbf[rloc * 264 + wc * 64 + fc * 16 + cl] =
                            f2bf(acc[fr][fc][i] + bcol[fc]);
                }
        }
        __syncthreads();
        // t = relu(x@W1 + b1): wave (rb = wid&3, ch = wid>>2) does a 16x16 tile, K=256
        {
            const int rb = wid & 3, ch = wid >> 2;
            f32x4 at = (f32x4)0.f;
#pragma unroll
            for (int s = 0; s < 8; ++s) {
                s16x8 aF = *(const s16x8*)&xbf[(rb * 16 + cl) * 264 + s * 32 + kq * 8];
                s16x8 bF = *(const s16x8*)&W1p[((s * 2 + ch) * 64 + lane) * 8];
                at = __builtin_amdgcn_mfma_f32_16x16x32_bf16(aF, bF, at, 0, 0, 0);
            }
            const float b1v = b1[ch * 16 + cl];
#pragma unroll
            for (int i = 0; i < 4; ++i)
                tbf[(rb * 16 + kq * 4 + i) * 40 + ch * 16 + cl] =
                    f2bf(fmaxf(at[i] + b1v, 0.f));
        }
        __syncthreads();
        // y' = sigmoid(t@W2 + b2) * x  -> back into xbf
        {
            s16x8 aF[4];
#pragma unroll
            for (int rg = 0; rg < 4; ++rg)
                aF[rg] = *(const s16x8*)&tbf[(rg * 16 + cl) * 40 + kq * 8];
#pragma unroll
            for (int q2 = 0; q2 < 2; ++q2) {
                const int colb = (wid * 2 + q2) * 16;
                s16x8 bF = *(const s16x8*)&W2p[((wid * 2 + q2) * 64 + lane) * 8];
                const float b2v = b2[colb + cl];
#pragma unroll
                for (int rg = 0; rg < 4; ++rg) {
                    f32x4 a2 = __builtin_amdgcn_mfma_f32_16x16x32_bf16(
                        aF[rg], bF, (f32x4)0.f, 0, 0, 0);
#pragma unroll
                    for (int i = 0; i < 4; ++i) {
                        const int ea = (rg * 16 + kq * 4 + i) * 264 + colb + cl;
                        float s = a2[i] + b2v;
                        float sig = 1.f / (1.f + __expf(-s));
                        xbf[ea] = f2bf(sig * bf2f(xbf[ea]));
                    }
                }
            }
        }
        __syncthreads();
        // gelu(y' + res), coalesced store + stats
        float ps[8] = {0, 0, 0, 0, 0, 0, 0, 0}, pq[8] = {0, 0, 0, 0, 0, 0, 0, 0};
#pragma unroll
        for (int it = 0; it < 4; ++it) {
            const int e = tid + it * 512;
            const int row = e >> 5, cb = (e & 31) * 8;
            const int grow = rowbase + h * 64 + row;
            if (grow < Mrows) {
                us8v xv = *(const us8v*)&xbf[row * 264 + cb];
                us8v rv = *(const us8v*)&Yout[((size_t)c * N_ + grow) * 256 + cb];
                us8v ov;
#pragma unroll
                for (int j = 0; j < 8; ++j) {
                    float v = gelu_f(bf2f(xv[j]) + bf2f(rv[j]));
                    ov[j] = f2bf(v);
                    ps[j] += v;
                    if (SMODE == 1) pq[j] += v * v;
                }
                *(us8v*)&Yout[((size_t)c * N_ + grow) * 256 + cb] = ov;
            }
        }
        __syncthreads();                 // xbf dead -> red may alias it
#pragma unroll
        for (int j = 0; j < 8; ++j)
            red[((tid >> 5) * 32 + (tid & 31)) * 8 + j] = ps[j];
        __syncthreads();
        if (tid < 256) {
            const int cb2 = tid >> 3, j2 = tid & 7;
            float s = 0.f;
#pragma unroll
            for (int r16 = 0; r16 < 16; ++r16) s += red[(r16 * 32 + cb2) * 8 + j2];
            atomicAdd(&ssum[c * 256 + cb2 * 8 + j2], s);
        }
        if (SMODE == 1) {
            __syncthreads();
#pragma unroll
            for (int j = 0; j < 8; ++j)
                red[((tid >> 5) * 32 + (tid & 31)) * 8 + j] = pq[j];
            __syncthreads();
            if (tid < 256) {
                const int cb2 = tid >> 3, j2 = tid & 7;
                float s = 0.f;
#pragma unroll
                for (int r16 = 0; r16 < 16; ++r16) s += red[(r16 * 32 + cb2) * 8 + j2];
                atomicAdd(&ssq[c * 256 + cb2 * 8 + j2], s);
            }
        }
    }
}

// ---------------- fp32 tiled GEMM (one-time base GEMM) ----------------
__global__ __launch_bounds__(256) void gemm_k(const float* __restrict__ A1, int lda1,
                                              const float* __restrict__ W1, int K1,
                                              const float* __restrict__ bias,
                                              float* __restrict__ Y, int Mrows) {
    __shared__ float As[16][132];
    __shared__ float Bs[16][132];
    float acc[8][8];
#pragma unroll
    for (int i = 0; i < 8; ++i)
#pragma unroll
        for (int j = 0; j < 8; ++j) acc[i][j] = 0.f;

    const int tid = threadIdx.x;
    const int tr = tid >> 4, tc = tid & 15;
    const int rowbase = blockIdx.y * 128, colbase = blockIdx.x * 128;

    for (int k0 = 0; k0 < K1; k0 += 16) {
#pragma unroll
        for (int ii = 0; ii < 2; ++ii) {
            int i = tid + ii * 256;
            int rr = i >> 2, qq = i & 3;
            int grow = rowbase + rr;
            float4 vv = make_float4(0.f, 0.f, 0.f, 0.f);
            if (grow < Mrows) vv = *(const float4*)&A1[(size_t)grow * lda1 + k0 + qq * 4];
            As[qq * 4 + 0][rr] = vv.x;
            As[qq * 4 + 1][rr] = vv.y;
            As[qq * 4 + 2][rr] = vv.z;
            As[qq * 4 + 3][rr] = vv.w;
        }
#pragma unroll
        for (int ii = 0; ii < 2; ++ii) {
            int i = tid + ii * 256;
            int rr = i >> 5, qq = i & 31;
            float4 vv = *(const float4*)&W1[(size_t)(k0 + rr) * 256 + colbase + qq * 4];
            *(float4*)&Bs[rr][qq * 4] = vv;
        }
        __syncthreads();
#pragma unroll
        for (int kk = 0; kk < 16; ++kk) {
            float a[8], b[8];
            *(float4*)&a[0] = *(const float4*)&As[kk][tr * 4];
            *(float4*)&a[4] = *(const float4*)&As[kk][64 + tr * 4];
            *(float4*)&b[0] = *(const float4*)&Bs[kk][tc * 4];
            *(float4*)&b[4] = *(const float4*)&Bs[kk][64 + tc * 4];
#pragma unroll
            for (int i = 0; i < 8; ++i)
#pragma unroll
                for (int j = 0; j < 8; ++j)
                    acc[i][j] = fmaf(a[i], b[j], acc[i][j]);
        }
        __syncthreads();
    }

    float4 blo = *(const float4*)&bias[colbase + tc * 4];
    float4 bhi = *(const float4*)&bias[colbase + 64 + tc * 4];
    float bb[8] = {blo.x, blo.y, blo.z, blo.w, bhi.x, bhi.y, bhi.z, bhi.w};
#pragma unroll
    for (int i = 0; i < 8; ++i)
#pragma unroll
        for (int j = 0; j < 8; ++j) acc[i][j] += bb[j];

#pragma unroll
    for (int i = 0; i < 8; ++i) {
        int lrow = (i < 4) ? (tr * 4 + i) : (64 + tr * 4 + (i - 4));
        int grow = rowbase + lrow;
        if (grow < Mrows) {
            *(float4*)&Y[(size_t)grow * 256 + colbase + tc * 4] =
                make_float4(acc[i][0], acc[i][1], acc[i][2], acc[i][3]);
            *(float4*)&Y[(size_t)grow * 256 + colbase + 64 + tc * 4] =
                make_float4(acc[i][4], acc[i][5], acc[i][6], acc[i][7]);
        }
    }
}

// ---------------- per-row epilogue with MFMA channel-attention (512 thr, 8 waves) ----------------
template <int NORM, int RES, int SMODE>
__global__ __launch_bounds__(512) void apply_k(const u16* __restrict__ Yin,
                                               u16* __restrict__ Hout,
                                               const u16* __restrict__ Hsc,
                                               const u16* __restrict__ W1p,
                                               const float* __restrict__ b1,
                                               const u16* __restrict__ W2p,
                                               const float* __restrict__ b2,
                                               const float* __restrict__ rs,
                                               const float* __restrict__ mrs,
                                               float* __restrict__ ssum,
                                               float* __restrict__ ssq) {
    __shared__ u16 vbf[16 * 264];
    __shared__ u16 scs[(RES ? 16 : 1) * 264];
    __shared__ float tpart[8 * 528];
    __shared__ u16 tbf[16 * 40];
    __shared__ float srs[NORM ? 256 : 1], smrs[NORM ? 256 : 1];
    const int c = blockIdx.z, n0 = blockIdx.x * 16, tid = threadIdx.x;
    const int lane = tid & 63, wid = tid >> 6;   // wid 0..7
    const size_t rowbase = ((size_t)c * N_ + n0) * 256;

    if (NORM && tid < 256) { srs[tid] = rs[c * 256 + tid]; smrs[tid] = mrs[c * 256 + tid]; }
    {
        const int row = tid >> 5, cb = (tid & 31) * 8;
        us8v x = *(const us8v*)&Yin[rowbase + row * 256 + cb];
        us8v r;
        if (RES) r = *(const us8v*)&Hsc[rowbase + row * 256 + cb];
        if (NORM) {
            __syncthreads();
            us8v y;
#pragma unroll
            for (int j = 0; j < 8; ++j)
                y[j] = f2bf(fmaf(bf2f(x[j]), srs[cb + j], -smrs[cb + j]));
            *(us8v*)&vbf[row * 264 + cb] = y;
        } else {
            *(us8v*)&vbf[row * 264 + cb] = x;
        }
        if (RES) *(us8v*)&scs[row * 264 + cb] = r;
    }
    __syncthreads();

    {
        const int arow = lane & 15, kq = lane >> 4;
        const int k = wid * 32 + kq * 8;
        s16x8 aF = *(const s16x8*)&vbf[arow * 264 + k];
        s16x8 bF0 = *(const s16x8*)&W1p[((wid * 2 + 0) * 64 + lane) * 8];
        s16x8 bF1 = *(const s16x8*)&W1p[((wid * 2 + 1) * 64 + lane) * 8];
        f32x4 at0 = __builtin_amdgcn_mfma_f32_16x16x32_bf16(aF, bF0, (f32x4)0.f, 0, 0, 0);
        f32x4 at1 = __builtin_amdgcn_mfma_f32_16x16x32_bf16(aF, bF1, (f32x4)0.f, 0, 0, 0);
#pragma unroll
        for (int i = 0; i < 4; ++i) {
            tpart[wid * 528 + (kq * 4 + i) * 33 + (lane & 15)] = at0[i];
            tpart[wid * 528 + (kq * 4 + i) * 33 + 16 + (lane & 15)] = at1[i];
        }
    }
    __syncthreads();

    {
        const int nr = tid >> 5, col = tid & 31;
        float s = b1[col];
#pragma unroll
        for (int w8 = 0; w8 < 8; ++w8)
            s += tpart[w8 * 528 + nr * 33 + col];
        tbf[nr * 40 + col] = f2bf(fmaxf(s, 0.f));
    }
    __syncthreads();

    {
        const int cl = lane & 15, kq = lane >> 4;
        s16x8 aF = *(const s16x8*)&tbf[cl * 40 + kq * 8];
        float ps[2] = {0, 0}, pq[2] = {0, 0};
#pragma unroll
        for (int q = 0; q < 2; ++q) {
            const int colb = (wid * 2 + q) * 16;
            s16x8 bF = *(const s16x8*)&W2p[((wid * 2 + q) * 64 + lane) * 8];
            f32x4 acc = __builtin_amdgcn_mfma_f32_16x16x32_bf16(aF, bF, (f32x4)0.f, 0, 0, 0);
            const float b2v = b2[colb + cl];
#pragma unroll
            for (int i = 0; i < 4; ++i) {
                const int row = kq * 4 + i;
                const int ea = row * 264 + colb + cl;
                float s = acc[i] + b2v;
                float sig = 1.0f / (1.0f + __expf(-s));
                float val = sig * bf2f(vbf[ea]);
                if (RES) val += bf2f(scs[ea]);
                val = gelu_f(val);
                vbf[ea] = f2bf(val);
                if (SMODE) { ps[q] += val; if (SMODE == 1) pq[q] += val * val; }
            }
        }
        if (SMODE) {
#pragma unroll
            for (int q = 0; q < 2; ++q) {
                float s = ps[q];
                s += __shfl_xor(s, 16); s += __shfl_xor(s, 32);
                if (SMODE == 1) {
                    float q2 = pq[q];
                    q2 += __shfl_xor(q2, 16); q2 += __shfl_xor(q2, 32);
                    if (lane < 16) atomicAdd(&ssq[c * 256 + (wid * 2 + q) * 16 + lane], q2);
                }
                if (lane < 16) atomicAdd(&ssum[c * 256 + (wid * 2 + q) * 16 + lane], s);
            }
        }
    }
    __syncthreads();

    {
        const int row = tid >> 5, cb = (tid & 31) * 8;
        us8v h = *(const us8v*)&vbf[row * 264 + cb];
        *(us8v*)&Hout[rowbase + row * 256 + cb] = h;
    }
}

// ---------------- classifier ----------------
__global__ __launch_bounds__(256) void cls_k(const float* __restrict__ pooled_sum,
                                             const float* __restrict__ clsW,
                                             const float* __restrict__ clsb,
                                             float* __restrict__ out) {
    __shared__ float red[256];
    int c = blockIdx.x, d = threadIdx.x;
    red[d] = pooled_sum[c * 256 + d] * (1.0f / (float)N_) * clsW[d];
    __syncthreads();
    for (int s = 128; s > 0; s >>= 1) {
        if (d < s) red[d] += red[d + s];
        __syncthreads();
    }
    if (d == 0) out[c] = red[0] + clsb[0];
}

// ---------------- host launch ----------------
static inline size_t alup(size_t x) { return (x + 255) & ~(size_t)255; }

extern "C" void kernel_launch(void* const* d_in, const int* in_sizes, int n_in,
                              void* d_out, int out_size, void* d_ws, size_t ws_size,
                              hipStream_t stream) {
    const int*   xcfg   = (const int*)d_in[0];
    const float* xfeat  = (const float*)d_in[1];
    const int*   xlay   = (const int*)d_in[2];
    const int*   xop    = (const int*)d_in[3];
    const int*   ei     = (const int*)d_in[4];
    const int*   ncid   = (const int*)d_in[5];
    const float* embO   = (const float*)d_in[6];
    const float* embL   = (const float*)d_in[7];
    const float* lin1W  = (const float*)d_in[8];
    const float* lin1b  = (const float*)d_in[9];
    const float* ca1W1  = (const float*)d_in[10];
    const float* ca1b1  = (const float*)d_in[11];
    const float* ca1W2  = (const float*)d_in[12];
    const float* ca1b2  = (const float*)d_in[13];
    const float* lin2W  = (const float*)d_in[14];
    const float* lin2b  = (const float*)d_in[15];
    const float* ca2W1  = (const float*)d_in[16];
    const float* ca2b1  = (const float*)d_in[17];
    const float* ca2W2  = (const float*)d_in[18];
    const float* ca2b2  = (const float*)d_in[19];
    const float* sageWl = (const float*)d_in[20];
    const float* sagebl = (const float*)d_in[21];
    const float* sageWr = (const float*)d_in[22];
    const float* scaW1  = (const float*)d_in[23];
    const float* scab1  = (const float*)d_in[24];
    const float* scaW2  = (const float*)d_in[25];
    const float* scab2  = (const float*)d_in[26];
    const float* clsW   = (const float*)d_in[27];
    const float* clsb   = (const float*)d_in[28];
    float* out = (float*)d_out;

    // ---- workspace carve-up ----
    char* w = (char*)d_ws;
    size_t o = 0;
    auto take = [&](size_t bytes) { char* p = w + o; o = alup(o + bytes); return p; };
    float* base    = (float*)take((size_t)N_ * 256 * 4);
    float* feat162 = (float*)take((size_t)N_ * 176 * 4);
    float* W162    = (float*)take((size_t)176 * 256 * 4);
    float* T       = (float*)take((size_t)18 * 8 * 256 * 4);
    float* csum    = (float*)take((size_t)256 * 4);
    float* stats   = (float*)take((size_t)6 * 8192 * 4);
    float* MU      = (float*)take((size_t)5 * 4096 * 4);
    float* RS      = (float*)take((size_t)5 * 4096 * 4);
    float* MRS     = (float*)take((size_t)5 * 4096 * 4);
    float* invcnt  = (float*)take((size_t)N_ * 4);
    int*   cnt     = (int*)take((size_t)N_ * 4);
    int*   off     = (int*)take((size_t)(N_ + 1) * 4);
    int*   cursor  = (int*)take((size_t)N_ * 4);
    int*   csr     = (int*)take((size_t)E_ * 4);
    int*   cfgpos  = (int*)take((size_t)N_ * 4);
    u16*   Wt2     = (u16*)take((size_t)256 * 256 * 2);
    u16*   Wfold   = (u16*)take((size_t)C_ * 256 * 512 * 2);   // 4 MB
    float* biasF   = (float*)take((size_t)C_ * 256 * 4);
    u16*   CAW1    = (u16*)take((size_t)5 * 8192 * 2);         // packed frag order
    u16*   CAW2    = (u16*)take((size_t)5 * 8192 * 2);

    const size_t slab = (size_t)SZ_ * 2;                       // bf16: 5.12 MB
    size_t avail = (ws_size > o) ? (ws_size - o) : 0;
    int Cc = (int)(avail / (3 * slab + 768));
    if (Cc > C_) Cc = C_;
    if (Cc < 1) Cc = 1;
    u16* BufH = (u16*)take((size_t)Cc * slab);
    u16* BufY = (u16*)take((size_t)Cc * slab);
    u16* BufA = (u16*)take((size_t)Cc * slab);
    (void)in_sizes; (void)n_in; (void)out_size;

    auto S = [&](int s) { return stats + (size_t)s * 8192; };
    auto Q = [&](int s) { return stats + (size_t)s * 8192 + 4096; };

    hipMemsetAsync(stats, 0, 6 * 8192 * 4, stream);
    hipMemsetAsync(cnt, 0, N_ * 4, stream);
    hipMemsetAsync(cfgpos, 0xFF, N_ * 4, stream);

    // shared prep
    tbl_k<<<144, 256, 0, stream>>>(embL, lin1W, T);
    csum_k<<<1, 256, 0, stream>>>(T, csum);
    feat_k<<<N_, 192, 0, stream>>>(xfeat, xlay, xop, embL, embO, feat162);
    wpack_k<<<176, 256, 0, stream>>>(lin1W, W162);
    wt2_k<<<256, 256, 0, stream>>>(lin2W, Wt2);
    packw1_k<<<32, 256, 0, stream>>>(ca1W1, CAW1 + 0 * 8192);
    packw1_k<<<32, 256, 0, stream>>>(ca2W1, CAW1 + 1 * 8192);
    packw1_k<<<32, 256, 0, stream>>>(scaW1 + 0 * 8192, CAW1 + 2 * 8192);
    packw1_k<<<32, 256, 0, stream>>>(scaW1 + 1 * 8192, CAW1 + 3 * 8192);
    packw1_k<<<32, 256, 0, stream>>>(scaW1 + 2 * 8192, CAW1 + 4 * 8192);
    packw2_k<<<32, 256, 0, stream>>>(ca1W2, CAW2 + 0 * 8192);
    packw2_k<<<32, 256, 0, stream>>>(ca2W2, CAW2 + 1 * 8192);
    packw2_k<<<32, 256, 0, stream>>>(scaW2 + 0 * 8192, CAW2 + 2 * 8192);
    packw2_k<<<32, 256, 0, stream>>>(scaW2 + 1 * 8192, CAW2 + 3 * 8192);
    packw2_k<<<32, 256, 0, stream>>>(scaW2 + 2 * 8192, CAW2 + 4 * 8192);
    cfgpos_k<<<(NC_ + 255) / 256, 256, 0, stream>>>(ncid, cfgpos);
    hist_k<<<(E_ + 255) / 256, 256, 0, stream>>>(ei, cnt);
    scan_k<<<1, 1024, 0, stream>>>(cnt, off, cursor, invcnt);
    fill_k<<<(E_ + 255) / 256, 256, 0, stream>>>(ei, cursor, csr);

    // base = feat162 @ W162 + lin1_b (fp32, one-time)
    gemm_k<<<dim3(2, 79, 1), 256, 0, stream>>>(feat162, 176, W162, 176, lin1b, base, N_);

    // ---- per-config-chunk pipeline ----
    for (int c0 = 0; c0 < C_; c0 += Cc) {
        const int nc = (C_ - c0 < Cc) ? (C_ - c0) : Cc;
        const int co = c0 * 256;

        lin1_cfg_k<<<dim3(NC_ / 16, 1, nc), 256, 0, stream>>>(
            base, T, ncid, xcfg + (size_t)c0 * NC_ * 18, BufH, S(0) + co, Q(0) + co);
        lin1_unc_k<<<625, 256, 0, stream>>>(
            base, csum, cfgpos, nc, BufH, S(0) + co, Q(0) + co);
        finstat_k<<<nc, 256, 0, stream>>>(S(0) + co, Q(0) + co,
                                          MU + co, RS + co, MRS + co);

        apply_k<1, 0, 0><<<dim3(625, 1, nc), 512, 0, stream>>>(
            BufH, BufH, nullptr, CAW1 + 0 * 8192, ca1b1, CAW2 + 0 * 8192, ca1b2,
            RS + co, MRS + co, nullptr, nullptr);

        mgemm_k<1><<<dim3(2, 79, nc), 256, 0, stream>>>(
            BufH, SZ_, nullptr, 0, Wt2, 0, 256, 256,
            lin2b, 0, BufY, SZ_, N_, S(1) + co, Q(1) + co);
        finstat_k<<<nc, 256, 0, stream>>>(S(1) + co, Q(1) + co,
                                          MU + 4096 + co, RS + 4096 + co, MRS + 4096 + co);

        apply_k<1, 0, 1><<<dim3(625, 1, nc), 512, 0, stream>>>(
            BufY, BufY, nullptr, CAW1 + 1 * 8192, ca2b1, CAW2 + 1 * 8192, ca2b2,
            RS + 4096 + co, MRS + 4096 + co, S(2) + co, Q(2) + co);

        for (int i = 0; i < 3; ++i) {
            const int set = 2 + i;
            finstat_k<<<nc, 256, 0, stream>>>(S(set) + co, Q(set) + co,
                                              MU + set * 4096 + co, RS + set * 4096 + co,
                                              MRS + set * 4096 + co);
            foldw_k<<<dim3(256, nc), 256, 0, stream>>>(
                sageWl + (size_t)i * 65536, sageWr + (size_t)i * 65536, sagebl + i * 256,
                MU + set * 4096 + co, RS + set * 4096 + co,
                Wfold + (size_t)c0 * 256 * 512, biasF + co);
            agg_k<<<nc * 2500, 256, 0, stream>>>(BufY, off, csr, invcnt,
                                                 MU + set * 4096 + co, BufA);
            if (i < 2) {
                msage_k<1><<<dim3(79, nc), 512, 0, stream>>>(
                    BufA, BufY, Wfold + (size_t)c0 * 256 * 512, 256 * 512, biasF + co,
                    CAW1 + (2 + i) * 8192, scab1 + i * 32,
                    CAW2 + (2 + i) * 8192, scab2 + i * 256,
                    BufY, N_, S(3 + i) + co, Q(3 + i) + co);
            } else {
                msage_k<2><<<dim3(79, nc), 512, 0, stream>>>(
                    BufA, BufY, Wfold + (size_t)c0 * 256 * 512, 256 * 512, biasF + co,
                    CAW1 + (2 + i) * 8192, scab1 + i * 32,
                    CAW2 + (2 + i) * 8192, scab2 + i * 256,
                    BufY, N_, S(5) + co, nullptr);
            }
        }
    }

    cls_k<<<16, 256, 0, stream>>>(S(5), clsW, clsb, out);
}